// Round 8
// baseline (2202.136 us; speedup 1.0000x reference)
//
#include <hip/hip_runtime.h>
#include <hip/hip_bf16.h>
#include <math.h>

// FNO2d: B=8, S=192, pad->201x201, C=64, modes 12x12, 4 layers.
// Pixel-major activations [b][p][c]; MFMA conv GEMMs, MFMA Gram, LDS-staged head.

#define NN 201
#define SS 192
#define NPIX 40401
#define QPIX 36864
#define BB 8
#define GNB2 20          // gram slabs per (z,b)
#define XWPL 1234944     // 1608*12*64 (re/im plane stride in floats)
#define PI_F 3.14159265358979323846f

typedef __hip_bfloat16 bf16;
typedef __attribute__((ext_vector_type(8))) short s8v;
typedef __attribute__((ext_vector_type(4))) float f32x4;

__device__ __forceinline__ float gelu_f(float x){
  return 0.5f*x*(1.0f+erff(x*0.7071067811865476f));
}
__device__ __forceinline__ float b2f(bf16 v){ return __bfloat162float(v); }
__device__ __forceinline__ bf16  f2b(float v){ return __float2bfloat16(v); }
__device__ __forceinline__ unsigned short f2bu(float x){
  bf16 h = __float2bfloat16(x);
  unsigned short u; __builtin_memcpy(&u,&h,2); return u;
}
__device__ __forceinline__ float bu2f(unsigned short u){
  unsigned int x = ((unsigned int)u)<<16; float f; __builtin_memcpy(&f,&x,4); return f;
}

// tab[k][n]: cos/sin(2*pi*k*n/201), k=0..12, exact mod-201 reduction
__global__ void k_tab(float* __restrict__ tab){
  int t = blockIdx.x*blockDim.x+threadIdx.x;
  if(t>=13*NN) return;
  int k=t/NN, n=t-k*NN;
  int m=(k*n)%NN;
  float ang = (2.0f*PI_F/201.0f)*(float)m;
  tab[2*t]   = cosf(ang);
  tab[2*t+1] = sinf(ang);
}

// Separable encoder tables. grid (192,2), 64 thr.
__global__ void k_pretab(const float* __restrict__ Wp, const float* __restrict__ bp,
                         float* __restrict__ Ux, float* __restrict__ Uy){
  int i = blockIdx.x;
  int ax = blockIdx.y;
  int c = threadIdx.x;
  float g = (float)i*(1.0f/191.0f);
  float acc;
  if(ax==0) acc = bp[c] + g*Wp[64+c];
  else      acc = g*Wp[128+c];
  int cosBase = (ax==0)? 3 : 4;
  int sinBase = (ax==0)? 23 : 24;
  #pragma unroll
  for(int l=0;l<10;l++){
    float f = PI_F*(float)(1<<l);
    float sv,cv;
    sincosf(g*f,&sv,&cv);
    acc += cv*Wp[(cosBase+2*l)*64+c] + sv*Wp[(sinBase+2*l)*64+c];
  }
  float* U = (ax==0)? Ux : Uy;
  U[i*64+c] = acc;
}

// Pack 16 64x64 weight matrices into bf16 MFMA-fragment order.
__global__ void k_wpack(const float* __restrict__ m1w, const float* __restrict__ m2w,
                        const float* __restrict__ ww,  const float* __restrict__ q1w,
                        unsigned short* __restrict__ WPK){
  int bx = blockIdx.x, tid = threadIdx.x;
  const float* src;
  if(bx<12){
    int l=bx/3, sel=bx-l*3;
    src = (sel==0)? m1w+(size_t)l*4096 : (sel==1)? m2w+(size_t)l*4096 : ww+(size_t)l*4096;
  } else {
    src = q1w + (size_t)(bx-12)*4096;
  }
  unsigned short* dst = WPK + (size_t)bx*4096;
  #pragma unroll
  for(int t=0;t<16;t++){
    int d = tid*16+t;
    int frag=d>>9, lane=(d>>3)&63, j=d&7;
    int mt=frag>>1, kh=frag&1, m_=lane&15, g=lane>>4;
    dst[d] = f2bu(src[(size_t)(16*mt+m_)*64 + 32*kh + 8*g + j]);
  }
}

// Transpose spectral weights for layer into WT[m][comp][io].
__global__ void __launch_bounds__(256) k_wtrans(const float* __restrict__ w1,
        const float* __restrict__ w2, float* __restrict__ WT){
  __shared__ float tile[64][65];
  int io0 = blockIdx.x*64;
  int c0  = blockIdx.y*64;
  int z   = blockIdx.z;
  const float* src = (z==0)? w1 : w2;
  int tid = threadIdx.x;
  #pragma unroll
  for(int it=0;it<16;it++){
    int e = tid + 256*it;
    int r = e>>6, c = e&63;
    if(c0+c<288) tile[r][c] = src[(size_t)(io0+r)*288 + c0 + c];
  }
  __syncthreads();
  #pragma unroll
  for(int it=0;it<16;it++){
    int e = tid + 256*it;
    int rp = e>>6, cp = e&63;
    int col = c0 + rp;
    if(col<288){
      int ky = col/24, rm = col - ky*24;
      int kx = rm>>1, comp = rm&1;
      int m = z*144 + ky*12 + kx;
      WT[(size_t)m*8192 + comp*4096 + io0 + cp] = tile[cp][rp];
    }
  }
}

// encoder: A[b][p][c] = x*Wp0[c] + Ux[hh][c] + Uy[ww][c]; zeros in pad.
__global__ void k_encoder(const float* __restrict__ x, const float* __restrict__ Wp,
                          const float* __restrict__ Ux, const float* __restrict__ Uy,
                          bf16* __restrict__ A){
  int tid=threadIdx.x;
  int p = blockIdx.x*256+tid;
  if(p>=NPIX) return;
  int b = blockIdx.y;
  uint4* dst = (uint4*)(A + ((size_t)b*NPIX + p)*64);
  int hh=p/NN, ww=p-hh*NN;
  if(hh>=SS || ww>=SS){
    uint4 z = {0,0,0,0};
    #pragma unroll
    for(int i=0;i<8;i++) dst[i]=z;
    return;
  }
  float xv = x[((size_t)b*SS+hh)*SS+ww];
  const float4* ux = (const float4*)(Ux + hh*64);
  const float4* uy = (const float4*)(Uy + ww*64);
  const float4* w0 = (const float4*)Wp;
  #pragma unroll
  for(int i=0;i<8;i++){
    float4 a0 = ux[2*i],   a1 = ux[2*i+1];
    float4 b0 = uy[2*i],   b1 = uy[2*i+1];
    float4 c0 = w0[2*i],   c1 = w0[2*i+1];
    float v0=xv*c0.x+a0.x+b0.x, v1=xv*c0.y+a0.y+b0.y;
    float v2=xv*c0.z+a0.z+b0.z, v3=xv*c0.w+a0.w+b0.w;
    float v4=xv*c1.x+a1.x+b1.x, v5=xv*c1.y+a1.y+b1.y;
    float v6=xv*c1.z+a1.z+b1.z, v7=xv*c1.w+a1.w+b1.w;
    uint4 v;
    v.x = (unsigned)f2bu(v0) | ((unsigned)f2bu(v1)<<16);
    v.y = (unsigned)f2bu(v2) | ((unsigned)f2bu(v3)<<16);
    v.z = (unsigned)f2bu(v4) | ((unsigned)f2bu(v5)<<16);
    v.w = (unsigned)f2bu(v6) | ((unsigned)f2bu(v7)<<16);
    dst[i]=v;
  }
}

// DFT along W. Wave per row R=b*201+h, lane=c. XW[re/im][R][kx][c].
__global__ void __launch_bounds__(256) k_dftw(const bf16* __restrict__ A,
        const float* __restrict__ tab, float* __restrict__ XW){
  __shared__ float2 st[2412];
  int tid=threadIdx.x;
  for(int i=tid;i<2412;i+=256) st[i]=((const float2*)tab)[i];
  __syncthreads();
  int R = blockIdx.x*4 + (tid>>6);
  int l = tid&63;
  const bf16* base = A + ((size_t)R*NN)*64 + l;
  float ar0=0.f;
  float ar[11], ai[11];
  #pragma unroll
  for(int k=0;k<11;k++){ ar[k]=0.f; ai[k]=0.f; }
  for(int w=0;w<NN;w++){
    float a = b2f(base[(size_t)w*64]);
    ar0 += a;
    #pragma unroll
    for(int k=0;k<11;k++){
      float2 cs = st[(k+1)*NN+w];
      ar[k] += a*cs.x;
      ai[k] += a*cs.y;
    }
  }
  float* xre = XW + ((size_t)R*12)*64 + l;
  float* xim = xre + XWPL;
  xre[0]=ar0; xim[0]=0.f;
  #pragma unroll
  for(int k=0;k<11;k++){
    xre[(size_t)(k+1)*64] = ar[k];
    xim[(size_t)(k+1)*64] = -ai[k];
  }
}

// DFT along H, LDS-staged: grid (12, 8, 4); z = (jhalf<<1)|chalf.
// Stages XW[b][*][kx][chalf] plane once, computes 12 j-modes from LDS.
__global__ void __launch_bounds__(256) k_dfth(const float* __restrict__ XW,
        const float* __restrict__ tab, float* __restrict__ XF){
  __shared__ float sre[201*32];
  __shared__ float sim[201*32];
  __shared__ float2 tw[13*NN];
  int kx=blockIdx.x, b=blockIdx.y;
  int z=blockIdx.z; int jh=z>>1, ch=z&1;
  int tid=threadIdx.x;
  for(int i=tid;i<13*NN;i+=256) tw[i]=((const float2*)tab)[i];
  for(int i=tid;i<201*32;i+=256){
    int h=i>>5, c=ch*32+(i&31);
    size_t idx=(((size_t)b*NN+h)*12+kx)*64+c;
    sre[i]=XW[idx];
    sim[i]=XW[idx+XWPL];
  }
  __syncthreads();
  for(int o=tid;o<384;o+=256){
    int jj=o>>5, cl=o&31;
    int j=jh*12+jj;
    int k2=(j<12)?j:24-j;
    float sgn=(j<12)?-1.f:1.f;
    float re=0.f,im=0.f;
    const float* pr=sre+cl;
    const float* pi=sim+cl;
    const float2* tk=tw+k2*NN;
    for(int h=0;h<NN;h++){
      float a=pr[h*32], bb=pi[h*32];
      float2 cs=tk[h];
      float cc=cs.x, s2=sgn*cs.y;
      re+=a*cc-bb*s2; im+=a*s2+bb*cc;
    }
    int m=j*12+kx;
    int c=ch*32+cl;
    XF[(size_t)m*1024+(b*64+c)*2]  =re;
    XF[(size_t)m*1024+(b*64+c)*2+1]=im;
  }
}

// per-mode 64x64 complex mix; weights from transposed WT
__global__ void __launch_bounds__(512) k_modemix(const float* __restrict__ XF,
     const float* __restrict__ WT, float* __restrict__ XO){
  __shared__ float sx[1024];
  __shared__ float swr[4096], swi[4096];
  int m=blockIdx.x;
  int tid=threadIdx.x;
  sx[tid]     = XF[(size_t)m*1024+tid];
  sx[tid+512] = XF[(size_t)m*1024+tid+512];
  const float* wr = WT + (size_t)m*8192;
  const float* wi = wr + 4096;
  for(int io=tid;io<4096;io+=512){
    swr[io]=wr[io];
    swi[io]=wi[io];
  }
  __syncthreads();
  int b=tid>>6, o=tid&63;
  const float* xb = sx + b*128;
  float re=0.0f,im=0.0f;
  #pragma unroll 8
  for(int i=0;i<64;i++){
    float a=xb[2*i], b2=xb[2*i+1];
    float c=swr[i*64+o], d=swi[i*64+o];
    re += a*c - b2*d;
    im += a*d + b2*c;
  }
  XO[2*((size_t)m*512+tid)]  =re;
  XO[2*((size_t)m*512+tid)+1]=im;
}

// Merged inverse: per row R, idfth into LDS, then C2R along W. C[b][p][o] bf16.
__global__ void __launch_bounds__(256) k_ispec(const float* __restrict__ XO,
        const float* __restrict__ tab, bf16* __restrict__ C){
  __shared__ float2 st[2412];
  __shared__ float2 yl[12][64];
  __shared__ float2 cs13[13];
  int R=blockIdx.x;
  int b=R/NN, h=R-b*NN;
  int tid=threadIdx.x;
  for(int i=tid;i<2412;i+=256) st[i]=((const float2*)tab)[i];
  if(tid<13) cs13[tid]=((const float2*)tab)[tid*NN+h];
  __syncthreads();
  #pragma unroll
  for(int it=0;it<3;it++){
    int item = tid + 256*it;
    int kx = item>>6, o = item&63;
    float re=0.f,im=0.f;
    #pragma unroll
    for(int j=0;j<24;j++){
      int k2=(j<12)?j:24-j;
      float sgn=(j<12)?1.0f:-1.0f;
      float2 xo = *(const float2*)(XO + 2*(((size_t)(j*12+kx)*512) + b*64 + o));
      float2 cs = cs13[k2];
      float cc=cs.x, s2=sgn*cs.y;
      re += xo.x*cc - xo.y*s2;
      im += xo.x*s2 + xo.y*cc;
    }
    yl[kx][o] = float2{re,im};
  }
  __syncthreads();
  int o = tid&63, wq = tid>>6;
  float yr[12], yi[12];
  #pragma unroll
  for(int k=0;k<12;k++){
    float2 v = yl[k][o];
    yr[k]=v.x; yi[k]=v.y;
  }
  int w0 = wq*51;
  int w1 = w0+51; if(w1>NN) w1=NN;
  bf16* cp = C + ((size_t)R*NN)*64 + o;
  for(int w=w0;w<w1;w++){
    float acc = yr[0];
    #pragma unroll
    for(int k=1;k<12;k++){
      float2 cs = st[k*NN+w];
      acc += 2.0f*(yr[k]*cs.x - yi[k]*cs.y);
    }
    cp[(size_t)w*64] = f2b(acc*(1.0f/40401.0f));
  }
}

// MFMA Gram partials. grid (nblk, BB, nsrc); block covers 2048 px (16 subtiles of 128).
// Stages transposed [c][px] tiles; one b128 read serves both A- and B-fragments.
__global__ void __launch_bounds__(256) k_gramp(const bf16* __restrict__ s0,
        const bf16* __restrict__ s1, float* __restrict__ Gpart,
        float* __restrict__ Spart, int HR, int WR){
  __shared__ unsigned short xt[64][132];
  __shared__ float ssum[256*8];
  int b = blockIdx.y, blk = blockIdx.x, z = blockIdx.z;
  const bf16* X = (z==0)? s0 : s1;
  int zb = z*BB + b;
  int npix = HR*WR;
  int tid=threadIdx.x, wid=tid>>6, l=tid&63;
  int m_=l&15, g=l>>4;
  f32x4 acc[4];
  #pragma unroll
  for(int mt=0;mt<4;mt++) acc[mt]=f32x4{0.f,0.f,0.f,0.f};
  float ps[8]={0,0,0,0,0,0,0,0};
  for(int sub=0;sub<16;sub++){
    int px0 = blk*2048 + sub*128;
    __syncthreads();
    #pragma unroll
    for(int it=0;it<4;it++){
      int chunk = tid + it*256;
      int px = chunk>>3, c0 = (chunk&7)*8;
      int rp = px0+px;
      s8v xv = {0,0,0,0,0,0,0,0};
      if(rp<npix){
        int gp;
        if(WR==NN) gp = rp;
        else { int hh=rp/WR, ww=rp-hh*WR; gp = hh*NN+ww; }
        xv = *(const s8v*)(X + ((size_t)b*NPIX + gp)*64 + c0);
      }
      #pragma unroll
      for(int j=0;j<8;j++){
        xt[c0+j][px] = (unsigned short)xv[j];
        ps[j] += bu2f((unsigned short)xv[j]);
      }
    }
    __syncthreads();
    #pragma unroll
    for(int kc=0;kc<4;kc++){
      s8v fr[4];
      #pragma unroll
      for(int t=0;t<4;t++)
        fr[t] = *(const s8v*)&xt[16*t+m_][kc*32+8*g];
      #pragma unroll
      for(int mt=0;mt<4;mt++)
        acc[mt]=__builtin_amdgcn_mfma_f32_16x16x32_bf16(fr[mt],fr[wid],acc[mt],0,0,0);
    }
  }
  // G write: tile (mt, wid): G[16mt + 4g + j][16*wid + m_]
  float* gp_ = Gpart + ((size_t)zb*GNB2 + blk)*4096;
  #pragma unroll
  for(int mt=0;mt<4;mt++){
    #pragma unroll
    for(int j=0;j<4;j++)
      gp_[(size_t)(16*mt + 4*g + j)*64 + 16*wid + m_] = acc[mt][j];
  }
  // column sums
  #pragma unroll
  for(int j=0;j<8;j++) ssum[tid*8+j]=ps[j];
  __syncthreads();
  if(tid<64){
    int r=tid>>3, j=tid&7;
    float s=0.f;
    for(int k=0;k<32;k++) s += ssum[(r+8*k)*8+j];
    Spart[((size_t)zb*GNB2 + blk)*64 + tid] = s;
  }
}

// Merged gram-reduce + GN stats (grid 16: zb<8 -> m1 stats, zb>=8 -> ww stats).
__global__ void __launch_bounds__(256) k_statsA(const float* __restrict__ Gpart,
        const float* __restrict__ Spart,
        const float* __restrict__ m1wl, const float* __restrict__ m1bl,
        const float* __restrict__ wwl,  const float* __restrict__ wbl,
        float* __restrict__ TSTAT, float* __restrict__ USTAT, int nblk){
  __shared__ float Gs[4096];
  __shared__ float Ss[64];
  __shared__ float rs[256], rq[256];
  int zb=blockIdx.x, t=threadIdx.x;
  float a[16];
  #pragma unroll
  for(int e=0;e<16;e++) a[e]=0.f;
  for(int k=0;k<nblk;k++){
    const float* g = Gpart + ((size_t)zb*GNB2 + k)*4096 + t*16;
    #pragma unroll
    for(int e=0;e<16;e++) a[e]+=g[e];
  }
  #pragma unroll
  for(int e=0;e<16;e++) Gs[t*16+e]=a[e];
  if(t<64){
    float s=0.f;
    for(int k=0;k<nblk;k++) s += Spart[((size_t)zb*GNB2 + k)*64 + t];
    Ss[t]=s;
  }
  __syncthreads();
  const float* W    = (zb<8)? m1wl : wwl;
  const float* bias = (zb<8)? m1bl : wbl;
  float* stat       = (zb<8)? TSTAT : USTAT;
  int b = (zb<8)? zb : zb-8;
  int o = t&63, sl = t>>6;
  float w[64];
  #pragma unroll
  for(int j2=0;j2<64;j2++) w[j2]=bu2f(f2bu(W[(size_t)o*64+j2]));
  const float* Gr = Gs + (size_t)(sl*16)*64;
  float quad=0.f;
  #pragma unroll
  for(int r=0;r<16;r++){
    const float* gr = Gr + r*64;
    float tt=0.f;
    #pragma unroll
    for(int j2=0;j2<64;j2++) tt += gr[j2]*w[j2];
    quad += w[sl*16+r]*tt;
  }
  float dot=0.f;
  #pragma unroll
  for(int j2=0;j2<64;j2++) dot += w[j2]*Ss[j2];
  float bo = bias[o];
  float Nf = (float)NPIX;
  float sm = (sl==0)? (dot + Nf*bo) : 0.f;
  float sq = quad + ((sl==0)? (2.f*bo*dot + Nf*bo*bo) : 0.f);
  rs[t]=sm; rq[t]=sq;
  __syncthreads();
  if(t<64){
    float s2 = rs[t]+rs[t+64]+rs[t+128]+rs[t+192];
    float q2 = rq[t]+rq[t+64]+rq[t+128]+rq[t+192];
    for(int off=16;off>0;off>>=1){
      s2 += __shfl_down(s2,off,32);
      q2 += __shfl_down(q2,off,32);
    }
    if((t&31)==0){
      int g=t>>5;
      float invN = 1.f/(Nf*32.f);
      float mean = s2*invN;
      float var = q2*invN - mean*mean;
      stat[b*4+g*2]   = mean;
      stat[b*4+g*2+1] = rsqrtf(fmaxf(var,0.f)+1e-5f);
    }
  }
}

// Merged gram-reduce + head stats (grid 8).
__global__ void __launch_bounds__(256) k_statsQ(const float* __restrict__ Gpart,
        const float* __restrict__ Spart,
        const float* __restrict__ W, const float* __restrict__ bias,
        float* __restrict__ stat, int nblk){
  __shared__ float Gs[4096];
  __shared__ float Ss[64];
  __shared__ float red[8];
  int b=blockIdx.x, t=threadIdx.x;
  float a[16];
  #pragma unroll
  for(int e=0;e<16;e++) a[e]=0.f;
  for(int k=0;k<nblk;k++){
    const float* g = Gpart + ((size_t)b*GNB2 + k)*4096 + t*16;
    #pragma unroll
    for(int e=0;e<16;e++) a[e]+=g[e];
  }
  #pragma unroll
  for(int e=0;e<16;e++) Gs[t*16+e]=a[e];
  if(t<64){
    float s=0.f;
    for(int k=0;k<nblk;k++) s += Spart[((size_t)b*GNB2 + k)*64 + t];
    Ss[t]=s;
  }
  __syncthreads();
  float w[64];
  #pragma unroll
  for(int j2=0;j2<64;j2++) w[j2]=bu2f(f2bu(W[(size_t)t*64+j2]));
  float quad=0.f;
  #pragma unroll
  for(int i=0;i<64;i++){
    const float* gr = Gs + i*64;
    float tt=0.f;
    #pragma unroll
    for(int j2=0;j2<64;j2++) tt += gr[j2]*w[j2];
    quad += w[i]*tt;
  }
  float dot=0.f;
  #pragma unroll
  for(int j2=0;j2<64;j2++) dot += w[j2]*Ss[j2];
  float bo=bias[t];
  float Nf=(float)QPIX;
  float sm = dot + Nf*bo;
  float sq = quad + 2.f*bo*dot + Nf*bo*bo;
  for(int off=32;off>0;off>>=1){
    sm += __shfl_down(sm,off,64);
    sq += __shfl_down(sq,off,64);
  }
  int wid=t>>6;
  if((t&63)==0){ red[wid*2]=sm; red[wid*2+1]=sq; }
  __syncthreads();
  if(t<2){
    float smt = red[t*4+0]+red[t*4+2];
    float sqt = red[t*4+1]+red[t*4+3];
    float invN = 1.f/(Nf*128.f);
    float mean = smt*invN;
    float var = sqt*invN - mean*mean;
    stat[b*4+t*2]   = mean;
    stat[b*4+t*2+1] = rsqrtf(fmaxf(var,0.f)+1e-5f);
  }
}

// MFMA fused layer with packed weights.
__global__ void __launch_bounds__(256) k_fuse(const bf16* __restrict__ Cb,
    bf16* __restrict__ A,
    const unsigned short* __restrict__ wp1, const float* __restrict__ m1b,
    const float* __restrict__ mg,  const float* __restrict__ mbt,
    const unsigned short* __restrict__ wp2, const float* __restrict__ m2b,
    const unsigned short* __restrict__ wpw, const float* __restrict__ wbk,
    const float* __restrict__ ng,  const float* __restrict__ nb,
    const float* __restrict__ tstat, const float* __restrict__ ustat, int last){
  __shared__ unsigned short vlds[4][64][72];
  int tid=threadIdx.x;
  int wid=tid>>6, l=tid&63;
  int m_=l&15, g=l>>4;
  int b=blockIdx.y;
  int p0=blockIdx.x*256 + wid*64;
  const bf16* cbb = Cb + (size_t)b*NPIX*64;
  const bf16* ab  = A  + (size_t)b*NPIX*64;

  s8v af[4][2];
  f32x4 acc[4][4];

  #pragma unroll
  for(int mt=0;mt<4;mt++){
    #pragma unroll
    for(int kh=0;kh<2;kh++)
      af[mt][kh]=*(const s8v*)(wp1 + (mt*2+kh)*512 + l*8);
    float4 b4 = *(const float4*)(m1b + 16*mt + 4*g);
    #pragma unroll
    for(int nt=0;nt<4;nt++) acc[mt][nt]=f32x4{b4.x,b4.y,b4.z,b4.w};
  }
  #pragma unroll
  for(int nt=0;nt<4;nt++){
    int p = p0 + 16*nt + m_;
    int pc = p<NPIX? p : NPIX-1;
    const s8v* xb = (const s8v*)(cbb + (size_t)pc*64);
    s8v b0 = xb[g], b1 = xb[4+g];
    #pragma unroll
    for(int mt=0;mt<4;mt++){
      acc[mt][nt]=__builtin_amdgcn_mfma_f32_16x16x32_bf16(af[mt][0],b0,acc[mt][nt],0,0,0);
      acc[mt][nt]=__builtin_amdgcn_mfma_f32_16x16x32_bf16(af[mt][1],b1,acc[mt][nt],0,0,0);
    }
  }
  {
    float tm0=tstat[b*4],tr0=tstat[b*4+1],tm1=tstat[b*4+2],tr1=tstat[b*4+3];
    #pragma unroll
    for(int mt=0;mt<4;mt++){
      float4 g4 = *(const float4*)(mg  + 16*mt + 4*g);
      float4 t4 = *(const float4*)(mbt + 16*mt + 4*g);
      float mn = (mt<2)? tm0 : tm1;
      float rs = (mt<2)? tr0 : tr1;
      #pragma unroll
      for(int nt=0;nt<4;nt++){
        int pl = 16*nt + m_;
        f32x4 t = acc[mt][nt];
        float v0 = gelu_f((t[0]-mn)*rs*g4.x + t4.x);
        float v1 = gelu_f((t[1]-mn)*rs*g4.y + t4.y);
        float v2 = gelu_f((t[2]-mn)*rs*g4.z + t4.z);
        float v3 = gelu_f((t[3]-mn)*rs*g4.w + t4.w);
        uint2 pk;
        pk.x = (unsigned)f2bu(v0) | ((unsigned)f2bu(v1)<<16);
        pk.y = (unsigned)f2bu(v2) | ((unsigned)f2bu(v3)<<16);
        *(uint2*)&vlds[wid][pl][16*mt+4*g] = pk;
      }
    }
  }
  __syncthreads();
  #pragma unroll
  for(int mt=0;mt<4;mt++){
    #pragma unroll
    for(int kh=0;kh<2;kh++)
      af[mt][kh]=*(const s8v*)(wpw + (mt*2+kh)*512 + l*8);
    float4 b4 = *(const float4*)(wbk + 16*mt + 4*g);
    #pragma unroll
    for(int nt=0;nt<4;nt++) acc[mt][nt]=f32x4{b4.x,b4.y,b4.z,b4.w};
  }
  #pragma unroll
  for(int nt=0;nt<4;nt++){
    int p = p0 + 16*nt + m_;
    int pc = p<NPIX? p : NPIX-1;
    const s8v* xb = (const s8v*)(ab + (size_t)pc*64);
    s8v b0 = xb[g], b1 = xb[4+g];
    #pragma unroll
    for(int mt=0;mt<4;mt++){
      acc[mt][nt]=__builtin_amdgcn_mfma_f32_16x16x32_bf16(af[mt][0],b0,acc[mt][nt],0,0,0);
      acc[mt][nt]=__builtin_amdgcn_mfma_f32_16x16x32_bf16(af[mt][1],b1,acc[mt][nt],0,0,0);
    }
  }
  {
    float um0=ustat[b*4],ur0=ustat[b*4+1],um1=ustat[b*4+2],ur1=ustat[b*4+3];
    #pragma unroll
    for(int mt=0;mt<4;mt++){
      float4 n4 = *(const float4*)(ng  + 16*mt + 4*g);
      float4 nb4= *(const float4*)(nb  + 16*mt + 4*g);
      float4 m24= *(const float4*)(m2b + 16*mt + 4*g);
      float mn = (mt<2)? um0 : um1;
      float rs = (mt<2)? ur0 : ur1;
      #pragma unroll
      for(int nt=0;nt<4;nt++){
        f32x4 u = acc[mt][nt];
        u[0] = m24.x + (u[0]-mn)*rs*n4.x + nb4.x;
        u[1] = m24.y + (u[1]-mn)*rs*n4.y + nb4.y;
        u[2] = m24.z + (u[2]-mn)*rs*n4.z + nb4.z;
        u[3] = m24.w + (u[3]-mn)*rs*n4.w + nb4.w;
        acc[mt][nt]=u;
      }
    }
  }
  #pragma unroll
  for(int mt=0;mt<4;mt++){
    #pragma unroll
    for(int kh=0;kh<2;kh++)
      af[mt][kh]=*(const s8v*)(wp2 + (mt*2+kh)*512 + l*8);
  }
  #pragma unroll
  for(int nt=0;nt<4;nt++){
    int pl = 16*nt + m_;
    const s8v* vp = (const s8v*)&vlds[wid][pl][0];
    s8v b0 = vp[g], b1 = vp[4+g];
    #pragma unroll
    for(int mt=0;mt<4;mt++){
      acc[mt][nt]=__builtin_amdgcn_mfma_f32_16x16x32_bf16(af[mt][0],b0,acc[mt][nt],0,0,0);
      acc[mt][nt]=__builtin_amdgcn_mfma_f32_16x16x32_bf16(af[mt][1],b1,acc[mt][nt],0,0,0);
    }
  }
  #pragma unroll
  for(int nt=0;nt<4;nt++){
    int p = p0 + 16*nt + m_;
    if(p>=NPIX) continue;
    bf16* dp = A + ((size_t)b*NPIX + p)*64;
    #pragma unroll
    for(int mt=0;mt<4;mt++){
      f32x4 h = acc[mt][nt];
      float h0=h[0],h1=h[1],h2=h[2],h3=h[3];
      if(!last){ h0=gelu_f(h0); h1=gelu_f(h1); h2=gelu_f(h2); h3=gelu_f(h3); }
      uint2 pk;
      pk.x = (unsigned)f2bu(h0) | ((unsigned)f2bu(h1)<<16);
      pk.y = (unsigned)f2bu(h2) | ((unsigned)f2bu(h3)<<16);
      *(uint2*)(dp + 16*mt + 4*g) = pk;
    }
  }
}

// Head: block stages 256 px of A-crop into LDS once; wave = one oc chunk; LDS reduce.
__global__ void __launch_bounds__(256) k_qout(const bf16* __restrict__ A,
    const unsigned short* __restrict__ qpack, const float* __restrict__ q1b,
    const float* __restrict__ qg, const float* __restrict__ qbt,
    const float* __restrict__ q2w, const float* __restrict__ q2b,
    const float* __restrict__ qstat, float* __restrict__ out){
  __shared__ unsigned short xq[256][72];
  __shared__ float part[4][256];
  int tid=threadIdx.x;
  int wid=tid>>6, l=tid&63;
  int m_=l&15, g=l>>4;
  int b=blockIdx.y;
  int px0=blockIdx.x*256;
  // stage A crop tile
  {
    int p = px0 + tid;
    int hh=p/SS, ww2=p-hh*SS;
    const uint4* src=(const uint4*)(A + (((size_t)b*NPIX) + (size_t)hh*NN + ww2)*64);
    uint4* drow=(uint4*)&xq[tid][0];
    #pragma unroll
    for(int i=0;i<8;i++) drow[i]=src[i];
  }
  __syncthreads();
  int oc=wid;
  const unsigned short* wp = qpack + (size_t)oc*4096;
  s8v af[4][2];
  f32x4 bi4[4];
  float4 g4[4], t4[4], w4[4];
  #pragma unroll
  for(int mt=0;mt<4;mt++){
    #pragma unroll
    for(int kh=0;kh<2;kh++)
      af[mt][kh]=*(const s8v*)(wp + (mt*2+kh)*512 + l*8);
    float4 b4=*(const float4*)(q1b + 64*oc + 16*mt + 4*g);
    bi4[mt]=f32x4{b4.x,b4.y,b4.z,b4.w};
    g4[mt]=*(const float4*)(qg  + 64*oc + 16*mt + 4*g);
    t4[mt]=*(const float4*)(qbt + 64*oc + 16*mt + 4*g);
    w4[mt]=*(const float4*)(q2w + 64*oc + 16*mt + 4*g);
  }
  float m0=qstat[b*4],r0=qstat[b*4+1],m1=qstat[b*4+2],r1=qstat[b*4+3];
  float mn=(oc<2)?m0:m1, rs=(oc<2)?r0:r1;
  #pragma unroll
  for(int nt=0;nt<16;nt++){
    const s8v* vp = (const s8v*)&xq[16*nt+m_][0];
    s8v b0=vp[g], b1=vp[4+g];
    f32x4 acc[4];
    #pragma unroll
    for(int mt=0;mt<4;mt++) acc[mt]=bi4[mt];
    #pragma unroll
    for(int mt=0;mt<4;mt++){
      acc[mt]=__builtin_amdgcn_mfma_f32_16x16x32_bf16(af[mt][0],b0,acc[mt],0,0,0);
      acc[mt]=__builtin_amdgcn_mfma_f32_16x16x32_bf16(af[mt][1],b1,acc[mt],0,0,0);
    }
    float pp=0.f;
    #pragma unroll
    for(int mt=0;mt<4;mt++){
      f32x4 t=acc[mt];
      pp += gelu_f((t[0]-mn)*rs*g4[mt].x + t4[mt].x)*w4[mt].x;
      pp += gelu_f((t[1]-mn)*rs*g4[mt].y + t4[mt].y)*w4[mt].y;
      pp += gelu_f((t[2]-mn)*rs*g4[mt].z + t4[mt].z)*w4[mt].z;
      pp += gelu_f((t[3]-mn)*rs*g4[mt].w + t4[mt].w)*w4[mt].w;
    }
    pp += __shfl_xor(pp,16,64);
    pp += __shfl_xor(pp,32,64);
    if(g==0) part[wid][16*nt+m_]=pp;
  }
  __syncthreads();
  out[(size_t)b*QPIX + px0 + tid] =
      q2b[0] + part[0][tid]+part[1][tid]+part[2][tid]+part[3][tid];
}

extern "C" void kernel_launch(void* const* d_in, const int* in_sizes, int n_in,
                              void* d_out, int out_size, void* d_ws, size_t ws_size,
                              hipStream_t stream){
  const float* x   = (const float*)d_in[0];
  const float* Wp  = (const float*)d_in[1];
  const float* bp  = (const float*)d_in[2];
  const float* sw1 = (const float*)d_in[3];
  const float* sw2 = (const float*)d_in[4];
  const float* m1w = (const float*)d_in[5];
  const float* m1b = (const float*)d_in[6];
  const float* mg  = (const float*)d_in[7];
  const float* mbt = (const float*)d_in[8];
  const float* m2w = (const float*)d_in[9];
  const float* m2b = (const float*)d_in[10];
  const float* ww  = (const float*)d_in[11];
  const float* wb  = (const float*)d_in[12];
  const float* ng  = (const float*)d_in[13];
  const float* nb  = (const float*)d_in[14];
  const float* q1w = (const float*)d_in[15];
  const float* q1b = (const float*)d_in[16];
  const float* qg  = (const float*)d_in[17];
  const float* qbt = (const float*)d_in[18];
  const float* q2w = (const float*)d_in[19];
  const float* q2b = (const float*)d_in[20];
  float* out = (float*)d_out;

  char* w8 = (char*)d_ws;
  const size_t ACT_B = (size_t)64*BB*NPIX*sizeof(bf16);   // 41,370,624
  bf16*  A    = (bf16*)(w8);
  bf16*  Cb   = (bf16*)(w8 + ACT_B);
  float* SPEC = (float*)(w8 + 2*ACT_B);                    // XW / WT / Gpart overlays
  float* XF   = (float*)(w8 + 2*ACT_B + 9879552);
  float* XO   = (float*)(w8 + 2*ACT_B + 9879552 + 1179648);
  float* TB   = (float*)(w8 + 2*ACT_B + 9879552 + 2*1179648);
  char*  g8   = w8 + 2*ACT_B + 9879552 + 2*1179648 + 20992;
  float* TSTAT= (float*)g8;
  float* USTAT= TSTAT + 32;
  float* QSTAT= USTAT + 32;
  float* UxT  = QSTAT + 32;                  // 192*64
  float* UyT  = UxT + 12288;                 // 192*64
  unsigned short* WPK = (unsigned short*)(UyT + 12288);   // 16*4096 bf16
  float* Gpart = SPEC;                       // 16*20*4096 = 5.24MB
  float* Spart = Gpart + (size_t)16*GNB2*4096;
  float* WT = SPEC;                          // 288*8192 floats = 9.44MB
  size_t needed = (size_t)(2*ACT_B) + 9879552 + 2*1179648 + 20992
                + 3*32*4 + 2*12288*4 + 16*4096*2;
  if(ws_size < needed) return;

  k_tab<<<11,256,0,stream>>>(TB);
  k_pretab<<<dim3(192,2),64,0,stream>>>(Wp, bp, UxT, UyT);
  k_wpack<<<16,256,0,stream>>>(m1w, m2w, ww, q1w, WPK);
  k_encoder<<<dim3(158,BB),256,0,stream>>>(x, Wp, UxT, UyT, A);

  for(int l=0;l<4;l++){
    const float* sw1l = sw1 + (size_t)l*1179648;
    const float* sw2l = sw2 + (size_t)l*1179648;
    k_dftw<<<402,256,0,stream>>>(A, TB, SPEC);
    k_dfth<<<dim3(12,BB,4),256,0,stream>>>(SPEC, TB, XF);
    k_wtrans<<<dim3(64,5,2),256,0,stream>>>(sw1l, sw2l, WT);
    k_modemix<<<288,512,0,stream>>>(XF, WT, XO);
    k_ispec<<<1608,256,0,stream>>>(XO, TB, Cb);
    k_gramp<<<dim3(GNB2,BB,2),256,0,stream>>>(Cb, A, Gpart, Spart, NN, NN);
    k_statsA<<<16,256,0,stream>>>(Gpart, Spart,
          m1w + (size_t)l*4096, m1b + l*64, ww + (size_t)l*4096, wb + l*64,
          TSTAT, USTAT, GNB2);
    k_fuse<<<dim3(158,BB),256,0,stream>>>(Cb, A,
          WPK + (size_t)(l*3+0)*4096, m1b + l*64, mg + l*64, mbt + l*64,
          WPK + (size_t)(l*3+1)*4096, m2b + l*64,
          WPK + (size_t)(l*3+2)*4096, wb  + l*64, ng + l*64, nb + l*64,
          TSTAT, USTAT, (l==3)?1:0);
  }

  k_gramp<<<dim3(18,BB,1),256,0,stream>>>(A, A, Gpart, Spart, SS, SS);
  k_statsQ<<<BB,256,0,stream>>>(Gpart, Spart, q1w, q1b, QSTAT, 18);
  k_qout<<<dim3(144,BB),256,0,stream>>>(A, WPK + (size_t)12*4096, q1b,
          qg, qbt, q2w, q2b, QSTAT, out);
}

// Round 9
// 1558.085 us; speedup vs baseline: 1.4134x; 1.4134x over previous
//
#include <hip/hip_runtime.h>
#include <hip/hip_bf16.h>
#include <math.h>

// FNO2d: B=8, S=192, pad->201x201, C=64, modes 12x12, 4 layers.
// Pixel-major activations [b][p][c]; MFMA conv GEMMs; float register-tile Gram.

#define NN 201
#define SS 192
#define NPIX 40401
#define QPIX 36864
#define BB 8
#define GNB 40           // gram slabs per (z,b), 1024 px each
#define XWPL 1234944     // 1608*12*64 (re/im plane stride in floats)
#define PI_F 3.14159265358979323846f

typedef __hip_bfloat16 bf16;
typedef __attribute__((ext_vector_type(8))) short s8v;
typedef __attribute__((ext_vector_type(4))) float f32x4;

__device__ __forceinline__ float gelu_f(float x){
  return 0.5f*x*(1.0f+erff(x*0.7071067811865476f));
}
__device__ __forceinline__ float b2f(bf16 v){ return __bfloat162float(v); }
__device__ __forceinline__ bf16  f2b(float v){ return __float2bfloat16(v); }
__device__ __forceinline__ unsigned short f2bu(float x){
  bf16 h = __float2bfloat16(x);
  unsigned short u; __builtin_memcpy(&u,&h,2); return u;
}
__device__ __forceinline__ float bu2f(unsigned short u){
  unsigned int x = ((unsigned int)u)<<16; float f; __builtin_memcpy(&f,&x,4); return f;
}

// tab[k][n]: cos/sin(2*pi*k*n/201), k=0..12, exact mod-201 reduction
__global__ void k_tab(float* __restrict__ tab){
  int t = blockIdx.x*blockDim.x+threadIdx.x;
  if(t>=13*NN) return;
  int k=t/NN, n=t-k*NN;
  int m=(k*n)%NN;
  float ang = (2.0f*PI_F/201.0f)*(float)m;
  tab[2*t]   = cosf(ang);
  tab[2*t+1] = sinf(ang);
}

// Separable encoder tables. grid (192,2), 64 thr.
__global__ void k_pretab(const float* __restrict__ Wp, const float* __restrict__ bp,
                         float* __restrict__ Ux, float* __restrict__ Uy){
  int i = blockIdx.x;
  int ax = blockIdx.y;
  int c = threadIdx.x;
  float g = (float)i*(1.0f/191.0f);
  float acc;
  if(ax==0) acc = bp[c] + g*Wp[64+c];
  else      acc = g*Wp[128+c];
  int cosBase = (ax==0)? 3 : 4;
  int sinBase = (ax==0)? 23 : 24;
  #pragma unroll
  for(int l=0;l<10;l++){
    float f = PI_F*(float)(1<<l);
    float sv,cv;
    sincosf(g*f,&sv,&cv);
    acc += cv*Wp[(cosBase+2*l)*64+c] + sv*Wp[(sinBase+2*l)*64+c];
  }
  float* U = (ax==0)? Ux : Uy;
  U[i*64+c] = acc;
}

// Pack 16 64x64 weight matrices into bf16 MFMA-fragment order.
__global__ void k_wpack(const float* __restrict__ m1w, const float* __restrict__ m2w,
                        const float* __restrict__ ww,  const float* __restrict__ q1w,
                        unsigned short* __restrict__ WPK){
  int bx = blockIdx.x, tid = threadIdx.x;
  const float* src;
  if(bx<12){
    int l=bx/3, sel=bx-l*3;
    src = (sel==0)? m1w+(size_t)l*4096 : (sel==1)? m2w+(size_t)l*4096 : ww+(size_t)l*4096;
  } else {
    src = q1w + (size_t)(bx-12)*4096;
  }
  unsigned short* dst = WPK + (size_t)bx*4096;
  #pragma unroll
  for(int t=0;t<16;t++){
    int d = tid*16+t;
    int frag=d>>9, lane=(d>>3)&63, j=d&7;
    int mt=frag>>1, kh=frag&1, m_=lane&15, g=lane>>4;
    dst[d] = f2bu(src[(size_t)(16*mt+m_)*64 + 32*kh + 8*g + j]);
  }
}

// Transpose spectral weights for layer into WT[m][comp][io].
__global__ void __launch_bounds__(256) k_wtrans(const float* __restrict__ w1,
        const float* __restrict__ w2, float* __restrict__ WT){
  __shared__ float tile[64][65];
  int io0 = blockIdx.x*64;
  int c0  = blockIdx.y*64;
  int z   = blockIdx.z;
  const float* src = (z==0)? w1 : w2;
  int tid = threadIdx.x;
  #pragma unroll
  for(int it=0;it<16;it++){
    int e = tid + 256*it;
    int r = e>>6, c = e&63;
    if(c0+c<288) tile[r][c] = src[(size_t)(io0+r)*288 + c0 + c];
  }
  __syncthreads();
  #pragma unroll
  for(int it=0;it<16;it++){
    int e = tid + 256*it;
    int rp = e>>6, cp = e&63;
    int col = c0 + rp;
    if(col<288){
      int ky = col/24, rm = col - ky*24;
      int kx = rm>>1, comp = rm&1;
      int m = z*144 + ky*12 + kx;
      WT[(size_t)m*8192 + comp*4096 + io0 + cp] = tile[cp][rp];
    }
  }
}

// encoder: A[b][p][c] = x*Wp0[c] + Ux[hh][c] + Uy[ww][c]; zeros in pad.
__global__ void k_encoder(const float* __restrict__ x, const float* __restrict__ Wp,
                          const float* __restrict__ Ux, const float* __restrict__ Uy,
                          bf16* __restrict__ A){
  int tid=threadIdx.x;
  int p = blockIdx.x*256+tid;
  if(p>=NPIX) return;
  int b = blockIdx.y;
  uint4* dst = (uint4*)(A + ((size_t)b*NPIX + p)*64);
  int hh=p/NN, ww=p-hh*NN;
  if(hh>=SS || ww>=SS){
    uint4 z = {0,0,0,0};
    #pragma unroll
    for(int i=0;i<8;i++) dst[i]=z;
    return;
  }
  float xv = x[((size_t)b*SS+hh)*SS+ww];
  const float4* ux = (const float4*)(Ux + hh*64);
  const float4* uy = (const float4*)(Uy + ww*64);
  const float4* w0 = (const float4*)Wp;
  #pragma unroll
  for(int i=0;i<8;i++){
    float4 a0 = ux[2*i],   a1 = ux[2*i+1];
    float4 b0 = uy[2*i],   b1 = uy[2*i+1];
    float4 c0 = w0[2*i],   c1 = w0[2*i+1];
    float v0=xv*c0.x+a0.x+b0.x, v1=xv*c0.y+a0.y+b0.y;
    float v2=xv*c0.z+a0.z+b0.z, v3=xv*c0.w+a0.w+b0.w;
    float v4=xv*c1.x+a1.x+b1.x, v5=xv*c1.y+a1.y+b1.y;
    float v6=xv*c1.z+a1.z+b1.z, v7=xv*c1.w+a1.w+b1.w;
    uint4 v;
    v.x = (unsigned)f2bu(v0) | ((unsigned)f2bu(v1)<<16);
    v.y = (unsigned)f2bu(v2) | ((unsigned)f2bu(v3)<<16);
    v.z = (unsigned)f2bu(v4) | ((unsigned)f2bu(v5)<<16);
    v.w = (unsigned)f2bu(v6) | ((unsigned)f2bu(v7)<<16);
    dst[i]=v;
  }
}

// DFT along W. Wave per row R=b*201+h, lane=c. XW[re/im][R][kx][c].
__global__ void __launch_bounds__(256) k_dftw(const bf16* __restrict__ A,
        const float* __restrict__ tab, float* __restrict__ XW){
  __shared__ float2 st[2412];
  int tid=threadIdx.x;
  for(int i=tid;i<2412;i+=256) st[i]=((const float2*)tab)[i];
  __syncthreads();
  int R = blockIdx.x*4 + (tid>>6);
  int l = tid&63;
  const bf16* base = A + ((size_t)R*NN)*64 + l;
  float ar0=0.f;
  float ar[11], ai[11];
  #pragma unroll
  for(int k=0;k<11;k++){ ar[k]=0.f; ai[k]=0.f; }
  for(int w=0;w<NN;w++){
    float a = b2f(base[(size_t)w*64]);
    ar0 += a;
    #pragma unroll
    for(int k=0;k<11;k++){
      float2 cs = st[(k+1)*NN+w];
      ar[k] += a*cs.x;
      ai[k] += a*cs.y;
    }
  }
  float* xre = XW + ((size_t)R*12)*64 + l;
  float* xim = xre + XWPL;
  xre[0]=ar0; xim[0]=0.f;
  #pragma unroll
  for(int k=0;k<11;k++){
    xre[(size_t)(k+1)*64] = ar[k];
    xim[(size_t)(k+1)*64] = -ai[k];
  }
}

// DFT along H, LDS-staged: grid (12, 8, 4); z = (jhalf<<1)|chalf.
__global__ void __launch_bounds__(256) k_dfth(const float* __restrict__ XW,
        const float* __restrict__ tab, float* __restrict__ XF){
  __shared__ float sre[201*32];
  __shared__ float sim[201*32];
  __shared__ float2 tw[13*NN];
  int kx=blockIdx.x, b=blockIdx.y;
  int z=blockIdx.z; int jh=z>>1, ch=z&1;
  int tid=threadIdx.x;
  for(int i=tid;i<13*NN;i+=256) tw[i]=((const float2*)tab)[i];
  for(int i=tid;i<201*32;i+=256){
    int h=i>>5, c=ch*32+(i&31);
    size_t idx=(((size_t)b*NN+h)*12+kx)*64+c;
    sre[i]=XW[idx];
    sim[i]=XW[idx+XWPL];
  }
  __syncthreads();
  for(int o=tid;o<384;o+=256){
    int jj=o>>5, cl=o&31;
    int j=jh*12+jj;
    int k2=(j<12)?j:24-j;
    float sgn=(j<12)?-1.f:1.f;
    float re=0.f,im=0.f;
    const float* pr=sre+cl;
    const float* pi=sim+cl;
    const float2* tk=tw+k2*NN;
    for(int h=0;h<NN;h++){
      float a=pr[h*32], bb=pi[h*32];
      float2 cs=tk[h];
      float cc=cs.x, s2=sgn*cs.y;
      re+=a*cc-bb*s2; im+=a*s2+bb*cc;
    }
    int m=j*12+kx;
    int c=ch*32+cl;
    XF[(size_t)m*1024+(b*64+c)*2]  =re;
    XF[(size_t)m*1024+(b*64+c)*2+1]=im;
  }
}

// per-mode 64x64 complex mix; weights from transposed WT
__global__ void __launch_bounds__(512) k_modemix(const float* __restrict__ XF,
     const float* __restrict__ WT, float* __restrict__ XO){
  __shared__ float sx[1024];
  __shared__ float swr[4096], swi[4096];
  int m=blockIdx.x;
  int tid=threadIdx.x;
  sx[tid]     = XF[(size_t)m*1024+tid];
  sx[tid+512] = XF[(size_t)m*1024+tid+512];
  const float* wr = WT + (size_t)m*8192;
  const float* wi = wr + 4096;
  for(int io=tid;io<4096;io+=512){
    swr[io]=wr[io];
    swi[io]=wi[io];
  }
  __syncthreads();
  int b=tid>>6, o=tid&63;
  const float* xb = sx + b*128;
  float re=0.0f,im=0.0f;
  #pragma unroll 8
  for(int i=0;i<64;i++){
    float a=xb[2*i], b2=xb[2*i+1];
    float c=swr[i*64+o], d=swi[i*64+o];
    re += a*c - b2*d;
    im += a*d + b2*c;
  }
  XO[2*((size_t)m*512+tid)]  =re;
  XO[2*((size_t)m*512+tid)+1]=im;
}

// Merged inverse: per row R, idfth into LDS, then C2R along W. C[b][p][o] bf16.
__global__ void __launch_bounds__(256) k_ispec(const float* __restrict__ XO,
        const float* __restrict__ tab, bf16* __restrict__ C){
  __shared__ float2 st[2412];
  __shared__ float2 yl[12][64];
  __shared__ float2 cs13[13];
  int R=blockIdx.x;
  int b=R/NN, h=R-b*NN;
  int tid=threadIdx.x;
  for(int i=tid;i<2412;i+=256) st[i]=((const float2*)tab)[i];
  if(tid<13) cs13[tid]=((const float2*)tab)[tid*NN+h];
  __syncthreads();
  #pragma unroll
  for(int it=0;it<3;it++){
    int item = tid + 256*it;
    int kx = item>>6, o = item&63;
    float re=0.f,im=0.f;
    #pragma unroll
    for(int j=0;j<24;j++){
      int k2=(j<12)?j:24-j;
      float sgn=(j<12)?1.0f:-1.0f;
      float2 xo = *(const float2*)(XO + 2*(((size_t)(j*12+kx)*512) + b*64 + o));
      float2 cs = cs13[k2];
      float cc=cs.x, s2=sgn*cs.y;
      re += xo.x*cc - xo.y*s2;
      im += xo.x*s2 + xo.y*cc;
    }
    yl[kx][o] = float2{re,im};
  }
  __syncthreads();
  int o = tid&63, wq = tid>>6;
  float yr[12], yi[12];
  #pragma unroll
  for(int k=0;k<12;k++){
    float2 v = yl[k][o];
    yr[k]=v.x; yi[k]=v.y;
  }
  int w0 = wq*51;
  int w1 = w0+51; if(w1>NN) w1=NN;
  bf16* cp = C + ((size_t)R*NN)*64 + o;
  for(int w=w0;w<w1;w++){
    float acc = yr[0];
    #pragma unroll
    for(int k=1;k<12;k++){
      float2 cs = st[k*NN+w];
      acc += 2.0f*(yr[k]*cs.x - yi[k]*cs.y);
    }
    cp[(size_t)w*64] = f2b(acc*(1.0f/40401.0f));
  }
}

// Gram partials (float register tiles, proven). grid (nblk, BB, nsrc); 1024 px/block.
__global__ void __launch_bounds__(256) k_gramp(const bf16* __restrict__ s0,
        const bf16* __restrict__ s1, float* __restrict__ Gpart,
        float* __restrict__ Spart, int HR, int WR){
  __shared__ float sx[8704];
  int b = blockIdx.y, blk = blockIdx.x, z = blockIdx.z;
  const bf16* X = (z==0)? s0 : s1;
  int zb = z*BB + b;
  int npix = HR*WR;
  int tid = threadIdx.x;
  int wid = tid>>6, lane = tid&63;
  int i0 = (lane>>3)*8, j0 = (lane&7)*8;
  float acc[8][8];
  #pragma unroll
  for(int r=0;r<8;r++){
    #pragma unroll
    for(int s=0;s<8;s++) acc[r][s]=0.f;
  }
  float cs = 0.f;
  for(int tile=0;tile<8;tile++){
    int rp0 = blk*1024 + tile*128;
    __syncthreads();
    #pragma unroll
    for(int it=0;it<4;it++){
      int chunk = tid + it*256;
      int k = chunk>>3, c0 = (chunk&7)*8;
      int rp = rp0+k;
      float v[8]={0,0,0,0,0,0,0,0};
      if(rp<npix){
        int gp;
        if(WR==NN) gp = rp;
        else { int hh=rp/WR, ww=rp-hh*WR; gp = hh*NN+ww; }
        s8v xv = *(const s8v*)(X + ((size_t)b*NPIX + gp)*64 + c0);
        #pragma unroll
        for(int j=0;j<8;j++) v[j]=bu2f((unsigned short)xv[j]);
      }
      #pragma unroll
      for(int j=0;j<8;j++) sx[k*68+c0+j]=v[j];
    }
    __syncthreads();
    for(int pp=0;pp<32;pp++){
      const float* row = sx + (wid*32+pp)*68;
      cs += row[lane];
      const float4* ri = (const float4*)(row + i0);
      const float4* rj = (const float4*)(row + j0);
      float4 xi0 = ri[0], xi1 = ri[1];
      float4 xj0 = rj[0], xj1 = rj[1];
      float xi[8] = {xi0.x,xi0.y,xi0.z,xi0.w, xi1.x,xi1.y,xi1.z,xi1.w};
      float xj[8] = {xj0.x,xj0.y,xj0.z,xj0.w, xj1.x,xj1.y,xj1.z,xj1.w};
      #pragma unroll
      for(int r=0;r<8;r++){
        #pragma unroll
        for(int s=0;s<8;s++) acc[r][s] += xi[r]*xj[s];
      }
    }
  }
  __syncthreads();
  float* scol = sx + 8320;
  scol[tid] = cs;
  if(wid>=2){
    float* d = sx + (tid-128)*65;
    #pragma unroll
    for(int r=0;r<8;r++){
      #pragma unroll
      for(int s=0;s<8;s++) d[r*8+s]=acc[r][s];
    }
  }
  __syncthreads();
  if(wid<2){
    const float* d = sx + tid*65;
    #pragma unroll
    for(int r=0;r<8;r++){
      #pragma unroll
      for(int s=0;s<8;s++) acc[r][s]+=d[r*8+s];
    }
  }
  if(tid<64){
    float tot = scol[tid]+scol[tid+64]+scol[tid+128]+scol[tid+192];
    Spart[((size_t)zb*GNB + blk)*64 + tid] = tot;
  }
  __syncthreads();
  if(wid==1){
    float* d = sx + (tid-64)*65;
    #pragma unroll
    for(int r=0;r<8;r++){
      #pragma unroll
      for(int s=0;s<8;s++) d[r*8+s]=acc[r][s];
    }
  }
  __syncthreads();
  if(wid==0){
    const float* d = sx + tid*65;
    #pragma unroll
    for(int r=0;r<8;r++){
      #pragma unroll
      for(int s=0;s<8;s++) acc[r][s]+=d[r*8+s];
    }
    float* g = Gpart + ((size_t)zb*GNB + blk)*4096;
    #pragma unroll
    for(int r=0;r<8;r++){
      #pragma unroll
      for(int s=0;s<8;s++) g[(i0+r)*64 + (j0+s)] = acc[r][s];
    }
  }
}

// Merged gram-reduce + GN stats (grid 16: zb<8 -> m1 stats, zb>=8 -> ww stats).
__global__ void __launch_bounds__(256) k_statsA(const float* __restrict__ Gpart,
        const float* __restrict__ Spart,
        const float* __restrict__ m1wl, const float* __restrict__ m1bl,
        const float* __restrict__ wwl,  const float* __restrict__ wbl,
        float* __restrict__ TSTAT, float* __restrict__ USTAT, int nblk){
  __shared__ float Gs[4096];
  __shared__ float Ss[64];
  __shared__ float rs[256], rq[256];
  int zb=blockIdx.x, t=threadIdx.x;
  float a[16];
  #pragma unroll
  for(int e=0;e<16;e++) a[e]=0.f;
  for(int k=0;k<nblk;k++){
    const float* g = Gpart + ((size_t)zb*GNB + k)*4096 + t*16;
    #pragma unroll
    for(int e=0;e<16;e++) a[e]+=g[e];
  }
  #pragma unroll
  for(int e=0;e<16;e++) Gs[t*16+e]=a[e];
  if(t<64){
    float s=0.f;
    for(int k=0;k<nblk;k++) s += Spart[((size_t)zb*GNB + k)*64 + t];
    Ss[t]=s;
  }
  __syncthreads();
  const float* W    = (zb<8)? m1wl : wwl;
  const float* bias = (zb<8)? m1bl : wbl;
  float* stat       = (zb<8)? TSTAT : USTAT;
  int b = (zb<8)? zb : zb-8;
  int o = t&63, sl = t>>6;
  float w[64];
  #pragma unroll
  for(int j2=0;j2<64;j2++) w[j2]=bu2f(f2bu(W[(size_t)o*64+j2]));
  const float* Gr = Gs + (size_t)(sl*16)*64;
  float quad=0.f;
  #pragma unroll
  for(int r=0;r<16;r++){
    const float* gr = Gr + r*64;
    float tt=0.f;
    #pragma unroll
    for(int j2=0;j2<64;j2++) tt += gr[j2]*w[j2];
    quad += w[sl*16+r]*tt;
  }
  float dot=0.f;
  #pragma unroll
  for(int j2=0;j2<64;j2++) dot += w[j2]*Ss[j2];
  float bo = bias[o];
  float Nf = (float)NPIX;
  float sm = (sl==0)? (dot + Nf*bo) : 0.f;
  float sq = quad + ((sl==0)? (2.f*bo*dot + Nf*bo*bo) : 0.f);
  rs[t]=sm; rq[t]=sq;
  __syncthreads();
  if(t<64){
    float s2 = rs[t]+rs[t+64]+rs[t+128]+rs[t+192];
    float q2 = rq[t]+rq[t+64]+rq[t+128]+rq[t+192];
    for(int off=16;off>0;off>>=1){
      s2 += __shfl_down(s2,off,32);
      q2 += __shfl_down(q2,off,32);
    }
    if((t&31)==0){
      int g=t>>5;
      float invN = 1.f/(Nf*32.f);
      float mean = s2*invN;
      float var = q2*invN - mean*mean;
      stat[b*4+g*2]   = mean;
      stat[b*4+g*2+1] = rsqrtf(fmaxf(var,0.f)+1e-5f);
    }
  }
}

// Merged gram-reduce + head stats (grid 8).
__global__ void __launch_bounds__(256) k_statsQ(const float* __restrict__ Gpart,
        const float* __restrict__ Spart,
        const float* __restrict__ W, const float* __restrict__ bias,
        float* __restrict__ stat, int nblk){
  __shared__ float Gs[4096];
  __shared__ float Ss[64];
  __shared__ float red[8];
  int b=blockIdx.x, t=threadIdx.x;
  float a[16];
  #pragma unroll
  for(int e=0;e<16;e++) a[e]=0.f;
  for(int k=0;k<nblk;k++){
    const float* g = Gpart + ((size_t)b*GNB + k)*4096 + t*16;
    #pragma unroll
    for(int e=0;e<16;e++) a[e]+=g[e];
  }
  #pragma unroll
  for(int e=0;e<16;e++) Gs[t*16+e]=a[e];
  if(t<64){
    float s=0.f;
    for(int k=0;k<nblk;k++) s += Spart[((size_t)b*GNB + k)*64 + t];
    Ss[t]=s;
  }
  __syncthreads();
  float w[64];
  #pragma unroll
  for(int j2=0;j2<64;j2++) w[j2]=bu2f(f2bu(W[(size_t)t*64+j2]));
  float quad=0.f;
  #pragma unroll
  for(int i=0;i<64;i++){
    const float* gr = Gs + i*64;
    float tt=0.f;
    #pragma unroll
    for(int j2=0;j2<64;j2++) tt += gr[j2]*w[j2];
    quad += w[i]*tt;
  }
  float dot=0.f;
  #pragma unroll
  for(int j2=0;j2<64;j2++) dot += w[j2]*Ss[j2];
  float bo=bias[t];
  float Nf=(float)QPIX;
  float sm = dot + Nf*bo;
  float sq = quad + 2.f*bo*dot + Nf*bo*bo;
  for(int off=32;off>0;off>>=1){
    sm += __shfl_down(sm,off,64);
    sq += __shfl_down(sq,off,64);
  }
  int wid=t>>6;
  if((t&63)==0){ red[wid*2]=sm; red[wid*2+1]=sq; }
  __syncthreads();
  if(t<2){
    float smt = red[t*4+0]+red[t*4+2];
    float sqt = red[t*4+1]+red[t*4+3];
    float invN = 1.f/(Nf*128.f);
    float mean = smt*invN;
    float var = sqt*invN - mean*mean;
    stat[b*4+t*2]   = mean;
    stat[b*4+t*2+1] = rsqrtf(fmaxf(var,0.f)+1e-5f);
  }
}

// MFMA fused layer with packed weights.
__global__ void __launch_bounds__(256) k_fuse(const bf16* __restrict__ Cb,
    bf16* __restrict__ A,
    const unsigned short* __restrict__ wp1, const float* __restrict__ m1b,
    const float* __restrict__ mg,  const float* __restrict__ mbt,
    const unsigned short* __restrict__ wp2, const float* __restrict__ m2b,
    const unsigned short* __restrict__ wpw, const float* __restrict__ wbk,
    const float* __restrict__ ng,  const float* __restrict__ nb,
    const float* __restrict__ tstat, const float* __restrict__ ustat, int last){
  __shared__ unsigned short vlds[4][64][72];
  int tid=threadIdx.x;
  int wid=tid>>6, l=tid&63;
  int m_=l&15, g=l>>4;
  int b=blockIdx.y;
  int p0=blockIdx.x*256 + wid*64;
  const bf16* cbb = Cb + (size_t)b*NPIX*64;
  const bf16* ab  = A  + (size_t)b*NPIX*64;

  s8v af[4][2];
  f32x4 acc[4][4];

  #pragma unroll
  for(int mt=0;mt<4;mt++){
    #pragma unroll
    for(int kh=0;kh<2;kh++)
      af[mt][kh]=*(const s8v*)(wp1 + (mt*2+kh)*512 + l*8);
    float4 b4 = *(const float4*)(m1b + 16*mt + 4*g);
    #pragma unroll
    for(int nt=0;nt<4;nt++) acc[mt][nt]=f32x4{b4.x,b4.y,b4.z,b4.w};
  }
  #pragma unroll
  for(int nt=0;nt<4;nt++){
    int p = p0 + 16*nt + m_;
    int pc = p<NPIX? p : NPIX-1;
    const s8v* xb = (const s8v*)(cbb + (size_t)pc*64);
    s8v b0 = xb[g], b1 = xb[4+g];
    #pragma unroll
    for(int mt=0;mt<4;mt++){
      acc[mt][nt]=__builtin_amdgcn_mfma_f32_16x16x32_bf16(af[mt][0],b0,acc[mt][nt],0,0,0);
      acc[mt][nt]=__builtin_amdgcn_mfma_f32_16x16x32_bf16(af[mt][1],b1,acc[mt][nt],0,0,0);
    }
  }
  {
    float tm0=tstat[b*4],tr0=tstat[b*4+1],tm1=tstat[b*4+2],tr1=tstat[b*4+3];
    #pragma unroll
    for(int mt=0;mt<4;mt++){
      float4 g4 = *(const float4*)(mg  + 16*mt + 4*g);
      float4 t4 = *(const float4*)(mbt + 16*mt + 4*g);
      float mn = (mt<2)? tm0 : tm1;
      float rs = (mt<2)? tr0 : tr1;
      #pragma unroll
      for(int nt=0;nt<4;nt++){
        int pl = 16*nt + m_;
        f32x4 t = acc[mt][nt];
        float v0 = gelu_f((t[0]-mn)*rs*g4.x + t4.x);
        float v1 = gelu_f((t[1]-mn)*rs*g4.y + t4.y);
        float v2 = gelu_f((t[2]-mn)*rs*g4.z + t4.z);
        float v3 = gelu_f((t[3]-mn)*rs*g4.w + t4.w);
        uint2 pk;
        pk.x = (unsigned)f2bu(v0) | ((unsigned)f2bu(v1)<<16);
        pk.y = (unsigned)f2bu(v2) | ((unsigned)f2bu(v3)<<16);
        *(uint2*)&vlds[wid][pl][16*mt+4*g] = pk;
      }
    }
  }
  __syncthreads();
  #pragma unroll
  for(int mt=0;mt<4;mt++){
    #pragma unroll
    for(int kh=0;kh<2;kh++)
      af[mt][kh]=*(const s8v*)(wpw + (mt*2+kh)*512 + l*8);
    float4 b4 = *(const float4*)(wbk + 16*mt + 4*g);
    #pragma unroll
    for(int nt=0;nt<4;nt++) acc[mt][nt]=f32x4{b4.x,b4.y,b4.z,b4.w};
  }
  #pragma unroll
  for(int nt=0;nt<4;nt++){
    int p = p0 + 16*nt + m_;
    int pc = p<NPIX? p : NPIX-1;
    const s8v* xb = (const s8v*)(ab + (size_t)pc*64);
    s8v b0 = xb[g], b1 = xb[4+g];
    #pragma unroll
    for(int mt=0;mt<4;mt++){
      acc[mt][nt]=__builtin_amdgcn_mfma_f32_16x16x32_bf16(af[mt][0],b0,acc[mt][nt],0,0,0);
      acc[mt][nt]=__builtin_amdgcn_mfma_f32_16x16x32_bf16(af[mt][1],b1,acc[mt][nt],0,0,0);
    }
  }
  {
    float um0=ustat[b*4],ur0=ustat[b*4+1],um1=ustat[b*4+2],ur1=ustat[b*4+3];
    #pragma unroll
    for(int mt=0;mt<4;mt++){
      float4 n4 = *(const float4*)(ng  + 16*mt + 4*g);
      float4 nb4= *(const float4*)(nb  + 16*mt + 4*g);
      float4 m24= *(const float4*)(m2b + 16*mt + 4*g);
      float mn = (mt<2)? um0 : um1;
      float rs = (mt<2)? ur0 : ur1;
      #pragma unroll
      for(int nt=0;nt<4;nt++){
        f32x4 u = acc[mt][nt];
        u[0] = m24.x + (u[0]-mn)*rs*n4.x + nb4.x;
        u[1] = m24.y + (u[1]-mn)*rs*n4.y + nb4.y;
        u[2] = m24.z + (u[2]-mn)*rs*n4.z + nb4.z;
        u[3] = m24.w + (u[3]-mn)*rs*n4.w + nb4.w;
        acc[mt][nt]=u;
      }
    }
  }
  #pragma unroll
  for(int mt=0;mt<4;mt++){
    #pragma unroll
    for(int kh=0;kh<2;kh++)
      af[mt][kh]=*(const s8v*)(wp2 + (mt*2+kh)*512 + l*8);
  }
  #pragma unroll
  for(int nt=0;nt<4;nt++){
    int pl = 16*nt + m_;
    const s8v* vp = (const s8v*)&vlds[wid][pl][0];
    s8v b0 = vp[g], b1 = vp[4+g];
    #pragma unroll
    for(int mt=0;mt<4;mt++){
      acc[mt][nt]=__builtin_amdgcn_mfma_f32_16x16x32_bf16(af[mt][0],b0,acc[mt][nt],0,0,0);
      acc[mt][nt]=__builtin_amdgcn_mfma_f32_16x16x32_bf16(af[mt][1],b1,acc[mt][nt],0,0,0);
    }
  }
  #pragma unroll
  for(int nt=0;nt<4;nt++){
    int p = p0 + 16*nt + m_;
    if(p>=NPIX) continue;
    bf16* dp = A + ((size_t)b*NPIX + p)*64;
    #pragma unroll
    for(int mt=0;mt<4;mt++){
      f32x4 h = acc[mt][nt];
      float h0=h[0],h1=h[1],h2=h[2],h3=h[3];
      if(!last){ h0=gelu_f(h0); h1=gelu_f(h1); h2=gelu_f(h2); h3=gelu_f(h3); }
      uint2 pk;
      pk.x = (unsigned)f2bu(h0) | ((unsigned)f2bu(h1)<<16);
      pk.y = (unsigned)f2bu(h2) | ((unsigned)f2bu(h3)<<16);
      *(uint2*)(dp + 16*mt + 4*g) = pk;
    }
  }
}

// Head: block stages 256 px of A-crop into LDS once; wave = one oc chunk; LDS reduce.
__global__ void __launch_bounds__(256) k_qout(const bf16* __restrict__ A,
    const unsigned short* __restrict__ qpack, const float* __restrict__ q1b,
    const float* __restrict__ qg, const float* __restrict__ qbt,
    const float* __restrict__ q2w, const float* __restrict__ q2b,
    const float* __restrict__ qstat, float* __restrict__ out){
  __shared__ unsigned short xq[256][72];
  __shared__ float part[4][256];
  int tid=threadIdx.x;
  int wid=tid>>6, l=tid&63;
  int m_=l&15, g=l>>4;
  int b=blockIdx.y;
  int px0=blockIdx.x*256;
  {
    int p = px0 + tid;
    int hh=p/SS, ww2=p-hh*SS;
    const uint4* src=(const uint4*)(A + (((size_t)b*NPIX) + (size_t)hh*NN + ww2)*64);
    uint4* drow=(uint4*)&xq[tid][0];
    #pragma unroll
    for(int i=0;i<8;i++) drow[i]=src[i];
  }
  __syncthreads();
  int oc=wid;
  const unsigned short* wp = qpack + (size_t)oc*4096;
  s8v af[4][2];
  f32x4 bi4[4];
  float4 g4[4], t4[4], w4[4];
  #pragma unroll
  for(int mt=0;mt<4;mt++){
    #pragma unroll
    for(int kh=0;kh<2;kh++)
      af[mt][kh]=*(const s8v*)(wp + (mt*2+kh)*512 + l*8);
    float4 b4=*(const float4*)(q1b + 64*oc + 16*mt + 4*g);
    bi4[mt]=f32x4{b4.x,b4.y,b4.z,b4.w};
    g4[mt]=*(const float4*)(qg  + 64*oc + 16*mt + 4*g);
    t4[mt]=*(const float4*)(qbt + 64*oc + 16*mt + 4*g);
    w4[mt]=*(const float4*)(q2w + 64*oc + 16*mt + 4*g);
  }
  float m0=qstat[b*4],r0=qstat[b*4+1],m1=qstat[b*4+2],r1=qstat[b*4+3];
  float mn=(oc<2)?m0:m1, rs=(oc<2)?r0:r1;
  #pragma unroll
  for(int nt=0;nt<16;nt++){
    const s8v* vp = (const s8v*)&xq[16*nt+m_][0];
    s8v b0=vp[g], b1=vp[4+g];
    f32x4 acc[4];
    #pragma unroll
    for(int mt=0;mt<4;mt++) acc[mt]=bi4[mt];
    #pragma unroll
    for(int mt=0;mt<4;mt++){
      acc[mt]=__builtin_amdgcn_mfma_f32_16x16x32_bf16(af[mt][0],b0,acc[mt],0,0,0);
      acc[mt]=__builtin_amdgcn_mfma_f32_16x16x32_bf16(af[mt][1],b1,acc[mt],0,0,0);
    }
    float pp=0.f;
    #pragma unroll
    for(int mt=0;mt<4;mt++){
      f32x4 t=acc[mt];
      pp += gelu_f((t[0]-mn)*rs*g4[mt].x + t4[mt].x)*w4[mt].x;
      pp += gelu_f((t[1]-mn)*rs*g4[mt].y + t4[mt].y)*w4[mt].y;
      pp += gelu_f((t[2]-mn)*rs*g4[mt].z + t4[mt].z)*w4[mt].z;
      pp += gelu_f((t[3]-mn)*rs*g4[mt].w + t4[mt].w)*w4[mt].w;
    }
    pp += __shfl_xor(pp,16,64);
    pp += __shfl_xor(pp,32,64);
    if(g==0) part[wid][16*nt+m_]=pp;
  }
  __syncthreads();
  out[(size_t)b*QPIX + px0 + tid] =
      q2b[0] + part[0][tid]+part[1][tid]+part[2][tid]+part[3][tid];
}

extern "C" void kernel_launch(void* const* d_in, const int* in_sizes, int n_in,
                              void* d_out, int out_size, void* d_ws, size_t ws_size,
                              hipStream_t stream){
  const float* x   = (const float*)d_in[0];
  const float* Wp  = (const float*)d_in[1];
  const float* bp  = (const float*)d_in[2];
  const float* sw1 = (const float*)d_in[3];
  const float* sw2 = (const float*)d_in[4];
  const float* m1w = (const float*)d_in[5];
  const float* m1b = (const float*)d_in[6];
  const float* mg  = (const float*)d_in[7];
  const float* mbt = (const float*)d_in[8];
  const float* m2w = (const float*)d_in[9];
  const float* m2b = (const float*)d_in[10];
  const float* ww  = (const float*)d_in[11];
  const float* wb  = (const float*)d_in[12];
  const float* ng  = (const float*)d_in[13];
  const float* nb  = (const float*)d_in[14];
  const float* q1w = (const float*)d_in[15];
  const float* q1b = (const float*)d_in[16];
  const float* qg  = (const float*)d_in[17];
  const float* qbt = (const float*)d_in[18];
  const float* q2w = (const float*)d_in[19];
  const float* q2b = (const float*)d_in[20];
  float* out = (float*)d_out;

  char* w8 = (char*)d_ws;
  const size_t ACT_B = (size_t)64*BB*NPIX*sizeof(bf16);   // 41,370,624
  bf16*  A    = (bf16*)(w8);
  bf16*  Cb   = (bf16*)(w8 + ACT_B);
  float* SPEC = (float*)(w8 + 2*ACT_B);                    // XW / WT / Gpart overlays
  float* XF   = (float*)(w8 + 2*ACT_B + 9879552);
  float* XO   = (float*)(w8 + 2*ACT_B + 9879552 + 1179648);
  float* TB   = (float*)(w8 + 2*ACT_B + 9879552 + 2*1179648);
  char*  g8   = w8 + 2*ACT_B + 9879552 + 2*1179648 + 20992;
  float* TSTAT= (float*)g8;
  float* USTAT= TSTAT + 32;
  float* QSTAT= USTAT + 32;
  float* UxT  = QSTAT + 32;                  // 192*64
  float* UyT  = UxT + 12288;                 // 192*64
  unsigned short* WPK = (unsigned short*)(UyT + 12288);   // 16*4096 bf16
  float* Gpart = SPEC;                       // overlays SPEC+XF (dead at gram time)
  float* Spart = Gpart + (size_t)16*GNB*4096;
  float* WT = SPEC;                          // 288*8192 floats = 9.44MB
  size_t needed = (size_t)(2*ACT_B) + 9879552 + 2*1179648 + 20992
                + 3*32*4 + 2*12288*4 + 16*4096*2;
  if(ws_size < needed) return;

  k_tab<<<11,256,0,stream>>>(TB);
  k_pretab<<<dim3(192,2),64,0,stream>>>(Wp, bp, UxT, UyT);
  k_wpack<<<16,256,0,stream>>>(m1w, m2w, ww, q1w, WPK);
  k_encoder<<<dim3(158,BB),256,0,stream>>>(x, Wp, UxT, UyT, A);

  for(int l=0;l<4;l++){
    const float* sw1l = sw1 + (size_t)l*1179648;
    const float* sw2l = sw2 + (size_t)l*1179648;
    k_dftw<<<402,256,0,stream>>>(A, TB, SPEC);
    k_dfth<<<dim3(12,BB,4),256,0,stream>>>(SPEC, TB, XF);
    k_wtrans<<<dim3(64,5,2),256,0,stream>>>(sw1l, sw2l, WT);
    k_modemix<<<288,512,0,stream>>>(XF, WT, XO);
    k_ispec<<<1608,256,0,stream>>>(XO, TB, Cb);
    k_gramp<<<dim3(GNB,BB,2),256,0,stream>>>(Cb, A, Gpart, Spart, NN, NN);
    k_statsA<<<16,256,0,stream>>>(Gpart, Spart,
          m1w + (size_t)l*4096, m1b + l*64, ww + (size_t)l*4096, wb + l*64,
          TSTAT, USTAT, GNB);
    k_fuse<<<dim3(158,BB),256,0,stream>>>(Cb, A,
          WPK + (size_t)(l*3+0)*4096, m1b + l*64, mg + l*64, mbt + l*64,
          WPK + (size_t)(l*3+1)*4096, m2b + l*64,
          WPK + (size_t)(l*3+2)*4096, wb  + l*64, ng + l*64, nb + l*64,
          TSTAT, USTAT, (l==3)?1:0);
  }

  k_gramp<<<dim3(36,BB,1),256,0,stream>>>(A, A, Gpart, Spart, SS, SS);
  k_statsQ<<<BB,256,0,stream>>>(Gpart, Spart, q1w, q1b, QSTAT, 36);
  k_qout<<<dim3(144,BB),256,0,stream>>>(A, WPK + (size_t)12*4096, q1b,
          qg, qbt, q2w, q2b, QSTAT, out);
}

// Round 10
// 1524.339 us; speedup vs baseline: 1.4446x; 1.0221x over previous
//
#include <hip/hip_runtime.h>
#include <hip/hip_bf16.h>
#include <math.h>

// FNO2d: B=8, S=192, pad->201x201, C=64, modes 12x12, 4 layers.
// Pixel-major activations [b][p][c]; MFMA conv GEMMs; Parseval Gram for spectral
// branch (k_gramC from XO); float register-tile Gram for bypass; fast sigmoid-gelu.

#define NN 201
#define SS 192
#define NPIX 40401
#define QPIX 36864
#define BB 8
#define GNB 40           // gram slabs per (z,b), 1024 px each
#define XWPL 1234944     // 1608*12*64 (re/im plane stride in floats)
#define PI_F 3.14159265358979323846f

typedef __hip_bfloat16 bf16;
typedef __attribute__((ext_vector_type(8))) short s8v;
typedef __attribute__((ext_vector_type(4))) float f32x4;

// tanh-form gelu via sigmoid: x*sigma(1.5957691x + 0.0713548x^3); |err| <= ~1e-3
__device__ __forceinline__ float gelu_f(float x){
  float x2 = x*x;
  float t  = fmaf(x2, 0.0713548162f, 1.5957691216f);
  float e  = __expf(-x*t);
  return x*__builtin_amdgcn_rcpf(1.0f+e);
}
__device__ __forceinline__ float b2f(bf16 v){ return __bfloat162float(v); }
__device__ __forceinline__ bf16  f2b(float v){ return __float2bfloat16(v); }
__device__ __forceinline__ unsigned short f2bu(float x){
  bf16 h = __float2bfloat16(x);
  unsigned short u; __builtin_memcpy(&u,&h,2); return u;
}
__device__ __forceinline__ float bu2f(unsigned short u){
  unsigned int x = ((unsigned int)u)<<16; float f; __builtin_memcpy(&f,&x,4); return f;
}

// tab[k][n]: cos/sin(2*pi*k*n/201), k=0..12, exact mod-201 reduction
__global__ void k_tab(float* __restrict__ tab){
  int t = blockIdx.x*blockDim.x+threadIdx.x;
  if(t>=13*NN) return;
  int k=t/NN, n=t-k*NN;
  int m=(k*n)%NN;
  float ang = (2.0f*PI_F/201.0f)*(float)m;
  tab[2*t]   = cosf(ang);
  tab[2*t+1] = sinf(ang);
}

// Separable encoder tables. grid (192,2), 64 thr.
__global__ void k_pretab(const float* __restrict__ Wp, const float* __restrict__ bp,
                         float* __restrict__ Ux, float* __restrict__ Uy){
  int i = blockIdx.x;
  int ax = blockIdx.y;
  int c = threadIdx.x;
  float g = (float)i*(1.0f/191.0f);
  float acc;
  if(ax==0) acc = bp[c] + g*Wp[64+c];
  else      acc = g*Wp[128+c];
  int cosBase = (ax==0)? 3 : 4;
  int sinBase = (ax==0)? 23 : 24;
  #pragma unroll
  for(int l=0;l<10;l++){
    float f = PI_F*(float)(1<<l);
    float sv,cv;
    sincosf(g*f,&sv,&cv);
    acc += cv*Wp[(cosBase+2*l)*64+c] + sv*Wp[(sinBase+2*l)*64+c];
  }
  float* U = (ax==0)? Ux : Uy;
  U[i*64+c] = acc;
}

// Pack 16 64x64 weight matrices into bf16 MFMA-fragment order.
__global__ void k_wpack(const float* __restrict__ m1w, const float* __restrict__ m2w,
                        const float* __restrict__ ww,  const float* __restrict__ q1w,
                        unsigned short* __restrict__ WPK){
  int bx = blockIdx.x, tid = threadIdx.x;
  const float* src;
  if(bx<12){
    int l=bx/3, sel=bx-l*3;
    src = (sel==0)? m1w+(size_t)l*4096 : (sel==1)? m2w+(size_t)l*4096 : ww+(size_t)l*4096;
  } else {
    src = q1w + (size_t)(bx-12)*4096;
  }
  unsigned short* dst = WPK + (size_t)bx*4096;
  #pragma unroll
  for(int t=0;t<16;t++){
    int d = tid*16+t;
    int frag=d>>9, lane=(d>>3)&63, j=d&7;
    int mt=frag>>1, kh=frag&1, m_=lane&15, g=lane>>4;
    dst[d] = f2bu(src[(size_t)(16*mt+m_)*64 + 32*kh + 8*g + j]);
  }
}

// Transpose spectral weights for layer into WT[m][comp][io].
__global__ void __launch_bounds__(256) k_wtrans(const float* __restrict__ w1,
        const float* __restrict__ w2, float* __restrict__ WT){
  __shared__ float tile[64][65];
  int io0 = blockIdx.x*64;
  int c0  = blockIdx.y*64;
  int z   = blockIdx.z;
  const float* src = (z==0)? w1 : w2;
  int tid = threadIdx.x;
  #pragma unroll
  for(int it=0;it<16;it++){
    int e = tid + 256*it;
    int r = e>>6, c = e&63;
    if(c0+c<288) tile[r][c] = src[(size_t)(io0+r)*288 + c0 + c];
  }
  __syncthreads();
  #pragma unroll
  for(int it=0;it<16;it++){
    int e = tid + 256*it;
    int rp = e>>6, cp = e&63;
    int col = c0 + rp;
    if(col<288){
      int ky = col/24, rm = col - ky*24;
      int kx = rm>>1, comp = rm&1;
      int m = z*144 + ky*12 + kx;
      WT[(size_t)m*8192 + comp*4096 + io0 + cp] = tile[cp][rp];
    }
  }
}

// encoder: A[b][p][c] = x*Wp0[c] + Ux[hh][c] + Uy[ww][c]; zeros in pad.
__global__ void k_encoder(const float* __restrict__ x, const float* __restrict__ Wp,
                          const float* __restrict__ Ux, const float* __restrict__ Uy,
                          bf16* __restrict__ A){
  int tid=threadIdx.x;
  int p = blockIdx.x*256+tid;
  if(p>=NPIX) return;
  int b = blockIdx.y;
  uint4* dst = (uint4*)(A + ((size_t)b*NPIX + p)*64);
  int hh=p/NN, ww=p-hh*NN;
  if(hh>=SS || ww>=SS){
    uint4 z = {0,0,0,0};
    #pragma unroll
    for(int i=0;i<8;i++) dst[i]=z;
    return;
  }
  float xv = x[((size_t)b*SS+hh)*SS+ww];
  const float4* ux = (const float4*)(Ux + hh*64);
  const float4* uy = (const float4*)(Uy + ww*64);
  const float4* w0 = (const float4*)Wp;
  #pragma unroll
  for(int i=0;i<8;i++){
    float4 a0 = ux[2*i],   a1 = ux[2*i+1];
    float4 b0 = uy[2*i],   b1 = uy[2*i+1];
    float4 c0 = w0[2*i],   c1 = w0[2*i+1];
    float v0=xv*c0.x+a0.x+b0.x, v1=xv*c0.y+a0.y+b0.y;
    float v2=xv*c0.z+a0.z+b0.z, v3=xv*c0.w+a0.w+b0.w;
    float v4=xv*c1.x+a1.x+b1.x, v5=xv*c1.y+a1.y+b1.y;
    float v6=xv*c1.z+a1.z+b1.z, v7=xv*c1.w+a1.w+b1.w;
    uint4 v;
    v.x = (unsigned)f2bu(v0) | ((unsigned)f2bu(v1)<<16);
    v.y = (unsigned)f2bu(v2) | ((unsigned)f2bu(v3)<<16);
    v.z = (unsigned)f2bu(v4) | ((unsigned)f2bu(v5)<<16);
    v.w = (unsigned)f2bu(v6) | ((unsigned)f2bu(v7)<<16);
    dst[i]=v;
  }
}

// DFT along W. Wave per row R=b*201+h, lane=c. XW[re/im][R][kx][c].
__global__ void __launch_bounds__(256) k_dftw(const bf16* __restrict__ A,
        const float* __restrict__ tab, float* __restrict__ XW){
  __shared__ float2 st[2412];
  int tid=threadIdx.x;
  for(int i=tid;i<2412;i+=256) st[i]=((const float2*)tab)[i];
  __syncthreads();
  int R = blockIdx.x*4 + (tid>>6);
  int l = tid&63;
  const bf16* base = A + ((size_t)R*NN)*64 + l;
  float ar0=0.f;
  float ar[11], ai[11];
  #pragma unroll
  for(int k=0;k<11;k++){ ar[k]=0.f; ai[k]=0.f; }
  for(int w=0;w<NN;w++){
    float a = b2f(base[(size_t)w*64]);
    ar0 += a;
    #pragma unroll
    for(int k=0;k<11;k++){
      float2 cs = st[(k+1)*NN+w];
      ar[k] += a*cs.x;
      ai[k] += a*cs.y;
    }
  }
  float* xre = XW + ((size_t)R*12)*64 + l;
  float* xim = xre + XWPL;
  xre[0]=ar0; xim[0]=0.f;
  #pragma unroll
  for(int k=0;k<11;k++){
    xre[(size_t)(k+1)*64] = ar[k];
    xim[(size_t)(k+1)*64] = -ai[k];
  }
}

// DFT along H, LDS-staged: grid (12, 8, 4); z = (jhalf<<1)|chalf.
__global__ void __launch_bounds__(256) k_dfth(const float* __restrict__ XW,
        const float* __restrict__ tab, float* __restrict__ XF){
  __shared__ float sre[201*32];
  __shared__ float sim[201*32];
  __shared__ float2 tw[13*NN];
  int kx=blockIdx.x, b=blockIdx.y;
  int z=blockIdx.z; int jh=z>>1, ch=z&1;
  int tid=threadIdx.x;
  for(int i=tid;i<13*NN;i+=256) tw[i]=((const float2*)tab)[i];
  for(int i=tid;i<201*32;i+=256){
    int h=i>>5, c=ch*32+(i&31);
    size_t idx=(((size_t)b*NN+h)*12+kx)*64+c;
    sre[i]=XW[idx];
    sim[i]=XW[idx+XWPL];
  }
  __syncthreads();
  for(int o=tid;o<384;o+=256){
    int jj=o>>5, cl=o&31;
    int j=jh*12+jj;
    int k2=(j<12)?j:24-j;
    float sgn=(j<12)?-1.f:1.f;
    float re=0.f,im=0.f;
    const float* pr=sre+cl;
    const float* pi=sim+cl;
    const float2* tk=tw+k2*NN;
    for(int h=0;h<NN;h++){
      float a=pr[h*32], bb=pi[h*32];
      float2 cs=tk[h];
      float cc=cs.x, s2=sgn*cs.y;
      re+=a*cc-bb*s2; im+=a*s2+bb*cc;
    }
    int m=j*12+kx;
    int c=ch*32+cl;
    XF[(size_t)m*1024+(b*64+c)*2]  =re;
    XF[(size_t)m*1024+(b*64+c)*2+1]=im;
  }
}

// per-mode 64x64 complex mix; weights from transposed WT
__global__ void __launch_bounds__(512) k_modemix(const float* __restrict__ XF,
     const float* __restrict__ WT, float* __restrict__ XO){
  __shared__ float sx[1024];
  __shared__ float swr[4096], swi[4096];
  int m=blockIdx.x;
  int tid=threadIdx.x;
  sx[tid]     = XF[(size_t)m*1024+tid];
  sx[tid+512] = XF[(size_t)m*1024+tid+512];
  const float* wr = WT + (size_t)m*8192;
  const float* wi = wr + 4096;
  for(int io=tid;io<4096;io+=512){
    swr[io]=wr[io];
    swi[io]=wi[io];
  }
  __syncthreads();
  int b=tid>>6, o=tid&63;
  const float* xb = sx + b*128;
  float re=0.0f,im=0.0f;
  #pragma unroll 8
  for(int i=0;i<64;i++){
    float a=xb[2*i], b2=xb[2*i+1];
    float c=swr[i*64+o], d=swi[i*64+o];
    re += a*c - b2*d;
    im += a*d + b2*c;
  }
  XO[2*((size_t)m*512+tid)]  =re;
  XO[2*((size_t)m*512+tid)+1]=im;
}

// Merged inverse: per row R, idfth into LDS, then C2R along W. C[b][p][o] bf16.
__global__ void __launch_bounds__(256) k_ispec(const float* __restrict__ XO,
        const float* __restrict__ tab, bf16* __restrict__ C){
  __shared__ float2 st[2412];
  __shared__ float2 yl[12][64];
  __shared__ float2 cs13[13];
  int R=blockIdx.x;
  int b=R/NN, h=R-b*NN;
  int tid=threadIdx.x;
  for(int i=tid;i<2412;i+=256) st[i]=((const float2*)tab)[i];
  if(tid<13) cs13[tid]=((const float2*)tab)[tid*NN+h];
  __syncthreads();
  #pragma unroll
  for(int it=0;it<3;it++){
    int item = tid + 256*it;
    int kx = item>>6, o = item&63;
    float re=0.f,im=0.f;
    #pragma unroll
    for(int j=0;j<24;j++){
      int k2=(j<12)?j:24-j;
      float sgn=(j<12)?1.0f:-1.0f;
      float2 xo = *(const float2*)(XO + 2*(((size_t)(j*12+kx)*512) + b*64 + o));
      float2 cs = cs13[k2];
      float cc=cs.x, s2=sgn*cs.y;
      re += xo.x*cc - xo.y*s2;
      im += xo.x*s2 + xo.y*cc;
    }
    yl[kx][o] = float2{re,im};
  }
  __syncthreads();
  int o = tid&63, wq = tid>>6;
  float yr[12], yi[12];
  #pragma unroll
  for(int k=0;k<12;k++){
    float2 v = yl[k][o];
    yr[k]=v.x; yi[k]=v.y;
  }
  int w0 = wq*51;
  int w1 = w0+51; if(w1>NN) w1=NN;
  bf16* cp = C + ((size_t)R*NN)*64 + o;
  for(int w=w0;w<w1;w++){
    float acc = yr[0];
    #pragma unroll
    for(int k=1;k<12;k++){
      float2 cs = st[k*NN+w];
      acc += 2.0f*(yr[k]*cs.x - yi[k]*cs.y);
    }
    cp[(size_t)w*64] = f2b(acc*(1.0f/40401.0f));
  }
}

// Parseval Gram of the spectral output Cb, computed from XO. grid = 8 (per batch).
// G = V V^T where V[64][576] bf16 features (weights baked in, scale 1/201 each):
//  f<528 : kx=1..11, m=0..23, {Re,Im} -> sqrt(2)*XO
//  f=528 : Re XO[ky=0][kx=0]
//  529..550: pairs m=1..11 at kx=0: (Re_m+Re_{24-m})/sqrt2, (Im_m-Im_{24-m})/sqrt2
//  551,552 : lone ky=189 (m=12) at kx=0: Re/sqrt2, Im/sqrt2
// S_i = Re XO_i[0,0] exactly.
__global__ void __launch_bounds__(256) k_gramC(const float* __restrict__ XO,
        float* __restrict__ GC, float* __restrict__ SC){
  __shared__ unsigned short V[64][584];
  int b=blockIdx.x, tid=threadIdx.x;
  const float s1=1.0f/201.0f;
  const float r2=0.70710678118f;
  const float q2=1.41421356237f;
  for(int e=tid;e<576*64;e+=256){
    int f=e>>6, ch=e&63;
    int base = b*64+ch;
    float v=0.f;
    if(f<528){
      int comp=f&1, kxm=f>>1;
      int kx0=kxm/24;
      int kx=1+kx0, m=kxm-kx0*24;
      v = q2*XO[2*((size_t)(m*12+kx)*512 + base)+comp];
    } else if(f==528){
      v = XO[2*(size_t)base];
    } else if(f<551){
      int q=f-529; int mm=1+(q>>1);
      const float* p1 = XO + 2*((size_t)(mm*12)*512 + base);
      const float* p2 = XO + 2*((size_t)((24-mm)*12)*512 + base);
      v = ((q&1)==0)? r2*(p1[0]+p2[0]) : r2*(p1[1]-p2[1]);
    } else if(f==551){
      v = r2*XO[2*((size_t)(144)*512 + base)];
    } else if(f==552){
      v = r2*XO[2*((size_t)(144)*512 + base)+1];
    }
    V[ch][f]=f2bu(v*s1);
  }
  __syncthreads();
  int wid=tid>>6, l=tid&63, m_=l&15, g=l>>4;
  f32x4 acc[4];
  #pragma unroll
  for(int mt=0;mt<4;mt++) acc[mt]=f32x4{0.f,0.f,0.f,0.f};
  #pragma unroll
  for(int kc=0;kc<18;kc++){
    s8v bfr = *(const s8v*)&V[16*wid+m_][kc*32+8*g];
    #pragma unroll
    for(int mt=0;mt<4;mt++){
      s8v afr = *(const s8v*)&V[16*mt+m_][kc*32+8*g];
      acc[mt]=__builtin_amdgcn_mfma_f32_16x16x32_bf16(afr,bfr,acc[mt],0,0,0);
    }
  }
  float* gb = GC + (size_t)b*4096;
  #pragma unroll
  for(int mt=0;mt<4;mt++){
    #pragma unroll
    for(int e=0;e<4;e++)
      gb[(size_t)(16*mt+4*g+e)*64 + 16*wid + m_] = acc[mt][e];
  }
  if(tid<64) SC[b*64+tid] = XO[2*(size_t)(b*64+tid)];
}

// Gram partials for A (float register tiles). grid (nblk, BB, 1); 1024 px/block.
__global__ void __launch_bounds__(256) k_gramp(const bf16* __restrict__ s0,
        const bf16* __restrict__ s1, float* __restrict__ Gpart,
        float* __restrict__ Spart, int HR, int WR){
  __shared__ float sx[8704];
  int b = blockIdx.y, blk = blockIdx.x, z = blockIdx.z;
  const bf16* X = (z==0)? s0 : s1;
  int zb = z*BB + b;
  int npix = HR*WR;
  int tid = threadIdx.x;
  int wid = tid>>6, lane = tid&63;
  int i0 = (lane>>3)*8, j0 = (lane&7)*8;
  float acc[8][8];
  #pragma unroll
  for(int r=0;r<8;r++){
    #pragma unroll
    for(int s=0;s<8;s++) acc[r][s]=0.f;
  }
  float cs = 0.f;
  for(int tile=0;tile<8;tile++){
    int rp0 = blk*1024 + tile*128;
    __syncthreads();
    #pragma unroll
    for(int it=0;it<4;it++){
      int chunk = tid + it*256;
      int k = chunk>>3, c0 = (chunk&7)*8;
      int rp = rp0+k;
      float v[8]={0,0,0,0,0,0,0,0};
      if(rp<npix){
        int gp;
        if(WR==NN) gp = rp;
        else { int hh=rp/WR, ww=rp-hh*WR; gp = hh*NN+ww; }
        s8v xv = *(const s8v*)(X + ((size_t)b*NPIX + gp)*64 + c0);
        #pragma unroll
        for(int j=0;j<8;j++) v[j]=bu2f((unsigned short)xv[j]);
      }
      #pragma unroll
      for(int j=0;j<8;j++) sx[k*68+c0+j]=v[j];
    }
    __syncthreads();
    for(int pp=0;pp<32;pp++){
      const float* row = sx + (wid*32+pp)*68;
      cs += row[lane];
      const float4* ri = (const float4*)(row + i0);
      const float4* rj = (const float4*)(row + j0);
      float4 xi0 = ri[0], xi1 = ri[1];
      float4 xj0 = rj[0], xj1 = rj[1];
      float xi[8] = {xi0.x,xi0.y,xi0.z,xi0.w, xi1.x,xi1.y,xi1.z,xi1.w};
      float xj[8] = {xj0.x,xj0.y,xj0.z,xj0.w, xj1.x,xj1.y,xj1.z,xj1.w};
      #pragma unroll
      for(int r=0;r<8;r++){
        #pragma unroll
        for(int s=0;s<8;s++) acc[r][s] += xi[r]*xj[s];
      }
    }
  }
  __syncthreads();
  float* scol = sx + 8320;
  scol[tid] = cs;
  if(wid>=2){
    float* d = sx + (tid-128)*65;
    #pragma unroll
    for(int r=0;r<8;r++){
      #pragma unroll
      for(int s=0;s<8;s++) d[r*8+s]=acc[r][s];
    }
  }
  __syncthreads();
  if(wid<2){
    const float* d = sx + tid*65;
    #pragma unroll
    for(int r=0;r<8;r++){
      #pragma unroll
      for(int s=0;s<8;s++) acc[r][s]+=d[r*8+s];
    }
  }
  if(tid<64){
    float tot = scol[tid]+scol[tid+64]+scol[tid+128]+scol[tid+192];
    Spart[((size_t)zb*GNB + blk)*64 + tid] = tot;
  }
  __syncthreads();
  if(wid==1){
    float* d = sx + (tid-64)*65;
    #pragma unroll
    for(int r=0;r<8;r++){
      #pragma unroll
      for(int s=0;s<8;s++) d[r*8+s]=acc[r][s];
    }
  }
  __syncthreads();
  if(wid==0){
    const float* d = sx + tid*65;
    #pragma unroll
    for(int r=0;r<8;r++){
      #pragma unroll
      for(int s=0;s<8;s++) acc[r][s]+=d[r*8+s];
    }
    float* g = Gpart + ((size_t)zb*GNB + blk)*4096;
    #pragma unroll
    for(int r=0;r<8;r++){
      #pragma unroll
      for(int s=0;s<8;s++) g[(i0+r)*64 + (j0+s)] = acc[r][s];
    }
  }
}

// Merged stats (grid 16): zb<8 -> Cb-stats from GC/SC (Parseval); zb>=8 -> A-stats
// by reducing Gpart slabs (zb-8).
__global__ void __launch_bounds__(256) k_statsA(
        const float* __restrict__ GC, const float* __restrict__ SC,
        const float* __restrict__ Gpart, const float* __restrict__ Spart,
        const float* __restrict__ m1wl, const float* __restrict__ m1bl,
        const float* __restrict__ wwl,  const float* __restrict__ wbl,
        float* __restrict__ TSTAT, float* __restrict__ USTAT, int nblk){
  __shared__ float Gs[4096];
  __shared__ float Ss[64];
  __shared__ float rs[256], rq[256];
  int zb=blockIdx.x, t=threadIdx.x;
  if(zb<8){
    #pragma unroll
    for(int e=0;e<16;e++) Gs[t*16+e]=GC[(size_t)zb*4096 + t*16+e];
    if(t<64) Ss[t]=SC[zb*64+t];
  } else {
    int bb=zb-8;
    float a[16];
    #pragma unroll
    for(int e=0;e<16;e++) a[e]=0.f;
    for(int k=0;k<nblk;k++){
      const float* g = Gpart + ((size_t)bb*GNB + k)*4096 + t*16;
      #pragma unroll
      for(int e=0;e<16;e++) a[e]+=g[e];
    }
    #pragma unroll
    for(int e=0;e<16;e++) Gs[t*16+e]=a[e];
    if(t<64){
      float s=0.f;
      for(int k=0;k<nblk;k++) s += Spart[((size_t)bb*GNB + k)*64 + t];
      Ss[t]=s;
    }
  }
  __syncthreads();
  const float* W    = (zb<8)? m1wl : wwl;
  const float* bias = (zb<8)? m1bl : wbl;
  float* stat       = (zb<8)? TSTAT : USTAT;
  int b = (zb<8)? zb : zb-8;
  int o = t&63, sl = t>>6;
  float w[64];
  #pragma unroll
  for(int j2=0;j2<64;j2++) w[j2]=bu2f(f2bu(W[(size_t)o*64+j2]));
  const float* Gr = Gs + (size_t)(sl*16)*64;
  float quad=0.f;
  #pragma unroll
  for(int r=0;r<16;r++){
    const float* gr = Gr + r*64;
    float tt=0.f;
    #pragma unroll
    for(int j2=0;j2<64;j2++) tt += gr[j2]*w[j2];
    quad += w[sl*16+r]*tt;
  }
  float dot=0.f;
  #pragma unroll
  for(int j2=0;j2<64;j2++) dot += w[j2]*Ss[j2];
  float bo = bias[o];
  float Nf = (float)NPIX;
  float sm = (sl==0)? (dot + Nf*bo) : 0.f;
  float sq = quad + ((sl==0)? (2.f*bo*dot + Nf*bo*bo) : 0.f);
  rs[t]=sm; rq[t]=sq;
  __syncthreads();
  if(t<64){
    float s2 = rs[t]+rs[t+64]+rs[t+128]+rs[t+192];
    float q2 = rq[t]+rq[t+64]+rq[t+128]+rq[t+192];
    for(int off=16;off>0;off>>=1){
      s2 += __shfl_down(s2,off,32);
      q2 += __shfl_down(q2,off,32);
    }
    if((t&31)==0){
      int g=t>>5;
      float invN = 1.f/(Nf*32.f);
      float mean = s2*invN;
      float var = q2*invN - mean*mean;
      stat[b*4+g*2]   = mean;
      stat[b*4+g*2+1] = rsqrtf(fmaxf(var,0.f)+1e-5f);
    }
  }
}

// Merged gram-reduce + head stats (grid 8).
__global__ void __launch_bounds__(256) k_statsQ(const float* __restrict__ Gpart,
        const float* __restrict__ Spart,
        const float* __restrict__ W, const float* __restrict__ bias,
        float* __restrict__ stat, int nblk){
  __shared__ float Gs[4096];
  __shared__ float Ss[64];
  __shared__ float red[8];
  int b=blockIdx.x, t=threadIdx.x;
  float a[16];
  #pragma unroll
  for(int e=0;e<16;e++) a[e]=0.f;
  for(int k=0;k<nblk;k++){
    const float* g = Gpart + ((size_t)b*GNB + k)*4096 + t*16;
    #pragma unroll
    for(int e=0;e<16;e++) a[e]+=g[e];
  }
  #pragma unroll
  for(int e=0;e<16;e++) Gs[t*16+e]=a[e];
  if(t<64){
    float s=0.f;
    for(int k=0;k<nblk;k++) s += Spart[((size_t)b*GNB + k)*64 + t];
    Ss[t]=s;
  }
  __syncthreads();
  float w[64];
  #pragma unroll
  for(int j2=0;j2<64;j2++) w[j2]=bu2f(f2bu(W[(size_t)t*64+j2]));
  float quad=0.f;
  #pragma unroll
  for(int i=0;i<64;i++){
    const float* gr = Gs + i*64;
    float tt=0.f;
    #pragma unroll
    for(int j2=0;j2<64;j2++) tt += gr[j2]*w[j2];
    quad += w[i]*tt;
  }
  float dot=0.f;
  #pragma unroll
  for(int j2=0;j2<64;j2++) dot += w[j2]*Ss[j2];
  float bo=bias[t];
  float Nf=(float)QPIX;
  float sm = dot + Nf*bo;
  float sq = quad + 2.f*bo*dot + Nf*bo*bo;
  for(int off=32;off>0;off>>=1){
    sm += __shfl_down(sm,off,64);
    sq += __shfl_down(sq,off,64);
  }
  int wid=t>>6;
  if((t&63)==0){ red[wid*2]=sm; red[wid*2+1]=sq; }
  __syncthreads();
  if(t<2){
    float smt = red[t*4+0]+red[t*4+2];
    float sqt = red[t*4+1]+red[t*4+3];
    float invN = 1.f/(Nf*128.f);
    float mean = smt*invN;
    float var = sqt*invN - mean*mean;
    stat[b*4+t*2]   = mean;
    stat[b*4+t*2+1] = rsqrtf(fmaxf(var,0.f)+1e-5f);
  }
}

// MFMA fused layer with packed weights.
__global__ void __launch_bounds__(256) k_fuse(const bf16* __restrict__ Cb,
    bf16* __restrict__ A,
    const unsigned short* __restrict__ wp1, const float* __restrict__ m1b,
    const float* __restrict__ mg,  const float* __restrict__ mbt,
    const unsigned short* __restrict__ wp2, const float* __restrict__ m2b,
    const unsigned short* __restrict__ wpw, const float* __restrict__ wbk,
    const float* __restrict__ ng,  const float* __restrict__ nb,
    const float* __restrict__ tstat, const float* __restrict__ ustat, int last){
  __shared__ unsigned short vlds[4][64][72];
  int tid=threadIdx.x;
  int wid=tid>>6, l=tid&63;
  int m_=l&15, g=l>>4;
  int b=blockIdx.y;
  int p0=blockIdx.x*256 + wid*64;
  const bf16* cbb = Cb + (size_t)b*NPIX*64;
  const bf16* ab  = A  + (size_t)b*NPIX*64;

  s8v af[4][2];
  f32x4 acc[4][4];

  #pragma unroll
  for(int mt=0;mt<4;mt++){
    #pragma unroll
    for(int kh=0;kh<2;kh++)
      af[mt][kh]=*(const s8v*)(wp1 + (mt*2+kh)*512 + l*8);
    float4 b4 = *(const float4*)(m1b + 16*mt + 4*g);
    #pragma unroll
    for(int nt=0;nt<4;nt++) acc[mt][nt]=f32x4{b4.x,b4.y,b4.z,b4.w};
  }
  #pragma unroll
  for(int nt=0;nt<4;nt++){
    int p = p0 + 16*nt + m_;
    int pc = p<NPIX? p : NPIX-1;
    const s8v* xb = (const s8v*)(cbb + (size_t)pc*64);
    s8v b0 = xb[g], b1 = xb[4+g];
    #pragma unroll
    for(int mt=0;mt<4;mt++){
      acc[mt][nt]=__builtin_amdgcn_mfma_f32_16x16x32_bf16(af[mt][0],b0,acc[mt][nt],0,0,0);
      acc[mt][nt]=__builtin_amdgcn_mfma_f32_16x16x32_bf16(af[mt][1],b1,acc[mt][nt],0,0,0);
    }
  }
  {
    float tm0=tstat[b*4],tr0=tstat[b*4+1],tm1=tstat[b*4+2],tr1=tstat[b*4+3];
    #pragma unroll
    for(int mt=0;mt<4;mt++){
      float4 g4 = *(const float4*)(mg  + 16*mt + 4*g);
      float4 t4 = *(const float4*)(mbt + 16*mt + 4*g);
      float mn = (mt<2)? tm0 : tm1;
      float rs = (mt<2)? tr0 : tr1;
      #pragma unroll
      for(int nt=0;nt<4;nt++){
        int pl = 16*nt + m_;
        f32x4 t = acc[mt][nt];
        float v0 = gelu_f((t[0]-mn)*rs*g4.x + t4.x);
        float v1 = gelu_f((t[1]-mn)*rs*g4.y + t4.y);
        float v2 = gelu_f((t[2]-mn)*rs*g4.z + t4.z);
        float v3 = gelu_f((t[3]-mn)*rs*g4.w + t4.w);
        uint2 pk;
        pk.x = (unsigned)f2bu(v0) | ((unsigned)f2bu(v1)<<16);
        pk.y = (unsigned)f2bu(v2) | ((unsigned)f2bu(v3)<<16);
        *(uint2*)&vlds[wid][pl][16*mt+4*g] = pk;
      }
    }
  }
  __syncthreads();
  #pragma unroll
  for(int mt=0;mt<4;mt++){
    #pragma unroll
    for(int kh=0;kh<2;kh++)
      af[mt][kh]=*(const s8v*)(wpw + (mt*2+kh)*512 + l*8);
    float4 b4 = *(const float4*)(wbk + 16*mt + 4*g);
    #pragma unroll
    for(int nt=0;nt<4;nt++) acc[mt][nt]=f32x4{b4.x,b4.y,b4.z,b4.w};
  }
  #pragma unroll
  for(int nt=0;nt<4;nt++){
    int p = p0 + 16*nt + m_;
    int pc = p<NPIX? p : NPIX-1;
    const s8v* xb = (const s8v*)(ab + (size_t)pc*64);
    s8v b0 = xb[g], b1 = xb[4+g];
    #pragma unroll
    for(int mt=0;mt<4;mt++){
      acc[mt][nt]=__builtin_amdgcn_mfma_f32_16x16x32_bf16(af[mt][0],b0,acc[mt][nt],0,0,0);
      acc[mt][nt]=__builtin_amdgcn_mfma_f32_16x16x32_bf16(af[mt][1],b1,acc[mt][nt],0,0,0);
    }
  }
  {
    float um0=ustat[b*4],ur0=ustat[b*4+1],um1=ustat[b*4+2],ur1=ustat[b*4+3];
    #pragma unroll
    for(int mt=0;mt<4;mt++){
      float4 n4 = *(const float4*)(ng  + 16*mt + 4*g);
      float4 nb4= *(const float4*)(nb  + 16*mt + 4*g);
      float4 m24= *(const float4*)(m2b + 16*mt + 4*g);
      float mn = (mt<2)? um0 : um1;
      float rs = (mt<2)? ur0 : ur1;
      #pragma unroll
      for(int nt=0;nt<4;nt++){
        f32x4 u = acc[mt][nt];
        u[0] = m24.x + (u[0]-mn)*rs*n4.x + nb4.x;
        u[1] = m24.y + (u[1]-mn)*rs*n4.y + nb4.y;
        u[2] = m24.z + (u[2]-mn)*rs*n4.z + nb4.z;
        u[3] = m24.w + (u[3]-mn)*rs*n4.w + nb4.w;
        acc[mt][nt]=u;
      }
    }
  }
  #pragma unroll
  for(int mt=0;mt<4;mt++){
    #pragma unroll
    for(int kh=0;kh<2;kh++)
      af[mt][kh]=*(const s8v*)(wp2 + (mt*2+kh)*512 + l*8);
  }
  #pragma unroll
  for(int nt=0;nt<4;nt++){
    int pl = 16*nt + m_;
    const s8v* vp = (const s8v*)&vlds[wid][pl][0];
    s8v b0 = vp[g], b1 = vp[4+g];
    #pragma unroll
    for(int mt=0;mt<4;mt++){
      acc[mt][nt]=__builtin_amdgcn_mfma_f32_16x16x32_bf16(af[mt][0],b0,acc[mt][nt],0,0,0);
      acc[mt][nt]=__builtin_amdgcn_mfma_f32_16x16x32_bf16(af[mt][1],b1,acc[mt][nt],0,0,0);
    }
  }
  #pragma unroll
  for(int nt=0;nt<4;nt++){
    int p = p0 + 16*nt + m_;
    if(p>=NPIX) continue;
    bf16* dp = A + ((size_t)b*NPIX + p)*64;
    #pragma unroll
    for(int mt=0;mt<4;mt++){
      f32x4 h = acc[mt][nt];
      float h0=h[0],h1=h[1],h2=h[2],h3=h[3];
      if(!last){ h0=gelu_f(h0); h1=gelu_f(h1); h2=gelu_f(h2); h3=gelu_f(h3); }
      uint2 pk;
      pk.x = (unsigned)f2bu(h0) | ((unsigned)f2bu(h1)<<16);
      pk.y = (unsigned)f2bu(h2) | ((unsigned)f2bu(h3)<<16);
      *(uint2*)(dp + 16*mt + 4*g) = pk;
    }
  }
}

// Head: block stages 256 px of A-crop into LDS once; wave = one oc chunk; LDS reduce.
__global__ void __launch_bounds__(256) k_qout(const bf16* __restrict__ A,
    const unsigned short* __restrict__ qpack, const float* __restrict__ q1b,
    const float* __restrict__ qg, const float* __restrict__ qbt,
    const float* __restrict__ q2w, const float* __restrict__ q2b,
    const float* __restrict__ qstat, float* __restrict__ out){
  __shared__ unsigned short xq[256][72];
  __shared__ float part[4][256];
  int tid=threadIdx.x;
  int wid=tid>>6, l=tid&63;
  int m_=l&15, g=l>>4;
  int b=blockIdx.y;
  int px0=blockIdx.x*256;
  {
    int p = px0 + tid;
    int hh=p/SS, ww2=p-hh*SS;
    const uint4* src=(const uint4*)(A + (((size_t)b*NPIX) + (size_t)hh*NN + ww2)*64);
    uint4* drow=(uint4*)&xq[tid][0];
    #pragma unroll
    for(int i=0;i<8;i++) drow[i]=src[i];
  }
  __syncthreads();
  int oc=wid;
  const unsigned short* wp = qpack + (size_t)oc*4096;
  s8v af[4][2];
  f32x4 bi4[4];
  float4 g4[4], t4[4], w4[4];
  #pragma unroll
  for(int mt=0;mt<4;mt++){
    #pragma unroll
    for(int kh=0;kh<2;kh++)
      af[mt][kh]=*(const s8v*)(wp + (mt*2+kh)*512 + l*8);
    float4 b4=*(const float4*)(q1b + 64*oc + 16*mt + 4*g);
    bi4[mt]=f32x4{b4.x,b4.y,b4.z,b4.w};
    g4[mt]=*(const float4*)(qg  + 64*oc + 16*mt + 4*g);
    t4[mt]=*(const float4*)(qbt + 64*oc + 16*mt + 4*g);
    w4[mt]=*(const float4*)(q2w + 64*oc + 16*mt + 4*g);
  }
  float m0=qstat[b*4],r0=qstat[b*4+1],m1=qstat[b*4+2],r1=qstat[b*4+3];
  float mn=(oc<2)?m0:m1, rs=(oc<2)?r0:r1;
  #pragma unroll
  for(int nt=0;nt<16;nt++){
    const s8v* vp = (const s8v*)&xq[16*nt+m_][0];
    s8v b0=vp[g], b1=vp[4+g];
    f32x4 acc[4];
    #pragma unroll
    for(int mt=0;mt<4;mt++) acc[mt]=bi4[mt];
    #pragma unroll
    for(int mt=0;mt<4;mt++){
      acc[mt]=__builtin_amdgcn_mfma_f32_16x16x32_bf16(af[mt][0],b0,acc[mt],0,0,0);
      acc[mt]=__builtin_amdgcn_mfma_f32_16x16x32_bf16(af[mt][1],b1,acc[mt],0,0,0);
    }
    float pp=0.f;
    #pragma unroll
    for(int mt=0;mt<4;mt++){
      f32x4 t=acc[mt];
      pp += gelu_f((t[0]-mn)*rs*g4[mt].x + t4[mt].x)*w4[mt].x;
      pp += gelu_f((t[1]-mn)*rs*g4[mt].y + t4[mt].y)*w4[mt].y;
      pp += gelu_f((t[2]-mn)*rs*g4[mt].z + t4[mt].z)*w4[mt].z;
      pp += gelu_f((t[3]-mn)*rs*g4[mt].w + t4[mt].w)*w4[mt].w;
    }
    pp += __shfl_xor(pp,16,64);
    pp += __shfl_xor(pp,32,64);
    if(g==0) part[wid][16*nt+m_]=pp;
  }
  __syncthreads();
  out[(size_t)b*QPIX + px0 + tid] =
      q2b[0] + part[0][tid]+part[1][tid]+part[2][tid]+part[3][tid];
}

extern "C" void kernel_launch(void* const* d_in, const int* in_sizes, int n_in,
                              void* d_out, int out_size, void* d_ws, size_t ws_size,
                              hipStream_t stream){
  const float* x   = (const float*)d_in[0];
  const float* Wp  = (const float*)d_in[1];
  const float* bp  = (const float*)d_in[2];
  const float* sw1 = (const float*)d_in[3];
  const float* sw2 = (const float*)d_in[4];
  const float* m1w = (const float*)d_in[5];
  const float* m1b = (const float*)d_in[6];
  const float* mg  = (const float*)d_in[7];
  const float* mbt = (const float*)d_in[8];
  const float* m2w = (const float*)d_in[9];
  const float* m2b = (const float*)d_in[10];
  const float* ww  = (const float*)d_in[11];
  const float* wb  = (const float*)d_in[12];
  const float* ng  = (const float*)d_in[13];
  const float* nb  = (const float*)d_in[14];
  const float* q1w = (const float*)d_in[15];
  const float* q1b = (const float*)d_in[16];
  const float* qg  = (const float*)d_in[17];
  const float* qbt = (const float*)d_in[18];
  const float* q2w = (const float*)d_in[19];
  const float* q2b = (const float*)d_in[20];
  float* out = (float*)d_out;

  char* w8 = (char*)d_ws;
  const size_t ACT_B = (size_t)64*BB*NPIX*sizeof(bf16);   // 41,370,624
  bf16*  A    = (bf16*)(w8);
  bf16*  Cb   = (bf16*)(w8 + ACT_B);
  float* SPEC = (float*)(w8 + 2*ACT_B);                    // XW / WT / Gpart overlays
  float* XF   = (float*)(w8 + 2*ACT_B + 9879552);
  float* XO   = (float*)(w8 + 2*ACT_B + 9879552 + 1179648);
  float* TB   = (float*)(w8 + 2*ACT_B + 9879552 + 2*1179648);
  char*  g8   = w8 + 2*ACT_B + 9879552 + 2*1179648 + 20992;
  float* TSTAT= (float*)g8;
  float* USTAT= TSTAT + 32;
  float* QSTAT= USTAT + 32;
  float* UxT  = QSTAT + 32;                  // 192*64
  float* UyT  = UxT + 12288;                 // 192*64
  unsigned short* WPK = (unsigned short*)(UyT + 12288);   // 16*4096 bf16
  float* GC   = (float*)(WPK + 16*4096);     // 8*4096 (Parseval gram)
  float* SC   = GC + 8*4096;                 // 8*64
  float* Gpart = SPEC;                       // overlays SPEC+XF (dead at gram time)
  float* Spart = Gpart + (size_t)16*GNB*4096;
  float* WT = SPEC;                          // 288*8192 floats = 9.44MB
  size_t needed = (size_t)(2*ACT_B) + 9879552 + 2*1179648 + 20992
                + 3*32*4 + 2*12288*4 + 16*4096*2 + (8*4096+8*64)*4;
  if(ws_size < needed) return;

  k_tab<<<11,256,0,stream>>>(TB);
  k_pretab<<<dim3(192,2),64,0,stream>>>(Wp, bp, UxT, UyT);
  k_wpack<<<16,256,0,stream>>>(m1w, m2w, ww, q1w, WPK);
  k_encoder<<<dim3(158,BB),256,0,stream>>>(x, Wp, UxT, UyT, A);

  for(int l=0;l<4;l++){
    const float* sw1l = sw1 + (size_t)l*1179648;
    const float* sw2l = sw2 + (size_t)l*1179648;
    k_dftw<<<402,256,0,stream>>>(A, TB, SPEC);
    k_dfth<<<dim3(12,BB,4),256,0,stream>>>(SPEC, TB, XF);
    k_wtrans<<<dim3(64,5,2),256,0,stream>>>(sw1l, sw2l, WT);
    k_modemix<<<288,512,0,stream>>>(XF, WT, XO);
    k_ispec<<<1608,256,0,stream>>>(XO, TB, Cb);
    k_gramC<<<BB,256,0,stream>>>(XO, GC, SC);
    k_gramp<<<dim3(GNB,BB,1),256,0,stream>>>(A, A, Gpart, Spart, NN, NN);
    k_statsA<<<16,256,0,stream>>>(GC, SC, Gpart, Spart,
          m1w + (size_t)l*4096, m1b + l*64, ww + (size_t)l*4096, wb + l*64,
          TSTAT, USTAT, GNB);
    k_fuse<<<dim3(158,BB),256,0,stream>>>(Cb, A,
          WPK + (size_t)(l*3+0)*4096, m1b + l*64, mg + l*64, mbt + l*64,
          WPK + (size_t)(l*3+1)*4096, m2b + l*64,
          WPK + (size_t)(l*3+2)*4096, wb  + l*64, ng + l*64, nb + l*64,
          TSTAT, USTAT, (l==3)?1:0);
  }

  k_gramp<<<dim3(36,BB,1),256,0,stream>>>(A, A, Gpart, Spart, SS, SS);
  k_statsQ<<<BB,256,0,stream>>>(Gpart, Spart, q1w, q1b, QSTAT, 36);
  k_qout<<<dim3(144,BB),256,0,stream>>>(A, WPK + (size_t)12*4096, q1b,
          qg, qbt, q2w, q2b, QSTAT, out);
}

// Round 11
// 1389.943 us; speedup vs baseline: 1.5843x; 1.0967x over previous
//
#include <hip/hip_runtime.h>
#include <hip/hip_bf16.h>
#include <math.h>

// FNO2d: B=8, S=192, pad->201x201, C=64, modes 12x12, 4 layers.
// Pixel-major activations [b][p][c]; MFMA conv GEMMs; Parseval Gram for spectral
// branch; float register-tile Gram for bypass; fast sigmoid-gelu; ILP-split DFTs.

#define NN 201
#define SS 192
#define NPIX 40401
#define QPIX 36864
#define BB 8
#define GNB 40           // gram slabs per (z,b), 1024 px each
#define XWPL 1234944     // 1608*12*64 (re/im plane stride in floats)
#define PI_F 3.14159265358979323846f

typedef __hip_bfloat16 bf16;
typedef __attribute__((ext_vector_type(8))) short s8v;
typedef __attribute__((ext_vector_type(4))) float f32x4;

// tanh-form gelu via sigmoid: x*sigma(1.5957691x + 0.0713548x^3); |err| <= ~1e-3
__device__ __forceinline__ float gelu_f(float x){
  float x2 = x*x;
  float t  = fmaf(x2, 0.0713548162f, 1.5957691216f);
  float e  = __expf(-x*t);
  return x*__builtin_amdgcn_rcpf(1.0f+e);
}
__device__ __forceinline__ float b2f(bf16 v){ return __bfloat162float(v); }
__device__ __forceinline__ bf16  f2b(float v){ return __float2bfloat16(v); }
__device__ __forceinline__ unsigned short f2bu(float x){
  bf16 h = __float2bfloat16(x);
  unsigned short u; __builtin_memcpy(&u,&h,2); return u;
}
__device__ __forceinline__ float bu2f(unsigned short u){
  unsigned int x = ((unsigned int)u)<<16; float f; __builtin_memcpy(&f,&x,4); return f;
}

// tab[k][n]: cos/sin(2*pi*k*n/201), k=0..12, exact mod-201 reduction
__global__ void k_tab(float* __restrict__ tab){
  int t = blockIdx.x*blockDim.x+threadIdx.x;
  if(t>=13*NN) return;
  int k=t/NN, n=t-k*NN;
  int m=(k*n)%NN;
  float ang = (2.0f*PI_F/201.0f)*(float)m;
  tab[2*t]   = cosf(ang);
  tab[2*t+1] = sinf(ang);
}

// Separable encoder tables. grid (192,2), 64 thr.
__global__ void k_pretab(const float* __restrict__ Wp, const float* __restrict__ bp,
                         float* __restrict__ Ux, float* __restrict__ Uy){
  int i = blockIdx.x;
  int ax = blockIdx.y;
  int c = threadIdx.x;
  float g = (float)i*(1.0f/191.0f);
  float acc;
  if(ax==0) acc = bp[c] + g*Wp[64+c];
  else      acc = g*Wp[128+c];
  int cosBase = (ax==0)? 3 : 4;
  int sinBase = (ax==0)? 23 : 24;
  #pragma unroll
  for(int l=0;l<10;l++){
    float f = PI_F*(float)(1<<l);
    float sv,cv;
    sincosf(g*f,&sv,&cv);
    acc += cv*Wp[(cosBase+2*l)*64+c] + sv*Wp[(sinBase+2*l)*64+c];
  }
  float* U = (ax==0)? Ux : Uy;
  U[i*64+c] = acc;
}

// Pack 16 64x64 weight matrices into bf16 MFMA-fragment order.
__global__ void k_wpack(const float* __restrict__ m1w, const float* __restrict__ m2w,
                        const float* __restrict__ ww,  const float* __restrict__ q1w,
                        unsigned short* __restrict__ WPK){
  int bx = blockIdx.x, tid = threadIdx.x;
  const float* src;
  if(bx<12){
    int l=bx/3, sel=bx-l*3;
    src = (sel==0)? m1w+(size_t)l*4096 : (sel==1)? m2w+(size_t)l*4096 : ww+(size_t)l*4096;
  } else {
    src = q1w + (size_t)(bx-12)*4096;
  }
  unsigned short* dst = WPK + (size_t)bx*4096;
  #pragma unroll
  for(int t=0;t<16;t++){
    int d = tid*16+t;
    int frag=d>>9, lane=(d>>3)&63, j=d&7;
    int mt=frag>>1, kh=frag&1, m_=lane&15, g=lane>>4;
    dst[d] = f2bu(src[(size_t)(16*mt+m_)*64 + 32*kh + 8*g + j]);
  }
}

// Transpose spectral weights for layer into WT[m][comp][io].
__global__ void __launch_bounds__(256) k_wtrans(const float* __restrict__ w1,
        const float* __restrict__ w2, float* __restrict__ WT){
  __shared__ float tile[64][65];
  int io0 = blockIdx.x*64;
  int c0  = blockIdx.y*64;
  int z   = blockIdx.z;
  const float* src = (z==0)? w1 : w2;
  int tid = threadIdx.x;
  #pragma unroll
  for(int it=0;it<16;it++){
    int e = tid + 256*it;
    int r = e>>6, c = e&63;
    if(c0+c<288) tile[r][c] = src[(size_t)(io0+r)*288 + c0 + c];
  }
  __syncthreads();
  #pragma unroll
  for(int it=0;it<16;it++){
    int e = tid + 256*it;
    int rp = e>>6, cp = e&63;
    int col = c0 + rp;
    if(col<288){
      int ky = col/24, rm = col - ky*24;
      int kx = rm>>1, comp = rm&1;
      int m = z*144 + ky*12 + kx;
      WT[(size_t)m*8192 + comp*4096 + io0 + cp] = tile[cp][rp];
    }
  }
}

// encoder: A[b][p][c] = x*Wp0[c] + Ux[hh][c] + Uy[ww][c]; zeros in pad.
__global__ void k_encoder(const float* __restrict__ x, const float* __restrict__ Wp,
                          const float* __restrict__ Ux, const float* __restrict__ Uy,
                          bf16* __restrict__ A){
  int tid=threadIdx.x;
  int p = blockIdx.x*256+tid;
  if(p>=NPIX) return;
  int b = blockIdx.y;
  uint4* dst = (uint4*)(A + ((size_t)b*NPIX + p)*64);
  int hh=p/NN, ww=p-hh*NN;
  if(hh>=SS || ww>=SS){
    uint4 z = {0,0,0,0};
    #pragma unroll
    for(int i=0;i<8;i++) dst[i]=z;
    return;
  }
  float xv = x[((size_t)b*SS+hh)*SS+ww];
  const float4* ux = (const float4*)(Ux + hh*64);
  const float4* uy = (const float4*)(Uy + ww*64);
  const float4* w0 = (const float4*)Wp;
  #pragma unroll
  for(int i=0;i<8;i++){
    float4 a0 = ux[2*i],   a1 = ux[2*i+1];
    float4 b0 = uy[2*i],   b1 = uy[2*i+1];
    float4 c0 = w0[2*i],   c1 = w0[2*i+1];
    float v0=xv*c0.x+a0.x+b0.x, v1=xv*c0.y+a0.y+b0.y;
    float v2=xv*c0.z+a0.z+b0.z, v3=xv*c0.w+a0.w+b0.w;
    float v4=xv*c1.x+a1.x+b1.x, v5=xv*c1.y+a1.y+b1.y;
    float v6=xv*c1.z+a1.z+b1.z, v7=xv*c1.w+a1.w+b1.w;
    uint4 v;
    v.x = (unsigned)f2bu(v0) | ((unsigned)f2bu(v1)<<16);
    v.y = (unsigned)f2bu(v2) | ((unsigned)f2bu(v3)<<16);
    v.z = (unsigned)f2bu(v4) | ((unsigned)f2bu(v5)<<16);
    v.w = (unsigned)f2bu(v6) | ((unsigned)f2bu(v7)<<16);
    dst[i]=v;
  }
}

// DFT along W. Wave per row R=b*201+h, lane=c. XW[re/im][R][kx][c].
__global__ void __launch_bounds__(256) k_dftw(const bf16* __restrict__ A,
        const float* __restrict__ tab, float* __restrict__ XW){
  __shared__ float2 st[2412];
  int tid=threadIdx.x;
  for(int i=tid;i<2412;i+=256) st[i]=((const float2*)tab)[i];
  __syncthreads();
  int R = blockIdx.x*4 + (tid>>6);
  int l = tid&63;
  const bf16* base = A + ((size_t)R*NN)*64 + l;
  float ar0=0.f;
  float ar[11], ai[11];
  #pragma unroll
  for(int k=0;k<11;k++){ ar[k]=0.f; ai[k]=0.f; }
  for(int w=0;w<NN;w++){
    float a = b2f(base[(size_t)w*64]);
    ar0 += a;
    #pragma unroll
    for(int k=0;k<11;k++){
      float2 cs = st[(k+1)*NN+w];
      ar[k] += a*cs.x;
      ai[k] += a*cs.y;
    }
  }
  float* xre = XW + ((size_t)R*12)*64 + l;
  float* xim = xre + XWPL;
  xre[0]=ar0; xim[0]=0.f;
  #pragma unroll
  for(int k=0;k<11;k++){
    xre[(size_t)(k+1)*64] = ar[k];
    xim[(size_t)(k+1)*64] = -ai[k];
  }
}

// DFT along H, LDS-staged: grid (12, 8, 4); z = (jhalf<<1)|chalf.
// ILP: h unrolled x2 with split accumulators.
__global__ void __launch_bounds__(256) k_dfth(const float* __restrict__ XW,
        const float* __restrict__ tab, float* __restrict__ XF){
  __shared__ float sre[201*32];
  __shared__ float sim[201*32];
  __shared__ float2 tw[13*NN];
  int kx=blockIdx.x, b=blockIdx.y;
  int z=blockIdx.z; int jh=z>>1, ch=z&1;
  int tid=threadIdx.x;
  for(int i=tid;i<13*NN;i+=256) tw[i]=((const float2*)tab)[i];
  for(int i=tid;i<201*32;i+=256){
    int h=i>>5, c=ch*32+(i&31);
    size_t idx=(((size_t)b*NN+h)*12+kx)*64+c;
    sre[i]=XW[idx];
    sim[i]=XW[idx+XWPL];
  }
  __syncthreads();
  for(int o=tid;o<384;o+=256){
    int jj=o>>5, cl=o&31;
    int j=jh*12+jj;
    int k2=(j<12)?j:24-j;
    float sgn=(j<12)?-1.f:1.f;
    float re0=0.f,im0=0.f,re1=0.f,im1=0.f;
    const float* pr=sre+cl;
    const float* pi=sim+cl;
    const float2* tk=tw+k2*NN;
    int h=0;
    for(;h+1<NN;h+=2){
      float a0=pr[h*32], b0=pi[h*32];
      float2 cs0=tk[h];
      float c0=cs0.x, s0=sgn*cs0.y;
      re0 = fmaf(a0,c0, fmaf(-b0,s0, re0));
      im0 = fmaf(a0,s0, fmaf( b0,c0, im0));
      float a1=pr[(h+1)*32], b1=pi[(h+1)*32];
      float2 cs1=tk[h+1];
      float c1=cs1.x, s1=sgn*cs1.y;
      re1 = fmaf(a1,c1, fmaf(-b1,s1, re1));
      im1 = fmaf(a1,s1, fmaf( b1,c1, im1));
    }
    {
      float a0=pr[h*32], b0=pi[h*32];
      float2 cs0=tk[h];
      float c0=cs0.x, s0=sgn*cs0.y;
      re0 = fmaf(a0,c0, fmaf(-b0,s0, re0));
      im0 = fmaf(a0,s0, fmaf( b0,c0, im0));
    }
    int m=j*12+kx;
    int c=ch*32+cl;
    XF[(size_t)m*1024+(b*64+c)*2]  =re0+re1;
    XF[(size_t)m*1024+(b*64+c)*2+1]=im0+im1;
  }
}

// per-mode 64x64 complex mix; ILP split accumulators.
__global__ void __launch_bounds__(512) k_modemix(const float* __restrict__ XF,
     const float* __restrict__ WT, float* __restrict__ XO){
  __shared__ float sx[1024];
  __shared__ float swr[4096], swi[4096];
  int m=blockIdx.x;
  int tid=threadIdx.x;
  sx[tid]     = XF[(size_t)m*1024+tid];
  sx[tid+512] = XF[(size_t)m*1024+tid+512];
  const float* wr = WT + (size_t)m*8192;
  const float* wi = wr + 4096;
  for(int io=tid;io<4096;io+=512){
    swr[io]=wr[io];
    swi[io]=wi[io];
  }
  __syncthreads();
  int b=tid>>6, o=tid&63;
  const float* xb = sx + b*128;
  float re0=0.f,re1=0.f,im0=0.f,im1=0.f;
  #pragma unroll 8
  for(int i=0;i<64;i+=2){
    float a=xb[2*i], b2=xb[2*i+1];
    float c=swr[i*64+o], d=swi[i*64+o];
    re0 = fmaf(a,c, fmaf(-b2,d, re0));
    im0 = fmaf(a,d, fmaf( b2,c, im0));
    float a1=xb[2*i+2], b3=xb[2*i+3];
    float c1=swr[(i+1)*64+o], d1=swi[(i+1)*64+o];
    re1 = fmaf(a1,c1, fmaf(-b3,d1, re1));
    im1 = fmaf(a1,d1, fmaf( b3,c1, im1));
  }
  XO[2*((size_t)m*512+tid)]  =re0+re1;
  XO[2*((size_t)m*512+tid)+1]=im0+im1;
}

// Merged inverse: per row R, idfth into LDS (scale + conj-sym factors folded),
// then C2R along W with 4 partial accumulators. C[b][p][o] bf16.
__global__ void __launch_bounds__(256) k_ispec(const float* __restrict__ XO,
        const float* __restrict__ tab, bf16* __restrict__ C){
  __shared__ float2 st[2412];
  __shared__ float2 yl[12][64];
  __shared__ float2 cs13[13];
  int R=blockIdx.x;
  int b=R/NN, h=R-b*NN;
  int tid=threadIdx.x;
  for(int i=tid;i<2412;i+=256) st[i]=((const float2*)tab)[i];
  if(tid<13) cs13[tid]=((const float2*)tab)[tid*NN+h];
  __syncthreads();
  const float sc = 1.0f/40401.0f;
  #pragma unroll
  for(int it=0;it<3;it++){
    int item = tid + 256*it;
    int kx = item>>6, o = item&63;
    float re0=0.f,im0=0.f,re1=0.f,im1=0.f;
    #pragma unroll
    for(int j=0;j<24;j+=2){
      {
        int k2=(j<12)?j:24-j;
        float sgn=(j<12)?1.0f:-1.0f;
        float2 xo = *(const float2*)(XO + 2*(((size_t)(j*12+kx)*512) + b*64 + o));
        float2 cs = cs13[k2];
        float cc=cs.x, s2=sgn*cs.y;
        re0 = fmaf(xo.x,cc, fmaf(-xo.y,s2, re0));
        im0 = fmaf(xo.x,s2, fmaf( xo.y,cc, im0));
      }
      {
        int j1=j+1;
        int k2=(j1<12)?j1:24-j1;
        float sgn=(j1<12)?1.0f:-1.0f;
        float2 xo = *(const float2*)(XO + 2*(((size_t)(j1*12+kx)*512) + b*64 + o));
        float2 cs = cs13[k2];
        float cc=cs.x, s2=sgn*cs.y;
        re1 = fmaf(xo.x,cc, fmaf(-xo.y,s2, re1));
        im1 = fmaf(xo.x,s2, fmaf( xo.y,cc, im1));
      }
    }
    // fold 1/N^2 and the C2R conjugate-symmetry factor (2 for kx>=1, sign for im)
    float fr = (kx==0)? sc : 2.0f*sc;
    float fi = (kx==0)? sc : -2.0f*sc;
    yl[kx][o] = float2{ (re0+re1)*fr, (im0+im1)*fi };
  }
  __syncthreads();
  int o = tid&63, wq = tid>>6;
  float yr[12], yi[12];
  #pragma unroll
  for(int k=0;k<12;k++){
    float2 v = yl[k][o];
    yr[k]=v.x; yi[k]=v.y;
  }
  int w0 = wq*51;
  int w1 = w0+51; if(w1>NN) w1=NN;
  bf16* cp = C + ((size_t)R*NN)*64 + o;
  for(int w=w0;w<w1;w++){
    float a0=yr[0], a1=0.f, a2=0.f, a3=0.f;
    #pragma unroll
    for(int k=1;k<12;k+=4){
      float2 c0 = st[k*NN+w];
      a0 = fmaf(yr[k], c0.x, fmaf(yi[k], c0.y, a0));
      if(k+1<12){ float2 c1 = st[(k+1)*NN+w];
        a1 = fmaf(yr[k+1], c1.x, fmaf(yi[k+1], c1.y, a1)); }
      if(k+2<12){ float2 c2 = st[(k+2)*NN+w];
        a2 = fmaf(yr[k+2], c2.x, fmaf(yi[k+2], c2.y, a2)); }
      if(k+3<12){ float2 c3 = st[(k+3)*NN+w];
        a3 = fmaf(yr[k+3], c3.x, fmaf(yi[k+3], c3.y, a3)); }
    }
    cp[(size_t)w*64] = f2b((a0+a1)+(a2+a3));
  }
}

// Parseval Gram of the spectral output Cb, computed from XO. grid = 8 (per batch).
__global__ void __launch_bounds__(256) k_gramC(const float* __restrict__ XO,
        float* __restrict__ GC, float* __restrict__ SC){
  __shared__ unsigned short V[64][584];
  int b=blockIdx.x, tid=threadIdx.x;
  const float s1=1.0f/201.0f;
  const float r2=0.70710678118f;
  const float q2=1.41421356237f;
  for(int e=tid;e<576*64;e+=256){
    int f=e>>6, ch=e&63;
    int base = b*64+ch;
    float v=0.f;
    if(f<528){
      int comp=f&1, kxm=f>>1;
      int kx0=kxm/24;
      int kx=1+kx0, m=kxm-kx0*24;
      v = q2*XO[2*((size_t)(m*12+kx)*512 + base)+comp];
    } else if(f==528){
      v = XO[2*(size_t)base];
    } else if(f<551){
      int q=f-529; int mm=1+(q>>1);
      const float* p1 = XO + 2*((size_t)(mm*12)*512 + base);
      const float* p2 = XO + 2*((size_t)((24-mm)*12)*512 + base);
      v = ((q&1)==0)? r2*(p1[0]+p2[0]) : r2*(p1[1]-p2[1]);
    } else if(f==551){
      v = r2*XO[2*((size_t)(144)*512 + base)];
    } else if(f==552){
      v = r2*XO[2*((size_t)(144)*512 + base)+1];
    }
    V[ch][f]=f2bu(v*s1);
  }
  __syncthreads();
  int wid=tid>>6, l=tid&63, m_=l&15, g=l>>4;
  f32x4 acc[4];
  #pragma unroll
  for(int mt=0;mt<4;mt++) acc[mt]=f32x4{0.f,0.f,0.f,0.f};
  #pragma unroll
  for(int kc=0;kc<18;kc++){
    s8v bfr = *(const s8v*)&V[16*wid+m_][kc*32+8*g];
    #pragma unroll
    for(int mt=0;mt<4;mt++){
      s8v afr = *(const s8v*)&V[16*mt+m_][kc*32+8*g];
      acc[mt]=__builtin_amdgcn_mfma_f32_16x16x32_bf16(afr,bfr,acc[mt],0,0,0);
    }
  }
  float* gb = GC + (size_t)b*4096;
  #pragma unroll
  for(int mt=0;mt<4;mt++){
    #pragma unroll
    for(int e=0;e<4;e++)
      gb[(size_t)(16*mt+4*g+e)*64 + 16*wid + m_] = acc[mt][e];
  }
  if(tid<64) SC[b*64+tid] = XO[2*(size_t)(b*64+tid)];
}

// Gram partials for A (float register tiles). grid (nblk, BB, 1); 1024 px/block.
__global__ void __launch_bounds__(256) k_gramp(const bf16* __restrict__ s0,
        const bf16* __restrict__ s1, float* __restrict__ Gpart,
        float* __restrict__ Spart, int HR, int WR){
  __shared__ float sx[8704];
  int b = blockIdx.y, blk = blockIdx.x, z = blockIdx.z;
  const bf16* X = (z==0)? s0 : s1;
  int zb = z*BB + b;
  int npix = HR*WR;
  int tid = threadIdx.x;
  int wid = tid>>6, lane = tid&63;
  int i0 = (lane>>3)*8, j0 = (lane&7)*8;
  float acc[8][8];
  #pragma unroll
  for(int r=0;r<8;r++){
    #pragma unroll
    for(int s=0;s<8;s++) acc[r][s]=0.f;
  }
  float cs = 0.f;
  for(int tile=0;tile<8;tile++){
    int rp0 = blk*1024 + tile*128;
    __syncthreads();
    #pragma unroll
    for(int it=0;it<4;it++){
      int chunk = tid + it*256;
      int k = chunk>>3, c0 = (chunk&7)*8;
      int rp = rp0+k;
      float v[8]={0,0,0,0,0,0,0,0};
      if(rp<npix){
        int gp;
        if(WR==NN) gp = rp;
        else { int hh=rp/WR, ww=rp-hh*WR; gp = hh*NN+ww; }
        s8v xv = *(const s8v*)(X + ((size_t)b*NPIX + gp)*64 + c0);
        #pragma unroll
        for(int j=0;j<8;j++) v[j]=bu2f((unsigned short)xv[j]);
      }
      #pragma unroll
      for(int j=0;j<8;j++) sx[k*68+c0+j]=v[j];
    }
    __syncthreads();
    for(int pp=0;pp<32;pp++){
      const float* row = sx + (wid*32+pp)*68;
      cs += row[lane];
      const float4* ri = (const float4*)(row + i0);
      const float4* rj = (const float4*)(row + j0);
      float4 xi0 = ri[0], xi1 = ri[1];
      float4 xj0 = rj[0], xj1 = rj[1];
      float xi[8] = {xi0.x,xi0.y,xi0.z,xi0.w, xi1.x,xi1.y,xi1.z,xi1.w};
      float xj[8] = {xj0.x,xj0.y,xj0.z,xj0.w, xj1.x,xj1.y,xj1.z,xj1.w};
      #pragma unroll
      for(int r=0;r<8;r++){
        #pragma unroll
        for(int s=0;s<8;s++) acc[r][s] += xi[r]*xj[s];
      }
    }
  }
  __syncthreads();
  float* scol = sx + 8320;
  scol[tid] = cs;
  if(wid>=2){
    float* d = sx + (tid-128)*65;
    #pragma unroll
    for(int r=0;r<8;r++){
      #pragma unroll
      for(int s=0;s<8;s++) d[r*8+s]=acc[r][s];
    }
  }
  __syncthreads();
  if(wid<2){
    const float* d = sx + tid*65;
    #pragma unroll
    for(int r=0;r<8;r++){
      #pragma unroll
      for(int s=0;s<8;s++) acc[r][s]+=d[r*8+s];
    }
  }
  if(tid<64){
    float tot = scol[tid]+scol[tid+64]+scol[tid+128]+scol[tid+192];
    Spart[((size_t)zb*GNB + blk)*64 + tid] = tot;
  }
  __syncthreads();
  if(wid==1){
    float* d = sx + (tid-64)*65;
    #pragma unroll
    for(int r=0;r<8;r++){
      #pragma unroll
      for(int s=0;s<8;s++) d[r*8+s]=acc[r][s];
    }
  }
  __syncthreads();
  if(wid==0){
    const float* d = sx + tid*65;
    #pragma unroll
    for(int r=0;r<8;r++){
      #pragma unroll
      for(int s=0;s<8;s++) acc[r][s]+=d[r*8+s];
    }
    float* g = Gpart + ((size_t)zb*GNB + blk)*4096;
    #pragma unroll
    for(int r=0;r<8;r++){
      #pragma unroll
      for(int s=0;s<8;s++) g[(i0+r)*64 + (j0+s)] = acc[r][s];
    }
  }
}

// Merged stats (grid 16): zb<8 -> Cb-stats from GC/SC (Parseval); zb>=8 -> A-stats.
__global__ void __launch_bounds__(256) k_statsA(
        const float* __restrict__ GC, const float* __restrict__ SC,
        const float* __restrict__ Gpart, const float* __restrict__ Spart,
        const float* __restrict__ m1wl, const float* __restrict__ m1bl,
        const float* __restrict__ wwl,  const float* __restrict__ wbl,
        float* __restrict__ TSTAT, float* __restrict__ USTAT, int nblk){
  __shared__ float Gs[4096];
  __shared__ float Ss[64];
  __shared__ float rs[256], rq[256];
  int zb=blockIdx.x, t=threadIdx.x;
  if(zb<8){
    #pragma unroll
    for(int e=0;e<16;e++) Gs[t*16+e]=GC[(size_t)zb*4096 + t*16+e];
    if(t<64) Ss[t]=SC[zb*64+t];
  } else {
    int bb=zb-8;
    float a[16];
    #pragma unroll
    for(int e=0;e<16;e++) a[e]=0.f;
    for(int k=0;k<nblk;k++){
      const float* g = Gpart + ((size_t)bb*GNB + k)*4096 + t*16;
      #pragma unroll
      for(int e=0;e<16;e++) a[e]+=g[e];
    }
    #pragma unroll
    for(int e=0;e<16;e++) Gs[t*16+e]=a[e];
    if(t<64){
      float s=0.f;
      for(int k=0;k<nblk;k++) s += Spart[((size_t)bb*GNB + k)*64 + t];
      Ss[t]=s;
    }
  }
  __syncthreads();
  const float* W    = (zb<8)? m1wl : wwl;
  const float* bias = (zb<8)? m1bl : wbl;
  float* stat       = (zb<8)? TSTAT : USTAT;
  int b = (zb<8)? zb : zb-8;
  int o = t&63, sl = t>>6;
  float w[64];
  #pragma unroll
  for(int j2=0;j2<64;j2++) w[j2]=bu2f(f2bu(W[(size_t)o*64+j2]));
  const float* Gr = Gs + (size_t)(sl*16)*64;
  float quad=0.f;
  #pragma unroll
  for(int r=0;r<16;r++){
    const float* gr = Gr + r*64;
    float tt=0.f;
    #pragma unroll
    for(int j2=0;j2<64;j2++) tt += gr[j2]*w[j2];
    quad += w[sl*16+r]*tt;
  }
  float dot=0.f;
  #pragma unroll
  for(int j2=0;j2<64;j2++) dot += w[j2]*Ss[j2];
  float bo = bias[o];
  float Nf = (float)NPIX;
  float sm = (sl==0)? (dot + Nf*bo) : 0.f;
  float sq = quad + ((sl==0)? (2.f*bo*dot + Nf*bo*bo) : 0.f);
  rs[t]=sm; rq[t]=sq;
  __syncthreads();
  if(t<64){
    float s2 = rs[t]+rs[t+64]+rs[t+128]+rs[t+192];
    float q2 = rq[t]+rq[t+64]+rq[t+128]+rq[t+192];
    for(int off=16;off>0;off>>=1){
      s2 += __shfl_down(s2,off,32);
      q2 += __shfl_down(q2,off,32);
    }
    if((t&31)==0){
      int g=t>>5;
      float invN = 1.f/(Nf*32.f);
      float mean = s2*invN;
      float var = q2*invN - mean*mean;
      stat[b*4+g*2]   = mean;
      stat[b*4+g*2+1] = rsqrtf(fmaxf(var,0.f)+1e-5f);
    }
  }
}

// Merged gram-reduce + head stats (grid 8).
__global__ void __launch_bounds__(256) k_statsQ(const float* __restrict__ Gpart,
        const float* __restrict__ Spart,
        const float* __restrict__ W, const float* __restrict__ bias,
        float* __restrict__ stat, int nblk){
  __shared__ float Gs[4096];
  __shared__ float Ss[64];
  __shared__ float red[8];
  int b=blockIdx.x, t=threadIdx.x;
  float a[16];
  #pragma unroll
  for(int e=0;e<16;e++) a[e]=0.f;
  for(int k=0;k<nblk;k++){
    const float* g = Gpart + ((size_t)b*GNB + k)*4096 + t*16;
    #pragma unroll
    for(int e=0;e<16;e++) a[e]+=g[e];
  }
  #pragma unroll
  for(int e=0;e<16;e++) Gs[t*16+e]=a[e];
  if(t<64){
    float s=0.f;
    for(int k=0;k<nblk;k++) s += Spart[((size_t)b*GNB + k)*64 + t];
    Ss[t]=s;
  }
  __syncthreads();
  float w[64];
  #pragma unroll
  for(int j2=0;j2<64;j2++) w[j2]=bu2f(f2bu(W[(size_t)t*64+j2]));
  float quad=0.f;
  #pragma unroll
  for(int i=0;i<64;i++){
    const float* gr = Gs + i*64;
    float tt=0.f;
    #pragma unroll
    for(int j2=0;j2<64;j2++) tt += gr[j2]*w[j2];
    quad += w[i]*tt;
  }
  float dot=0.f;
  #pragma unroll
  for(int j2=0;j2<64;j2++) dot += w[j2]*Ss[j2];
  float bo=bias[t];
  float Nf=(float)QPIX;
  float sm = dot + Nf*bo;
  float sq = quad + 2.f*bo*dot + Nf*bo*bo;
  for(int off=32;off>0;off>>=1){
    sm += __shfl_down(sm,off,64);
    sq += __shfl_down(sq,off,64);
  }
  int wid=t>>6;
  if((t&63)==0){ red[wid*2]=sm; red[wid*2+1]=sq; }
  __syncthreads();
  if(t<2){
    float smt = red[t*4+0]+red[t*4+2];
    float sqt = red[t*4+1]+red[t*4+3];
    float invN = 1.f/(Nf*128.f);
    float mean = smt*invN;
    float var = sqt*invN - mean*mean;
    stat[b*4+t*2]   = mean;
    stat[b*4+t*2+1] = rsqrtf(fmaxf(var,0.f)+1e-5f);
  }
}

// MFMA fused layer with packed weights.
__global__ void __launch_bounds__(256) k_fuse(const bf16* __restrict__ Cb,
    bf16* __restrict__ A,
    const unsigned short* __restrict__ wp1, const float* __restrict__ m1b,
    const float* __restrict__ mg,  const float* __restrict__ mbt,
    const unsigned short* __restrict__ wp2, const float* __restrict__ m2b,
    const unsigned short* __restrict__ wpw, const float* __restrict__ wbk,
    const float* __restrict__ ng,  const float* __restrict__ nb,
    const float* __restrict__ tstat, const float* __restrict__ ustat, int last){
  __shared__ unsigned short vlds[4][64][72];
  int tid=threadIdx.x;
  int wid=tid>>6, l=tid&63;
  int m_=l&15, g=l>>4;
  int b=blockIdx.y;
  int p0=blockIdx.x*256 + wid*64;
  const bf16* cbb = Cb + (size_t)b*NPIX*64;
  const bf16* ab  = A  + (size_t)b*NPIX*64;

  s8v af[4][2];
  f32x4 acc[4][4];

  #pragma unroll
  for(int mt=0;mt<4;mt++){
    #pragma unroll
    for(int kh=0;kh<2;kh++)
      af[mt][kh]=*(const s8v*)(wp1 + (mt*2+kh)*512 + l*8);
    float4 b4 = *(const float4*)(m1b + 16*mt + 4*g);
    #pragma unroll
    for(int nt=0;nt<4;nt++) acc[mt][nt]=f32x4{b4.x,b4.y,b4.z,b4.w};
  }
  #pragma unroll
  for(int nt=0;nt<4;nt++){
    int p = p0 + 16*nt + m_;
    int pc = p<NPIX? p : NPIX-1;
    const s8v* xb = (const s8v*)(cbb + (size_t)pc*64);
    s8v b0 = xb[g], b1 = xb[4+g];
    #pragma unroll
    for(int mt=0;mt<4;mt++){
      acc[mt][nt]=__builtin_amdgcn_mfma_f32_16x16x32_bf16(af[mt][0],b0,acc[mt][nt],0,0,0);
      acc[mt][nt]=__builtin_amdgcn_mfma_f32_16x16x32_bf16(af[mt][1],b1,acc[mt][nt],0,0,0);
    }
  }
  {
    float tm0=tstat[b*4],tr0=tstat[b*4+1],tm1=tstat[b*4+2],tr1=tstat[b*4+3];
    #pragma unroll
    for(int mt=0;mt<4;mt++){
      float4 g4 = *(const float4*)(mg  + 16*mt + 4*g);
      float4 t4 = *(const float4*)(mbt + 16*mt + 4*g);
      float mn = (mt<2)? tm0 : tm1;
      float rs = (mt<2)? tr0 : tr1;
      #pragma unroll
      for(int nt=0;nt<4;nt++){
        int pl = 16*nt + m_;
        f32x4 t = acc[mt][nt];
        float v0 = gelu_f((t[0]-mn)*rs*g4.x + t4.x);
        float v1 = gelu_f((t[1]-mn)*rs*g4.y + t4.y);
        float v2 = gelu_f((t[2]-mn)*rs*g4.z + t4.z);
        float v3 = gelu_f((t[3]-mn)*rs*g4.w + t4.w);
        uint2 pk;
        pk.x = (unsigned)f2bu(v0) | ((unsigned)f2bu(v1)<<16);
        pk.y = (unsigned)f2bu(v2) | ((unsigned)f2bu(v3)<<16);
        *(uint2*)&vlds[wid][pl][16*mt+4*g] = pk;
      }
    }
  }
  __syncthreads();
  #pragma unroll
  for(int mt=0;mt<4;mt++){
    #pragma unroll
    for(int kh=0;kh<2;kh++)
      af[mt][kh]=*(const s8v*)(wpw + (mt*2+kh)*512 + l*8);
    float4 b4 = *(const float4*)(wbk + 16*mt + 4*g);
    #pragma unroll
    for(int nt=0;nt<4;nt++) acc[mt][nt]=f32x4{b4.x,b4.y,b4.z,b4.w};
  }
  #pragma unroll
  for(int nt=0;nt<4;nt++){
    int p = p0 + 16*nt + m_;
    int pc = p<NPIX? p : NPIX-1;
    const s8v* xb = (const s8v*)(ab + (size_t)pc*64);
    s8v b0 = xb[g], b1 = xb[4+g];
    #pragma unroll
    for(int mt=0;mt<4;mt++){
      acc[mt][nt]=__builtin_amdgcn_mfma_f32_16x16x32_bf16(af[mt][0],b0,acc[mt][nt],0,0,0);
      acc[mt][nt]=__builtin_amdgcn_mfma_f32_16x16x32_bf16(af[mt][1],b1,acc[mt][nt],0,0,0);
    }
  }
  {
    float um0=ustat[b*4],ur0=ustat[b*4+1],um1=ustat[b*4+2],ur1=ustat[b*4+3];
    #pragma unroll
    for(int mt=0;mt<4;mt++){
      float4 n4 = *(const float4*)(ng  + 16*mt + 4*g);
      float4 nb4= *(const float4*)(nb  + 16*mt + 4*g);
      float4 m24= *(const float4*)(m2b + 16*mt + 4*g);
      float mn = (mt<2)? um0 : um1;
      float rs = (mt<2)? ur0 : ur1;
      #pragma unroll
      for(int nt=0;nt<4;nt++){
        f32x4 u = acc[mt][nt];
        u[0] = m24.x + (u[0]-mn)*rs*n4.x + nb4.x;
        u[1] = m24.y + (u[1]-mn)*rs*n4.y + nb4.y;
        u[2] = m24.z + (u[2]-mn)*rs*n4.z + nb4.z;
        u[3] = m24.w + (u[3]-mn)*rs*n4.w + nb4.w;
        acc[mt][nt]=u;
      }
    }
  }
  #pragma unroll
  for(int mt=0;mt<4;mt++){
    #pragma unroll
    for(int kh=0;kh<2;kh++)
      af[mt][kh]=*(const s8v*)(wp2 + (mt*2+kh)*512 + l*8);
  }
  #pragma unroll
  for(int nt=0;nt<4;nt++){
    int pl = 16*nt + m_;
    const s8v* vp = (const s8v*)&vlds[wid][pl][0];
    s8v b0 = vp[g], b1 = vp[4+g];
    #pragma unroll
    for(int mt=0;mt<4;mt++){
      acc[mt][nt]=__builtin_amdgcn_mfma_f32_16x16x32_bf16(af[mt][0],b0,acc[mt][nt],0,0,0);
      acc[mt][nt]=__builtin_amdgcn_mfma_f32_16x16x32_bf16(af[mt][1],b1,acc[mt][nt],0,0,0);
    }
  }
  #pragma unroll
  for(int nt=0;nt<4;nt++){
    int p = p0 + 16*nt + m_;
    if(p>=NPIX) continue;
    bf16* dp = A + ((size_t)b*NPIX + p)*64;
    #pragma unroll
    for(int mt=0;mt<4;mt++){
      f32x4 h = acc[mt][nt];
      float h0=h[0],h1=h[1],h2=h[2],h3=h[3];
      if(!last){ h0=gelu_f(h0); h1=gelu_f(h1); h2=gelu_f(h2); h3=gelu_f(h3); }
      uint2 pk;
      pk.x = (unsigned)f2bu(h0) | ((unsigned)f2bu(h1)<<16);
      pk.y = (unsigned)f2bu(h2) | ((unsigned)f2bu(h3)<<16);
      *(uint2*)(dp + 16*mt + 4*g) = pk;
    }
  }
}

// Head: block stages 256 px of A-crop into LDS once; wave = one oc chunk; LDS reduce.
__global__ void __launch_bounds__(256) k_qout(const bf16* __restrict__ A,
    const unsigned short* __restrict__ qpack, const float* __restrict__ q1b,
    const float* __restrict__ qg, const float* __restrict__ qbt,
    const float* __restrict__ q2w, const float* __restrict__ q2b,
    const float* __restrict__ qstat, float* __restrict__ out){
  __shared__ unsigned short xq[256][72];
  __shared__ float part[4][256];
  int tid=threadIdx.x;
  int wid=tid>>6, l=tid&63;
  int m_=l&15, g=l>>4;
  int b=blockIdx.y;
  int px0=blockIdx.x*256;
  {
    int p = px0 + tid;
    int hh=p/SS, ww2=p-hh*SS;
    const uint4* src=(const uint4*)(A + (((size_t)b*NPIX) + (size_t)hh*NN + ww2)*64);
    uint4* drow=(uint4*)&xq[tid][0];
    #pragma unroll
    for(int i=0;i<8;i++) drow[i]=src[i];
  }
  __syncthreads();
  int oc=wid;
  const unsigned short* wp = qpack + (size_t)oc*4096;
  s8v af[4][2];
  f32x4 bi4[4];
  float4 g4[4], t4[4], w4[4];
  #pragma unroll
  for(int mt=0;mt<4;mt++){
    #pragma unroll
    for(int kh=0;kh<2;kh++)
      af[mt][kh]=*(const s8v*)(wp + (mt*2+kh)*512 + l*8);
    float4 b4=*(const float4*)(q1b + 64*oc + 16*mt + 4*g);
    bi4[mt]=f32x4{b4.x,b4.y,b4.z,b4.w};
    g4[mt]=*(const float4*)(qg  + 64*oc + 16*mt + 4*g);
    t4[mt]=*(const float4*)(qbt + 64*oc + 16*mt + 4*g);
    w4[mt]=*(const float4*)(q2w + 64*oc + 16*mt + 4*g);
  }
  float m0=qstat[b*4],r0=qstat[b*4+1],m1=qstat[b*4+2],r1=qstat[b*4+3];
  float mn=(oc<2)?m0:m1, rs=(oc<2)?r0:r1;
  #pragma unroll
  for(int nt=0;nt<16;nt++){
    const s8v* vp = (const s8v*)&xq[16*nt+m_][0];
    s8v b0=vp[g], b1=vp[4+g];
    f32x4 acc[4];
    #pragma unroll
    for(int mt=0;mt<4;mt++) acc[mt]=bi4[mt];
    #pragma unroll
    for(int mt=0;mt<4;mt++){
      acc[mt]=__builtin_amdgcn_mfma_f32_16x16x32_bf16(af[mt][0],b0,acc[mt],0,0,0);
      acc[mt]=__builtin_amdgcn_mfma_f32_16x16x32_bf16(af[mt][1],b1,acc[mt],0,0,0);
    }
    float pp=0.f;
    #pragma unroll
    for(int mt=0;mt<4;mt++){
      f32x4 t=acc[mt];
      pp += gelu_f((t[0]-mn)*rs*g4[mt].x + t4[mt].x)*w4[mt].x;
      pp += gelu_f((t[1]-mn)*rs*g4[mt].y + t4[mt].y)*w4[mt].y;
      pp += gelu_f((t[2]-mn)*rs*g4[mt].z + t4[mt].z)*w4[mt].z;
      pp += gelu_f((t[3]-mn)*rs*g4[mt].w + t4[mt].w)*w4[mt].w;
    }
    pp += __shfl_xor(pp,16,64);
    pp += __shfl_xor(pp,32,64);
    if(g==0) part[wid][16*nt+m_]=pp;
  }
  __syncthreads();
  out[(size_t)b*QPIX + px0 + tid] =
      q2b[0] + part[0][tid]+part[1][tid]+part[2][tid]+part[3][tid];
}

extern "C" void kernel_launch(void* const* d_in, const int* in_sizes, int n_in,
                              void* d_out, int out_size, void* d_ws, size_t ws_size,
                              hipStream_t stream){
  const float* x   = (const float*)d_in[0];
  const float* Wp  = (const float*)d_in[1];
  const float* bp  = (const float*)d_in[2];
  const float* sw1 = (const float*)d_in[3];
  const float* sw2 = (const float*)d_in[4];
  const float* m1w = (const float*)d_in[5];
  const float* m1b = (const float*)d_in[6];
  const float* mg  = (const float*)d_in[7];
  const float* mbt = (const float*)d_in[8];
  const float* m2w = (const float*)d_in[9];
  const float* m2b = (const float*)d_in[10];
  const float* ww  = (const float*)d_in[11];
  const float* wb  = (const float*)d_in[12];
  const float* ng  = (const float*)d_in[13];
  const float* nb  = (const float*)d_in[14];
  const float* q1w = (const float*)d_in[15];
  const float* q1b = (const float*)d_in[16];
  const float* qg  = (const float*)d_in[17];
  const float* qbt = (const float*)d_in[18];
  const float* q2w = (const float*)d_in[19];
  const float* q2b = (const float*)d_in[20];
  float* out = (float*)d_out;

  char* w8 = (char*)d_ws;
  const size_t ACT_B = (size_t)64*BB*NPIX*sizeof(bf16);   // 41,370,624
  bf16*  A    = (bf16*)(w8);
  bf16*  Cb   = (bf16*)(w8 + ACT_B);
  float* SPEC = (float*)(w8 + 2*ACT_B);                    // XW / WT / Gpart overlays
  float* XF   = (float*)(w8 + 2*ACT_B + 9879552);
  float* XO   = (float*)(w8 + 2*ACT_B + 9879552 + 1179648);
  float* TB   = (float*)(w8 + 2*ACT_B + 9879552 + 2*1179648);
  char*  g8   = w8 + 2*ACT_B + 9879552 + 2*1179648 + 20992;
  float* TSTAT= (float*)g8;
  float* USTAT= TSTAT + 32;
  float* QSTAT= USTAT + 32;
  float* UxT  = QSTAT + 32;                  // 192*64
  float* UyT  = UxT + 12288;                 // 192*64
  unsigned short* WPK = (unsigned short*)(UyT + 12288);   // 16*4096 bf16
  float* GC   = (float*)(WPK + 16*4096);     // 8*4096 (Parseval gram)
  float* SC   = GC + 8*4096;                 // 8*64
  float* Gpart = SPEC;                       // overlays SPEC+XF (dead at gram time)
  float* Spart = Gpart + (size_t)16*GNB*4096;
  float* WT = SPEC;                          // 288*8192 floats = 9.44MB
  size_t needed = (size_t)(2*ACT_B) + 9879552 + 2*1179648 + 20992
                + 3*32*4 + 2*12288*4 + 16*4096*2 + (8*4096+8*64)*4;
  if(ws_size < needed) return;

  k_tab<<<11,256,0,stream>>>(TB);
  k_pretab<<<dim3(192,2),64,0,stream>>>(Wp, bp, UxT, UyT);
  k_wpack<<<16,256,0,stream>>>(m1w, m2w, ww, q1w, WPK);
  k_encoder<<<dim3(158,BB),256,0,stream>>>(x, Wp, UxT, UyT, A);

  for(int l=0;l<4;l++){
    const float* sw1l = sw1 + (size_t)l*1179648;
    const float* sw2l = sw2 + (size_t)l*1179648;
    k_dftw<<<402,256,0,stream>>>(A, TB, SPEC);
    k_dfth<<<dim3(12,BB,4),256,0,stream>>>(SPEC, TB, XF);
    k_wtrans<<<dim3(64,5,2),256,0,stream>>>(sw1l, sw2l, WT);
    k_modemix<<<288,512,0,stream>>>(XF, WT, XO);
    k_ispec<<<1608,256,0,stream>>>(XO, TB, Cb);
    k_gramC<<<BB,256,0,stream>>>(XO, GC, SC);
    k_gramp<<<dim3(GNB,BB,1),256,0,stream>>>(A, A, Gpart, Spart, NN, NN);
    k_statsA<<<16,256,0,stream>>>(GC, SC, Gpart, Spart,
          m1w + (size_t)l*4096, m1b + l*64, ww + (size_t)l*4096, wb + l*64,
          TSTAT, USTAT, GNB);
    k_fuse<<<dim3(158,BB),256,0,stream>>>(Cb, A,
          WPK + (size_t)(l*3+0)*4096, m1b + l*64, mg + l*64, mbt + l*64,
          WPK + (size_t)(l*3+1)*4096, m2b + l*64,
          WPK + (size_t)(l*3+2)*4096, wb  + l*64, ng + l*64, nb + l*64,
          TSTAT, USTAT, (l==3)?1:0);
  }

  k_gramp<<<dim3(36,BB,1),256,0,stream>>>(A, A, Gpart, Spart, SS, SS);
  k_statsQ<<<BB,256,0,stream>>>(Gpart, Spart, q1w, q1b, QSTAT, 36);
  k_qout<<<dim3(144,BB),256,0,stream>>>(A, WPK + (size_t)12*4096, q1b,
          qg, qbt, q2w, q2b, QSTAT, out);
}

// Round 12
// 1351.412 us; speedup vs baseline: 1.6295x; 1.0285x over previous
//
#include <hip/hip_runtime.h>
#include <hip/hip_bf16.h>
#include <math.h>

// FNO2d: B=8, S=192, pad->201x201, C=64, modes 12x12, 4 layers.
// Pixel-major activations [b][p][c]; MFMA conv GEMMs; Parseval Gram for spectral
// branch; float register-tile Gram for bypass (parallel slab reduce); fast gelu.

#define NN 201
#define SS 192
#define NPIX 40401
#define QPIX 36864
#define BB 8
#define GNB 40           // gram slabs per (z,b), 1024 px each
#define XWPL 1234944     // 1608*12*64 (re/im plane stride in floats)
#define PI_F 3.14159265358979323846f

typedef __hip_bfloat16 bf16;
typedef __attribute__((ext_vector_type(8))) short s8v;
typedef __attribute__((ext_vector_type(4))) float f32x4;

// tanh-form gelu via sigmoid: x*sigma(1.5957691x + 0.0713548x^3); |err| <= ~1e-3
__device__ __forceinline__ float gelu_f(float x){
  float x2 = x*x;
  float t  = fmaf(x2, 0.0713548162f, 1.5957691216f);
  float e  = __expf(-x*t);
  return x*__builtin_amdgcn_rcpf(1.0f+e);
}
__device__ __forceinline__ float b2f(bf16 v){ return __bfloat162float(v); }
__device__ __forceinline__ bf16  f2b(float v){ return __float2bfloat16(v); }
__device__ __forceinline__ unsigned short f2bu(float x){
  bf16 h = __float2bfloat16(x);
  unsigned short u; __builtin_memcpy(&u,&h,2); return u;
}
__device__ __forceinline__ float bu2f(unsigned short u){
  unsigned int x = ((unsigned int)u)<<16; float f; __builtin_memcpy(&f,&x,4); return f;
}

// tab[k][n]: cos/sin(2*pi*k*n/201), k=0..12, exact mod-201 reduction
__global__ void k_tab(float* __restrict__ tab){
  int t = blockIdx.x*blockDim.x+threadIdx.x;
  if(t>=13*NN) return;
  int k=t/NN, n=t-k*NN;
  int m=(k*n)%NN;
  float ang = (2.0f*PI_F/201.0f)*(float)m;
  tab[2*t]   = cosf(ang);
  tab[2*t+1] = sinf(ang);
}

// Separable encoder tables. grid (192,2), 64 thr.
__global__ void k_pretab(const float* __restrict__ Wp, const float* __restrict__ bp,
                         float* __restrict__ Ux, float* __restrict__ Uy){
  int i = blockIdx.x;
  int ax = blockIdx.y;
  int c = threadIdx.x;
  float g = (float)i*(1.0f/191.0f);
  float acc;
  if(ax==0) acc = bp[c] + g*Wp[64+c];
  else      acc = g*Wp[128+c];
  int cosBase = (ax==0)? 3 : 4;
  int sinBase = (ax==0)? 23 : 24;
  #pragma unroll
  for(int l=0;l<10;l++){
    float f = PI_F*(float)(1<<l);
    float sv,cv;
    sincosf(g*f,&sv,&cv);
    acc += cv*Wp[(cosBase+2*l)*64+c] + sv*Wp[(sinBase+2*l)*64+c];
  }
  float* U = (ax==0)? Ux : Uy;
  U[i*64+c] = acc;
}

// Pack 16 64x64 weight matrices into bf16 MFMA-fragment order.
__global__ void k_wpack(const float* __restrict__ m1w, const float* __restrict__ m2w,
                        const float* __restrict__ ww,  const float* __restrict__ q1w,
                        unsigned short* __restrict__ WPK){
  int bx = blockIdx.x, tid = threadIdx.x;
  const float* src;
  if(bx<12){
    int l=bx/3, sel=bx-l*3;
    src = (sel==0)? m1w+(size_t)l*4096 : (sel==1)? m2w+(size_t)l*4096 : ww+(size_t)l*4096;
  } else {
    src = q1w + (size_t)(bx-12)*4096;
  }
  unsigned short* dst = WPK + (size_t)bx*4096;
  #pragma unroll
  for(int t=0;t<16;t++){
    int d = tid*16+t;
    int frag=d>>9, lane=(d>>3)&63, j=d&7;
    int mt=frag>>1, kh=frag&1, m_=lane&15, g=lane>>4;
    dst[d] = f2bu(src[(size_t)(16*mt+m_)*64 + 32*kh + 8*g + j]);
  }
}

// Transpose spectral weights for layer into WT[m][comp][io].
__global__ void __launch_bounds__(256) k_wtrans(const float* __restrict__ w1,
        const float* __restrict__ w2, float* __restrict__ WT){
  __shared__ float tile[64][65];
  int io0 = blockIdx.x*64;
  int c0  = blockIdx.y*64;
  int z   = blockIdx.z;
  const float* src = (z==0)? w1 : w2;
  int tid = threadIdx.x;
  #pragma unroll
  for(int it=0;it<16;it++){
    int e = tid + 256*it;
    int r = e>>6, c = e&63;
    if(c0+c<288) tile[r][c] = src[(size_t)(io0+r)*288 + c0 + c];
  }
  __syncthreads();
  #pragma unroll
  for(int it=0;it<16;it++){
    int e = tid + 256*it;
    int rp = e>>6, cp = e&63;
    int col = c0 + rp;
    if(col<288){
      int ky = col/24, rm = col - ky*24;
      int kx = rm>>1, comp = rm&1;
      int m = z*144 + ky*12 + kx;
      WT[(size_t)m*8192 + comp*4096 + io0 + cp] = tile[cp][rp];
    }
  }
}

// encoder: A[b][p][c] = x*Wp0[c] + Ux[hh][c] + Uy[ww][c]; zeros in pad.
__global__ void k_encoder(const float* __restrict__ x, const float* __restrict__ Wp,
                          const float* __restrict__ Ux, const float* __restrict__ Uy,
                          bf16* __restrict__ A){
  int tid=threadIdx.x;
  int p = blockIdx.x*256+tid;
  if(p>=NPIX) return;
  int b = blockIdx.y;
  uint4* dst = (uint4*)(A + ((size_t)b*NPIX + p)*64);
  int hh=p/NN, ww=p-hh*NN;
  if(hh>=SS || ww>=SS){
    uint4 z = {0,0,0,0};
    #pragma unroll
    for(int i=0;i<8;i++) dst[i]=z;
    return;
  }
  float xv = x[((size_t)b*SS+hh)*SS+ww];
  const float4* ux = (const float4*)(Ux + hh*64);
  const float4* uy = (const float4*)(Uy + ww*64);
  const float4* w0 = (const float4*)Wp;
  #pragma unroll
  for(int i=0;i<8;i++){
    float4 a0 = ux[2*i],   a1 = ux[2*i+1];
    float4 b0 = uy[2*i],   b1 = uy[2*i+1];
    float4 c0 = w0[2*i],   c1 = w0[2*i+1];
    float v0=xv*c0.x+a0.x+b0.x, v1=xv*c0.y+a0.y+b0.y;
    float v2=xv*c0.z+a0.z+b0.z, v3=xv*c0.w+a0.w+b0.w;
    float v4=xv*c1.x+a1.x+b1.x, v5=xv*c1.y+a1.y+b1.y;
    float v6=xv*c1.z+a1.z+b1.z, v7=xv*c1.w+a1.w+b1.w;
    uint4 v;
    v.x = (unsigned)f2bu(v0) | ((unsigned)f2bu(v1)<<16);
    v.y = (unsigned)f2bu(v2) | ((unsigned)f2bu(v3)<<16);
    v.z = (unsigned)f2bu(v4) | ((unsigned)f2bu(v5)<<16);
    v.w = (unsigned)f2bu(v6) | ((unsigned)f2bu(v7)<<16);
    dst[i]=v;
  }
}

// DFT along W. Wave per row R=b*201+h, lane=c. XW[re/im][R][kx][c].
__global__ void __launch_bounds__(256) k_dftw(const bf16* __restrict__ A,
        const float* __restrict__ tab, float* __restrict__ XW){
  __shared__ float2 st[2412];
  int tid=threadIdx.x;
  for(int i=tid;i<2412;i+=256) st[i]=((const float2*)tab)[i];
  __syncthreads();
  int R = blockIdx.x*4 + (tid>>6);
  int l = tid&63;
  const bf16* base = A + ((size_t)R*NN)*64 + l;
  float ar0=0.f;
  float ar[11], ai[11];
  #pragma unroll
  for(int k=0;k<11;k++){ ar[k]=0.f; ai[k]=0.f; }
  for(int w=0;w<NN;w++){
    float a = b2f(base[(size_t)w*64]);
    ar0 += a;
    #pragma unroll
    for(int k=0;k<11;k++){
      float2 cs = st[(k+1)*NN+w];
      ar[k] += a*cs.x;
      ai[k] += a*cs.y;
    }
  }
  float* xre = XW + ((size_t)R*12)*64 + l;
  float* xim = xre + XWPL;
  xre[0]=ar0; xim[0]=0.f;
  #pragma unroll
  for(int k=0;k<11;k++){
    xre[(size_t)(k+1)*64] = ar[k];
    xim[(size_t)(k+1)*64] = -ai[k];
  }
}

// DFT along H, LDS-staged: grid (12, 8, 4); z = (jhalf<<1)|chalf. ILP x2.
__global__ void __launch_bounds__(256) k_dfth(const float* __restrict__ XW,
        const float* __restrict__ tab, float* __restrict__ XF){
  __shared__ float sre[201*32];
  __shared__ float sim[201*32];
  __shared__ float2 tw[13*NN];
  int kx=blockIdx.x, b=blockIdx.y;
  int z=blockIdx.z; int jh=z>>1, ch=z&1;
  int tid=threadIdx.x;
  for(int i=tid;i<13*NN;i+=256) tw[i]=((const float2*)tab)[i];
  for(int i=tid;i<201*32;i+=256){
    int h=i>>5, c=ch*32+(i&31);
    size_t idx=(((size_t)b*NN+h)*12+kx)*64+c;
    sre[i]=XW[idx];
    sim[i]=XW[idx+XWPL];
  }
  __syncthreads();
  for(int o=tid;o<384;o+=256){
    int jj=o>>5, cl=o&31;
    int j=jh*12+jj;
    int k2=(j<12)?j:24-j;
    float sgn=(j<12)?-1.f:1.f;
    float re0=0.f,im0=0.f,re1=0.f,im1=0.f;
    const float* pr=sre+cl;
    const float* pi=sim+cl;
    const float2* tk=tw+k2*NN;
    int h=0;
    for(;h+1<NN;h+=2){
      float a0=pr[h*32], b0=pi[h*32];
      float2 cs0=tk[h];
      float c0=cs0.x, s0=sgn*cs0.y;
      re0 = fmaf(a0,c0, fmaf(-b0,s0, re0));
      im0 = fmaf(a0,s0, fmaf( b0,c0, im0));
      float a1=pr[(h+1)*32], b1=pi[(h+1)*32];
      float2 cs1=tk[h+1];
      float c1=cs1.x, s1=sgn*cs1.y;
      re1 = fmaf(a1,c1, fmaf(-b1,s1, re1));
      im1 = fmaf(a1,s1, fmaf( b1,c1, im1));
    }
    {
      float a0=pr[h*32], b0=pi[h*32];
      float2 cs0=tk[h];
      float c0=cs0.x, s0=sgn*cs0.y;
      re0 = fmaf(a0,c0, fmaf(-b0,s0, re0));
      im0 = fmaf(a0,s0, fmaf( b0,c0, im0));
    }
    int m=j*12+kx;
    int c=ch*32+cl;
    XF[(size_t)m*1024+(b*64+c)*2]  =re0+re1;
    XF[(size_t)m*1024+(b*64+c)*2+1]=im0+im1;
  }
}

// per-mode 64x64 complex mix; ILP split accumulators.
__global__ void __launch_bounds__(512) k_modemix(const float* __restrict__ XF,
     const float* __restrict__ WT, float* __restrict__ XO){
  __shared__ float sx[1024];
  __shared__ float swr[4096], swi[4096];
  int m=blockIdx.x;
  int tid=threadIdx.x;
  sx[tid]     = XF[(size_t)m*1024+tid];
  sx[tid+512] = XF[(size_t)m*1024+tid+512];
  const float* wr = WT + (size_t)m*8192;
  const float* wi = wr + 4096;
  for(int io=tid;io<4096;io+=512){
    swr[io]=wr[io];
    swi[io]=wi[io];
  }
  __syncthreads();
  int b=tid>>6, o=tid&63;
  const float* xb = sx + b*128;
  float re0=0.f,re1=0.f,im0=0.f,im1=0.f;
  #pragma unroll 8
  for(int i=0;i<64;i+=2){
    float a=xb[2*i], b2=xb[2*i+1];
    float c=swr[i*64+o], d=swi[i*64+o];
    re0 = fmaf(a,c, fmaf(-b2,d, re0));
    im0 = fmaf(a,d, fmaf( b2,c, im0));
    float a1=xb[2*i+2], b3=xb[2*i+3];
    float c1=swr[(i+1)*64+o], d1=swi[(i+1)*64+o];
    re1 = fmaf(a1,c1, fmaf(-b3,d1, re1));
    im1 = fmaf(a1,d1, fmaf( b3,c1, im1));
  }
  XO[2*((size_t)m*512+tid)]  =re0+re1;
  XO[2*((size_t)m*512+tid)+1]=im0+im1;
}

// Merged inverse: per row R, idfth into LDS (scale folded), then C2R along W.
__global__ void __launch_bounds__(256) k_ispec(const float* __restrict__ XO,
        const float* __restrict__ tab, bf16* __restrict__ C){
  __shared__ float2 st[2412];
  __shared__ float2 yl[12][64];
  __shared__ float2 cs13[13];
  int R=blockIdx.x;
  int b=R/NN, h=R-b*NN;
  int tid=threadIdx.x;
  for(int i=tid;i<2412;i+=256) st[i]=((const float2*)tab)[i];
  if(tid<13) cs13[tid]=((const float2*)tab)[tid*NN+h];
  __syncthreads();
  const float sc = 1.0f/40401.0f;
  #pragma unroll
  for(int it=0;it<3;it++){
    int item = tid + 256*it;
    int kx = item>>6, o = item&63;
    float re0=0.f,im0=0.f,re1=0.f,im1=0.f;
    #pragma unroll
    for(int j=0;j<24;j+=2){
      {
        int k2=(j<12)?j:24-j;
        float sgn=(j<12)?1.0f:-1.0f;
        float2 xo = *(const float2*)(XO + 2*(((size_t)(j*12+kx)*512) + b*64 + o));
        float2 cs = cs13[k2];
        float cc=cs.x, s2=sgn*cs.y;
        re0 = fmaf(xo.x,cc, fmaf(-xo.y,s2, re0));
        im0 = fmaf(xo.x,s2, fmaf( xo.y,cc, im0));
      }
      {
        int j1=j+1;
        int k2=(j1<12)?j1:24-j1;
        float sgn=(j1<12)?1.0f:-1.0f;
        float2 xo = *(const float2*)(XO + 2*(((size_t)(j1*12+kx)*512) + b*64 + o));
        float2 cs = cs13[k2];
        float cc=cs.x, s2=sgn*cs.y;
        re1 = fmaf(xo.x,cc, fmaf(-xo.y,s2, re1));
        im1 = fmaf(xo.x,s2, fmaf( xo.y,cc, im1));
      }
    }
    float fr = (kx==0)? sc : 2.0f*sc;
    float fi = (kx==0)? sc : -2.0f*sc;
    yl[kx][o] = float2{ (re0+re1)*fr, (im0+im1)*fi };
  }
  __syncthreads();
  int o = tid&63, wq = tid>>6;
  float yr[12], yi[12];
  #pragma unroll
  for(int k=0;k<12;k++){
    float2 v = yl[k][o];
    yr[k]=v.x; yi[k]=v.y;
  }
  int w0 = wq*51;
  int w1 = w0+51; if(w1>NN) w1=NN;
  bf16* cp = C + ((size_t)R*NN)*64 + o;
  for(int w=w0;w<w1;w++){
    float a0=yr[0], a1=0.f, a2=0.f, a3=0.f;
    #pragma unroll
    for(int k=1;k<12;k+=4){
      float2 c0 = st[k*NN+w];
      a0 = fmaf(yr[k], c0.x, fmaf(yi[k], c0.y, a0));
      if(k+1<12){ float2 c1 = st[(k+1)*NN+w];
        a1 = fmaf(yr[k+1], c1.x, fmaf(yi[k+1], c1.y, a1)); }
      if(k+2<12){ float2 c2 = st[(k+2)*NN+w];
        a2 = fmaf(yr[k+2], c2.x, fmaf(yi[k+2], c2.y, a2)); }
      if(k+3<12){ float2 c3 = st[(k+3)*NN+w];
        a3 = fmaf(yr[k+3], c3.x, fmaf(yi[k+3], c3.y, a3)); }
    }
    cp[(size_t)w*64] = f2b((a0+a1)+(a2+a3));
  }
}

// Parseval Gram of the spectral output Cb, computed from XO. grid = 8 (per batch).
__global__ void __launch_bounds__(256) k_gramC(const float* __restrict__ XO,
        float* __restrict__ GC, float* __restrict__ SC){
  __shared__ unsigned short V[64][584];
  int b=blockIdx.x, tid=threadIdx.x;
  const float s1=1.0f/201.0f;
  const float r2=0.70710678118f;
  const float q2=1.41421356237f;
  for(int e=tid;e<576*64;e+=256){
    int f=e>>6, ch=e&63;
    int base = b*64+ch;
    float v=0.f;
    if(f<528){
      int comp=f&1, kxm=f>>1;
      int kx0=kxm/24;
      int kx=1+kx0, m=kxm-kx0*24;
      v = q2*XO[2*((size_t)(m*12+kx)*512 + base)+comp];
    } else if(f==528){
      v = XO[2*(size_t)base];
    } else if(f<551){
      int q=f-529; int mm=1+(q>>1);
      const float* p1 = XO + 2*((size_t)(mm*12)*512 + base);
      const float* p2 = XO + 2*((size_t)((24-mm)*12)*512 + base);
      v = ((q&1)==0)? r2*(p1[0]+p2[0]) : r2*(p1[1]-p2[1]);
    } else if(f==551){
      v = r2*XO[2*((size_t)(144)*512 + base)];
    } else if(f==552){
      v = r2*XO[2*((size_t)(144)*512 + base)+1];
    }
    V[ch][f]=f2bu(v*s1);
  }
  __syncthreads();
  int wid=tid>>6, l=tid&63, m_=l&15, g=l>>4;
  f32x4 acc[4];
  #pragma unroll
  for(int mt=0;mt<4;mt++) acc[mt]=f32x4{0.f,0.f,0.f,0.f};
  #pragma unroll
  for(int kc=0;kc<18;kc++){
    s8v bfr = *(const s8v*)&V[16*wid+m_][kc*32+8*g];
    #pragma unroll
    for(int mt=0;mt<4;mt++){
      s8v afr = *(const s8v*)&V[16*mt+m_][kc*32+8*g];
      acc[mt]=__builtin_amdgcn_mfma_f32_16x16x32_bf16(afr,bfr,acc[mt],0,0,0);
    }
  }
  float* gb = GC + (size_t)b*4096;
  #pragma unroll
  for(int mt=0;mt<4;mt++){
    #pragma unroll
    for(int e=0;e<4;e++)
      gb[(size_t)(16*mt+4*g+e)*64 + 16*wid + m_] = acc[mt][e];
  }
  if(tid<64) SC[b*64+tid] = XO[2*(size_t)(b*64+tid)];
}

// Gram partials for A (float register tiles). grid (nblk, BB, 1); 1024 px/block.
__global__ void __launch_bounds__(256) k_gramp(const bf16* __restrict__ s0,
        const bf16* __restrict__ s1, float* __restrict__ Gpart,
        float* __restrict__ Spart, int HR, int WR){
  __shared__ float sx[8704];
  int b = blockIdx.y, blk = blockIdx.x, z = blockIdx.z;
  const bf16* X = (z==0)? s0 : s1;
  int zb = z*BB + b;
  int npix = HR*WR;
  int tid = threadIdx.x;
  int wid = tid>>6, lane = tid&63;
  int i0 = (lane>>3)*8, j0 = (lane&7)*8;
  float acc[8][8];
  #pragma unroll
  for(int r=0;r<8;r++){
    #pragma unroll
    for(int s=0;s<8;s++) acc[r][s]=0.f;
  }
  float cs = 0.f;
  for(int tile=0;tile<8;tile++){
    int rp0 = blk*1024 + tile*128;
    __syncthreads();
    #pragma unroll
    for(int it=0;it<4;it++){
      int chunk = tid + it*256;
      int k = chunk>>3, c0 = (chunk&7)*8;
      int rp = rp0+k;
      float v[8]={0,0,0,0,0,0,0,0};
      if(rp<npix){
        int gp;
        if(WR==NN) gp = rp;
        else { int hh=rp/WR, ww=rp-hh*WR; gp = hh*NN+ww; }
        s8v xv = *(const s8v*)(X + ((size_t)b*NPIX + gp)*64 + c0);
        #pragma unroll
        for(int j=0;j<8;j++) v[j]=bu2f((unsigned short)xv[j]);
      }
      #pragma unroll
      for(int j=0;j<8;j++) sx[k*68+c0+j]=v[j];
    }
    __syncthreads();
    for(int pp=0;pp<32;pp++){
      const float* row = sx + (wid*32+pp)*68;
      cs += row[lane];
      const float4* ri = (const float4*)(row + i0);
      const float4* rj = (const float4*)(row + j0);
      float4 xi0 = ri[0], xi1 = ri[1];
      float4 xj0 = rj[0], xj1 = rj[1];
      float xi[8] = {xi0.x,xi0.y,xi0.z,xi0.w, xi1.x,xi1.y,xi1.z,xi1.w};
      float xj[8] = {xj0.x,xj0.y,xj0.z,xj0.w, xj1.x,xj1.y,xj1.z,xj1.w};
      #pragma unroll
      for(int r=0;r<8;r++){
        #pragma unroll
        for(int s=0;s<8;s++) acc[r][s] += xi[r]*xj[s];
      }
    }
  }
  __syncthreads();
  float* scol = sx + 8320;
  scol[tid] = cs;
  if(wid>=2){
    float* d = sx + (tid-128)*65;
    #pragma unroll
    for(int r=0;r<8;r++){
      #pragma unroll
      for(int s=0;s<8;s++) d[r*8+s]=acc[r][s];
    }
  }
  __syncthreads();
  if(wid<2){
    const float* d = sx + tid*65;
    #pragma unroll
    for(int r=0;r<8;r++){
      #pragma unroll
      for(int s=0;s<8;s++) acc[r][s]+=d[r*8+s];
    }
  }
  if(tid<64){
    float tot = scol[tid]+scol[tid+64]+scol[tid+128]+scol[tid+192];
    Spart[((size_t)zb*GNB + blk)*64 + tid] = tot;
  }
  __syncthreads();
  if(wid==1){
    float* d = sx + (tid-64)*65;
    #pragma unroll
    for(int r=0;r<8;r++){
      #pragma unroll
      for(int s=0;s<8;s++) d[r*8+s]=acc[r][s];
    }
  }
  __syncthreads();
  if(wid==0){
    const float* d = sx + tid*65;
    #pragma unroll
    for(int r=0;r<8;r++){
      #pragma unroll
      for(int s=0;s<8;s++) acc[r][s]+=d[r*8+s];
    }
    float* g = Gpart + ((size_t)zb*GNB + blk)*4096;
    #pragma unroll
    for(int r=0;r<8;r++){
      #pragma unroll
      for(int s=0;s<8;s++) g[(i0+r)*64 + (j0+s)] = acc[r][s];
    }
  }
}

// Parallel slab reduce: grid (16, BB). Gfin[b][4096], Sfin[b][64].
__global__ void __launch_bounds__(256) k_gramr(const float* __restrict__ Gpart,
        const float* __restrict__ Spart, float* __restrict__ Gfin,
        float* __restrict__ Sfin, int nblk){
  int b = blockIdx.y;
  int idx = blockIdx.x*256 + threadIdx.x;
  float s0=0.f,s1=0.f,s2=0.f,s3=0.f;
  int k=0;
  for(;k+3<nblk;k+=4){
    s0 += Gpart[((size_t)b*GNB + k  )*4096 + idx];
    s1 += Gpart[((size_t)b*GNB + k+1)*4096 + idx];
    s2 += Gpart[((size_t)b*GNB + k+2)*4096 + idx];
    s3 += Gpart[((size_t)b*GNB + k+3)*4096 + idx];
  }
  for(;k<nblk;k++) s0 += Gpart[((size_t)b*GNB + k)*4096 + idx];
  Gfin[(size_t)b*4096 + idx] = (s0+s1)+(s2+s3);
  if(blockIdx.x==0 && threadIdx.x<64){
    float ss=0.f;
    for(int j=0;j<nblk;j++) ss += Spart[((size_t)b*GNB + j)*64 + threadIdx.x];
    Sfin[b*64 + threadIdx.x]=ss;
  }
}

// Merged stats (grid 16): zb<8 -> Cb-stats from GC/SC (Parseval); zb>=8 -> A-stats
// from the pre-reduced Gfin/Sfin.
__global__ void __launch_bounds__(256) k_statsA(
        const float* __restrict__ GC, const float* __restrict__ SC,
        const float* __restrict__ Gfin, const float* __restrict__ Sfin,
        const float* __restrict__ m1wl, const float* __restrict__ m1bl,
        const float* __restrict__ wwl,  const float* __restrict__ wbl,
        float* __restrict__ TSTAT, float* __restrict__ USTAT){
  __shared__ float Gs[4096];
  __shared__ float Ss[64];
  __shared__ float rs[256], rq[256];
  int zb=blockIdx.x, t=threadIdx.x;
  const float* GS = (zb<8)? (GC + (size_t)zb*4096) : (Gfin + (size_t)(zb-8)*4096);
  const float* SS_ = (zb<8)? (SC + (size_t)zb*64)   : (Sfin + (size_t)(zb-8)*64);
  #pragma unroll
  for(int e=0;e<16;e++) Gs[t*16+e]=GS[t*16+e];
  if(t<64) Ss[t]=SS_[t];
  __syncthreads();
  const float* W    = (zb<8)? m1wl : wwl;
  const float* bias = (zb<8)? m1bl : wbl;
  float* stat       = (zb<8)? TSTAT : USTAT;
  int b = (zb<8)? zb : zb-8;
  int o = t&63, sl = t>>6;
  float w[64];
  #pragma unroll
  for(int j2=0;j2<64;j2++) w[j2]=bu2f(f2bu(W[(size_t)o*64+j2]));
  const float* Gr = Gs + (size_t)(sl*16)*64;
  float quad=0.f;
  #pragma unroll
  for(int r=0;r<16;r++){
    const float* gr = Gr + r*64;
    float tt=0.f;
    #pragma unroll
    for(int j2=0;j2<64;j2++) tt += gr[j2]*w[j2];
    quad += w[sl*16+r]*tt;
  }
  float dot=0.f;
  #pragma unroll
  for(int j2=0;j2<64;j2++) dot += w[j2]*Ss[j2];
  float bo = bias[o];
  float Nf = (float)NPIX;
  float sm = (sl==0)? (dot + Nf*bo) : 0.f;
  float sq = quad + ((sl==0)? (2.f*bo*dot + Nf*bo*bo) : 0.f);
  rs[t]=sm; rq[t]=sq;
  __syncthreads();
  if(t<64){
    float s2 = rs[t]+rs[t+64]+rs[t+128]+rs[t+192];
    float q2 = rq[t]+rq[t+64]+rq[t+128]+rq[t+192];
    for(int off=16;off>0;off>>=1){
      s2 += __shfl_down(s2,off,32);
      q2 += __shfl_down(q2,off,32);
    }
    if((t&31)==0){
      int g=t>>5;
      float invN = 1.f/(Nf*32.f);
      float mean = s2*invN;
      float var = q2*invN - mean*mean;
      stat[b*4+g*2]   = mean;
      stat[b*4+g*2+1] = rsqrtf(fmaxf(var,0.f)+1e-5f);
    }
  }
}

// Head stats from pre-reduced Gfin/Sfin (grid 8).
__global__ void __launch_bounds__(256) k_statsQ(const float* __restrict__ Gfin,
        const float* __restrict__ Sfin,
        const float* __restrict__ W, const float* __restrict__ bias,
        float* __restrict__ stat){
  __shared__ float Gs[4096];
  __shared__ float Ss[64];
  __shared__ float red[8];
  int b=blockIdx.x, t=threadIdx.x;
  #pragma unroll
  for(int e=0;e<16;e++) Gs[t*16+e]=Gfin[(size_t)b*4096 + t*16+e];
  if(t<64) Ss[t]=Sfin[b*64+t];
  __syncthreads();
  float w[64];
  #pragma unroll
  for(int j2=0;j2<64;j2++) w[j2]=bu2f(f2bu(W[(size_t)t*64+j2]));
  float quad=0.f;
  #pragma unroll
  for(int i=0;i<64;i++){
    const float* gr = Gs + i*64;
    float tt=0.f;
    #pragma unroll
    for(int j2=0;j2<64;j2++) tt += gr[j2]*w[j2];
    quad += w[i]*tt;
  }
  float dot=0.f;
  #pragma unroll
  for(int j2=0;j2<64;j2++) dot += w[j2]*Ss[j2];
  float bo=bias[t];
  float Nf=(float)QPIX;
  float sm = dot + Nf*bo;
  float sq = quad + 2.f*bo*dot + Nf*bo*bo;
  for(int off=32;off>0;off>>=1){
    sm += __shfl_down(sm,off,64);
    sq += __shfl_down(sq,off,64);
  }
  int wid=t>>6;
  if((t&63)==0){ red[wid*2]=sm; red[wid*2+1]=sq; }
  __syncthreads();
  if(t<2){
    float smt = red[t*4+0]+red[t*4+2];
    float sqt = red[t*4+1]+red[t*4+3];
    float invN = 1.f/(Nf*128.f);
    float mean = smt*invN;
    float var = sqt*invN - mean*mean;
    stat[b*4+t*2]   = mean;
    stat[b*4+t*2+1] = rsqrtf(fmaxf(var,0.f)+1e-5f);
  }
}

// MFMA fused layer with packed weights.
__global__ void __launch_bounds__(256) k_fuse(const bf16* __restrict__ Cb,
    bf16* __restrict__ A,
    const unsigned short* __restrict__ wp1, const float* __restrict__ m1b,
    const float* __restrict__ mg,  const float* __restrict__ mbt,
    const unsigned short* __restrict__ wp2, const float* __restrict__ m2b,
    const unsigned short* __restrict__ wpw, const float* __restrict__ wbk,
    const float* __restrict__ ng,  const float* __restrict__ nb,
    const float* __restrict__ tstat, const float* __restrict__ ustat, int last){
  __shared__ unsigned short vlds[4][64][72];
  int tid=threadIdx.x;
  int wid=tid>>6, l=tid&63;
  int m_=l&15, g=l>>4;
  int b=blockIdx.y;
  int p0=blockIdx.x*256 + wid*64;
  const bf16* cbb = Cb + (size_t)b*NPIX*64;
  const bf16* ab  = A  + (size_t)b*NPIX*64;

  s8v af[4][2];
  f32x4 acc[4][4];

  #pragma unroll
  for(int mt=0;mt<4;mt++){
    #pragma unroll
    for(int kh=0;kh<2;kh++)
      af[mt][kh]=*(const s8v*)(wp1 + (mt*2+kh)*512 + l*8);
    float4 b4 = *(const float4*)(m1b + 16*mt + 4*g);
    #pragma unroll
    for(int nt=0;nt<4;nt++) acc[mt][nt]=f32x4{b4.x,b4.y,b4.z,b4.w};
  }
  #pragma unroll
  for(int nt=0;nt<4;nt++){
    int p = p0 + 16*nt + m_;
    int pc = p<NPIX? p : NPIX-1;
    const s8v* xb = (const s8v*)(cbb + (size_t)pc*64);
    s8v b0 = xb[g], b1 = xb[4+g];
    #pragma unroll
    for(int mt=0;mt<4;mt++){
      acc[mt][nt]=__builtin_amdgcn_mfma_f32_16x16x32_bf16(af[mt][0],b0,acc[mt][nt],0,0,0);
      acc[mt][nt]=__builtin_amdgcn_mfma_f32_16x16x32_bf16(af[mt][1],b1,acc[mt][nt],0,0,0);
    }
  }
  {
    float tm0=tstat[b*4],tr0=tstat[b*4+1],tm1=tstat[b*4+2],tr1=tstat[b*4+3];
    #pragma unroll
    for(int mt=0;mt<4;mt++){
      float4 g4 = *(const float4*)(mg  + 16*mt + 4*g);
      float4 t4 = *(const float4*)(mbt + 16*mt + 4*g);
      float mn = (mt<2)? tm0 : tm1;
      float rs = (mt<2)? tr0 : tr1;
      #pragma unroll
      for(int nt=0;nt<4;nt++){
        int pl = 16*nt + m_;
        f32x4 t = acc[mt][nt];
        float v0 = gelu_f((t[0]-mn)*rs*g4.x + t4.x);
        float v1 = gelu_f((t[1]-mn)*rs*g4.y + t4.y);
        float v2 = gelu_f((t[2]-mn)*rs*g4.z + t4.z);
        float v3 = gelu_f((t[3]-mn)*rs*g4.w + t4.w);
        uint2 pk;
        pk.x = (unsigned)f2bu(v0) | ((unsigned)f2bu(v1)<<16);
        pk.y = (unsigned)f2bu(v2) | ((unsigned)f2bu(v3)<<16);
        *(uint2*)&vlds[wid][pl][16*mt+4*g] = pk;
      }
    }
  }
  __syncthreads();
  #pragma unroll
  for(int mt=0;mt<4;mt++){
    #pragma unroll
    for(int kh=0;kh<2;kh++)
      af[mt][kh]=*(const s8v*)(wpw + (mt*2+kh)*512 + l*8);
    float4 b4 = *(const float4*)(wbk + 16*mt + 4*g);
    #pragma unroll
    for(int nt=0;nt<4;nt++) acc[mt][nt]=f32x4{b4.x,b4.y,b4.z,b4.w};
  }
  #pragma unroll
  for(int nt=0;nt<4;nt++){
    int p = p0 + 16*nt + m_;
    int pc = p<NPIX? p : NPIX-1;
    const s8v* xb = (const s8v*)(ab + (size_t)pc*64);
    s8v b0 = xb[g], b1 = xb[4+g];
    #pragma unroll
    for(int mt=0;mt<4;mt++){
      acc[mt][nt]=__builtin_amdgcn_mfma_f32_16x16x32_bf16(af[mt][0],b0,acc[mt][nt],0,0,0);
      acc[mt][nt]=__builtin_amdgcn_mfma_f32_16x16x32_bf16(af[mt][1],b1,acc[mt][nt],0,0,0);
    }
  }
  {
    float um0=ustat[b*4],ur0=ustat[b*4+1],um1=ustat[b*4+2],ur1=ustat[b*4+3];
    #pragma unroll
    for(int mt=0;mt<4;mt++){
      float4 n4 = *(const float4*)(ng  + 16*mt + 4*g);
      float4 nb4= *(const float4*)(nb  + 16*mt + 4*g);
      float4 m24= *(const float4*)(m2b + 16*mt + 4*g);
      float mn = (mt<2)? um0 : um1;
      float rs = (mt<2)? ur0 : ur1;
      #pragma unroll
      for(int nt=0;nt<4;nt++){
        f32x4 u = acc[mt][nt];
        u[0] = m24.x + (u[0]-mn)*rs*n4.x + nb4.x;
        u[1] = m24.y + (u[1]-mn)*rs*n4.y + nb4.y;
        u[2] = m24.z + (u[2]-mn)*rs*n4.z + nb4.z;
        u[3] = m24.w + (u[3]-mn)*rs*n4.w + nb4.w;
        acc[mt][nt]=u;
      }
    }
  }
  #pragma unroll
  for(int mt=0;mt<4;mt++){
    #pragma unroll
    for(int kh=0;kh<2;kh++)
      af[mt][kh]=*(const s8v*)(wp2 + (mt*2+kh)*512 + l*8);
  }
  #pragma unroll
  for(int nt=0;nt<4;nt++){
    int pl = 16*nt + m_;
    const s8v* vp = (const s8v*)&vlds[wid][pl][0];
    s8v b0 = vp[g], b1 = vp[4+g];
    #pragma unroll
    for(int mt=0;mt<4;mt++){
      acc[mt][nt]=__builtin_amdgcn_mfma_f32_16x16x32_bf16(af[mt][0],b0,acc[mt][nt],0,0,0);
      acc[mt][nt]=__builtin_amdgcn_mfma_f32_16x16x32_bf16(af[mt][1],b1,acc[mt][nt],0,0,0);
    }
  }
  #pragma unroll
  for(int nt=0;nt<4;nt++){
    int p = p0 + 16*nt + m_;
    if(p>=NPIX) continue;
    bf16* dp = A + ((size_t)b*NPIX + p)*64;
    #pragma unroll
    for(int mt=0;mt<4;mt++){
      f32x4 h = acc[mt][nt];
      float h0=h[0],h1=h[1],h2=h[2],h3=h[3];
      if(!last){ h0=gelu_f(h0); h1=gelu_f(h1); h2=gelu_f(h2); h3=gelu_f(h3); }
      uint2 pk;
      pk.x = (unsigned)f2bu(h0) | ((unsigned)f2bu(h1)<<16);
      pk.y = (unsigned)f2bu(h2) | ((unsigned)f2bu(h3)<<16);
      *(uint2*)(dp + 16*mt + 4*g) = pk;
    }
  }
}

// Head: block stages 256 px of A-crop into LDS once; wave = one oc chunk; LDS reduce.
__global__ void __launch_bounds__(256) k_qout(const bf16* __restrict__ A,
    const unsigned short* __restrict__ qpack, const float* __restrict__ q1b,
    const float* __restrict__ qg, const float* __restrict__ qbt,
    const float* __restrict__ q2w, const float* __restrict__ q2b,
    const float* __restrict__ qstat, float* __restrict__ out){
  __shared__ unsigned short xq[256][72];
  __shared__ float part[4][256];
  int tid=threadIdx.x;
  int wid=tid>>6, l=tid&63;
  int m_=l&15, g=l>>4;
  int b=blockIdx.y;
  int px0=blockIdx.x*256;
  {
    int p = px0 + tid;
    int hh=p/SS, ww2=p-hh*SS;
    const uint4* src=(const uint4*)(A + (((size_t)b*NPIX) + (size_t)hh*NN + ww2)*64);
    uint4* drow=(uint4*)&xq[tid][0];
    #pragma unroll
    for(int i=0;i<8;i++) drow[i]=src[i];
  }
  __syncthreads();
  int oc=wid;
  const unsigned short* wp = qpack + (size_t)oc*4096;
  s8v af[4][2];
  f32x4 bi4[4];
  float4 g4[4], t4[4], w4[4];
  #pragma unroll
  for(int mt=0;mt<4;mt++){
    #pragma unroll
    for(int kh=0;kh<2;kh++)
      af[mt][kh]=*(const s8v*)(wp + (mt*2+kh)*512 + l*8);
    float4 b4=*(const float4*)(q1b + 64*oc + 16*mt + 4*g);
    bi4[mt]=f32x4{b4.x,b4.y,b4.z,b4.w};
    g4[mt]=*(const float4*)(qg  + 64*oc + 16*mt + 4*g);
    t4[mt]=*(const float4*)(qbt + 64*oc + 16*mt + 4*g);
    w4[mt]=*(const float4*)(q2w + 64*oc + 16*mt + 4*g);
  }
  float m0=qstat[b*4],r0=qstat[b*4+1],m1=qstat[b*4+2],r1=qstat[b*4+3];
  float mn=(oc<2)?m0:m1, rs=(oc<2)?r0:r1;
  #pragma unroll
  for(int nt=0;nt<16;nt++){
    const s8v* vp = (const s8v*)&xq[16*nt+m_][0];
    s8v b0=vp[g], b1=vp[4+g];
    f32x4 acc[4];
    #pragma unroll
    for(int mt=0;mt<4;mt++) acc[mt]=bi4[mt];
    #pragma unroll
    for(int mt=0;mt<4;mt++){
      acc[mt]=__builtin_amdgcn_mfma_f32_16x16x32_bf16(af[mt][0],b0,acc[mt],0,0,0);
      acc[mt]=__builtin_amdgcn_mfma_f32_16x16x32_bf16(af[mt][1],b1,acc[mt],0,0,0);
    }
    float pp=0.f;
    #pragma unroll
    for(int mt=0;mt<4;mt++){
      f32x4 t=acc[mt];
      pp += gelu_f((t[0]-mn)*rs*g4[mt].x + t4[mt].x)*w4[mt].x;
      pp += gelu_f((t[1]-mn)*rs*g4[mt].y + t4[mt].y)*w4[mt].y;
      pp += gelu_f((t[2]-mn)*rs*g4[mt].z + t4[mt].z)*w4[mt].z;
      pp += gelu_f((t[3]-mn)*rs*g4[mt].w + t4[mt].w)*w4[mt].w;
    }
    pp += __shfl_xor(pp,16,64);
    pp += __shfl_xor(pp,32,64);
    if(g==0) part[wid][16*nt+m_]=pp;
  }
  __syncthreads();
  out[(size_t)b*QPIX + px0 + tid] =
      q2b[0] + part[0][tid]+part[1][tid]+part[2][tid]+part[3][tid];
}

extern "C" void kernel_launch(void* const* d_in, const int* in_sizes, int n_in,
                              void* d_out, int out_size, void* d_ws, size_t ws_size,
                              hipStream_t stream){
  const float* x   = (const float*)d_in[0];
  const float* Wp  = (const float*)d_in[1];
  const float* bp  = (const float*)d_in[2];
  const float* sw1 = (const float*)d_in[3];
  const float* sw2 = (const float*)d_in[4];
  const float* m1w = (const float*)d_in[5];
  const float* m1b = (const float*)d_in[6];
  const float* mg  = (const float*)d_in[7];
  const float* mbt = (const float*)d_in[8];
  const float* m2w = (const float*)d_in[9];
  const float* m2b = (const float*)d_in[10];
  const float* ww  = (const float*)d_in[11];
  const float* wb  = (const float*)d_in[12];
  const float* ng  = (const float*)d_in[13];
  const float* nb  = (const float*)d_in[14];
  const float* q1w = (const float*)d_in[15];
  const float* q1b = (const float*)d_in[16];
  const float* qg  = (const float*)d_in[17];
  const float* qbt = (const float*)d_in[18];
  const float* q2w = (const float*)d_in[19];
  const float* q2b = (const float*)d_in[20];
  float* out = (float*)d_out;

  char* w8 = (char*)d_ws;
  const size_t ACT_B = (size_t)64*BB*NPIX*sizeof(bf16);   // 41,370,624
  bf16*  A    = (bf16*)(w8);
  bf16*  Cb   = (bf16*)(w8 + ACT_B);
  float* SPEC = (float*)(w8 + 2*ACT_B);                    // XW / WT / Gpart overlays
  float* XF   = (float*)(w8 + 2*ACT_B + 9879552);
  float* XO   = (float*)(w8 + 2*ACT_B + 9879552 + 1179648);
  float* TB   = (float*)(w8 + 2*ACT_B + 9879552 + 2*1179648);
  char*  g8   = w8 + 2*ACT_B + 9879552 + 2*1179648 + 20992;
  float* TSTAT= (float*)g8;
  float* USTAT= TSTAT + 32;
  float* QSTAT= USTAT + 32;
  float* UxT  = QSTAT + 32;                  // 192*64
  float* UyT  = UxT + 12288;                 // 192*64
  unsigned short* WPK = (unsigned short*)(UyT + 12288);   // 16*4096 bf16
  float* GC   = (float*)(WPK + 16*4096);     // 8*4096 (Parseval gram)
  float* SC   = GC + 8*4096;                 // 8*64
  float* GFIN = SC + 8*64;                   // 8*4096 (reduced bypass gram)
  float* SFIN = GFIN + 8*4096;               // 8*64
  float* Gpart = SPEC;                       // overlays SPEC+XF (dead at gram time)
  float* Spart = Gpart + (size_t)8*GNB*4096;
  float* WT = SPEC;                          // 288*8192 floats = 9.44MB
  size_t needed = (size_t)(2*ACT_B) + 9879552 + 2*1179648 + 20992
                + 3*32*4 + 2*12288*4 + 16*4096*2 + 2*(8*4096+8*64)*4;
  if(ws_size < needed) return;

  k_tab<<<11,256,0,stream>>>(TB);
  k_pretab<<<dim3(192,2),64,0,stream>>>(Wp, bp, UxT, UyT);
  k_wpack<<<16,256,0,stream>>>(m1w, m2w, ww, q1w, WPK);
  k_encoder<<<dim3(158,BB),256,0,stream>>>(x, Wp, UxT, UyT, A);

  for(int l=0;l<4;l++){
    const float* sw1l = sw1 + (size_t)l*1179648;
    const float* sw2l = sw2 + (size_t)l*1179648;
    k_dftw<<<402,256,0,stream>>>(A, TB, SPEC);
    k_dfth<<<dim3(12,BB,4),256,0,stream>>>(SPEC, TB, XF);
    k_wtrans<<<dim3(64,5,2),256,0,stream>>>(sw1l, sw2l, WT);
    k_modemix<<<288,512,0,stream>>>(XF, WT, XO);
    k_ispec<<<1608,256,0,stream>>>(XO, TB, Cb);
    k_gramC<<<BB,256,0,stream>>>(XO, GC, SC);
    k_gramp<<<dim3(GNB,BB,1),256,0,stream>>>(A, A, Gpart, Spart, NN, NN);
    k_gramr<<<dim3(16,BB),256,0,stream>>>(Gpart, Spart, GFIN, SFIN, GNB);
    k_statsA<<<16,256,0,stream>>>(GC, SC, GFIN, SFIN,
          m1w + (size_t)l*4096, m1b + l*64, ww + (size_t)l*4096, wb + l*64,
          TSTAT, USTAT);
    k_fuse<<<dim3(158,BB),256,0,stream>>>(Cb, A,
          WPK + (size_t)(l*3+0)*4096, m1b + l*64, mg + l*64, mbt + l*64,
          WPK + (size_t)(l*3+1)*4096, m2b + l*64,
          WPK + (size_t)(l*3+2)*4096, wb  + l*64, ng + l*64, nb + l*64,
          TSTAT, USTAT, (l==3)?1:0);
  }

  k_gramp<<<dim3(36,BB,1),256,0,stream>>>(A, A, Gpart, Spart, SS, SS);
  k_gramr<<<dim3(16,BB),256,0,stream>>>(Gpart, Spart, GFIN, SFIN, 36);
  k_statsQ<<<BB,256,0,stream>>>(GFIN, SFIN, q1w, q1b, QSTAT);
  k_qout<<<dim3(144,BB),256,0,stream>>>(A, WPK + (size_t)12*4096, q1b,
          qg, qbt, q2w, q2b, QSTAT, out);
}

// Round 13
// 1333.246 us; speedup vs baseline: 1.6517x; 1.0136x over previous
//
#include <hip/hip_runtime.h>
#include <hip/hip_bf16.h>
#include <math.h>

// FNO2d: B=8, S=192, pad->201x201, C=64, modes 12x12, 4 layers.
// Pixel-major activations [b][p][c]; MFMA conv GEMMs; Parseval Gram for spectral
// branch; float register-tile Gram for bypass (512px/block, parallel slab reduce).

#define NN 201
#define SS 192
#define NPIX 40401
#define QPIX 36864
#define BB 8
#define GNB 80           // gram slabs per b, 512 px each
#define XWPL 1234944     // 1608*12*64 (re/im plane stride in floats)
#define PI_F 3.14159265358979323846f

typedef __hip_bfloat16 bf16;
typedef __attribute__((ext_vector_type(8))) short s8v;
typedef __attribute__((ext_vector_type(4))) float f32x4;

// tanh-form gelu via sigmoid: x*sigma(1.5957691x + 0.0713548x^3); |err| <= ~1e-3
__device__ __forceinline__ float gelu_f(float x){
  float x2 = x*x;
  float t  = fmaf(x2, 0.0713548162f, 1.5957691216f);
  float e  = __expf(-x*t);
  return x*__builtin_amdgcn_rcpf(1.0f+e);
}
__device__ __forceinline__ float b2f(bf16 v){ return __bfloat162float(v); }
__device__ __forceinline__ bf16  f2b(float v){ return __float2bfloat16(v); }
__device__ __forceinline__ unsigned short f2bu(float x){
  bf16 h = __float2bfloat16(x);
  unsigned short u; __builtin_memcpy(&u,&h,2); return u;
}
__device__ __forceinline__ float bu2f(unsigned short u){
  unsigned int x = ((unsigned int)u)<<16; float f; __builtin_memcpy(&f,&x,4); return f;
}

// tab[k][n]: cos/sin(2*pi*k*n/201), k=0..12, exact mod-201 reduction
__global__ void k_tab(float* __restrict__ tab){
  int t = blockIdx.x*blockDim.x+threadIdx.x;
  if(t>=13*NN) return;
  int k=t/NN, n=t-k*NN;
  int m=(k*n)%NN;
  float ang = (2.0f*PI_F/201.0f)*(float)m;
  tab[2*t]   = cosf(ang);
  tab[2*t+1] = sinf(ang);
}

// Separable encoder tables. grid (192,2), 64 thr.
__global__ void k_pretab(const float* __restrict__ Wp, const float* __restrict__ bp,
                         float* __restrict__ Ux, float* __restrict__ Uy){
  int i = blockIdx.x;
  int ax = blockIdx.y;
  int c = threadIdx.x;
  float g = (float)i*(1.0f/191.0f);
  float acc;
  if(ax==0) acc = bp[c] + g*Wp[64+c];
  else      acc = g*Wp[128+c];
  int cosBase = (ax==0)? 3 : 4;
  int sinBase = (ax==0)? 23 : 24;
  #pragma unroll
  for(int l=0;l<10;l++){
    float f = PI_F*(float)(1<<l);
    float sv,cv;
    sincosf(g*f,&sv,&cv);
    acc += cv*Wp[(cosBase+2*l)*64+c] + sv*Wp[(sinBase+2*l)*64+c];
  }
  float* U = (ax==0)? Ux : Uy;
  U[i*64+c] = acc;
}

// Pack 16 64x64 weight matrices into bf16 MFMA-fragment order.
__global__ void k_wpack(const float* __restrict__ m1w, const float* __restrict__ m2w,
                        const float* __restrict__ ww,  const float* __restrict__ q1w,
                        unsigned short* __restrict__ WPK){
  int bx = blockIdx.x, tid = threadIdx.x;
  const float* src;
  if(bx<12){
    int l=bx/3, sel=bx-l*3;
    src = (sel==0)? m1w+(size_t)l*4096 : (sel==1)? m2w+(size_t)l*4096 : ww+(size_t)l*4096;
  } else {
    src = q1w + (size_t)(bx-12)*4096;
  }
  unsigned short* dst = WPK + (size_t)bx*4096;
  #pragma unroll
  for(int t=0;t<16;t++){
    int d = tid*16+t;
    int frag=d>>9, lane=(d>>3)&63, j=d&7;
    int mt=frag>>1, kh=frag&1, m_=lane&15, g=lane>>4;
    dst[d] = f2bu(src[(size_t)(16*mt+m_)*64 + 32*kh + 8*g + j]);
  }
}

// Transpose spectral weights for layer into WT[m][comp][io].
__global__ void __launch_bounds__(256) k_wtrans(const float* __restrict__ w1,
        const float* __restrict__ w2, float* __restrict__ WT){
  __shared__ float tile[64][65];
  int io0 = blockIdx.x*64;
  int c0  = blockIdx.y*64;
  int z   = blockIdx.z;
  const float* src = (z==0)? w1 : w2;
  int tid = threadIdx.x;
  #pragma unroll
  for(int it=0;it<16;it++){
    int e = tid + 256*it;
    int r = e>>6, c = e&63;
    if(c0+c<288) tile[r][c] = src[(size_t)(io0+r)*288 + c0 + c];
  }
  __syncthreads();
  #pragma unroll
  for(int it=0;it<16;it++){
    int e = tid + 256*it;
    int rp = e>>6, cp = e&63;
    int col = c0 + rp;
    if(col<288){
      int ky = col/24, rm = col - ky*24;
      int kx = rm>>1, comp = rm&1;
      int m = z*144 + ky*12 + kx;
      WT[(size_t)m*8192 + comp*4096 + io0 + cp] = tile[cp][rp];
    }
  }
}

// encoder: A[b][p][c] = x*Wp0[c] + Ux[hh][c] + Uy[ww][c]; zeros in pad.
__global__ void k_encoder(const float* __restrict__ x, const float* __restrict__ Wp,
                          const float* __restrict__ Ux, const float* __restrict__ Uy,
                          bf16* __restrict__ A){
  int tid=threadIdx.x;
  int p = blockIdx.x*256+tid;
  if(p>=NPIX) return;
  int b = blockIdx.y;
  uint4* dst = (uint4*)(A + ((size_t)b*NPIX + p)*64);
  int hh=p/NN, ww=p-hh*NN;
  if(hh>=SS || ww>=SS){
    uint4 z = {0,0,0,0};
    #pragma unroll
    for(int i=0;i<8;i++) dst[i]=z;
    return;
  }
  float xv = x[((size_t)b*SS+hh)*SS+ww];
  const float4* ux = (const float4*)(Ux + hh*64);
  const float4* uy = (const float4*)(Uy + ww*64);
  const float4* w0 = (const float4*)Wp;
  #pragma unroll
  for(int i=0;i<8;i++){
    float4 a0 = ux[2*i],   a1 = ux[2*i+1];
    float4 b0 = uy[2*i],   b1 = uy[2*i+1];
    float4 c0 = w0[2*i],   c1 = w0[2*i+1];
    float v0=xv*c0.x+a0.x+b0.x, v1=xv*c0.y+a0.y+b0.y;
    float v2=xv*c0.z+a0.z+b0.z, v3=xv*c0.w+a0.w+b0.w;
    float v4=xv*c1.x+a1.x+b1.x, v5=xv*c1.y+a1.y+b1.y;
    float v6=xv*c1.z+a1.z+b1.z, v7=xv*c1.w+a1.w+b1.w;
    uint4 v;
    v.x = (unsigned)f2bu(v0) | ((unsigned)f2bu(v1)<<16);
    v.y = (unsigned)f2bu(v2) | ((unsigned)f2bu(v3)<<16);
    v.z = (unsigned)f2bu(v4) | ((unsigned)f2bu(v5)<<16);
    v.w = (unsigned)f2bu(v6) | ((unsigned)f2bu(v7)<<16);
    dst[i]=v;
  }
}

// DFT along W. Wave per row R=b*201+h, lane=c. XW[re/im][R][kx][c].
__global__ void __launch_bounds__(256) k_dftw(const bf16* __restrict__ A,
        const float* __restrict__ tab, float* __restrict__ XW){
  __shared__ float2 st[2412];
  int tid=threadIdx.x;
  for(int i=tid;i<2412;i+=256) st[i]=((const float2*)tab)[i];
  __syncthreads();
  int R = blockIdx.x*4 + (tid>>6);
  int l = tid&63;
  const bf16* base = A + ((size_t)R*NN)*64 + l;
  float ar0=0.f;
  float ar[11], ai[11];
  #pragma unroll
  for(int k=0;k<11;k++){ ar[k]=0.f; ai[k]=0.f; }
  for(int w=0;w<NN;w++){
    float a = b2f(base[(size_t)w*64]);
    ar0 += a;
    #pragma unroll
    for(int k=0;k<11;k++){
      float2 cs = st[(k+1)*NN+w];
      ar[k] += a*cs.x;
      ai[k] += a*cs.y;
    }
  }
  float* xre = XW + ((size_t)R*12)*64 + l;
  float* xim = xre + XWPL;
  xre[0]=ar0; xim[0]=0.f;
  #pragma unroll
  for(int k=0;k<11;k++){
    xre[(size_t)(k+1)*64] = ar[k];
    xim[(size_t)(k+1)*64] = -ai[k];
  }
}

// DFT along H, LDS-staged: grid (12, 8, 4); z = (jhalf<<1)|chalf. ILP x2.
__global__ void __launch_bounds__(256) k_dfth(const float* __restrict__ XW,
        const float* __restrict__ tab, float* __restrict__ XF){
  __shared__ float sre[201*32];
  __shared__ float sim[201*32];
  __shared__ float2 tw[13*NN];
  int kx=blockIdx.x, b=blockIdx.y;
  int z=blockIdx.z; int jh=z>>1, ch=z&1;
  int tid=threadIdx.x;
  for(int i=tid;i<13*NN;i+=256) tw[i]=((const float2*)tab)[i];
  for(int i=tid;i<201*32;i+=256){
    int h=i>>5, c=ch*32+(i&31);
    size_t idx=(((size_t)b*NN+h)*12+kx)*64+c;
    sre[i]=XW[idx];
    sim[i]=XW[idx+XWPL];
  }
  __syncthreads();
  for(int o=tid;o<384;o+=256){
    int jj=o>>5, cl=o&31;
    int j=jh*12+jj;
    int k2=(j<12)?j:24-j;
    float sgn=(j<12)?-1.f:1.f;
    float re0=0.f,im0=0.f,re1=0.f,im1=0.f;
    const float* pr=sre+cl;
    const float* pi=sim+cl;
    const float2* tk=tw+k2*NN;
    int h=0;
    for(;h+1<NN;h+=2){
      float a0=pr[h*32], b0=pi[h*32];
      float2 cs0=tk[h];
      float c0=cs0.x, s0=sgn*cs0.y;
      re0 = fmaf(a0,c0, fmaf(-b0,s0, re0));
      im0 = fmaf(a0,s0, fmaf( b0,c0, im0));
      float a1=pr[(h+1)*32], b1=pi[(h+1)*32];
      float2 cs1=tk[h+1];
      float c1=cs1.x, s1=sgn*cs1.y;
      re1 = fmaf(a1,c1, fmaf(-b1,s1, re1));
      im1 = fmaf(a1,s1, fmaf( b1,c1, im1));
    }
    {
      float a0=pr[h*32], b0=pi[h*32];
      float2 cs0=tk[h];
      float c0=cs0.x, s0=sgn*cs0.y;
      re0 = fmaf(a0,c0, fmaf(-b0,s0, re0));
      im0 = fmaf(a0,s0, fmaf( b0,c0, im0));
    }
    int m=j*12+kx;
    int c=ch*32+cl;
    XF[(size_t)m*1024+(b*64+c)*2]  =re0+re1;
    XF[(size_t)m*1024+(b*64+c)*2+1]=im0+im1;
  }
}

// per-mode 64x64 complex mix; ILP split accumulators.
__global__ void __launch_bounds__(512) k_modemix(const float* __restrict__ XF,
     const float* __restrict__ WT, float* __restrict__ XO){
  __shared__ float sx[1024];
  __shared__ float swr[4096], swi[4096];
  int m=blockIdx.x;
  int tid=threadIdx.x;
  sx[tid]     = XF[(size_t)m*1024+tid];
  sx[tid+512] = XF[(size_t)m*1024+tid+512];
  const float* wr = WT + (size_t)m*8192;
  const float* wi = wr + 4096;
  for(int io=tid;io<4096;io+=512){
    swr[io]=wr[io];
    swi[io]=wi[io];
  }
  __syncthreads();
  int b=tid>>6, o=tid&63;
  const float* xb = sx + b*128;
  float re0=0.f,re1=0.f,im0=0.f,im1=0.f;
  #pragma unroll 8
  for(int i=0;i<64;i+=2){
    float a=xb[2*i], b2=xb[2*i+1];
    float c=swr[i*64+o], d=swi[i*64+o];
    re0 = fmaf(a,c, fmaf(-b2,d, re0));
    im0 = fmaf(a,d, fmaf( b2,c, im0));
    float a1=xb[2*i+2], b3=xb[2*i+3];
    float c1=swr[(i+1)*64+o], d1=swi[(i+1)*64+o];
    re1 = fmaf(a1,c1, fmaf(-b3,d1, re1));
    im1 = fmaf(a1,d1, fmaf( b3,c1, im1));
  }
  XO[2*((size_t)m*512+tid)]  =re0+re1;
  XO[2*((size_t)m*512+tid)+1]=im0+im1;
}

// Merged inverse: per row R, idfth into LDS (scale folded), then C2R along W.
__global__ void __launch_bounds__(256) k_ispec(const float* __restrict__ XO,
        const float* __restrict__ tab, bf16* __restrict__ C){
  __shared__ float2 st[2412];
  __shared__ float2 yl[12][64];
  __shared__ float2 cs13[13];
  int R=blockIdx.x;
  int b=R/NN, h=R-b*NN;
  int tid=threadIdx.x;
  for(int i=tid;i<2412;i+=256) st[i]=((const float2*)tab)[i];
  if(tid<13) cs13[tid]=((const float2*)tab)[tid*NN+h];
  __syncthreads();
  const float sc = 1.0f/40401.0f;
  #pragma unroll
  for(int it=0;it<3;it++){
    int item = tid + 256*it;
    int kx = item>>6, o = item&63;
    float re0=0.f,im0=0.f,re1=0.f,im1=0.f;
    #pragma unroll
    for(int j=0;j<24;j+=2){
      {
        int k2=(j<12)?j:24-j;
        float sgn=(j<12)?1.0f:-1.0f;
        float2 xo = *(const float2*)(XO + 2*(((size_t)(j*12+kx)*512) + b*64 + o));
        float2 cs = cs13[k2];
        float cc=cs.x, s2=sgn*cs.y;
        re0 = fmaf(xo.x,cc, fmaf(-xo.y,s2, re0));
        im0 = fmaf(xo.x,s2, fmaf( xo.y,cc, im0));
      }
      {
        int j1=j+1;
        int k2=(j1<12)?j1:24-j1;
        float sgn=(j1<12)?1.0f:-1.0f;
        float2 xo = *(const float2*)(XO + 2*(((size_t)(j1*12+kx)*512) + b*64 + o));
        float2 cs = cs13[k2];
        float cc=cs.x, s2=sgn*cs.y;
        re1 = fmaf(xo.x,cc, fmaf(-xo.y,s2, re1));
        im1 = fmaf(xo.x,s2, fmaf( xo.y,cc, im1));
      }
    }
    float fr = (kx==0)? sc : 2.0f*sc;
    float fi = (kx==0)? sc : -2.0f*sc;
    yl[kx][o] = float2{ (re0+re1)*fr, (im0+im1)*fi };
  }
  __syncthreads();
  int o = tid&63, wq = tid>>6;
  float yr[12], yi[12];
  #pragma unroll
  for(int k=0;k<12;k++){
    float2 v = yl[k][o];
    yr[k]=v.x; yi[k]=v.y;
  }
  int w0 = wq*51;
  int w1 = w0+51; if(w1>NN) w1=NN;
  bf16* cp = C + ((size_t)R*NN)*64 + o;
  for(int w=w0;w<w1;w++){
    float a0=yr[0], a1=0.f, a2=0.f, a3=0.f;
    #pragma unroll
    for(int k=1;k<12;k+=4){
      float2 c0 = st[k*NN+w];
      a0 = fmaf(yr[k], c0.x, fmaf(yi[k], c0.y, a0));
      if(k+1<12){ float2 c1 = st[(k+1)*NN+w];
        a1 = fmaf(yr[k+1], c1.x, fmaf(yi[k+1], c1.y, a1)); }
      if(k+2<12){ float2 c2 = st[(k+2)*NN+w];
        a2 = fmaf(yr[k+2], c2.x, fmaf(yi[k+2], c2.y, a2)); }
      if(k+3<12){ float2 c3 = st[(k+3)*NN+w];
        a3 = fmaf(yr[k+3], c3.x, fmaf(yi[k+3], c3.y, a3)); }
    }
    cp[(size_t)w*64] = f2b((a0+a1)+(a2+a3));
  }
}

// Parseval Gram of the spectral output Cb, computed from XO. grid = 8 (per batch).
__global__ void __launch_bounds__(256) k_gramC(const float* __restrict__ XO,
        float* __restrict__ GC, float* __restrict__ SC){
  __shared__ unsigned short V[64][584];
  int b=blockIdx.x, tid=threadIdx.x;
  const float s1=1.0f/201.0f;
  const float r2=0.70710678118f;
  const float q2=1.41421356237f;
  for(int e=tid;e<576*64;e+=256){
    int f=e>>6, ch=e&63;
    int base = b*64+ch;
    float v=0.f;
    if(f<528){
      int comp=f&1, kxm=f>>1;
      int kx0=kxm/24;
      int kx=1+kx0, m=kxm-kx0*24;
      v = q2*XO[2*((size_t)(m*12+kx)*512 + base)+comp];
    } else if(f==528){
      v = XO[2*(size_t)base];
    } else if(f<551){
      int q=f-529; int mm=1+(q>>1);
      const float* p1 = XO + 2*((size_t)(mm*12)*512 + base);
      const float* p2 = XO + 2*((size_t)((24-mm)*12)*512 + base);
      v = ((q&1)==0)? r2*(p1[0]+p2[0]) : r2*(p1[1]-p2[1]);
    } else if(f==551){
      v = r2*XO[2*((size_t)(144)*512 + base)];
    } else if(f==552){
      v = r2*XO[2*((size_t)(144)*512 + base)+1];
    }
    V[ch][f]=f2bu(v*s1);
  }
  __syncthreads();
  int wid=tid>>6, l=tid&63, m_=l&15, g=l>>4;
  f32x4 acc[4];
  #pragma unroll
  for(int mt=0;mt<4;mt++) acc[mt]=f32x4{0.f,0.f,0.f,0.f};
  #pragma unroll
  for(int kc=0;kc<18;kc++){
    s8v bfr = *(const s8v*)&V[16*wid+m_][kc*32+8*g];
    #pragma unroll
    for(int mt=0;mt<4;mt++){
      s8v afr = *(const s8v*)&V[16*mt+m_][kc*32+8*g];
      acc[mt]=__builtin_amdgcn_mfma_f32_16x16x32_bf16(afr,bfr,acc[mt],0,0,0);
    }
  }
  float* gb = GC + (size_t)b*4096;
  #pragma unroll
  for(int mt=0;mt<4;mt++){
    #pragma unroll
    for(int e=0;e<4;e++)
      gb[(size_t)(16*mt+4*g+e)*64 + 16*wid + m_] = acc[mt][e];
  }
  if(tid<64) SC[b*64+tid] = XO[2*(size_t)(b*64+tid)];
}

// Gram partials for A (float register tiles). grid (nblk, BB); 512 px/block.
__global__ void __launch_bounds__(256) k_gramp(const bf16* __restrict__ X,
        float* __restrict__ Gpart, float* __restrict__ Spart, int HR, int WR){
  __shared__ float sx[8704];
  int b = blockIdx.y, blk = blockIdx.x;
  int npix = HR*WR;
  int tid = threadIdx.x;
  int wid = tid>>6, lane = tid&63;
  int i0 = (lane>>3)*8, j0 = (lane&7)*8;
  float acc[8][8];
  #pragma unroll
  for(int r=0;r<8;r++){
    #pragma unroll
    for(int s=0;s<8;s++) acc[r][s]=0.f;
  }
  float cs = 0.f;
  for(int tile=0;tile<4;tile++){
    int rp0 = blk*512 + tile*128;
    __syncthreads();
    #pragma unroll
    for(int it=0;it<4;it++){
      int chunk = tid + it*256;
      int k = chunk>>3, c0 = (chunk&7)*8;
      int rp = rp0+k;
      float v[8]={0,0,0,0,0,0,0,0};
      if(rp<npix){
        int gp;
        if(WR==NN) gp = rp;
        else { int hh=rp/WR, ww=rp-hh*WR; gp = hh*NN+ww; }
        s8v xv = *(const s8v*)(X + ((size_t)b*NPIX + gp)*64 + c0);
        #pragma unroll
        for(int j=0;j<8;j++) v[j]=bu2f((unsigned short)xv[j]);
      }
      #pragma unroll
      for(int j=0;j<8;j++) sx[k*68+c0+j]=v[j];
    }
    __syncthreads();
    for(int pp=0;pp<32;pp++){
      const float* row = sx + (wid*32+pp)*68;
      cs += row[lane];
      const float4* ri = (const float4*)(row + i0);
      const float4* rj = (const float4*)(row + j0);
      float4 xi0 = ri[0], xi1 = ri[1];
      float4 xj0 = rj[0], xj1 = rj[1];
      float xi[8] = {xi0.x,xi0.y,xi0.z,xi0.w, xi1.x,xi1.y,xi1.z,xi1.w};
      float xj[8] = {xj0.x,xj0.y,xj0.z,xj0.w, xj1.x,xj1.y,xj1.z,xj1.w};
      #pragma unroll
      for(int r=0;r<8;r++){
        #pragma unroll
        for(int s=0;s<8;s++) acc[r][s] += xi[r]*xj[s];
      }
    }
  }
  __syncthreads();
  float* scol = sx + 8320;
  scol[tid] = cs;
  if(wid>=2){
    float* d = sx + (tid-128)*65;
    #pragma unroll
    for(int r=0;r<8;r++){
      #pragma unroll
      for(int s=0;s<8;s++) d[r*8+s]=acc[r][s];
    }
  }
  __syncthreads();
  if(wid<2){
    const float* d = sx + tid*65;
    #pragma unroll
    for(int r=0;r<8;r++){
      #pragma unroll
      for(int s=0;s<8;s++) acc[r][s]+=d[r*8+s];
    }
  }
  if(tid<64){
    float tot = scol[tid]+scol[tid+64]+scol[tid+128]+scol[tid+192];
    Spart[((size_t)b*GNB + blk)*64 + tid] = tot;
  }
  __syncthreads();
  if(wid==1){
    float* d = sx + (tid-64)*65;
    #pragma unroll
    for(int r=0;r<8;r++){
      #pragma unroll
      for(int s=0;s<8;s++) d[r*8+s]=acc[r][s];
    }
  }
  __syncthreads();
  if(wid==0){
    const float* d = sx + tid*65;
    #pragma unroll
    for(int r=0;r<8;r++){
      #pragma unroll
      for(int s=0;s<8;s++) acc[r][s]+=d[r*8+s];
    }
    float* g = Gpart + ((size_t)b*GNB + blk)*4096;
    #pragma unroll
    for(int r=0;r<8;r++){
      #pragma unroll
      for(int s=0;s<8;s++) g[(i0+r)*64 + (j0+s)] = acc[r][s];
    }
  }
}

// Parallel slab reduce: grid (16, BB). Gfin[b][4096], Sfin[b][64].
__global__ void __launch_bounds__(256) k_gramr(const float* __restrict__ Gpart,
        const float* __restrict__ Spart, float* __restrict__ Gfin,
        float* __restrict__ Sfin, int nblk){
  int b = blockIdx.y;
  int idx = blockIdx.x*256 + threadIdx.x;
  float s0=0.f,s1=0.f,s2=0.f,s3=0.f;
  int k=0;
  for(;k+3<nblk;k+=4){
    s0 += Gpart[((size_t)b*GNB + k  )*4096 + idx];
    s1 += Gpart[((size_t)b*GNB + k+1)*4096 + idx];
    s2 += Gpart[((size_t)b*GNB + k+2)*4096 + idx];
    s3 += Gpart[((size_t)b*GNB + k+3)*4096 + idx];
  }
  for(;k<nblk;k++) s0 += Gpart[((size_t)b*GNB + k)*4096 + idx];
  Gfin[(size_t)b*4096 + idx] = (s0+s1)+(s2+s3);
  if(blockIdx.x==0 && threadIdx.x<64){
    float ss=0.f;
    for(int j=0;j<nblk;j++) ss += Spart[((size_t)b*GNB + j)*64 + threadIdx.x];
    Sfin[b*64 + threadIdx.x]=ss;
  }
}

// Merged stats (grid 16): zb<8 -> Cb-stats from GC/SC (Parseval); zb>=8 -> A-stats
// from the pre-reduced Gfin/Sfin.
__global__ void __launch_bounds__(256) k_statsA(
        const float* __restrict__ GC, const float* __restrict__ SC,
        const float* __restrict__ Gfin, const float* __restrict__ Sfin,
        const float* __restrict__ m1wl, const float* __restrict__ m1bl,
        const float* __restrict__ wwl,  const float* __restrict__ wbl,
        float* __restrict__ TSTAT, float* __restrict__ USTAT){
  __shared__ float Gs[4096];
  __shared__ float Ss[64];
  __shared__ float rs[256], rq[256];
  int zb=blockIdx.x, t=threadIdx.x;
  const float* GS = (zb<8)? (GC + (size_t)zb*4096) : (Gfin + (size_t)(zb-8)*4096);
  const float* SS_ = (zb<8)? (SC + (size_t)zb*64)   : (Sfin + (size_t)(zb-8)*64);
  #pragma unroll
  for(int e=0;e<16;e++) Gs[t*16+e]=GS[t*16+e];
  if(t<64) Ss[t]=SS_[t];
  __syncthreads();
  const float* W    = (zb<8)? m1wl : wwl;
  const float* bias = (zb<8)? m1bl : wbl;
  float* stat       = (zb<8)? TSTAT : USTAT;
  int b = (zb<8)? zb : zb-8;
  int o = t&63, sl = t>>6;
  float w[64];
  #pragma unroll
  for(int j2=0;j2<64;j2++) w[j2]=bu2f(f2bu(W[(size_t)o*64+j2]));
  const float* Gr = Gs + (size_t)(sl*16)*64;
  float quad=0.f;
  #pragma unroll
  for(int r=0;r<16;r++){
    const float* gr = Gr + r*64;
    float tt=0.f;
    #pragma unroll
    for(int j2=0;j2<64;j2++) tt += gr[j2]*w[j2];
    quad += w[sl*16+r]*tt;
  }
  float dot=0.f;
  #pragma unroll
  for(int j2=0;j2<64;j2++) dot += w[j2]*Ss[j2];
  float bo = bias[o];
  float Nf = (float)NPIX;
  float sm = (sl==0)? (dot + Nf*bo) : 0.f;
  float sq = quad + ((sl==0)? (2.f*bo*dot + Nf*bo*bo) : 0.f);
  rs[t]=sm; rq[t]=sq;
  __syncthreads();
  if(t<64){
    float s2 = rs[t]+rs[t+64]+rs[t+128]+rs[t+192];
    float q2 = rq[t]+rq[t+64]+rq[t+128]+rq[t+192];
    for(int off=16;off>0;off>>=1){
      s2 += __shfl_down(s2,off,32);
      q2 += __shfl_down(q2,off,32);
    }
    if((t&31)==0){
      int g=t>>5;
      float invN = 1.f/(Nf*32.f);
      float mean = s2*invN;
      float var = q2*invN - mean*mean;
      stat[b*4+g*2]   = mean;
      stat[b*4+g*2+1] = rsqrtf(fmaxf(var,0.f)+1e-5f);
    }
  }
}

// Head stats from pre-reduced Gfin/Sfin (grid 8).
__global__ void __launch_bounds__(256) k_statsQ(const float* __restrict__ Gfin,
        const float* __restrict__ Sfin,
        const float* __restrict__ W, const float* __restrict__ bias,
        float* __restrict__ stat){
  __shared__ float Gs[4096];
  __shared__ float Ss[64];
  __shared__ float red[8];
  int b=blockIdx.x, t=threadIdx.x;
  #pragma unroll
  for(int e=0;e<16;e++) Gs[t*16+e]=Gfin[(size_t)b*4096 + t*16+e];
  if(t<64) Ss[t]=Sfin[b*64+t];
  __syncthreads();
  float w[64];
  #pragma unroll
  for(int j2=0;j2<64;j2++) w[j2]=bu2f(f2bu(W[(size_t)t*64+j2]));
  float quad=0.f;
  #pragma unroll
  for(int i=0;i<64;i++){
    const float* gr = Gs + i*64;
    float tt=0.f;
    #pragma unroll
    for(int j2=0;j2<64;j2++) tt += gr[j2]*w[j2];
    quad += w[i]*tt;
  }
  float dot=0.f;
  #pragma unroll
  for(int j2=0;j2<64;j2++) dot += w[j2]*Ss[j2];
  float bo=bias[t];
  float Nf=(float)QPIX;
  float sm = dot + Nf*bo;
  float sq = quad + 2.f*bo*dot + Nf*bo*bo;
  for(int off=32;off>0;off>>=1){
    sm += __shfl_down(sm,off,64);
    sq += __shfl_down(sq,off,64);
  }
  int wid=t>>6;
  if((t&63)==0){ red[wid*2]=sm; red[wid*2+1]=sq; }
  __syncthreads();
  if(t<2){
    float smt = red[t*4+0]+red[t*4+2];
    float sqt = red[t*4+1]+red[t*4+3];
    float invN = 1.f/(Nf*128.f);
    float mean = smt*invN;
    float var = sqt*invN - mean*mean;
    stat[b*4+t*2]   = mean;
    stat[b*4+t*2+1] = rsqrtf(fmaxf(var,0.f)+1e-5f);
  }
}

// MFMA fused layer with packed weights.
__global__ void __launch_bounds__(256) k_fuse(const bf16* __restrict__ Cb,
    bf16* __restrict__ A,
    const unsigned short* __restrict__ wp1, const float* __restrict__ m1b,
    const float* __restrict__ mg,  const float* __restrict__ mbt,
    const unsigned short* __restrict__ wp2, const float* __restrict__ m2b,
    const unsigned short* __restrict__ wpw, const float* __restrict__ wbk,
    const float* __restrict__ ng,  const float* __restrict__ nb,
    const float* __restrict__ tstat, const float* __restrict__ ustat, int last){
  __shared__ unsigned short vlds[4][64][72];
  int tid=threadIdx.x;
  int wid=tid>>6, l=tid&63;
  int m_=l&15, g=l>>4;
  int b=blockIdx.y;
  int p0=blockIdx.x*256 + wid*64;
  const bf16* cbb = Cb + (size_t)b*NPIX*64;
  const bf16* ab  = A  + (size_t)b*NPIX*64;

  s8v af[4][2];
  f32x4 acc[4][4];

  #pragma unroll
  for(int mt=0;mt<4;mt++){
    #pragma unroll
    for(int kh=0;kh<2;kh++)
      af[mt][kh]=*(const s8v*)(wp1 + (mt*2+kh)*512 + l*8);
    float4 b4 = *(const float4*)(m1b + 16*mt + 4*g);
    #pragma unroll
    for(int nt=0;nt<4;nt++) acc[mt][nt]=f32x4{b4.x,b4.y,b4.z,b4.w};
  }
  #pragma unroll
  for(int nt=0;nt<4;nt++){
    int p = p0 + 16*nt + m_;
    int pc = p<NPIX? p : NPIX-1;
    const s8v* xb = (const s8v*)(cbb + (size_t)pc*64);
    s8v b0 = xb[g], b1 = xb[4+g];
    #pragma unroll
    for(int mt=0;mt<4;mt++){
      acc[mt][nt]=__builtin_amdgcn_mfma_f32_16x16x32_bf16(af[mt][0],b0,acc[mt][nt],0,0,0);
      acc[mt][nt]=__builtin_amdgcn_mfma_f32_16x16x32_bf16(af[mt][1],b1,acc[mt][nt],0,0,0);
    }
  }
  {
    float tm0=tstat[b*4],tr0=tstat[b*4+1],tm1=tstat[b*4+2],tr1=tstat[b*4+3];
    #pragma unroll
    for(int mt=0;mt<4;mt++){
      float4 g4 = *(const float4*)(mg  + 16*mt + 4*g);
      float4 t4 = *(const float4*)(mbt + 16*mt + 4*g);
      float mn = (mt<2)? tm0 : tm1;
      float rs = (mt<2)? tr0 : tr1;
      #pragma unroll
      for(int nt=0;nt<4;nt++){
        int pl = 16*nt + m_;
        f32x4 t = acc[mt][nt];
        float v0 = gelu_f((t[0]-mn)*rs*g4.x + t4.x);
        float v1 = gelu_f((t[1]-mn)*rs*g4.y + t4.y);
        float v2 = gelu_f((t[2]-mn)*rs*g4.z + t4.z);
        float v3 = gelu_f((t[3]-mn)*rs*g4.w + t4.w);
        uint2 pk;
        pk.x = (unsigned)f2bu(v0) | ((unsigned)f2bu(v1)<<16);
        pk.y = (unsigned)f2bu(v2) | ((unsigned)f2bu(v3)<<16);
        *(uint2*)&vlds[wid][pl][16*mt+4*g] = pk;
      }
    }
  }
  __syncthreads();
  #pragma unroll
  for(int mt=0;mt<4;mt++){
    #pragma unroll
    for(int kh=0;kh<2;kh++)
      af[mt][kh]=*(const s8v*)(wpw + (mt*2+kh)*512 + l*8);
    float4 b4 = *(const float4*)(wbk + 16*mt + 4*g);
    #pragma unroll
    for(int nt=0;nt<4;nt++) acc[mt][nt]=f32x4{b4.x,b4.y,b4.z,b4.w};
  }
  #pragma unroll
  for(int nt=0;nt<4;nt++){
    int p = p0 + 16*nt + m_;
    int pc = p<NPIX? p : NPIX-1;
    const s8v* xb = (const s8v*)(ab + (size_t)pc*64);
    s8v b0 = xb[g], b1 = xb[4+g];
    #pragma unroll
    for(int mt=0;mt<4;mt++){
      acc[mt][nt]=__builtin_amdgcn_mfma_f32_16x16x32_bf16(af[mt][0],b0,acc[mt][nt],0,0,0);
      acc[mt][nt]=__builtin_amdgcn_mfma_f32_16x16x32_bf16(af[mt][1],b1,acc[mt][nt],0,0,0);
    }
  }
  {
    float um0=ustat[b*4],ur0=ustat[b*4+1],um1=ustat[b*4+2],ur1=ustat[b*4+3];
    #pragma unroll
    for(int mt=0;mt<4;mt++){
      float4 n4 = *(const float4*)(ng  + 16*mt + 4*g);
      float4 nb4= *(const float4*)(nb  + 16*mt + 4*g);
      float4 m24= *(const float4*)(m2b + 16*mt + 4*g);
      float mn = (mt<2)? um0 : um1;
      float rs = (mt<2)? ur0 : ur1;
      #pragma unroll
      for(int nt=0;nt<4;nt++){
        f32x4 u = acc[mt][nt];
        u[0] = m24.x + (u[0]-mn)*rs*n4.x + nb4.x;
        u[1] = m24.y + (u[1]-mn)*rs*n4.y + nb4.y;
        u[2] = m24.z + (u[2]-mn)*rs*n4.z + nb4.z;
        u[3] = m24.w + (u[3]-mn)*rs*n4.w + nb4.w;
        acc[mt][nt]=u;
      }
    }
  }
  #pragma unroll
  for(int mt=0;mt<4;mt++){
    #pragma unroll
    for(int kh=0;kh<2;kh++)
      af[mt][kh]=*(const s8v*)(wp2 + (mt*2+kh)*512 + l*8);
  }
  #pragma unroll
  for(int nt=0;nt<4;nt++){
    int pl = 16*nt + m_;
    const s8v* vp = (const s8v*)&vlds[wid][pl][0];
    s8v b0 = vp[g], b1 = vp[4+g];
    #pragma unroll
    for(int mt=0;mt<4;mt++){
      acc[mt][nt]=__builtin_amdgcn_mfma_f32_16x16x32_bf16(af[mt][0],b0,acc[mt][nt],0,0,0);
      acc[mt][nt]=__builtin_amdgcn_mfma_f32_16x16x32_bf16(af[mt][1],b1,acc[mt][nt],0,0,0);
    }
  }
  #pragma unroll
  for(int nt=0;nt<4;nt++){
    int p = p0 + 16*nt + m_;
    if(p>=NPIX) continue;
    bf16* dp = A + ((size_t)b*NPIX + p)*64;
    #pragma unroll
    for(int mt=0;mt<4;mt++){
      f32x4 h = acc[mt][nt];
      float h0=h[0],h1=h[1],h2=h[2],h3=h[3];
      if(!last){ h0=gelu_f(h0); h1=gelu_f(h1); h2=gelu_f(h2); h3=gelu_f(h3); }
      uint2 pk;
      pk.x = (unsigned)f2bu(h0) | ((unsigned)f2bu(h1)<<16);
      pk.y = (unsigned)f2bu(h2) | ((unsigned)f2bu(h3)<<16);
      *(uint2*)(dp + 16*mt + 4*g) = pk;
    }
  }
}

// Head: block stages 256 px of A-crop into LDS once; wave = one oc chunk; LDS reduce.
__global__ void __launch_bounds__(256) k_qout(const bf16* __restrict__ A,
    const unsigned short* __restrict__ qpack, const float* __restrict__ q1b,
    const float* __restrict__ qg, const float* __restrict__ qbt,
    const float* __restrict__ q2w, const float* __restrict__ q2b,
    const float* __restrict__ qstat, float* __restrict__ out){
  __shared__ unsigned short xq[256][72];
  __shared__ float part[4][256];
  int tid=threadIdx.x;
  int wid=tid>>6, l=tid&63;
  int m_=l&15, g=l>>4;
  int b=blockIdx.y;
  int px0=blockIdx.x*256;
  {
    int p = px0 + tid;
    int hh=p/SS, ww2=p-hh*SS;
    const uint4* src=(const uint4*)(A + (((size_t)b*NPIX) + (size_t)hh*NN + ww2)*64);
    uint4* drow=(uint4*)&xq[tid][0];
    #pragma unroll
    for(int i=0;i<8;i++) drow[i]=src[i];
  }
  __syncthreads();
  int oc=wid;
  const unsigned short* wp = qpack + (size_t)oc*4096;
  s8v af[4][2];
  f32x4 bi4[4];
  float4 g4[4], t4[4], w4[4];
  #pragma unroll
  for(int mt=0;mt<4;mt++){
    #pragma unroll
    for(int kh=0;kh<2;kh++)
      af[mt][kh]=*(const s8v*)(wp + (mt*2+kh)*512 + l*8);
    float4 b4=*(const float4*)(q1b + 64*oc + 16*mt + 4*g);
    bi4[mt]=f32x4{b4.x,b4.y,b4.z,b4.w};
    g4[mt]=*(const float4*)(qg  + 64*oc + 16*mt + 4*g);
    t4[mt]=*(const float4*)(qbt + 64*oc + 16*mt + 4*g);
    w4[mt]=*(const float4*)(q2w + 64*oc + 16*mt + 4*g);
  }
  float m0=qstat[b*4],r0=qstat[b*4+1],m1=qstat[b*4+2],r1=qstat[b*4+3];
  float mn=(oc<2)?m0:m1, rs=(oc<2)?r0:r1;
  #pragma unroll
  for(int nt=0;nt<16;nt++){
    const s8v* vp = (const s8v*)&xq[16*nt+m_][0];
    s8v b0=vp[g], b1=vp[4+g];
    f32x4 acc[4];
    #pragma unroll
    for(int mt=0;mt<4;mt++) acc[mt]=bi4[mt];
    #pragma unroll
    for(int mt=0;mt<4;mt++){
      acc[mt]=__builtin_amdgcn_mfma_f32_16x16x32_bf16(af[mt][0],b0,acc[mt],0,0,0);
      acc[mt]=__builtin_amdgcn_mfma_f32_16x16x32_bf16(af[mt][1],b1,acc[mt],0,0,0);
    }
    float pp=0.f;
    #pragma unroll
    for(int mt=0;mt<4;mt++){
      f32x4 t=acc[mt];
      pp += gelu_f((t[0]-mn)*rs*g4[mt].x + t4[mt].x)*w4[mt].x;
      pp += gelu_f((t[1]-mn)*rs*g4[mt].y + t4[mt].y)*w4[mt].y;
      pp += gelu_f((t[2]-mn)*rs*g4[mt].z + t4[mt].z)*w4[mt].z;
      pp += gelu_f((t[3]-mn)*rs*g4[mt].w + t4[mt].w)*w4[mt].w;
    }
    pp += __shfl_xor(pp,16,64);
    pp += __shfl_xor(pp,32,64);
    if(g==0) part[wid][16*nt+m_]=pp;
  }
  __syncthreads();
  out[(size_t)b*QPIX + px0 + tid] =
      q2b[0] + part[0][tid]+part[1][tid]+part[2][tid]+part[3][tid];
}

extern "C" void kernel_launch(void* const* d_in, const int* in_sizes, int n_in,
                              void* d_out, int out_size, void* d_ws, size_t ws_size,
                              hipStream_t stream){
  const float* x   = (const float*)d_in[0];
  const float* Wp  = (const float*)d_in[1];
  const float* bp  = (const float*)d_in[2];
  const float* sw1 = (const float*)d_in[3];
  const float* sw2 = (const float*)d_in[4];
  const float* m1w = (const float*)d_in[5];
  const float* m1b = (const float*)d_in[6];
  const float* mg  = (const float*)d_in[7];
  const float* mbt = (const float*)d_in[8];
  const float* m2w = (const float*)d_in[9];
  const float* m2b = (const float*)d_in[10];
  const float* ww  = (const float*)d_in[11];
  const float* wb  = (const float*)d_in[12];
  const float* ng  = (const float*)d_in[13];
  const float* nb  = (const float*)d_in[14];
  const float* q1w = (const float*)d_in[15];
  const float* q1b = (const float*)d_in[16];
  const float* qg  = (const float*)d_in[17];
  const float* qbt = (const float*)d_in[18];
  const float* q2w = (const float*)d_in[19];
  const float* q2b = (const float*)d_in[20];
  float* out = (float*)d_out;

  char* w8 = (char*)d_ws;
  const size_t ACT_B = (size_t)64*BB*NPIX*sizeof(bf16);   // 41,370,624
  bf16*  A    = (bf16*)(w8);
  bf16*  Cb   = (bf16*)(w8 + ACT_B);
  float* SPEC = (float*)(w8 + 2*ACT_B);                    // XW / WT / Gpart overlays
  float* XF   = (float*)(w8 + 2*ACT_B + 9879552);
  float* XO   = (float*)(w8 + 2*ACT_B + 9879552 + 1179648);
  float* TB   = (float*)(w8 + 2*ACT_B + 9879552 + 2*1179648);
  char*  g8   = w8 + 2*ACT_B + 9879552 + 2*1179648 + 20992;
  float* TSTAT= (float*)g8;
  float* USTAT= TSTAT + 32;
  float* QSTAT= USTAT + 32;
  float* UxT  = QSTAT + 32;                  // 192*64
  float* UyT  = UxT + 12288;                 // 192*64
  unsigned short* WPK = (unsigned short*)(UyT + 12288);   // 16*4096 bf16
  float* GC   = (float*)(WPK + 16*4096);     // 8*4096 (Parseval gram)
  float* SC   = GC + 8*4096;                 // 8*64
  float* GFIN = SC + 8*64;                   // 8*4096 (reduced bypass gram)
  float* SFIN = GFIN + 8*4096;               // 8*64
  float* Gpart = SPEC;                       // 8*80*4096 fl = 10.49MB <= SPEC+XF (11.06MB)
  float* Spart = Gpart + (size_t)8*GNB*4096;
  float* WT = SPEC;                          // 288*8192 floats = 9.44MB
  size_t needed = (size_t)(2*ACT_B) + 9879552 + 2*1179648 + 20992
                + 3*32*4 + 2*12288*4 + 16*4096*2 + 2*(8*4096+8*64)*4;
  if(ws_size < needed) return;

  k_tab<<<11,256,0,stream>>>(TB);
  k_pretab<<<dim3(192,2),64,0,stream>>>(Wp, bp, UxT, UyT);
  k_wpack<<<16,256,0,stream>>>(m1w, m2w, ww, q1w, WPK);
  k_encoder<<<dim3(158,BB),256,0,stream>>>(x, Wp, UxT, UyT, A);

  for(int l=0;l<4;l++){
    const float* sw1l = sw1 + (size_t)l*1179648;
    const float* sw2l = sw2 + (size_t)l*1179648;
    k_dftw<<<402,256,0,stream>>>(A, TB, SPEC);
    k_dfth<<<dim3(12,BB,4),256,0,stream>>>(SPEC, TB, XF);
    k_wtrans<<<dim3(64,5,2),256,0,stream>>>(sw1l, sw2l, WT);
    k_modemix<<<288,512,0,stream>>>(XF, WT, XO);
    k_ispec<<<1608,256,0,stream>>>(XO, TB, Cb);
    k_gramC<<<BB,256,0,stream>>>(XO, GC, SC);
    k_gramp<<<dim3(79,BB),256,0,stream>>>(A, Gpart, Spart, NN, NN);
    k_gramr<<<dim3(16,BB),256,0,stream>>>(Gpart, Spart, GFIN, SFIN, 79);
    k_statsA<<<16,256,0,stream>>>(GC, SC, GFIN, SFIN,
          m1w + (size_t)l*4096, m1b + l*64, ww + (size_t)l*4096, wb + l*64,
          TSTAT, USTAT);
    k_fuse<<<dim3(158,BB),256,0,stream>>>(Cb, A,
          WPK + (size_t)(l*3+0)*4096, m1b + l*64, mg + l*64, mbt + l*64,
          WPK + (size_t)(l*3+1)*4096, m2b + l*64,
          WPK + (size_t)(l*3+2)*4096, wb  + l*64, ng + l*64, nb + l*64,
          TSTAT, USTAT, (l==3)?1:0);
  }

  k_gramp<<<dim3(72,BB),256,0,stream>>>(A, Gpart, Spart, SS, SS);
  k_gramr<<<dim3(16,BB),256,0,stream>>>(Gpart, Spart, GFIN, SFIN, 72);
  k_statsQ<<<BB,256,0,stream>>>(GFIN, SFIN, q1w, q1b, QSTAT);
  k_qout<<<dim3(144,BB),256,0,stream>>>(A, WPK + (size_t)12*4096, q1b,
          qg, qbt, q2w, q2b, QSTAT, out);
}

// Round 14
// 1246.483 us; speedup vs baseline: 1.7667x; 1.0696x over previous
//
#include <hip/hip_runtime.h>
#include <hip/hip_bf16.h>
#include <math.h>

// FNO2d: B=8, S=192, pad->201x201, C=64, modes 12x12, 4 layers.
// Pixel-major activations [b][p][c]; MFMA conv GEMMs; MFMA inverse-W (ispec);
// Parseval Gram for spectral branch; register-tile Gram for bypass; fast gelu.

#define NN 201
#define SS 192
#define NPIX 40401
#define QPIX 36864
#define BB 8
#define GNB 80           // gram slabs per b, 512 px each
#define XWPL 1234944     // 1608*12*64 (re/im plane stride in floats)
#define PI_F 3.14159265358979323846f

typedef __hip_bfloat16 bf16;
typedef __attribute__((ext_vector_type(8))) short s8v;
typedef __attribute__((ext_vector_type(4))) float f32x4;

// tanh-form gelu via sigmoid: x*sigma(1.5957691x + 0.0713548x^3); |err| <= ~1e-3
__device__ __forceinline__ float gelu_f(float x){
  float x2 = x*x;
  float t  = fmaf(x2, 0.0713548162f, 1.5957691216f);
  float e  = __expf(-x*t);
  return x*__builtin_amdgcn_rcpf(1.0f+e);
}
__device__ __forceinline__ float b2f(bf16 v){ return __bfloat162float(v); }
__device__ __forceinline__ bf16  f2b(float v){ return __float2bfloat16(v); }
__device__ __forceinline__ unsigned short f2bu(float x){
  bf16 h = __float2bfloat16(x);
  unsigned short u; __builtin_memcpy(&u,&h,2); return u;
}
__device__ __forceinline__ float bu2f(unsigned short u){
  unsigned int x = ((unsigned int)u)<<16; float f; __builtin_memcpy(&f,&x,4); return f;
}

// tab[k][n]: cos/sin(2*pi*k*n/201), k=0..12, exact mod-201 reduction
__global__ void k_tab(float* __restrict__ tab){
  int t = blockIdx.x*blockDim.x+threadIdx.x;
  if(t>=13*NN) return;
  int k=t/NN, n=t-k*NN;
  int m=(k*n)%NN;
  float ang = (2.0f*PI_F/201.0f)*(float)m;
  tab[2*t]   = cosf(ang);
  tab[2*t+1] = sinf(ang);
}

// Pack inverse-W twiddles into MFMA A-fragment order (bf16).
// TPK[wt][lane][j]: A[m=w-in-tile][k24]; w=wt*16+(lane&15), k24=(lane>>4)*8+j.
// T[w][2k]=cos(2pi k w/201), T[w][2k+1]=sin(...); zero pad k24>=24 or w>=201.
__global__ void k_tpack(const float* __restrict__ tab, unsigned short* __restrict__ TPK){
  int e = blockIdx.x*256 + threadIdx.x;
  if(e>=6656) return;
  int wt=e>>9, lane=(e>>3)&63, j=e&7;
  int m_=lane&15, g=lane>>4;
  int w = wt*16+m_;
  int k24 = g*8+j;
  float v=0.f;
  if(k24<24 && w<201){
    float2 cs = ((const float2*)tab)[(k24>>1)*NN + w];
    v = (k24&1)? cs.y : cs.x;
  }
  TPK[e]=f2bu(v);
}

// Separable encoder tables. grid (192,2), 64 thr.
__global__ void k_pretab(const float* __restrict__ Wp, const float* __restrict__ bp,
                         float* __restrict__ Ux, float* __restrict__ Uy){
  int i = blockIdx.x;
  int ax = blockIdx.y;
  int c = threadIdx.x;
  float g = (float)i*(1.0f/191.0f);
  float acc;
  if(ax==0) acc = bp[c] + g*Wp[64+c];
  else      acc = g*Wp[128+c];
  int cosBase = (ax==0)? 3 : 4;
  int sinBase = (ax==0)? 23 : 24;
  #pragma unroll
  for(int l=0;l<10;l++){
    float f = PI_F*(float)(1<<l);
    float sv,cv;
    sincosf(g*f,&sv,&cv);
    acc += cv*Wp[(cosBase+2*l)*64+c] + sv*Wp[(sinBase+2*l)*64+c];
  }
  float* U = (ax==0)? Ux : Uy;
  U[i*64+c] = acc;
}

// Pack 16 64x64 weight matrices into bf16 MFMA-fragment order.
__global__ void k_wpack(const float* __restrict__ m1w, const float* __restrict__ m2w,
                        const float* __restrict__ ww,  const float* __restrict__ q1w,
                        unsigned short* __restrict__ WPK){
  int bx = blockIdx.x, tid = threadIdx.x;
  const float* src;
  if(bx<12){
    int l=bx/3, sel=bx-l*3;
    src = (sel==0)? m1w+(size_t)l*4096 : (sel==1)? m2w+(size_t)l*4096 : ww+(size_t)l*4096;
  } else {
    src = q1w + (size_t)(bx-12)*4096;
  }
  unsigned short* dst = WPK + (size_t)bx*4096;
  #pragma unroll
  for(int t=0;t<16;t++){
    int d = tid*16+t;
    int frag=d>>9, lane=(d>>3)&63, j=d&7;
    int mt=frag>>1, kh=frag&1, m_=lane&15, g=lane>>4;
    dst[d] = f2bu(src[(size_t)(16*mt+m_)*64 + 32*kh + 8*g + j]);
  }
}

// Transpose spectral weights for layer into WT[m][comp][io].
__global__ void __launch_bounds__(256) k_wtrans(const float* __restrict__ w1,
        const float* __restrict__ w2, float* __restrict__ WT){
  __shared__ float tile[64][65];
  int io0 = blockIdx.x*64;
  int c0  = blockIdx.y*64;
  int z   = blockIdx.z;
  const float* src = (z==0)? w1 : w2;
  int tid = threadIdx.x;
  #pragma unroll
  for(int it=0;it<16;it++){
    int e = tid + 256*it;
    int r = e>>6, c = e&63;
    if(c0+c<288) tile[r][c] = src[(size_t)(io0+r)*288 + c0 + c];
  }
  __syncthreads();
  #pragma unroll
  for(int it=0;it<16;it++){
    int e = tid + 256*it;
    int rp = e>>6, cp = e&63;
    int col = c0 + rp;
    if(col<288){
      int ky = col/24, rm = col - ky*24;
      int kx = rm>>1, comp = rm&1;
      int m = z*144 + ky*12 + kx;
      WT[(size_t)m*8192 + comp*4096 + io0 + cp] = tile[cp][rp];
    }
  }
}

// encoder: A[b][p][c] = x*Wp0[c] + Ux[hh][c] + Uy[ww][c]; zeros in pad.
__global__ void k_encoder(const float* __restrict__ x, const float* __restrict__ Wp,
                          const float* __restrict__ Ux, const float* __restrict__ Uy,
                          bf16* __restrict__ A){
  int tid=threadIdx.x;
  int p = blockIdx.x*256+tid;
  if(p>=NPIX) return;
  int b = blockIdx.y;
  uint4* dst = (uint4*)(A + ((size_t)b*NPIX + p)*64);
  int hh=p/NN, ww=p-hh*NN;
  if(hh>=SS || ww>=SS){
    uint4 z = {0,0,0,0};
    #pragma unroll
    for(int i=0;i<8;i++) dst[i]=z;
    return;
  }
  float xv = x[((size_t)b*SS+hh)*SS+ww];
  const float4* ux = (const float4*)(Ux + hh*64);
  const float4* uy = (const float4*)(Uy + ww*64);
  const float4* w0 = (const float4*)Wp;
  #pragma unroll
  for(int i=0;i<8;i++){
    float4 a0 = ux[2*i],   a1 = ux[2*i+1];
    float4 b0 = uy[2*i],   b1 = uy[2*i+1];
    float4 c0 = w0[2*i],   c1 = w0[2*i+1];
    float v0=xv*c0.x+a0.x+b0.x, v1=xv*c0.y+a0.y+b0.y;
    float v2=xv*c0.z+a0.z+b0.z, v3=xv*c0.w+a0.w+b0.w;
    float v4=xv*c1.x+a1.x+b1.x, v5=xv*c1.y+a1.y+b1.y;
    float v6=xv*c1.z+a1.z+b1.z, v7=xv*c1.w+a1.w+b1.w;
    uint4 v;
    v.x = (unsigned)f2bu(v0) | ((unsigned)f2bu(v1)<<16);
    v.y = (unsigned)f2bu(v2) | ((unsigned)f2bu(v3)<<16);
    v.z = (unsigned)f2bu(v4) | ((unsigned)f2bu(v5)<<16);
    v.w = (unsigned)f2bu(v6) | ((unsigned)f2bu(v7)<<16);
    dst[i]=v;
  }
}

// DFT along W. Wave per row R=b*201+h, lane=c. XW[re/im][R][kx][c].
__global__ void __launch_bounds__(256) k_dftw(const bf16* __restrict__ A,
        const float* __restrict__ tab, float* __restrict__ XW){
  __shared__ float2 st[2412];
  int tid=threadIdx.x;
  for(int i=tid;i<2412;i+=256) st[i]=((const float2*)tab)[i];
  __syncthreads();
  int R = blockIdx.x*4 + (tid>>6);
  int l = tid&63;
  const bf16* base = A + ((size_t)R*NN)*64 + l;
  float ar0=0.f;
  float ar[11], ai[11];
  #pragma unroll
  for(int k=0;k<11;k++){ ar[k]=0.f; ai[k]=0.f; }
  for(int w=0;w<NN;w++){
    float a = b2f(base[(size_t)w*64]);
    ar0 += a;
    #pragma unroll
    for(int k=0;k<11;k++){
      float2 cs = st[(k+1)*NN+w];
      ar[k] += a*cs.x;
      ai[k] += a*cs.y;
    }
  }
  float* xre = XW + ((size_t)R*12)*64 + l;
  float* xim = xre + XWPL;
  xre[0]=ar0; xim[0]=0.f;
  #pragma unroll
  for(int k=0;k<11;k++){
    xre[(size_t)(k+1)*64] = ar[k];
    xim[(size_t)(k+1)*64] = -ai[k];
  }
}

// DFT along H, LDS-staged: grid (12, 8, 4); z = (jhalf<<1)|chalf. ILP x2.
__global__ void __launch_bounds__(256) k_dfth(const float* __restrict__ XW,
        const float* __restrict__ tab, float* __restrict__ XF){
  __shared__ float sre[201*32];
  __shared__ float sim[201*32];
  __shared__ float2 tw[13*NN];
  int kx=blockIdx.x, b=blockIdx.y;
  int z=blockIdx.z; int jh=z>>1, ch=z&1;
  int tid=threadIdx.x;
  for(int i=tid;i<13*NN;i+=256) tw[i]=((const float2*)tab)[i];
  for(int i=tid;i<201*32;i+=256){
    int h=i>>5, c=ch*32+(i&31);
    size_t idx=(((size_t)b*NN+h)*12+kx)*64+c;
    sre[i]=XW[idx];
    sim[i]=XW[idx+XWPL];
  }
  __syncthreads();
  for(int o=tid;o<384;o+=256){
    int jj=o>>5, cl=o&31;
    int j=jh*12+jj;
    int k2=(j<12)?j:24-j;
    float sgn=(j<12)?-1.f:1.f;
    float re0=0.f,im0=0.f,re1=0.f,im1=0.f;
    const float* pr=sre+cl;
    const float* pi=sim+cl;
    const float2* tk=tw+k2*NN;
    int h=0;
    for(;h+1<NN;h+=2){
      float a0=pr[h*32], b0=pi[h*32];
      float2 cs0=tk[h];
      float c0=cs0.x, s0=sgn*cs0.y;
      re0 = fmaf(a0,c0, fmaf(-b0,s0, re0));
      im0 = fmaf(a0,s0, fmaf( b0,c0, im0));
      float a1=pr[(h+1)*32], b1=pi[(h+1)*32];
      float2 cs1=tk[h+1];
      float c1=cs1.x, s1=sgn*cs1.y;
      re1 = fmaf(a1,c1, fmaf(-b1,s1, re1));
      im1 = fmaf(a1,s1, fmaf( b1,c1, im1));
    }
    {
      float a0=pr[h*32], b0=pi[h*32];
      float2 cs0=tk[h];
      float c0=cs0.x, s0=sgn*cs0.y;
      re0 = fmaf(a0,c0, fmaf(-b0,s0, re0));
      im0 = fmaf(a0,s0, fmaf( b0,c0, im0));
    }
    int m=j*12+kx;
    int c=ch*32+cl;
    XF[(size_t)m*1024+(b*64+c)*2]  =re0+re1;
    XF[(size_t)m*1024+(b*64+c)*2+1]=im0+im1;
  }
}

// per-mode 64x64 complex mix; ILP split accumulators.
__global__ void __launch_bounds__(512) k_modemix(const float* __restrict__ XF,
     const float* __restrict__ WT, float* __restrict__ XO){
  __shared__ float sx[1024];
  __shared__ float swr[4096], swi[4096];
  int m=blockIdx.x;
  int tid=threadIdx.x;
  sx[tid]     = XF[(size_t)m*1024+tid];
  sx[tid+512] = XF[(size_t)m*1024+tid+512];
  const float* wr = WT + (size_t)m*8192;
  const float* wi = wr + 4096;
  for(int io=tid;io<4096;io+=512){
    swr[io]=wr[io];
    swi[io]=wi[io];
  }
  __syncthreads();
  int b=tid>>6, o=tid&63;
  const float* xb = sx + b*128;
  float re0=0.f,re1=0.f,im0=0.f,im1=0.f;
  #pragma unroll 8
  for(int i=0;i<64;i+=2){
    float a=xb[2*i], b2=xb[2*i+1];
    float c=swr[i*64+o], d=swi[i*64+o];
    re0 = fmaf(a,c, fmaf(-b2,d, re0));
    im0 = fmaf(a,d, fmaf( b2,c, im0));
    float a1=xb[2*i+2], b3=xb[2*i+3];
    float c1=swr[(i+1)*64+o], d1=swi[(i+1)*64+o];
    re1 = fmaf(a1,c1, fmaf(-b3,d1, re1));
    im1 = fmaf(a1,d1, fmaf( b3,c1, im1));
  }
  XO[2*((size_t)m*512+tid)]  =re0+re1;
  XO[2*((size_t)m*512+tid)+1]=im0+im1;
}

// Merged inverse: per row R, idfth into LDS (factors folded), then the C2R
// along W as MFMA: C[w][o] = sum_k24 T[w][k24]*Y24[k24][o], T prepacked (TPK).
__global__ void __launch_bounds__(256) k_ispec(const float* __restrict__ XO,
        const float* __restrict__ tab, const unsigned short* __restrict__ TPK,
        bf16* __restrict__ C){
  __shared__ float2 yl[12][64];
  __shared__ float2 cs13[13];
  int R=blockIdx.x;
  int b=R/NN, h=R-b*NN;
  int tid=threadIdx.x;
  if(tid<13) cs13[tid]=((const float2*)tab)[tid*NN+h];
  __syncthreads();
  const float sc = 1.0f/40401.0f;
  #pragma unroll
  for(int it=0;it<3;it++){
    int item = tid + 256*it;
    int kx = item>>6, o = item&63;
    float re0=0.f,im0=0.f,re1=0.f,im1=0.f;
    #pragma unroll
    for(int j=0;j<24;j+=2){
      {
        int k2=(j<12)?j:24-j;
        float sgn=(j<12)?1.0f:-1.0f;
        float2 xo = *(const float2*)(XO + 2*(((size_t)(j*12+kx)*512) + b*64 + o));
        float2 cs = cs13[k2];
        float cc=cs.x, s2=sgn*cs.y;
        re0 = fmaf(xo.x,cc, fmaf(-xo.y,s2, re0));
        im0 = fmaf(xo.x,s2, fmaf( xo.y,cc, im0));
      }
      {
        int j1=j+1;
        int k2=(j1<12)?j1:24-j1;
        float sgn=(j1<12)?1.0f:-1.0f;
        float2 xo = *(const float2*)(XO + 2*(((size_t)(j1*12+kx)*512) + b*64 + o));
        float2 cs = cs13[k2];
        float cc=cs.x, s2=sgn*cs.y;
        re1 = fmaf(xo.x,cc, fmaf(-xo.y,s2, re1));
        im1 = fmaf(xo.x,s2, fmaf( xo.y,cc, im1));
      }
    }
    float fr = (kx==0)? sc : 2.0f*sc;
    float fi = (kx==0)? sc : -2.0f*sc;
    yl[kx][o] = float2{ (re0+re1)*fr, (im0+im1)*fi };
  }
  __syncthreads();
  // phase 2: MFMA. wave = o-tile; B-frag: B[k24][o], k24=(lane>>4)*8+j, o=wid*16+(lane&15)
  int wid=tid>>6, l=tid&63, m_=l&15, g=l>>4;
  int o = wid*16 + m_;
  s8v bfr;
  #pragma unroll
  for(int j=0;j<4;j++){
    float2 v = yl[4*g+j][o];
    bfr[2*j]   = (short)f2bu(v.x);
    bfr[2*j+1] = (short)f2bu(v.y);
  }
  bf16* cp = C + (size_t)R*NN*64;
  #pragma unroll
  for(int wt=0; wt<13; wt++){
    s8v af = *(const s8v*)(TPK + (size_t)wt*512 + l*8);
    f32x4 acc = f32x4{0.f,0.f,0.f,0.f};
    acc = __builtin_amdgcn_mfma_f32_16x16x32_bf16(af, bfr, acc, 0,0,0);
    #pragma unroll
    for(int e=0;e<4;e++){
      int w = wt*16 + 4*g + e;
      if(w<NN) cp[(size_t)w*64 + o] = f2b(acc[e]);
    }
  }
}

// Parseval Gram of the spectral output Cb, computed from XO. grid = 8 (per batch).
__global__ void __launch_bounds__(256) k_gramC(const float* __restrict__ XO,
        float* __restrict__ GC, float* __restrict__ SC){
  __shared__ unsigned short V[64][584];
  int b=blockIdx.x, tid=threadIdx.x;
  const float s1=1.0f/201.0f;
  const float r2=0.70710678118f;
  const float q2=1.41421356237f;
  for(int e=tid;e<576*64;e+=256){
    int f=e>>6, ch=e&63;
    int base = b*64+ch;
    float v=0.f;
    if(f<528){
      int comp=f&1, kxm=f>>1;
      int kx0=kxm/24;
      int kx=1+kx0, m=kxm-kx0*24;
      v = q2*XO[2*((size_t)(m*12+kx)*512 + base)+comp];
    } else if(f==528){
      v = XO[2*(size_t)base];
    } else if(f<551){
      int q=f-529; int mm=1+(q>>1);
      const float* p1 = XO + 2*((size_t)(mm*12)*512 + base);
      const float* p2 = XO + 2*((size_t)((24-mm)*12)*512 + base);
      v = ((q&1)==0)? r2*(p1[0]+p2[0]) : r2*(p1[1]-p2[1]);
    } else if(f==551){
      v = r2*XO[2*((size_t)(144)*512 + base)];
    } else if(f==552){
      v = r2*XO[2*((size_t)(144)*512 + base)+1];
    }
    V[ch][f]=f2bu(v*s1);
  }
  __syncthreads();
  int wid=tid>>6, l=tid&63, m_=l&15, g=l>>4;
  f32x4 acc[4];
  #pragma unroll
  for(int mt=0;mt<4;mt++) acc[mt]=f32x4{0.f,0.f,0.f,0.f};
  #pragma unroll
  for(int kc=0;kc<18;kc++){
    s8v bfr = *(const s8v*)&V[16*wid+m_][kc*32+8*g];
    #pragma unroll
    for(int mt=0;mt<4;mt++){
      s8v afr = *(const s8v*)&V[16*mt+m_][kc*32+8*g];
      acc[mt]=__builtin_amdgcn_mfma_f32_16x16x32_bf16(afr,bfr,acc[mt],0,0,0);
    }
  }
  float* gb = GC + (size_t)b*4096;
  #pragma unroll
  for(int mt=0;mt<4;mt++){
    #pragma unroll
    for(int e=0;e<4;e++)
      gb[(size_t)(16*mt+4*g+e)*64 + 16*wid + m_] = acc[mt][e];
  }
  if(tid<64) SC[b*64+tid] = XO[2*(size_t)(b*64+tid)];
}

// Gram partials for A (float register tiles). grid (nblk, BB); 512 px/block.
__global__ void __launch_bounds__(256) k_gramp(const bf16* __restrict__ X,
        float* __restrict__ Gpart, float* __restrict__ Spart, int HR, int WR){
  __shared__ float sx[8704];
  int b = blockIdx.y, blk = blockIdx.x;
  int npix = HR*WR;
  int tid = threadIdx.x;
  int wid = tid>>6, lane = tid&63;
  int i0 = (lane>>3)*8, j0 = (lane&7)*8;
  float acc[8][8];
  #pragma unroll
  for(int r=0;r<8;r++){
    #pragma unroll
    for(int s=0;s<8;s++) acc[r][s]=0.f;
  }
  float cs = 0.f;
  for(int tile=0;tile<4;tile++){
    int rp0 = blk*512 + tile*128;
    __syncthreads();
    #pragma unroll
    for(int it=0;it<4;it++){
      int chunk = tid + it*256;
      int k = chunk>>3, c0 = (chunk&7)*8;
      int rp = rp0+k;
      float v[8]={0,0,0,0,0,0,0,0};
      if(rp<npix){
        int gp;
        if(WR==NN) gp = rp;
        else { int hh=rp/WR, ww=rp-hh*WR; gp = hh*NN+ww; }
        s8v xv = *(const s8v*)(X + ((size_t)b*NPIX + gp)*64 + c0);
        #pragma unroll
        for(int j=0;j<8;j++) v[j]=bu2f((unsigned short)xv[j]);
      }
      #pragma unroll
      for(int j=0;j<8;j++) sx[k*68+c0+j]=v[j];
    }
    __syncthreads();
    for(int pp=0;pp<32;pp++){
      const float* row = sx + (wid*32+pp)*68;
      cs += row[lane];
      const float4* ri = (const float4*)(row + i0);
      const float4* rj = (const float4*)(row + j0);
      float4 xi0 = ri[0], xi1 = ri[1];
      float4 xj0 = rj[0], xj1 = rj[1];
      float xi[8] = {xi0.x,xi0.y,xi0.z,xi0.w, xi1.x,xi1.y,xi1.z,xi1.w};
      float xj[8] = {xj0.x,xj0.y,xj0.z,xj0.w, xj1.x,xj1.y,xj1.z,xj1.w};
      #pragma unroll
      for(int r=0;r<8;r++){
        #pragma unroll
        for(int s=0;s<8;s++) acc[r][s] += xi[r]*xj[s];
      }
    }
  }
  __syncthreads();
  float* scol = sx + 8320;
  scol[tid] = cs;
  if(wid>=2){
    float* d = sx + (tid-128)*65;
    #pragma unroll
    for(int r=0;r<8;r++){
      #pragma unroll
      for(int s=0;s<8;s++) d[r*8+s]=acc[r][s];
    }
  }
  __syncthreads();
  if(wid<2){
    const float* d = sx + tid*65;
    #pragma unroll
    for(int r=0;r<8;r++){
      #pragma unroll
      for(int s=0;s<8;s++) acc[r][s]+=d[r*8+s];
    }
  }
  if(tid<64){
    float tot = scol[tid]+scol[tid+64]+scol[tid+128]+scol[tid+192];
    Spart[((size_t)b*GNB + blk)*64 + tid] = tot;
  }
  __syncthreads();
  if(wid==1){
    float* d = sx + (tid-64)*65;
    #pragma unroll
    for(int r=0;r<8;r++){
      #pragma unroll
      for(int s=0;s<8;s++) d[r*8+s]=acc[r][s];
    }
  }
  __syncthreads();
  if(wid==0){
    const float* d = sx + tid*65;
    #pragma unroll
    for(int r=0;r<8;r++){
      #pragma unroll
      for(int s=0;s<8;s++) acc[r][s]+=d[r*8+s];
    }
    float* g = Gpart + ((size_t)b*GNB + blk)*4096;
    #pragma unroll
    for(int r=0;r<8;r++){
      #pragma unroll
      for(int s=0;s<8;s++) g[(i0+r)*64 + (j0+s)] = acc[r][s];
    }
  }
}

// Parallel slab reduce: grid (16, BB). Gfin[b][4096], Sfin[b][64].
__global__ void __launch_bounds__(256) k_gramr(const float* __restrict__ Gpart,
        const float* __restrict__ Spart, float* __restrict__ Gfin,
        float* __restrict__ Sfin, int nblk){
  int b = blockIdx.y;
  int idx = blockIdx.x*256 + threadIdx.x;
  float s0=0.f,s1=0.f,s2=0.f,s3=0.f;
  int k=0;
  for(;k+3<nblk;k+=4){
    s0 += Gpart[((size_t)b*GNB + k  )*4096 + idx];
    s1 += Gpart[((size_t)b*GNB + k+1)*4096 + idx];
    s2 += Gpart[((size_t)b*GNB + k+2)*4096 + idx];
    s3 += Gpart[((size_t)b*GNB + k+3)*4096 + idx];
  }
  for(;k<nblk;k++) s0 += Gpart[((size_t)b*GNB + k)*4096 + idx];
  Gfin[(size_t)b*4096 + idx] = (s0+s1)+(s2+s3);
  if(blockIdx.x==0 && threadIdx.x<64){
    float ss=0.f;
    for(int j=0;j<nblk;j++) ss += Spart[((size_t)b*GNB + j)*64 + threadIdx.x];
    Sfin[b*64 + threadIdx.x]=ss;
  }
}

// Merged stats (grid 16): zb<8 -> Cb-stats from GC/SC (Parseval); zb>=8 -> A-stats
// from the pre-reduced Gfin/Sfin.
__global__ void __launch_bounds__(256) k_statsA(
        const float* __restrict__ GC, const float* __restrict__ SC,
        const float* __restrict__ Gfin, const float* __restrict__ Sfin,
        const float* __restrict__ m1wl, const float* __restrict__ m1bl,
        const float* __restrict__ wwl,  const float* __restrict__ wbl,
        float* __restrict__ TSTAT, float* __restrict__ USTAT){
  __shared__ float Gs[4096];
  __shared__ float Ss[64];
  __shared__ float rs[256], rq[256];
  int zb=blockIdx.x, t=threadIdx.x;
  const float* GS = (zb<8)? (GC + (size_t)zb*4096) : (Gfin + (size_t)(zb-8)*4096);
  const float* SS_ = (zb<8)? (SC + (size_t)zb*64)   : (Sfin + (size_t)(zb-8)*64);
  #pragma unroll
  for(int e=0;e<16;e++) Gs[t*16+e]=GS[t*16+e];
  if(t<64) Ss[t]=SS_[t];
  __syncthreads();
  const float* W    = (zb<8)? m1wl : wwl;
  const float* bias = (zb<8)? m1bl : wbl;
  float* stat       = (zb<8)? TSTAT : USTAT;
  int b = (zb<8)? zb : zb-8;
  int o = t&63, sl = t>>6;
  float w[64];
  #pragma unroll
  for(int j2=0;j2<64;j2++) w[j2]=bu2f(f2bu(W[(size_t)o*64+j2]));
  const float* Gr = Gs + (size_t)(sl*16)*64;
  float quad=0.f;
  #pragma unroll
  for(int r=0;r<16;r++){
    const float* gr = Gr + r*64;
    float tt=0.f;
    #pragma unroll
    for(int j2=0;j2<64;j2++) tt += gr[j2]*w[j2];
    quad += w[sl*16+r]*tt;
  }
  float dot=0.f;
  #pragma unroll
  for(int j2=0;j2<64;j2++) dot += w[j2]*Ss[j2];
  float bo = bias[o];
  float Nf = (float)NPIX;
  float sm = (sl==0)? (dot + Nf*bo) : 0.f;
  float sq = quad + ((sl==0)? (2.f*bo*dot + Nf*bo*bo) : 0.f);
  rs[t]=sm; rq[t]=sq;
  __syncthreads();
  if(t<64){
    float s2 = rs[t]+rs[t+64]+rs[t+128]+rs[t+192];
    float q2 = rq[t]+rq[t+64]+rq[t+128]+rq[t+192];
    for(int off=16;off>0;off>>=1){
      s2 += __shfl_down(s2,off,32);
      q2 += __shfl_down(q2,off,32);
    }
    if((t&31)==0){
      int g=t>>5;
      float invN = 1.f/(Nf*32.f);
      float mean = s2*invN;
      float var = q2*invN - mean*mean;
      stat[b*4+g*2]   = mean;
      stat[b*4+g*2+1] = rsqrtf(fmaxf(var,0.f)+1e-5f);
    }
  }
}

// Head stats from pre-reduced Gfin/Sfin (grid 8).
__global__ void __launch_bounds__(256) k_statsQ(const float* __restrict__ Gfin,
        const float* __restrict__ Sfin,
        const float* __restrict__ W, const float* __restrict__ bias,
        float* __restrict__ stat){
  __shared__ float Gs[4096];
  __shared__ float Ss[64];
  __shared__ float red[8];
  int b=blockIdx.x, t=threadIdx.x;
  #pragma unroll
  for(int e=0;e<16;e++) Gs[t*16+e]=Gfin[(size_t)b*4096 + t*16+e];
  if(t<64) Ss[t]=Sfin[b*64+t];
  __syncthreads();
  float w[64];
  #pragma unroll
  for(int j2=0;j2<64;j2++) w[j2]=bu2f(f2bu(W[(size_t)t*64+j2]));
  float quad=0.f;
  #pragma unroll
  for(int i=0;i<64;i++){
    const float* gr = Gs + i*64;
    float tt=0.f;
    #pragma unroll
    for(int j2=0;j2<64;j2++) tt += gr[j2]*w[j2];
    quad += w[i]*tt;
  }
  float dot=0.f;
  #pragma unroll
  for(int j2=0;j2<64;j2++) dot += w[j2]*Ss[j2];
  float bo=bias[t];
  float Nf=(float)QPIX;
  float sm = dot + Nf*bo;
  float sq = quad + 2.f*bo*dot + Nf*bo*bo;
  for(int off=32;off>0;off>>=1){
    sm += __shfl_down(sm,off,64);
    sq += __shfl_down(sq,off,64);
  }
  int wid=t>>6;
  if((t&63)==0){ red[wid*2]=sm; red[wid*2+1]=sq; }
  __syncthreads();
  if(t<2){
    float smt = red[t*4+0]+red[t*4+2];
    float sqt = red[t*4+1]+red[t*4+3];
    float invN = 1.f/(Nf*128.f);
    float mean = smt*invN;
    float var = sqt*invN - mean*mean;
    stat[b*4+t*2]   = mean;
    stat[b*4+t*2+1] = rsqrtf(fmaxf(var,0.f)+1e-5f);
  }
}

// MFMA fused layer with packed weights.
__global__ void __launch_bounds__(256) k_fuse(const bf16* __restrict__ Cb,
    bf16* __restrict__ A,
    const unsigned short* __restrict__ wp1, const float* __restrict__ m1b,
    const float* __restrict__ mg,  const float* __restrict__ mbt,
    const unsigned short* __restrict__ wp2, const float* __restrict__ m2b,
    const unsigned short* __restrict__ wpw, const float* __restrict__ wbk,
    const float* __restrict__ ng,  const float* __restrict__ nb,
    const float* __restrict__ tstat, const float* __restrict__ ustat, int last){
  __shared__ unsigned short vlds[4][64][72];
  int tid=threadIdx.x;
  int wid=tid>>6, l=tid&63;
  int m_=l&15, g=l>>4;
  int b=blockIdx.y;
  int p0=blockIdx.x*256 + wid*64;
  const bf16* cbb = Cb + (size_t)b*NPIX*64;
  const bf16* ab  = A  + (size_t)b*NPIX*64;

  s8v af[4][2];
  f32x4 acc[4][4];

  #pragma unroll
  for(int mt=0;mt<4;mt++){
    #pragma unroll
    for(int kh=0;kh<2;kh++)
      af[mt][kh]=*(const s8v*)(wp1 + (mt*2+kh)*512 + l*8);
    float4 b4 = *(const float4*)(m1b + 16*mt + 4*g);
    #pragma unroll
    for(int nt=0;nt<4;nt++) acc[mt][nt]=f32x4{b4.x,b4.y,b4.z,b4.w};
  }
  #pragma unroll
  for(int nt=0;nt<4;nt++){
    int p = p0 + 16*nt + m_;
    int pc = p<NPIX? p : NPIX-1;
    const s8v* xb = (const s8v*)(cbb + (size_t)pc*64);
    s8v b0 = xb[g], b1 = xb[4+g];
    #pragma unroll
    for(int mt=0;mt<4;mt++){
      acc[mt][nt]=__builtin_amdgcn_mfma_f32_16x16x32_bf16(af[mt][0],b0,acc[mt][nt],0,0,0);
      acc[mt][nt]=__builtin_amdgcn_mfma_f32_16x16x32_bf16(af[mt][1],b1,acc[mt][nt],0,0,0);
    }
  }
  {
    float tm0=tstat[b*4],tr0=tstat[b*4+1],tm1=tstat[b*4+2],tr1=tstat[b*4+3];
    #pragma unroll
    for(int mt=0;mt<4;mt++){
      float4 g4 = *(const float4*)(mg  + 16*mt + 4*g);
      float4 t4 = *(const float4*)(mbt + 16*mt + 4*g);
      float mn = (mt<2)? tm0 : tm1;
      float rs = (mt<2)? tr0 : tr1;
      #pragma unroll
      for(int nt=0;nt<4;nt++){
        int pl = 16*nt + m_;
        f32x4 t = acc[mt][nt];
        float v0 = gelu_f((t[0]-mn)*rs*g4.x + t4.x);
        float v1 = gelu_f((t[1]-mn)*rs*g4.y + t4.y);
        float v2 = gelu_f((t[2]-mn)*rs*g4.z + t4.z);
        float v3 = gelu_f((t[3]-mn)*rs*g4.w + t4.w);
        uint2 pk;
        pk.x = (unsigned)f2bu(v0) | ((unsigned)f2bu(v1)<<16);
        pk.y = (unsigned)f2bu(v2) | ((unsigned)f2bu(v3)<<16);
        *(uint2*)&vlds[wid][pl][16*mt+4*g] = pk;
      }
    }
  }
  __syncthreads();
  #pragma unroll
  for(int mt=0;mt<4;mt++){
    #pragma unroll
    for(int kh=0;kh<2;kh++)
      af[mt][kh]=*(const s8v*)(wpw + (mt*2+kh)*512 + l*8);
    float4 b4 = *(const float4*)(wbk + 16*mt + 4*g);
    #pragma unroll
    for(int nt=0;nt<4;nt++) acc[mt][nt]=f32x4{b4.x,b4.y,b4.z,b4.w};
  }
  #pragma unroll
  for(int nt=0;nt<4;nt++){
    int p = p0 + 16*nt + m_;
    int pc = p<NPIX? p : NPIX-1;
    const s8v* xb = (const s8v*)(ab + (size_t)pc*64);
    s8v b0 = xb[g], b1 = xb[4+g];
    #pragma unroll
    for(int mt=0;mt<4;mt++){
      acc[mt][nt]=__builtin_amdgcn_mfma_f32_16x16x32_bf16(af[mt][0],b0,acc[mt][nt],0,0,0);
      acc[mt][nt]=__builtin_amdgcn_mfma_f32_16x16x32_bf16(af[mt][1],b1,acc[mt][nt],0,0,0);
    }
  }
  {
    float um0=ustat[b*4],ur0=ustat[b*4+1],um1=ustat[b*4+2],ur1=ustat[b*4+3];
    #pragma unroll
    for(int mt=0;mt<4;mt++){
      float4 n4 = *(const float4*)(ng  + 16*mt + 4*g);
      float4 nb4= *(const float4*)(nb  + 16*mt + 4*g);
      float4 m24= *(const float4*)(m2b + 16*mt + 4*g);
      float mn = (mt<2)? um0 : um1;
      float rs = (mt<2)? ur0 : ur1;
      #pragma unroll
      for(int nt=0;nt<4;nt++){
        f32x4 u = acc[mt][nt];
        u[0] = m24.x + (u[0]-mn)*rs*n4.x + nb4.x;
        u[1] = m24.y + (u[1]-mn)*rs*n4.y + nb4.y;
        u[2] = m24.z + (u[2]-mn)*rs*n4.z + nb4.z;
        u[3] = m24.w + (u[3]-mn)*rs*n4.w + nb4.w;
        acc[mt][nt]=u;
      }
    }
  }
  #pragma unroll
  for(int mt=0;mt<4;mt++){
    #pragma unroll
    for(int kh=0;kh<2;kh++)
      af[mt][kh]=*(const s8v*)(wp2 + (mt*2+kh)*512 + l*8);
  }
  #pragma unroll
  for(int nt=0;nt<4;nt++){
    int pl = 16*nt + m_;
    const s8v* vp = (const s8v*)&vlds[wid][pl][0];
    s8v b0 = vp[g], b1 = vp[4+g];
    #pragma unroll
    for(int mt=0;mt<4;mt++){
      acc[mt][nt]=__builtin_amdgcn_mfma_f32_16x16x32_bf16(af[mt][0],b0,acc[mt][nt],0,0,0);
      acc[mt][nt]=__builtin_amdgcn_mfma_f32_16x16x32_bf16(af[mt][1],b1,acc[mt][nt],0,0,0);
    }
  }
  #pragma unroll
  for(int nt=0;nt<4;nt++){
    int p = p0 + 16*nt + m_;
    if(p>=NPIX) continue;
    bf16* dp = A + ((size_t)b*NPIX + p)*64;
    #pragma unroll
    for(int mt=0;mt<4;mt++){
      f32x4 h = acc[mt][nt];
      float h0=h[0],h1=h[1],h2=h[2],h3=h[3];
      if(!last){ h0=gelu_f(h0); h1=gelu_f(h1); h2=gelu_f(h2); h3=gelu_f(h3); }
      uint2 pk;
      pk.x = (unsigned)f2bu(h0) | ((unsigned)f2bu(h1)<<16);
      pk.y = (unsigned)f2bu(h2) | ((unsigned)f2bu(h3)<<16);
      *(uint2*)(dp + 16*mt + 4*g) = pk;
    }
  }
}

// Head: block stages 256 px of A-crop into LDS once; wave = one oc chunk; LDS reduce.
__global__ void __launch_bounds__(256) k_qout(const bf16* __restrict__ A,
    const unsigned short* __restrict__ qpack, const float* __restrict__ q1b,
    const float* __restrict__ qg, const float* __restrict__ qbt,
    const float* __restrict__ q2w, const float* __restrict__ q2b,
    const float* __restrict__ qstat, float* __restrict__ out){
  __shared__ unsigned short xq[256][72];
  __shared__ float part[4][256];
  int tid=threadIdx.x;
  int wid=tid>>6, l=tid&63;
  int m_=l&15, g=l>>4;
  int b=blockIdx.y;
  int px0=blockIdx.x*256;
  {
    int p = px0 + tid;
    int hh=p/SS, ww2=p-hh*SS;
    const uint4* src=(const uint4*)(A + (((size_t)b*NPIX) + (size_t)hh*NN + ww2)*64);
    uint4* drow=(uint4*)&xq[tid][0];
    #pragma unroll
    for(int i=0;i<8;i++) drow[i]=src[i];
  }
  __syncthreads();
  int oc=wid;
  const unsigned short* wp = qpack + (size_t)oc*4096;
  s8v af[4][2];
  f32x4 bi4[4];
  float4 g4[4], t4[4], w4[4];
  #pragma unroll
  for(int mt=0;mt<4;mt++){
    #pragma unroll
    for(int kh=0;kh<2;kh++)
      af[mt][kh]=*(const s8v*)(wp + (mt*2+kh)*512 + l*8);
    float4 b4=*(const float4*)(q1b + 64*oc + 16*mt + 4*g);
    bi4[mt]=f32x4{b4.x,b4.y,b4.z,b4.w};
    g4[mt]=*(const float4*)(qg  + 64*oc + 16*mt + 4*g);
    t4[mt]=*(const float4*)(qbt + 64*oc + 16*mt + 4*g);
    w4[mt]=*(const float4*)(q2w + 64*oc + 16*mt + 4*g);
  }
  float m0=qstat[b*4],r0=qstat[b*4+1],m1=qstat[b*4+2],r1=qstat[b*4+3];
  float mn=(oc<2)?m0:m1, rs=(oc<2)?r0:r1;
  #pragma unroll
  for(int nt=0;nt<16;nt++){
    const s8v* vp = (const s8v*)&xq[16*nt+m_][0];
    s8v b0=vp[g], b1=vp[4+g];
    f32x4 acc[4];
    #pragma unroll
    for(int mt=0;mt<4;mt++) acc[mt]=bi4[mt];
    #pragma unroll
    for(int mt=0;mt<4;mt++){
      acc[mt]=__builtin_amdgcn_mfma_f32_16x16x32_bf16(af[mt][0],b0,acc[mt],0,0,0);
      acc[mt]=__builtin_amdgcn_mfma_f32_16x16x32_bf16(af[mt][1],b1,acc[mt],0,0,0);
    }
    float pp=0.f;
    #pragma unroll
    for(int mt=0;mt<4;mt++){
      f32x4 t=acc[mt];
      pp += gelu_f((t[0]-mn)*rs*g4[mt].x + t4[mt].x)*w4[mt].x;
      pp += gelu_f((t[1]-mn)*rs*g4[mt].y + t4[mt].y)*w4[mt].y;
      pp += gelu_f((t[2]-mn)*rs*g4[mt].z + t4[mt].z)*w4[mt].z;
      pp += gelu_f((t[3]-mn)*rs*g4[mt].w + t4[mt].w)*w4[mt].w;
    }
    pp += __shfl_xor(pp,16,64);
    pp += __shfl_xor(pp,32,64);
    if(g==0) part[wid][16*nt+m_]=pp;
  }
  __syncthreads();
  out[(size_t)b*QPIX + px0 + tid] =
      q2b[0] + part[0][tid]+part[1][tid]+part[2][tid]+part[3][tid];
}

extern "C" void kernel_launch(void* const* d_in, const int* in_sizes, int n_in,
                              void* d_out, int out_size, void* d_ws, size_t ws_size,
                              hipStream_t stream){
  const float* x   = (const float*)d_in[0];
  const float* Wp  = (const float*)d_in[1];
  const float* bp  = (const float*)d_in[2];
  const float* sw1 = (const float*)d_in[3];
  const float* sw2 = (const float*)d_in[4];
  const float* m1w = (const float*)d_in[5];
  const float* m1b = (const float*)d_in[6];
  const float* mg  = (const float*)d_in[7];
  const float* mbt = (const float*)d_in[8];
  const float* m2w = (const float*)d_in[9];
  const float* m2b = (const float*)d_in[10];
  const float* ww  = (const float*)d_in[11];
  const float* wb  = (const float*)d_in[12];
  const float* ng  = (const float*)d_in[13];
  const float* nb  = (const float*)d_in[14];
  const float* q1w = (const float*)d_in[15];
  const float* q1b = (const float*)d_in[16];
  const float* qg  = (const float*)d_in[17];
  const float* qbt = (const float*)d_in[18];
  const float* q2w = (const float*)d_in[19];
  const float* q2b = (const float*)d_in[20];
  float* out = (float*)d_out;

  char* w8 = (char*)d_ws;
  const size_t ACT_B = (size_t)64*BB*NPIX*sizeof(bf16);   // 41,370,624
  bf16*  A    = (bf16*)(w8);
  bf16*  Cb   = (bf16*)(w8 + ACT_B);
  float* SPEC = (float*)(w8 + 2*ACT_B);                    // XW / WT / Gpart overlays
  float* XF   = (float*)(w8 + 2*ACT_B + 9879552);
  float* XO   = (float*)(w8 + 2*ACT_B + 9879552 + 1179648);
  float* TB   = (float*)(w8 + 2*ACT_B + 9879552 + 2*1179648);
  char*  g8   = w8 + 2*ACT_B + 9879552 + 2*1179648 + 20992;
  float* TSTAT= (float*)g8;
  float* USTAT= TSTAT + 32;
  float* QSTAT= USTAT + 32;
  float* UxT  = QSTAT + 32;                  // 192*64
  float* UyT  = UxT + 12288;                 // 192*64
  unsigned short* WPK = (unsigned short*)(UyT + 12288);   // 16*4096 bf16
  float* GC   = (float*)(WPK + 16*4096);     // 8*4096 (Parseval gram)
  float* SC   = GC + 8*4096;                 // 8*64
  float* GFIN = SC + 8*64;                   // 8*4096 (reduced bypass gram)
  float* SFIN = GFIN + 8*4096;               // 8*64
  unsigned short* TPK = (unsigned short*)(SFIN + 8*64);   // 13*512 bf16 twiddle frags
  float* Gpart = SPEC;                       // 8*80*4096 fl = 10.49MB <= SPEC+XF
  float* Spart = Gpart + (size_t)8*GNB*4096;
  float* WT = SPEC;                          // 288*8192 floats = 9.44MB
  size_t needed = (size_t)(2*ACT_B) + 9879552 + 2*1179648 + 20992
                + 3*32*4 + 2*12288*4 + 16*4096*2 + 2*(8*4096+8*64)*4 + 13312;
  if(ws_size < needed) return;

  k_tab<<<11,256,0,stream>>>(TB);
  k_tpack<<<26,256,0,stream>>>(TB, TPK);
  k_pretab<<<dim3(192,2),64,0,stream>>>(Wp, bp, UxT, UyT);
  k_wpack<<<16,256,0,stream>>>(m1w, m2w, ww, q1w, WPK);
  k_encoder<<<dim3(158,BB),256,0,stream>>>(x, Wp, UxT, UyT, A);

  for(int l=0;l<4;l++){
    const float* sw1l = sw1 + (size_t)l*1179648;
    const float* sw2l = sw2 + (size_t)l*1179648;
    k_dftw<<<402,256,0,stream>>>(A, TB, SPEC);
    k_dfth<<<dim3(12,BB,4),256,0,stream>>>(SPEC, TB, XF);
    k_wtrans<<<dim3(64,5,2),256,0,stream>>>(sw1l, sw2l, WT);
    k_modemix<<<288,512,0,stream>>>(XF, WT, XO);
    k_ispec<<<1608,256,0,stream>>>(XO, TB, TPK, Cb);
    k_gramC<<<BB,256,0,stream>>>(XO, GC, SC);
    k_gramp<<<dim3(79,BB),256,0,stream>>>(A, Gpart, Spart, NN, NN);
    k_gramr<<<dim3(16,BB),256,0,stream>>>(Gpart, Spart, GFIN, SFIN, 79);
    k_statsA<<<16,256,0,stream>>>(GC, SC, GFIN, SFIN,
          m1w + (size_t)l*4096, m1b + l*64, ww + (size_t)l*4096, wb + l*64,
          TSTAT, USTAT);
    k_fuse<<<dim3(158,BB),256,0,stream>>>(Cb, A,
          WPK + (size_t)(l*3+0)*4096, m1b + l*64, mg + l*64, mbt + l*64,
          WPK + (size_t)(l*3+1)*4096, m2b + l*64,
          WPK + (size_t)(l*3+2)*4096, wb  + l*64, ng + l*64, nb + l*64,
          TSTAT, USTAT, (l==3)?1:0);
  }

  k_gramp<<<dim3(72,BB),256,0,stream>>>(A, Gpart, Spart, SS, SS);
  k_gramr<<<dim3(16,BB),256,0,stream>>>(Gpart, Spart, GFIN, SFIN, 72);
  k_statsQ<<<BB,256,0,stream>>>(GFIN, SFIN, q1w, q1b, QSTAT);
  k_qout<<<dim3(144,BB),256,0,stream>>>(A, WPK + (size_t)12*4096, q1b,
          qg, qbt, q2w, q2b, QSTAT, out);
}

// Round 15
// 1077.355 us; speedup vs baseline: 2.0440x; 1.1570x over previous
//
#include <hip/hip_runtime.h>
#include <hip/hip_bf16.h>
#include <math.h>

// FNO2d: B=8, S=192, pad->201x201, C=64, modes 12x12, 4 layers.
// Pixel-major activations [b][p][c]; MFMA conv GEMMs; MFMA inverse-W (ispec);
// chunked Parseval Gram (k_gramC) for the spectral branch; register-tile Gram
// for the bypass (512px/block + parallel slab reduce); fast sigmoid-gelu.

#define NN 201
#define SS 192
#define NPIX 40401
#define QPIX 36864
#define BB 8
#define GNB 80           // gram slabs per b, 512 px each
#define XWPL 1234944     // 1608*12*64 (re/im plane stride in floats)
#define PI_F 3.14159265358979323846f

typedef __hip_bfloat16 bf16;
typedef __attribute__((ext_vector_type(8))) short s8v;
typedef __attribute__((ext_vector_type(4))) float f32x4;

// tanh-form gelu via sigmoid: x*sigma(1.5957691x + 0.0713548x^3); |err| <= ~1e-3
__device__ __forceinline__ float gelu_f(float x){
  float x2 = x*x;
  float t  = fmaf(x2, 0.0713548162f, 1.5957691216f);
  float e  = __expf(-x*t);
  return x*__builtin_amdgcn_rcpf(1.0f+e);
}
__device__ __forceinline__ float b2f(bf16 v){ return __bfloat162float(v); }
__device__ __forceinline__ bf16  f2b(float v){ return __float2bfloat16(v); }
__device__ __forceinline__ unsigned short f2bu(float x){
  bf16 h = __float2bfloat16(x);
  unsigned short u; __builtin_memcpy(&u,&h,2); return u;
}
__device__ __forceinline__ float bu2f(unsigned short u){
  unsigned int x = ((unsigned int)u)<<16; float f; __builtin_memcpy(&f,&x,4); return f;
}

// tab[k][n]: cos/sin(2*pi*k*n/201), k=0..12, exact mod-201 reduction
__global__ void k_tab(float* __restrict__ tab){
  int t = blockIdx.x*blockDim.x+threadIdx.x;
  if(t>=13*NN) return;
  int k=t/NN, n=t-k*NN;
  int m=(k*n)%NN;
  float ang = (2.0f*PI_F/201.0f)*(float)m;
  tab[2*t]   = cosf(ang);
  tab[2*t+1] = sinf(ang);
}

// Pack inverse-W twiddles into MFMA A-fragment order (bf16).
__global__ void k_tpack(const float* __restrict__ tab, unsigned short* __restrict__ TPK){
  int e = blockIdx.x*256 + threadIdx.x;
  if(e>=6656) return;
  int wt=e>>9, lane=(e>>3)&63, j=e&7;
  int m_=lane&15, g=lane>>4;
  int w = wt*16+m_;
  int k24 = g*8+j;
  float v=0.f;
  if(k24<24 && w<201){
    float2 cs = ((const float2*)tab)[(k24>>1)*NN + w];
    v = (k24&1)? cs.y : cs.x;
  }
  TPK[e]=f2bu(v);
}

// Separable encoder tables. grid (192,2), 64 thr.
__global__ void k_pretab(const float* __restrict__ Wp, const float* __restrict__ bp,
                         float* __restrict__ Ux, float* __restrict__ Uy){
  int i = blockIdx.x;
  int ax = blockIdx.y;
  int c = threadIdx.x;
  float g = (float)i*(1.0f/191.0f);
  float acc;
  if(ax==0) acc = bp[c] + g*Wp[64+c];
  else      acc = g*Wp[128+c];
  int cosBase = (ax==0)? 3 : 4;
  int sinBase = (ax==0)? 23 : 24;
  #pragma unroll
  for(int l=0;l<10;l++){
    float f = PI_F*(float)(1<<l);
    float sv,cv;
    sincosf(g*f,&sv,&cv);
    acc += cv*Wp[(cosBase+2*l)*64+c] + sv*Wp[(sinBase+2*l)*64+c];
  }
  float* U = (ax==0)? Ux : Uy;
  U[i*64+c] = acc;
}

// Pack 16 64x64 weight matrices into bf16 MFMA-fragment order.
__global__ void k_wpack(const float* __restrict__ m1w, const float* __restrict__ m2w,
                        const float* __restrict__ ww,  const float* __restrict__ q1w,
                        unsigned short* __restrict__ WPK){
  int bx = blockIdx.x, tid = threadIdx.x;
  const float* src;
  if(bx<12){
    int l=bx/3, sel=bx-l*3;
    src = (sel==0)? m1w+(size_t)l*4096 : (sel==1)? m2w+(size_t)l*4096 : ww+(size_t)l*4096;
  } else {
    src = q1w + (size_t)(bx-12)*4096;
  }
  unsigned short* dst = WPK + (size_t)bx*4096;
  #pragma unroll
  for(int t=0;t<16;t++){
    int d = tid*16+t;
    int frag=d>>9, lane=(d>>3)&63, j=d&7;
    int mt=frag>>1, kh=frag&1, m_=lane&15, g=lane>>4;
    dst[d] = f2bu(src[(size_t)(16*mt+m_)*64 + 32*kh + 8*g + j]);
  }
}

// Transpose spectral weights for layer into WT[m][comp][io].
__global__ void __launch_bounds__(256) k_wtrans(const float* __restrict__ w1,
        const float* __restrict__ w2, float* __restrict__ WT){
  __shared__ float tile[64][65];
  int io0 = blockIdx.x*64;
  int c0  = blockIdx.y*64;
  int z   = blockIdx.z;
  const float* src = (z==0)? w1 : w2;
  int tid = threadIdx.x;
  #pragma unroll
  for(int it=0;it<16;it++){
    int e = tid + 256*it;
    int r = e>>6, c = e&63;
    if(c0+c<288) tile[r][c] = src[(size_t)(io0+r)*288 + c0 + c];
  }
  __syncthreads();
  #pragma unroll
  for(int it=0;it<16;it++){
    int e = tid + 256*it;
    int rp = e>>6, cp = e&63;
    int col = c0 + rp;
    if(col<288){
      int ky = col/24, rm = col - ky*24;
      int kx = rm>>1, comp = rm&1;
      int m = z*144 + ky*12 + kx;
      WT[(size_t)m*8192 + comp*4096 + io0 + cp] = tile[cp][rp];
    }
  }
}

// encoder: A[b][p][c] = x*Wp0[c] + Ux[hh][c] + Uy[ww][c]; zeros in pad.
__global__ void k_encoder(const float* __restrict__ x, const float* __restrict__ Wp,
                          const float* __restrict__ Ux, const float* __restrict__ Uy,
                          bf16* __restrict__ A){
  int tid=threadIdx.x;
  int p = blockIdx.x*256+tid;
  if(p>=NPIX) return;
  int b = blockIdx.y;
  uint4* dst = (uint4*)(A + ((size_t)b*NPIX + p)*64);
  int hh=p/NN, ww=p-hh*NN;
  if(hh>=SS || ww>=SS){
    uint4 z = {0,0,0,0};
    #pragma unroll
    for(int i=0;i<8;i++) dst[i]=z;
    return;
  }
  float xv = x[((size_t)b*SS+hh)*SS+ww];
  const float4* ux = (const float4*)(Ux + hh*64);
  const float4* uy = (const float4*)(Uy + ww*64);
  const float4* w0 = (const float4*)Wp;
  #pragma unroll
  for(int i=0;i<8;i++){
    float4 a0 = ux[2*i],   a1 = ux[2*i+1];
    float4 b0 = uy[2*i],   b1 = uy[2*i+1];
    float4 c0 = w0[2*i],   c1 = w0[2*i+1];
    float v0=xv*c0.x+a0.x+b0.x, v1=xv*c0.y+a0.y+b0.y;
    float v2=xv*c0.z+a0.z+b0.z, v3=xv*c0.w+a0.w+b0.w;
    float v4=xv*c1.x+a1.x+b1.x, v5=xv*c1.y+a1.y+b1.y;
    float v6=xv*c1.z+a1.z+b1.z, v7=xv*c1.w+a1.w+b1.w;
    uint4 v;
    v.x = (unsigned)f2bu(v0) | ((unsigned)f2bu(v1)<<16);
    v.y = (unsigned)f2bu(v2) | ((unsigned)f2bu(v3)<<16);
    v.z = (unsigned)f2bu(v4) | ((unsigned)f2bu(v5)<<16);
    v.w = (unsigned)f2bu(v6) | ((unsigned)f2bu(v7)<<16);
    dst[i]=v;
  }
}

// DFT along W. Wave per row R=b*201+h, lane=c. XW[re/im][R][kx][c].
__global__ void __launch_bounds__(256) k_dftw(const bf16* __restrict__ A,
        const float* __restrict__ tab, float* __restrict__ XW){
  __shared__ float2 st[2412];
  int tid=threadIdx.x;
  for(int i=tid;i<2412;i+=256) st[i]=((const float2*)tab)[i];
  __syncthreads();
  int R = blockIdx.x*4 + (tid>>6);
  int l = tid&63;
  const bf16* base = A + ((size_t)R*NN)*64 + l;
  float ar0=0.f;
  float ar[11], ai[11];
  #pragma unroll
  for(int k=0;k<11;k++){ ar[k]=0.f; ai[k]=0.f; }
  for(int w=0;w<NN;w++){
    float a = b2f(base[(size_t)w*64]);
    ar0 += a;
    #pragma unroll
    for(int k=0;k<11;k++){
      float2 cs = st[(k+1)*NN+w];
      ar[k] += a*cs.x;
      ai[k] += a*cs.y;
    }
  }
  float* xre = XW + ((size_t)R*12)*64 + l;
  float* xim = xre + XWPL;
  xre[0]=ar0; xim[0]=0.f;
  #pragma unroll
  for(int k=0;k<11;k++){
    xre[(size_t)(k+1)*64] = ar[k];
    xim[(size_t)(k+1)*64] = -ai[k];
  }
}

// DFT along H, LDS-staged: grid (12, 8, 4); z = (jhalf<<1)|chalf. ILP x2.
__global__ void __launch_bounds__(256) k_dfth(const float* __restrict__ XW,
        const float* __restrict__ tab, float* __restrict__ XF){
  __shared__ float sre[201*32];
  __shared__ float sim[201*32];
  __shared__ float2 tw[13*NN];
  int kx=blockIdx.x, b=blockIdx.y;
  int z=blockIdx.z; int jh=z>>1, ch=z&1;
  int tid=threadIdx.x;
  for(int i=tid;i<13*NN;i+=256) tw[i]=((const float2*)tab)[i];
  for(int i=tid;i<201*32;i+=256){
    int h=i>>5, c=ch*32+(i&31);
    size_t idx=(((size_t)b*NN+h)*12+kx)*64+c;
    sre[i]=XW[idx];
    sim[i]=XW[idx+XWPL];
  }
  __syncthreads();
  for(int o=tid;o<384;o+=256){
    int jj=o>>5, cl=o&31;
    int j=jh*12+jj;
    int k2=(j<12)?j:24-j;
    float sgn=(j<12)?-1.f:1.f;
    float re0=0.f,im0=0.f,re1=0.f,im1=0.f;
    const float* pr=sre+cl;
    const float* pi=sim+cl;
    const float2* tk=tw+k2*NN;
    int h=0;
    for(;h+1<NN;h+=2){
      float a0=pr[h*32], b0=pi[h*32];
      float2 cs0=tk[h];
      float c0=cs0.x, s0=sgn*cs0.y;
      re0 = fmaf(a0,c0, fmaf(-b0,s0, re0));
      im0 = fmaf(a0,s0, fmaf( b0,c0, im0));
      float a1=pr[(h+1)*32], b1=pi[(h+1)*32];
      float2 cs1=tk[h+1];
      float c1=cs1.x, s1=sgn*cs1.y;
      re1 = fmaf(a1,c1, fmaf(-b1,s1, re1));
      im1 = fmaf(a1,s1, fmaf( b1,c1, im1));
    }
    {
      float a0=pr[h*32], b0=pi[h*32];
      float2 cs0=tk[h];
      float c0=cs0.x, s0=sgn*cs0.y;
      re0 = fmaf(a0,c0, fmaf(-b0,s0, re0));
      im0 = fmaf(a0,s0, fmaf( b0,c0, im0));
    }
    int m=j*12+kx;
    int c=ch*32+cl;
    XF[(size_t)m*1024+(b*64+c)*2]  =re0+re1;
    XF[(size_t)m*1024+(b*64+c)*2+1]=im0+im1;
  }
}

// per-mode 64x64 complex mix; ILP split accumulators.
__global__ void __launch_bounds__(512) k_modemix(const float* __restrict__ XF,
     const float* __restrict__ WT, float* __restrict__ XO){
  __shared__ float sx[1024];
  __shared__ float swr[4096], swi[4096];
  int m=blockIdx.x;
  int tid=threadIdx.x;
  sx[tid]     = XF[(size_t)m*1024+tid];
  sx[tid+512] = XF[(size_t)m*1024+tid+512];
  const float* wr = WT + (size_t)m*8192;
  const float* wi = wr + 4096;
  for(int io=tid;io<4096;io+=512){
    swr[io]=wr[io];
    swi[io]=wi[io];
  }
  __syncthreads();
  int b=tid>>6, o=tid&63;
  const float* xb = sx + b*128;
  float re0=0.f,re1=0.f,im0=0.f,im1=0.f;
  #pragma unroll 8
  for(int i=0;i<64;i+=2){
    float a=xb[2*i], b2=xb[2*i+1];
    float c=swr[i*64+o], d=swi[i*64+o];
    re0 = fmaf(a,c, fmaf(-b2,d, re0));
    im0 = fmaf(a,d, fmaf( b2,c, im0));
    float a1=xb[2*i+2], b3=xb[2*i+3];
    float c1=swr[(i+1)*64+o], d1=swi[(i+1)*64+o];
    re1 = fmaf(a1,c1, fmaf(-b3,d1, re1));
    im1 = fmaf(a1,d1, fmaf( b3,c1, im1));
  }
  XO[2*((size_t)m*512+tid)]  =re0+re1;
  XO[2*((size_t)m*512+tid)+1]=im0+im1;
}

// Merged inverse: per row R, idfth into LDS (factors folded), then the C2R
// along W as MFMA: C[w][o] = sum_k24 T[w][k24]*Y24[k24][o], T prepacked (TPK).
__global__ void __launch_bounds__(256) k_ispec(const float* __restrict__ XO,
        const float* __restrict__ tab, const unsigned short* __restrict__ TPK,
        bf16* __restrict__ C){
  __shared__ float2 yl[12][64];
  __shared__ float2 cs13[13];
  int R=blockIdx.x;
  int b=R/NN, h=R-b*NN;
  int tid=threadIdx.x;
  if(tid<13) cs13[tid]=((const float2*)tab)[tid*NN+h];
  __syncthreads();
  const float sc = 1.0f/40401.0f;
  #pragma unroll
  for(int it=0;it<3;it++){
    int item = tid + 256*it;
    int kx = item>>6, o = item&63;
    float re0=0.f,im0=0.f,re1=0.f,im1=0.f;
    #pragma unroll
    for(int j=0;j<24;j+=2){
      {
        int k2=(j<12)?j:24-j;
        float sgn=(j<12)?1.0f:-1.0f;
        float2 xo = *(const float2*)(XO + 2*(((size_t)(j*12+kx)*512) + b*64 + o));
        float2 cs = cs13[k2];
        float cc=cs.x, s2=sgn*cs.y;
        re0 = fmaf(xo.x,cc, fmaf(-xo.y,s2, re0));
        im0 = fmaf(xo.x,s2, fmaf( xo.y,cc, im0));
      }
      {
        int j1=j+1;
        int k2=(j1<12)?j1:24-j1;
        float sgn=(j1<12)?1.0f:-1.0f;
        float2 xo = *(const float2*)(XO + 2*(((size_t)(j1*12+kx)*512) + b*64 + o));
        float2 cs = cs13[k2];
        float cc=cs.x, s2=sgn*cs.y;
        re1 = fmaf(xo.x,cc, fmaf(-xo.y,s2, re1));
        im1 = fmaf(xo.x,s2, fmaf( xo.y,cc, im1));
      }
    }
    float fr = (kx==0)? sc : 2.0f*sc;
    float fi = (kx==0)? sc : -2.0f*sc;
    yl[kx][o] = float2{ (re0+re1)*fr, (im0+im1)*fi };
  }
  __syncthreads();
  int wid=tid>>6, l=tid&63, m_=l&15, g=l>>4;
  int o = wid*16 + m_;
  s8v bfr;
  #pragma unroll
  for(int j=0;j<4;j++){
    float2 v = yl[4*g+j][o];
    bfr[2*j]   = (short)f2bu(v.x);
    bfr[2*j+1] = (short)f2bu(v.y);
  }
  bf16* cp = C + (size_t)R*NN*64;
  #pragma unroll
  for(int wt=0; wt<13; wt++){
    s8v af = *(const s8v*)(TPK + (size_t)wt*512 + l*8);
    f32x4 acc = f32x4{0.f,0.f,0.f,0.f};
    acc = __builtin_amdgcn_mfma_f32_16x16x32_bf16(af, bfr, acc, 0,0,0);
    #pragma unroll
    for(int e=0;e<4;e++){
      int w = wt*16 + 4*g + e;
      if(w<NN) cp[(size_t)w*64 + o] = f2b(acc[e]);
    }
  }
}

// Chunked Parseval Gram from XO: grid (9, BB). Block = 64-feature chunk.
// Writes partial GCp[(b*9+chunk)][4096]; SC written exactly by chunk 0.
__global__ void __launch_bounds__(256) k_gramC(const float* __restrict__ XO,
        float* __restrict__ GCp, float* __restrict__ SC){
  __shared__ unsigned short V[64][72];   // [channel][feature-in-chunk]
  int chunk=blockIdx.x, b=blockIdx.y, tid=threadIdx.x;
  const float s1=1.0f/201.0f;
  const float r2=0.70710678118f;
  const float q2=1.41421356237f;
  #pragma unroll
  for(int it=0;it<16;it++){
    int e = tid + it*256;
    int fl=e>>6, ch=e&63;
    int f = chunk*64 + fl;
    int base = b*64+ch;
    float v=0.f;
    if(f<528){
      int comp=f&1, kxm=f>>1;
      int kx0=kxm/24;
      int kx=1+kx0, m=kxm-kx0*24;
      v = q2*XO[2*((size_t)(m*12+kx)*512 + base)+comp];
    } else if(f==528){
      v = XO[2*(size_t)base];
    } else if(f<551){
      int q=f-529; int mm=1+(q>>1);
      const float* p1 = XO + 2*((size_t)(mm*12)*512 + base);
      const float* p2 = XO + 2*((size_t)((24-mm)*12)*512 + base);
      v = ((q&1)==0)? r2*(p1[0]+p2[0]) : r2*(p1[1]-p2[1]);
    } else if(f==551){
      v = r2*XO[2*((size_t)(144)*512 + base)];
    } else if(f==552){
      v = r2*XO[2*((size_t)(144)*512 + base)+1];
    }
    V[ch][fl]=f2bu(v*s1);
  }
  __syncthreads();
  int wid=tid>>6, l=tid&63, m_=l&15, g=l>>4;
  f32x4 acc[4];
  #pragma unroll
  for(int mt=0;mt<4;mt++) acc[mt]=f32x4{0.f,0.f,0.f,0.f};
  #pragma unroll
  for(int kc=0;kc<2;kc++){
    s8v bfr = *(const s8v*)&V[16*wid+m_][kc*32+8*g];
    #pragma unroll
    for(int mt=0;mt<4;mt++){
      s8v afr = *(const s8v*)&V[16*mt+m_][kc*32+8*g];
      acc[mt]=__builtin_amdgcn_mfma_f32_16x16x32_bf16(afr,bfr,acc[mt],0,0,0);
    }
  }
  float* gb = GCp + ((size_t)(b*9+chunk))*4096;
  #pragma unroll
  for(int mt=0;mt<4;mt++){
    #pragma unroll
    for(int e=0;e<4;e++)
      gb[(size_t)(16*mt+4*g+e)*64 + 16*wid + m_] = acc[mt][e];
  }
  if(chunk==0 && tid<64) SC[b*64+tid] = XO[2*(size_t)(b*64+tid)];
}

// Reduce GCp chunks -> GC. grid (16, BB).
__global__ void k_gcred(const float* __restrict__ GCp, float* __restrict__ GC){
  int b=blockIdx.y;
  int idx=blockIdx.x*256+threadIdx.x;
  float s=0.f;
  #pragma unroll
  for(int k=0;k<9;k++) s += GCp[((size_t)(b*9+k))*4096 + idx];
  GC[(size_t)b*4096 + idx]=s;
}

// Gram partials for A (float register tiles). grid (nblk, BB); 512 px/block.
__global__ void __launch_bounds__(256) k_gramp(const bf16* __restrict__ X,
        float* __restrict__ Gpart, float* __restrict__ Spart, int HR, int WR){
  __shared__ float sx[8704];
  int b = blockIdx.y, blk = blockIdx.x;
  int npix = HR*WR;
  int tid = threadIdx.x;
  int wid = tid>>6, lane = tid&63;
  int i0 = (lane>>3)*8, j0 = (lane&7)*8;
  float acc[8][8];
  #pragma unroll
  for(int r=0;r<8;r++){
    #pragma unroll
    for(int s=0;s<8;s++) acc[r][s]=0.f;
  }
  float cs = 0.f;
  for(int tile=0;tile<4;tile++){
    int rp0 = blk*512 + tile*128;
    __syncthreads();
    #pragma unroll
    for(int it=0;it<4;it++){
      int chunk = tid + it*256;
      int k = chunk>>3, c0 = (chunk&7)*8;
      int rp = rp0+k;
      float v[8]={0,0,0,0,0,0,0,0};
      if(rp<npix){
        int gp;
        if(WR==NN) gp = rp;
        else { int hh=rp/WR, ww=rp-hh*WR; gp = hh*NN+ww; }
        s8v xv = *(const s8v*)(X + ((size_t)b*NPIX + gp)*64 + c0);
        #pragma unroll
        for(int j=0;j<8;j++) v[j]=bu2f((unsigned short)xv[j]);
      }
      #pragma unroll
      for(int j=0;j<8;j++) sx[k*68+c0+j]=v[j];
    }
    __syncthreads();
    for(int pp=0;pp<32;pp++){
      const float* row = sx + (wid*32+pp)*68;
      cs += row[lane];
      const float4* ri = (const float4*)(row + i0);
      const float4* rj = (const float4*)(row + j0);
      float4 xi0 = ri[0], xi1 = ri[1];
      float4 xj0 = rj[0], xj1 = rj[1];
      float xi[8] = {xi0.x,xi0.y,xi0.z,xi0.w, xi1.x,xi1.y,xi1.z,xi1.w};
      float xj[8] = {xj0.x,xj0.y,xj0.z,xj0.w, xj1.x,xj1.y,xj1.z,xj1.w};
      #pragma unroll
      for(int r=0;r<8;r++){
        #pragma unroll
        for(int s=0;s<8;s++) acc[r][s] += xi[r]*xj[s];
      }
    }
  }
  __syncthreads();
  float* scol = sx + 8320;
  scol[tid] = cs;
  if(wid>=2){
    float* d = sx + (tid-128)*65;
    #pragma unroll
    for(int r=0;r<8;r++){
      #pragma unroll
      for(int s=0;s<8;s++) d[r*8+s]=acc[r][s];
    }
  }
  __syncthreads();
  if(wid<2){
    const float* d = sx + tid*65;
    #pragma unroll
    for(int r=0;r<8;r++){
      #pragma unroll
      for(int s=0;s<8;s++) acc[r][s]+=d[r*8+s];
    }
  }
  if(tid<64){
    float tot = scol[tid]+scol[tid+64]+scol[tid+128]+scol[tid+192];
    Spart[((size_t)b*GNB + blk)*64 + tid] = tot;
  }
  __syncthreads();
  if(wid==1){
    float* d = sx + (tid-64)*65;
    #pragma unroll
    for(int r=0;r<8;r++){
      #pragma unroll
      for(int s=0;s<8;s++) d[r*8+s]=acc[r][s];
    }
  }
  __syncthreads();
  if(wid==0){
    const float* d = sx + tid*65;
    #pragma unroll
    for(int r=0;r<8;r++){
      #pragma unroll
      for(int s=0;s<8;s++) acc[r][s]+=d[r*8+s];
    }
    float* g = Gpart + ((size_t)b*GNB + blk)*4096;
    #pragma unroll
    for(int r=0;r<8;r++){
      #pragma unroll
      for(int s=0;s<8;s++) g[(i0+r)*64 + (j0+s)] = acc[r][s];
    }
  }
}

// Parallel slab reduce: grid (16, BB). Gfin[b][4096], Sfin[b][64].
__global__ void __launch_bounds__(256) k_gramr(const float* __restrict__ Gpart,
        const float* __restrict__ Spart, float* __restrict__ Gfin,
        float* __restrict__ Sfin, int nblk){
  int b = blockIdx.y;
  int idx = blockIdx.x*256 + threadIdx.x;
  float s0=0.f,s1=0.f,s2=0.f,s3=0.f;
  int k=0;
  for(;k+3<nblk;k+=4){
    s0 += Gpart[((size_t)b*GNB + k  )*4096 + idx];
    s1 += Gpart[((size_t)b*GNB + k+1)*4096 + idx];
    s2 += Gpart[((size_t)b*GNB + k+2)*4096 + idx];
    s3 += Gpart[((size_t)b*GNB + k+3)*4096 + idx];
  }
  for(;k<nblk;k++) s0 += Gpart[((size_t)b*GNB + k)*4096 + idx];
  Gfin[(size_t)b*4096 + idx] = (s0+s1)+(s2+s3);
  if(blockIdx.x==0 && threadIdx.x<64){
    float ss=0.f;
    for(int j=0;j<nblk;j++) ss += Spart[((size_t)b*GNB + j)*64 + threadIdx.x];
    Sfin[b*64 + threadIdx.x]=ss;
  }
}

// Merged stats (grid 16): zb<8 -> Cb-stats from GC/SC (Parseval); zb>=8 -> A-stats
// from the pre-reduced Gfin/Sfin.
__global__ void __launch_bounds__(256) k_statsA(
        const float* __restrict__ GC, const float* __restrict__ SC,
        const float* __restrict__ Gfin, const float* __restrict__ Sfin,
        const float* __restrict__ m1wl, const float* __restrict__ m1bl,
        const float* __restrict__ wwl,  const float* __restrict__ wbl,
        float* __restrict__ TSTAT, float* __restrict__ USTAT){
  __shared__ float Gs[4096];
  __shared__ float Ss[64];
  __shared__ float rs[256], rq[256];
  int zb=blockIdx.x, t=threadIdx.x;
  const float* GS = (zb<8)? (GC + (size_t)zb*4096) : (Gfin + (size_t)(zb-8)*4096);
  const float* SS_ = (zb<8)? (SC + (size_t)zb*64)   : (Sfin + (size_t)(zb-8)*64);
  #pragma unroll
  for(int e=0;e<16;e++) Gs[t*16+e]=GS[t*16+e];
  if(t<64) Ss[t]=SS_[t];
  __syncthreads();
  const float* W    = (zb<8)? m1wl : wwl;
  const float* bias = (zb<8)? m1bl : wbl;
  float* stat       = (zb<8)? TSTAT : USTAT;
  int b = (zb<8)? zb : zb-8;
  int o = t&63, sl = t>>6;
  float w[64];
  #pragma unroll
  for(int j2=0;j2<64;j2++) w[j2]=bu2f(f2bu(W[(size_t)o*64+j2]));
  const float* Gr = Gs + (size_t)(sl*16)*64;
  float quad=0.f;
  #pragma unroll
  for(int r=0;r<16;r++){
    const float* gr = Gr + r*64;
    float tt=0.f;
    #pragma unroll
    for(int j2=0;j2<64;j2++) tt += gr[j2]*w[j2];
    quad += w[sl*16+r]*tt;
  }
  float dot=0.f;
  #pragma unroll
  for(int j2=0;j2<64;j2++) dot += w[j2]*Ss[j2];
  float bo = bias[o];
  float Nf = (float)NPIX;
  float sm = (sl==0)? (dot + Nf*bo) : 0.f;
  float sq = quad + ((sl==0)? (2.f*bo*dot + Nf*bo*bo) : 0.f);
  rs[t]=sm; rq[t]=sq;
  __syncthreads();
  if(t<64){
    float s2 = rs[t]+rs[t+64]+rs[t+128]+rs[t+192];
    float q2 = rq[t]+rq[t+64]+rq[t+128]+rq[t+192];
    for(int off=16;off>0;off>>=1){
      s2 += __shfl_down(s2,off,32);
      q2 += __shfl_down(q2,off,32);
    }
    if((t&31)==0){
      int g=t>>5;
      float invN = 1.f/(Nf*32.f);
      float mean = s2*invN;
      float var = q2*invN - mean*mean;
      stat[b*4+g*2]   = mean;
      stat[b*4+g*2+1] = rsqrtf(fmaxf(var,0.f)+1e-5f);
    }
  }
}

// Head stats from pre-reduced Gfin/Sfin (grid 8).
__global__ void __launch_bounds__(256) k_statsQ(const float* __restrict__ Gfin,
        const float* __restrict__ Sfin,
        const float* __restrict__ W, const float* __restrict__ bias,
        float* __restrict__ stat){
  __shared__ float Gs[4096];
  __shared__ float Ss[64];
  __shared__ float red[8];
  int b=blockIdx.x, t=threadIdx.x;
  #pragma unroll
  for(int e=0;e<16;e++) Gs[t*16+e]=Gfin[(size_t)b*4096 + t*16+e];
  if(t<64) Ss[t]=Sfin[b*64+t];
  __syncthreads();
  float w[64];
  #pragma unroll
  for(int j2=0;j2<64;j2++) w[j2]=bu2f(f2bu(W[(size_t)t*64+j2]));
  float quad=0.f;
  #pragma unroll
  for(int i=0;i<64;i++){
    const float* gr = Gs + i*64;
    float tt=0.f;
    #pragma unroll
    for(int j2=0;j2<64;j2++) tt += gr[j2]*w[j2];
    quad += w[i]*tt;
  }
  float dot=0.f;
  #pragma unroll
  for(int j2=0;j2<64;j2++) dot += w[j2]*Ss[j2];
  float bo=bias[t];
  float Nf=(float)QPIX;
  float sm = dot + Nf*bo;
  float sq = quad + 2.f*bo*dot + Nf*bo*bo;
  for(int off=32;off>0;off>>=1){
    sm += __shfl_down(sm,off,64);
    sq += __shfl_down(sq,off,64);
  }
  int wid=t>>6;
  if((t&63)==0){ red[wid*2]=sm; red[wid*2+1]=sq; }
  __syncthreads();
  if(t<2){
    float smt = red[t*4+0]+red[t*4+2];
    float sqt = red[t*4+1]+red[t*4+3];
    float invN = 1.f/(Nf*128.f);
    float mean = smt*invN;
    float var = sqt*invN - mean*mean;
    stat[b*4+t*2]   = mean;
    stat[b*4+t*2+1] = rsqrtf(fmaxf(var,0.f)+1e-5f);
  }
}

// MFMA fused layer with packed weights.
__global__ void __launch_bounds__(256) k_fuse(const bf16* __restrict__ Cb,
    bf16* __restrict__ A,
    const unsigned short* __restrict__ wp1, const float* __restrict__ m1b,
    const float* __restrict__ mg,  const float* __restrict__ mbt,
    const unsigned short* __restrict__ wp2, const float* __restrict__ m2b,
    const unsigned short* __restrict__ wpw, const float* __restrict__ wbk,
    const float* __restrict__ ng,  const float* __restrict__ nb,
    const float* __restrict__ tstat, const float* __restrict__ ustat, int last){
  __shared__ unsigned short vlds[4][64][72];
  int tid=threadIdx.x;
  int wid=tid>>6, l=tid&63;
  int m_=l&15, g=l>>4;
  int b=blockIdx.y;
  int p0=blockIdx.x*256 + wid*64;
  const bf16* cbb = Cb + (size_t)b*NPIX*64;
  const bf16* ab  = A  + (size_t)b*NPIX*64;

  s8v af[4][2];
  f32x4 acc[4][4];

  #pragma unroll
  for(int mt=0;mt<4;mt++){
    #pragma unroll
    for(int kh=0;kh<2;kh++)
      af[mt][kh]=*(const s8v*)(wp1 + (mt*2+kh)*512 + l*8);
    float4 b4 = *(const float4*)(m1b + 16*mt + 4*g);
    #pragma unroll
    for(int nt=0;nt<4;nt++) acc[mt][nt]=f32x4{b4.x,b4.y,b4.z,b4.w};
  }
  #pragma unroll
  for(int nt=0;nt<4;nt++){
    int p = p0 + 16*nt + m_;
    int pc = p<NPIX? p : NPIX-1;
    const s8v* xb = (const s8v*)(cbb + (size_t)pc*64);
    s8v b0 = xb[g], b1 = xb[4+g];
    #pragma unroll
    for(int mt=0;mt<4;mt++){
      acc[mt][nt]=__builtin_amdgcn_mfma_f32_16x16x32_bf16(af[mt][0],b0,acc[mt][nt],0,0,0);
      acc[mt][nt]=__builtin_amdgcn_mfma_f32_16x16x32_bf16(af[mt][1],b1,acc[mt][nt],0,0,0);
    }
  }
  {
    float tm0=tstat[b*4],tr0=tstat[b*4+1],tm1=tstat[b*4+2],tr1=tstat[b*4+3];
    #pragma unroll
    for(int mt=0;mt<4;mt++){
      float4 g4 = *(const float4*)(mg  + 16*mt + 4*g);
      float4 t4 = *(const float4*)(mbt + 16*mt + 4*g);
      float mn = (mt<2)? tm0 : tm1;
      float rs = (mt<2)? tr0 : tr1;
      #pragma unroll
      for(int nt=0;nt<4;nt++){
        int pl = 16*nt + m_;
        f32x4 t = acc[mt][nt];
        float v0 = gelu_f((t[0]-mn)*rs*g4.x + t4.x);
        float v1 = gelu_f((t[1]-mn)*rs*g4.y + t4.y);
        float v2 = gelu_f((t[2]-mn)*rs*g4.z + t4.z);
        float v3 = gelu_f((t[3]-mn)*rs*g4.w + t4.w);
        uint2 pk;
        pk.x = (unsigned)f2bu(v0) | ((unsigned)f2bu(v1)<<16);
        pk.y = (unsigned)f2bu(v2) | ((unsigned)f2bu(v3)<<16);
        *(uint2*)&vlds[wid][pl][16*mt+4*g] = pk;
      }
    }
  }
  __syncthreads();
  #pragma unroll
  for(int mt=0;mt<4;mt++){
    #pragma unroll
    for(int kh=0;kh<2;kh++)
      af[mt][kh]=*(const s8v*)(wpw + (mt*2+kh)*512 + l*8);
    float4 b4 = *(const float4*)(wbk + 16*mt + 4*g);
    #pragma unroll
    for(int nt=0;nt<4;nt++) acc[mt][nt]=f32x4{b4.x,b4.y,b4.z,b4.w};
  }
  #pragma unroll
  for(int nt=0;nt<4;nt++){
    int p = p0 + 16*nt + m_;
    int pc = p<NPIX? p : NPIX-1;
    const s8v* xb = (const s8v*)(ab + (size_t)pc*64);
    s8v b0 = xb[g], b1 = xb[4+g];
    #pragma unroll
    for(int mt=0;mt<4;mt++){
      acc[mt][nt]=__builtin_amdgcn_mfma_f32_16x16x32_bf16(af[mt][0],b0,acc[mt][nt],0,0,0);
      acc[mt][nt]=__builtin_amdgcn_mfma_f32_16x16x32_bf16(af[mt][1],b1,acc[mt][nt],0,0,0);
    }
  }
  {
    float um0=ustat[b*4],ur0=ustat[b*4+1],um1=ustat[b*4+2],ur1=ustat[b*4+3];
    #pragma unroll
    for(int mt=0;mt<4;mt++){
      float4 n4 = *(const float4*)(ng  + 16*mt + 4*g);
      float4 nb4= *(const float4*)(nb  + 16*mt + 4*g);
      float4 m24= *(const float4*)(m2b + 16*mt + 4*g);
      float mn = (mt<2)? um0 : um1;
      float rs = (mt<2)? ur0 : ur1;
      #pragma unroll
      for(int nt=0;nt<4;nt++){
        f32x4 u = acc[mt][nt];
        u[0] = m24.x + (u[0]-mn)*rs*n4.x + nb4.x;
        u[1] = m24.y + (u[1]-mn)*rs*n4.y + nb4.y;
        u[2] = m24.z + (u[2]-mn)*rs*n4.z + nb4.z;
        u[3] = m24.w + (u[3]-mn)*rs*n4.w + nb4.w;
        acc[mt][nt]=u;
      }
    }
  }
  #pragma unroll
  for(int mt=0;mt<4;mt++){
    #pragma unroll
    for(int kh=0;kh<2;kh++)
      af[mt][kh]=*(const s8v*)(wp2 + (mt*2+kh)*512 + l*8);
  }
  #pragma unroll
  for(int nt=0;nt<4;nt++){
    int pl = 16*nt + m_;
    const s8v* vp = (const s8v*)&vlds[wid][pl][0];
    s8v b0 = vp[g], b1 = vp[4+g];
    #pragma unroll
    for(int mt=0;mt<4;mt++){
      acc[mt][nt]=__builtin_amdgcn_mfma_f32_16x16x32_bf16(af[mt][0],b0,acc[mt][nt],0,0,0);
      acc[mt][nt]=__builtin_amdgcn_mfma_f32_16x16x32_bf16(af[mt][1],b1,acc[mt][nt],0,0,0);
    }
  }
  #pragma unroll
  for(int nt=0;nt<4;nt++){
    int p = p0 + 16*nt + m_;
    if(p>=NPIX) continue;
    bf16* dp = A + ((size_t)b*NPIX + p)*64;
    #pragma unroll
    for(int mt=0;mt<4;mt++){
      f32x4 h = acc[mt][nt];
      float h0=h[0],h1=h[1],h2=h[2],h3=h[3];
      if(!last){ h0=gelu_f(h0); h1=gelu_f(h1); h2=gelu_f(h2); h3=gelu_f(h3); }
      uint2 pk;
      pk.x = (unsigned)f2bu(h0) | ((unsigned)f2bu(h1)<<16);
      pk.y = (unsigned)f2bu(h2) | ((unsigned)f2bu(h3)<<16);
      *(uint2*)(dp + 16*mt + 4*g) = pk;
    }
  }
}

// Head: block stages 256 px of A-crop into LDS once; wave = one oc chunk; LDS reduce.
__global__ void __launch_bounds__(256) k_qout(const bf16* __restrict__ A,
    const unsigned short* __restrict__ qpack, const float* __restrict__ q1b,
    const float* __restrict__ qg, const float* __restrict__ qbt,
    const float* __restrict__ q2w, const float* __restrict__ q2b,
    const float* __restrict__ qstat, float* __restrict__ out){
  __shared__ unsigned short xq[256][72];
  __shared__ float part[4][256];
  int tid=threadIdx.x;
  int wid=tid>>6, l=tid&63;
  int m_=l&15, g=l>>4;
  int b=blockIdx.y;
  int px0=blockIdx.x*256;
  {
    int p = px0 + tid;
    int hh=p/SS, ww2=p-hh*SS;
    const uint4* src=(const uint4*)(A + (((size_t)b*NPIX) + (size_t)hh*NN + ww2)*64);
    uint4* drow=(uint4*)&xq[tid][0];
    #pragma unroll
    for(int i=0;i<8;i++) drow[i]=src[i];
  }
  __syncthreads();
  int oc=wid;
  const unsigned short* wp = qpack + (size_t)oc*4096;
  s8v af[4][2];
  f32x4 bi4[4];
  float4 g4[4], t4[4], w4[4];
  #pragma unroll
  for(int mt=0;mt<4;mt++){
    #pragma unroll
    for(int kh=0;kh<2;kh++)
      af[mt][kh]=*(const s8v*)(wp + (mt*2+kh)*512 + l*8);
    float4 b4=*(const float4*)(q1b + 64*oc + 16*mt + 4*g);
    bi4[mt]=f32x4{b4.x,b4.y,b4.z,b4.w};
    g4[mt]=*(const float4*)(qg  + 64*oc + 16*mt + 4*g);
    t4[mt]=*(const float4*)(qbt + 64*oc + 16*mt + 4*g);
    w4[mt]=*(const float4*)(q2w + 64*oc + 16*mt + 4*g);
  }
  float m0=qstat[b*4],r0=qstat[b*4+1],m1=qstat[b*4+2],r1=qstat[b*4+3];
  float mn=(oc<2)?m0:m1, rs=(oc<2)?r0:r1;
  #pragma unroll
  for(int nt=0;nt<16;nt++){
    const s8v* vp = (const s8v*)&xq[16*nt+m_][0];
    s8v b0=vp[g], b1=vp[4+g];
    f32x4 acc[4];
    #pragma unroll
    for(int mt=0;mt<4;mt++) acc[mt]=bi4[mt];
    #pragma unroll
    for(int mt=0;mt<4;mt++){
      acc[mt]=__builtin_amdgcn_mfma_f32_16x16x32_bf16(af[mt][0],b0,acc[mt],0,0,0);
      acc[mt]=__builtin_amdgcn_mfma_f32_16x16x32_bf16(af[mt][1],b1,acc[mt],0,0,0);
    }
    float pp=0.f;
    #pragma unroll
    for(int mt=0;mt<4;mt++){
      f32x4 t=acc[mt];
      pp += gelu_f((t[0]-mn)*rs*g4[mt].x + t4[mt].x)*w4[mt].x;
      pp += gelu_f((t[1]-mn)*rs*g4[mt].y + t4[mt].y)*w4[mt].y;
      pp += gelu_f((t[2]-mn)*rs*g4[mt].z + t4[mt].z)*w4[mt].z;
      pp += gelu_f((t[3]-mn)*rs*g4[mt].w + t4[mt].w)*w4[mt].w;
    }
    pp += __shfl_xor(pp,16,64);
    pp += __shfl_xor(pp,32,64);
    if(g==0) part[wid][16*nt+m_]=pp;
  }
  __syncthreads();
  out[(size_t)b*QPIX + px0 + tid] =
      q2b[0] + part[0][tid]+part[1][tid]+part[2][tid]+part[3][tid];
}

extern "C" void kernel_launch(void* const* d_in, const int* in_sizes, int n_in,
                              void* d_out, int out_size, void* d_ws, size_t ws_size,
                              hipStream_t stream){
  const float* x   = (const float*)d_in[0];
  const float* Wp  = (const float*)d_in[1];
  const float* bp  = (const float*)d_in[2];
  const float* sw1 = (const float*)d_in[3];
  const float* sw2 = (const float*)d_in[4];
  const float* m1w = (const float*)d_in[5];
  const float* m1b = (const float*)d_in[6];
  const float* mg  = (const float*)d_in[7];
  const float* mbt = (const float*)d_in[8];
  const float* m2w = (const float*)d_in[9];
  const float* m2b = (const float*)d_in[10];
  const float* ww  = (const float*)d_in[11];
  const float* wb  = (const float*)d_in[12];
  const float* ng  = (const float*)d_in[13];
  const float* nb  = (const float*)d_in[14];
  const float* q1w = (const float*)d_in[15];
  const float* q1b = (const float*)d_in[16];
  const float* qg  = (const float*)d_in[17];
  const float* qbt = (const float*)d_in[18];
  const float* q2w = (const float*)d_in[19];
  const float* q2b = (const float*)d_in[20];
  float* out = (float*)d_out;

  char* w8 = (char*)d_ws;
  const size_t ACT_B = (size_t)64*BB*NPIX*sizeof(bf16);   // 41,370,624
  bf16*  A    = (bf16*)(w8);
  bf16*  Cb   = (bf16*)(w8 + ACT_B);
  float* SPEC = (float*)(w8 + 2*ACT_B);                    // XW / WT / GCp / Gpart overlays
  float* XF   = (float*)(w8 + 2*ACT_B + 9879552);
  float* XO   = (float*)(w8 + 2*ACT_B + 9879552 + 1179648);
  float* TB   = (float*)(w8 + 2*ACT_B + 9879552 + 2*1179648);
  char*  g8   = w8 + 2*ACT_B + 9879552 + 2*1179648 + 20992;
  float* TSTAT= (float*)g8;
  float* USTAT= TSTAT + 32;
  float* QSTAT= USTAT + 32;
  float* UxT  = QSTAT + 32;                  // 192*64
  float* UyT  = UxT + 12288;                 // 192*64
  unsigned short* WPK = (unsigned short*)(UyT + 12288);   // 16*4096 bf16
  float* GC   = (float*)(WPK + 16*4096);     // 8*4096 (Parseval gram, reduced)
  float* SC   = GC + 8*4096;                 // 8*64
  float* GFIN = SC + 8*64;                   // 8*4096 (reduced bypass gram)
  float* SFIN = GFIN + 8*4096;               // 8*64
  unsigned short* TPK = (unsigned short*)(SFIN + 8*64);   // 13*512 bf16 twiddle frags
  float* GCp  = SPEC;                        // 8*9*4096 fl = 1.18MB (dead-SPEC overlay)
  float* Gpart = SPEC;                       // 8*80*4096 fl = 10.49MB <= SPEC+XF
  float* Spart = Gpart + (size_t)8*GNB*4096;
  float* WT = SPEC;                          // 288*8192 floats = 9.44MB
  size_t needed = (size_t)(2*ACT_B) + 9879552 + 2*1179648 + 20992
                + 3*32*4 + 2*12288*4 + 16*4096*2 + 2*(8*4096+8*64)*4 + 13312;
  if(ws_size < needed) return;

  k_tab<<<11,256,0,stream>>>(TB);
  k_tpack<<<26,256,0,stream>>>(TB, TPK);
  k_pretab<<<dim3(192,2),64,0,stream>>>(Wp, bp, UxT, UyT);
  k_wpack<<<16,256,0,stream>>>(m1w, m2w, ww, q1w, WPK);
  k_encoder<<<dim3(158,BB),256,0,stream>>>(x, Wp, UxT, UyT, A);

  for(int l=0;l<4;l++){
    const float* sw1l = sw1 + (size_t)l*1179648;
    const float* sw2l = sw2 + (size_t)l*1179648;
    k_dftw<<<402,256,0,stream>>>(A, TB, SPEC);
    k_dfth<<<dim3(12,BB,4),256,0,stream>>>(SPEC, TB, XF);
    k_wtrans<<<dim3(64,5,2),256,0,stream>>>(sw1l, sw2l, WT);
    k_modemix<<<288,512,0,stream>>>(XF, WT, XO);
    k_ispec<<<1608,256,0,stream>>>(XO, TB, TPK, Cb);
    k_gramC<<<dim3(9,BB),256,0,stream>>>(XO, GCp, SC);
    k_gcred<<<dim3(16,BB),256,0,stream>>>(GCp, GC);
    k_gramp<<<dim3(79,BB),256,0,stream>>>(A, Gpart, Spart, NN, NN);
    k_gramr<<<dim3(16,BB),256,0,stream>>>(Gpart, Spart, GFIN, SFIN, 79);
    k_statsA<<<16,256,0,stream>>>(GC, SC, GFIN, SFIN,
          m1w + (size_t)l*4096, m1b + l*64, ww + (size_t)l*4096, wb + l*64,
          TSTAT, USTAT);
    k_fuse<<<dim3(158,BB),256,0,stream>>>(Cb, A,
          WPK + (size_t)(l*3+0)*4096, m1b + l*64, mg + l*64, mbt + l*64,
          WPK + (size_t)(l*3+1)*4096, m2b + l*64,
          WPK + (size_t)(l*3+2)*4096, wb  + l*64, ng + l*64, nb + l*64,
          TSTAT, USTAT, (l==3)?1:0);
  }

  k_gramp<<<dim3(72,BB),256,0,stream>>>(A, Gpart, Spart, SS, SS);
  k_gramr<<<dim3(16,BB),256,0,stream>>>(Gpart, Spart, GFIN, SFIN, 72);
  k_statsQ<<<BB,256,0,stream>>>(GFIN, SFIN, q1w, q1b, QSTAT);
  k_qout<<<dim3(144,BB),256,0,stream>>>(A, WPK + (size_t)12*4096, q1b,
          qg, qbt, q2w, q2b, QSTAT, out);
}

// Round 16
// 994.143 us; speedup vs baseline: 2.2151x; 1.0837x over previous
//
#include <hip/hip_runtime.h>
#include <hip/hip_bf16.h>
#include <math.h>

// FNO2d: B=8, S=192, pad->201x201, C=64, modes 12x12, 4 layers.
// Pixel-major activations [b][p][c]; MFMA conv GEMMs; MFMA inverse-W (ispec);
// chunked Parseval Gram (k_gramC); MFMA bypass Gram v2 (global-frag, no LDS);
// fast sigmoid-gelu.

#define NN 201
#define SS 192
#define NPIX 40401
#define QPIX 36864
#define BB 8
#define GNB 80           // gram slabs per b, 512 px each (one slab per wave)
#define XWPL 1234944     // 1608*12*64 (re/im plane stride in floats)
#define PI_F 3.14159265358979323846f

typedef __hip_bfloat16 bf16;
typedef __attribute__((ext_vector_type(8))) short s8v;
typedef __attribute__((ext_vector_type(4))) float f32x4;

// tanh-form gelu via sigmoid: x*sigma(1.5957691x + 0.0713548x^3); |err| <= ~1e-3
__device__ __forceinline__ float gelu_f(float x){
  float x2 = x*x;
  float t  = fmaf(x2, 0.0713548162f, 1.5957691216f);
  float e  = __expf(-x*t);
  return x*__builtin_amdgcn_rcpf(1.0f+e);
}
__device__ __forceinline__ float b2f(bf16 v){ return __bfloat162float(v); }
__device__ __forceinline__ bf16  f2b(float v){ return __float2bfloat16(v); }
__device__ __forceinline__ unsigned short f2bu(float x){
  bf16 h = __float2bfloat16(x);
  unsigned short u; __builtin_memcpy(&u,&h,2); return u;
}
__device__ __forceinline__ float bu2f(unsigned short u){
  unsigned int x = ((unsigned int)u)<<16; float f; __builtin_memcpy(&f,&x,4); return f;
}

// tab[k][n]: cos/sin(2*pi*k*n/201), k=0..12, exact mod-201 reduction
__global__ void k_tab(float* __restrict__ tab){
  int t = blockIdx.x*blockDim.x+threadIdx.x;
  if(t>=13*NN) return;
  int k=t/NN, n=t-k*NN;
  int m=(k*n)%NN;
  float ang = (2.0f*PI_F/201.0f)*(float)m;
  tab[2*t]   = cosf(ang);
  tab[2*t+1] = sinf(ang);
}

// Pack inverse-W twiddles into MFMA A-fragment order (bf16).
__global__ void k_tpack(const float* __restrict__ tab, unsigned short* __restrict__ TPK){
  int e = blockIdx.x*256 + threadIdx.x;
  if(e>=6656) return;
  int wt=e>>9, lane=(e>>3)&63, j=e&7;
  int m_=lane&15, g=lane>>4;
  int w = wt*16+m_;
  int k24 = g*8+j;
  float v=0.f;
  if(k24<24 && w<201){
    float2 cs = ((const float2*)tab)[(k24>>1)*NN + w];
    v = (k24&1)? cs.y : cs.x;
  }
  TPK[e]=f2bu(v);
}

// Separable encoder tables. grid (192,2), 64 thr.
__global__ void k_pretab(const float* __restrict__ Wp, const float* __restrict__ bp,
                         float* __restrict__ Ux, float* __restrict__ Uy){
  int i = blockIdx.x;
  int ax = blockIdx.y;
  int c = threadIdx.x;
  float g = (float)i*(1.0f/191.0f);
  float acc;
  if(ax==0) acc = bp[c] + g*Wp[64+c];
  else      acc = g*Wp[128+c];
  int cosBase = (ax==0)? 3 : 4;
  int sinBase = (ax==0)? 23 : 24;
  #pragma unroll
  for(int l=0;l<10;l++){
    float f = PI_F*(float)(1<<l);
    float sv,cv;
    sincosf(g*f,&sv,&cv);
    acc += cv*Wp[(cosBase+2*l)*64+c] + sv*Wp[(sinBase+2*l)*64+c];
  }
  float* U = (ax==0)? Ux : Uy;
  U[i*64+c] = acc;
}

// Pack 16 64x64 weight matrices into bf16 MFMA-fragment order.
__global__ void k_wpack(const float* __restrict__ m1w, const float* __restrict__ m2w,
                        const float* __restrict__ ww,  const float* __restrict__ q1w,
                        unsigned short* __restrict__ WPK){
  int bx = blockIdx.x, tid = threadIdx.x;
  const float* src;
  if(bx<12){
    int l=bx/3, sel=bx-l*3;
    src = (sel==0)? m1w+(size_t)l*4096 : (sel==1)? m2w+(size_t)l*4096 : ww+(size_t)l*4096;
  } else {
    src = q1w + (size_t)(bx-12)*4096;
  }
  unsigned short* dst = WPK + (size_t)bx*4096;
  #pragma unroll
  for(int t=0;t<16;t++){
    int d = tid*16+t;
    int frag=d>>9, lane=(d>>3)&63, j=d&7;
    int mt=frag>>1, kh=frag&1, m_=lane&15, g=lane>>4;
    dst[d] = f2bu(src[(size_t)(16*mt+m_)*64 + 32*kh + 8*g + j]);
  }
}

// Transpose spectral weights for layer into WT[m][comp][io].
__global__ void __launch_bounds__(256) k_wtrans(const float* __restrict__ w1,
        const float* __restrict__ w2, float* __restrict__ WT){
  __shared__ float tile[64][65];
  int io0 = blockIdx.x*64;
  int c0  = blockIdx.y*64;
  int z   = blockIdx.z;
  const float* src = (z==0)? w1 : w2;
  int tid = threadIdx.x;
  #pragma unroll
  for(int it=0;it<16;it++){
    int e = tid + 256*it;
    int r = e>>6, c = e&63;
    if(c0+c<288) tile[r][c] = src[(size_t)(io0+r)*288 + c0 + c];
  }
  __syncthreads();
  #pragma unroll
  for(int it=0;it<16;it++){
    int e = tid + 256*it;
    int rp = e>>6, cp = e&63;
    int col = c0 + rp;
    if(col<288){
      int ky = col/24, rm = col - ky*24;
      int kx = rm>>1, comp = rm&1;
      int m = z*144 + ky*12 + kx;
      WT[(size_t)m*8192 + comp*4096 + io0 + cp] = tile[cp][rp];
    }
  }
}

// encoder: A[b][p][c] = x*Wp0[c] + Ux[hh][c] + Uy[ww][c]; zeros in pad.
__global__ void k_encoder(const float* __restrict__ x, const float* __restrict__ Wp,
                          const float* __restrict__ Ux, const float* __restrict__ Uy,
                          bf16* __restrict__ A){
  int tid=threadIdx.x;
  int p = blockIdx.x*256+tid;
  if(p>=NPIX) return;
  int b = blockIdx.y;
  uint4* dst = (uint4*)(A + ((size_t)b*NPIX + p)*64);
  int hh=p/NN, ww=p-hh*NN;
  if(hh>=SS || ww>=SS){
    uint4 z = {0,0,0,0};
    #pragma unroll
    for(int i=0;i<8;i++) dst[i]=z;
    return;
  }
  float xv = x[((size_t)b*SS+hh)*SS+ww];
  const float4* ux = (const float4*)(Ux + hh*64);
  const float4* uy = (const float4*)(Uy + ww*64);
  const float4* w0 = (const float4*)Wp;
  #pragma unroll
  for(int i=0;i<8;i++){
    float4 a0 = ux[2*i],   a1 = ux[2*i+1];
    float4 b0 = uy[2*i],   b1 = uy[2*i+1];
    float4 c0 = w0[2*i],   c1 = w0[2*i+1];
    float v0=xv*c0.x+a0.x+b0.x, v1=xv*c0.y+a0.y+b0.y;
    float v2=xv*c0.z+a0.z+b0.z, v3=xv*c0.w+a0.w+b0.w;
    float v4=xv*c1.x+a1.x+b1.x, v5=xv*c1.y+a1.y+b1.y;
    float v6=xv*c1.z+a1.z+b1.z, v7=xv*c1.w+a1.w+b1.w;
    uint4 v;
    v.x = (unsigned)f2bu(v0) | ((unsigned)f2bu(v1)<<16);
    v.y = (unsigned)f2bu(v2) | ((unsigned)f2bu(v3)<<16);
    v.z = (unsigned)f2bu(v4) | ((unsigned)f2bu(v5)<<16);
    v.w = (unsigned)f2bu(v6) | ((unsigned)f2bu(v7)<<16);
    dst[i]=v;
  }
}

// DFT along W. Wave per row R=b*201+h, lane=c. XW[re/im][R][kx][c].
__global__ void __launch_bounds__(256) k_dftw(const bf16* __restrict__ A,
        const float* __restrict__ tab, float* __restrict__ XW){
  __shared__ float2 st[2412];
  int tid=threadIdx.x;
  for(int i=tid;i<2412;i+=256) st[i]=((const float2*)tab)[i];
  __syncthreads();
  int R = blockIdx.x*4 + (tid>>6);
  int l = tid&63;
  const bf16* base = A + ((size_t)R*NN)*64 + l;
  float ar0=0.f;
  float ar[11], ai[11];
  #pragma unroll
  for(int k=0;k<11;k++){ ar[k]=0.f; ai[k]=0.f; }
  for(int w=0;w<NN;w++){
    float a = b2f(base[(size_t)w*64]);
    ar0 += a;
    #pragma unroll
    for(int k=0;k<11;k++){
      float2 cs = st[(k+1)*NN+w];
      ar[k] += a*cs.x;
      ai[k] += a*cs.y;
    }
  }
  float* xre = XW + ((size_t)R*12)*64 + l;
  float* xim = xre + XWPL;
  xre[0]=ar0; xim[0]=0.f;
  #pragma unroll
  for(int k=0;k<11;k++){
    xre[(size_t)(k+1)*64] = ar[k];
    xim[(size_t)(k+1)*64] = -ai[k];
  }
}

// DFT along H, LDS-staged: grid (12, 8, 4); z = (jhalf<<1)|chalf. ILP x2.
__global__ void __launch_bounds__(256) k_dfth(const float* __restrict__ XW,
        const float* __restrict__ tab, float* __restrict__ XF){
  __shared__ float sre[201*32];
  __shared__ float sim[201*32];
  __shared__ float2 tw[13*NN];
  int kx=blockIdx.x, b=blockIdx.y;
  int z=blockIdx.z; int jh=z>>1, ch=z&1;
  int tid=threadIdx.x;
  for(int i=tid;i<13*NN;i+=256) tw[i]=((const float2*)tab)[i];
  for(int i=tid;i<201*32;i+=256){
    int h=i>>5, c=ch*32+(i&31);
    size_t idx=(((size_t)b*NN+h)*12+kx)*64+c;
    sre[i]=XW[idx];
    sim[i]=XW[idx+XWPL];
  }
  __syncthreads();
  for(int o=tid;o<384;o+=256){
    int jj=o>>5, cl=o&31;
    int j=jh*12+jj;
    int k2=(j<12)?j:24-j;
    float sgn=(j<12)?-1.f:1.f;
    float re0=0.f,im0=0.f,re1=0.f,im1=0.f;
    const float* pr=sre+cl;
    const float* pi=sim+cl;
    const float2* tk=tw+k2*NN;
    int h=0;
    for(;h+1<NN;h+=2){
      float a0=pr[h*32], b0=pi[h*32];
      float2 cs0=tk[h];
      float c0=cs0.x, s0=sgn*cs0.y;
      re0 = fmaf(a0,c0, fmaf(-b0,s0, re0));
      im0 = fmaf(a0,s0, fmaf( b0,c0, im0));
      float a1=pr[(h+1)*32], b1=pi[(h+1)*32];
      float2 cs1=tk[h+1];
      float c1=cs1.x, s1=sgn*cs1.y;
      re1 = fmaf(a1,c1, fmaf(-b1,s1, re1));
      im1 = fmaf(a1,s1, fmaf( b1,c1, im1));
    }
    {
      float a0=pr[h*32], b0=pi[h*32];
      float2 cs0=tk[h];
      float c0=cs0.x, s0=sgn*cs0.y;
      re0 = fmaf(a0,c0, fmaf(-b0,s0, re0));
      im0 = fmaf(a0,s0, fmaf( b0,c0, im0));
    }
    int m=j*12+kx;
    int c=ch*32+cl;
    XF[(size_t)m*1024+(b*64+c)*2]  =re0+re1;
    XF[(size_t)m*1024+(b*64+c)*2+1]=im0+im1;
  }
}

// per-mode 64x64 complex mix; ILP split accumulators.
__global__ void __launch_bounds__(512) k_modemix(const float* __restrict__ XF,
     const float* __restrict__ WT, float* __restrict__ XO){
  __shared__ float sx[1024];
  __shared__ float swr[4096], swi[4096];
  int m=blockIdx.x;
  int tid=threadIdx.x;
  sx[tid]     = XF[(size_t)m*1024+tid];
  sx[tid+512] = XF[(size_t)m*1024+tid+512];
  const float* wr = WT + (size_t)m*8192;
  const float* wi = wr + 4096;
  for(int io=tid;io<4096;io+=512){
    swr[io]=wr[io];
    swi[io]=wi[io];
  }
  __syncthreads();
  int b=tid>>6, o=tid&63;
  const float* xb = sx + b*128;
  float re0=0.f,re1=0.f,im0=0.f,im1=0.f;
  #pragma unroll 8
  for(int i=0;i<64;i+=2){
    float a=xb[2*i], b2=xb[2*i+1];
    float c=swr[i*64+o], d=swi[i*64+o];
    re0 = fmaf(a,c, fmaf(-b2,d, re0));
    im0 = fmaf(a,d, fmaf( b2,c, im0));
    float a1=xb[2*i+2], b3=xb[2*i+3];
    float c1=swr[(i+1)*64+o], d1=swi[(i+1)*64+o];
    re1 = fmaf(a1,c1, fmaf(-b3,d1, re1));
    im1 = fmaf(a1,d1, fmaf( b3,c1, im1));
  }
  XO[2*((size_t)m*512+tid)]  =re0+re1;
  XO[2*((size_t)m*512+tid)+1]=im0+im1;
}

// Merged inverse: per row R, idfth into LDS (factors folded), then the C2R
// along W as MFMA: C[w][o] = sum_k24 T[w][k24]*Y24[k24][o], T prepacked (TPK).
__global__ void __launch_bounds__(256) k_ispec(const float* __restrict__ XO,
        const float* __restrict__ tab, const unsigned short* __restrict__ TPK,
        bf16* __restrict__ C){
  __shared__ float2 yl[12][64];
  __shared__ float2 cs13[13];
  int R=blockIdx.x;
  int b=R/NN, h=R-b*NN;
  int tid=threadIdx.x;
  if(tid<13) cs13[tid]=((const float2*)tab)[tid*NN+h];
  __syncthreads();
  const float sc = 1.0f/40401.0f;
  #pragma unroll
  for(int it=0;it<3;it++){
    int item = tid + 256*it;
    int kx = item>>6, o = item&63;
    float re0=0.f,im0=0.f,re1=0.f,im1=0.f;
    #pragma unroll
    for(int j=0;j<24;j+=2){
      {
        int k2=(j<12)?j:24-j;
        float sgn=(j<12)?1.0f:-1.0f;
        float2 xo = *(const float2*)(XO + 2*(((size_t)(j*12+kx)*512) + b*64 + o));
        float2 cs = cs13[k2];
        float cc=cs.x, s2=sgn*cs.y;
        re0 = fmaf(xo.x,cc, fmaf(-xo.y,s2, re0));
        im0 = fmaf(xo.x,s2, fmaf( xo.y,cc, im0));
      }
      {
        int j1=j+1;
        int k2=(j1<12)?j1:24-j1;
        float sgn=(j1<12)?1.0f:-1.0f;
        float2 xo = *(const float2*)(XO + 2*(((size_t)(j1*12+kx)*512) + b*64 + o));
        float2 cs = cs13[k2];
        float cc=cs.x, s2=sgn*cs.y;
        re1 = fmaf(xo.x,cc, fmaf(-xo.y,s2, re1));
        im1 = fmaf(xo.x,s2, fmaf( xo.y,cc, im1));
      }
    }
    float fr = (kx==0)? sc : 2.0f*sc;
    float fi = (kx==0)? sc : -2.0f*sc;
    yl[kx][o] = float2{ (re0+re1)*fr, (im0+im1)*fi };
  }
  __syncthreads();
  int wid=tid>>6, l=tid&63, m_=l&15, g=l>>4;
  int o = wid*16 + m_;
  s8v bfr;
  #pragma unroll
  for(int j=0;j<4;j++){
    float2 v = yl[4*g+j][o];
    bfr[2*j]   = (short)f2bu(v.x);
    bfr[2*j+1] = (short)f2bu(v.y);
  }
  bf16* cp = C + (size_t)R*NN*64;
  #pragma unroll
  for(int wt=0; wt<13; wt++){
    s8v af = *(const s8v*)(TPK + (size_t)wt*512 + l*8);
    f32x4 acc = f32x4{0.f,0.f,0.f,0.f};
    acc = __builtin_amdgcn_mfma_f32_16x16x32_bf16(af, bfr, acc, 0,0,0);
    #pragma unroll
    for(int e=0;e<4;e++){
      int w = wt*16 + 4*g + e;
      if(w<NN) cp[(size_t)w*64 + o] = f2b(acc[e]);
    }
  }
}

// Chunked Parseval Gram from XO: grid (9, BB). Block = 64-feature chunk.
__global__ void __launch_bounds__(256) k_gramC(const float* __restrict__ XO,
        float* __restrict__ GCp, float* __restrict__ SC){
  __shared__ unsigned short V[64][72];
  int chunk=blockIdx.x, b=blockIdx.y, tid=threadIdx.x;
  const float s1=1.0f/201.0f;
  const float r2=0.70710678118f;
  const float q2=1.41421356237f;
  #pragma unroll
  for(int it=0;it<16;it++){
    int e = tid + it*256;
    int fl=e>>6, ch=e&63;
    int f = chunk*64 + fl;
    int base = b*64+ch;
    float v=0.f;
    if(f<528){
      int comp=f&1, kxm=f>>1;
      int kx0=kxm/24;
      int kx=1+kx0, m=kxm-kx0*24;
      v = q2*XO[2*((size_t)(m*12+kx)*512 + base)+comp];
    } else if(f==528){
      v = XO[2*(size_t)base];
    } else if(f<551){
      int q=f-529; int mm=1+(q>>1);
      const float* p1 = XO + 2*((size_t)(mm*12)*512 + base);
      const float* p2 = XO + 2*((size_t)((24-mm)*12)*512 + base);
      v = ((q&1)==0)? r2*(p1[0]+p2[0]) : r2*(p1[1]-p2[1]);
    } else if(f==551){
      v = r2*XO[2*((size_t)(144)*512 + base)];
    } else if(f==552){
      v = r2*XO[2*((size_t)(144)*512 + base)+1];
    }
    V[ch][fl]=f2bu(v*s1);
  }
  __syncthreads();
  int wid=tid>>6, l=tid&63, m_=l&15, g=l>>4;
  f32x4 acc[4];
  #pragma unroll
  for(int mt=0;mt<4;mt++) acc[mt]=f32x4{0.f,0.f,0.f,0.f};
  #pragma unroll
  for(int kc=0;kc<2;kc++){
    s8v bfr = *(const s8v*)&V[16*wid+m_][kc*32+8*g];
    #pragma unroll
    for(int mt=0;mt<4;mt++){
      s8v afr = *(const s8v*)&V[16*mt+m_][kc*32+8*g];
      acc[mt]=__builtin_amdgcn_mfma_f32_16x16x32_bf16(afr,bfr,acc[mt],0,0,0);
    }
  }
  float* gb = GCp + ((size_t)(b*9+chunk))*4096;
  #pragma unroll
  for(int mt=0;mt<4;mt++){
    #pragma unroll
    for(int e=0;e<4;e++)
      gb[(size_t)(16*mt+4*g+e)*64 + 16*wid + m_] = acc[mt][e];
  }
  if(chunk==0 && tid<64) SC[b*64+tid] = XO[2*(size_t)(b*64+tid)];
}

// Reduce GCp chunks -> GC. grid (16, BB).
__global__ void k_gcred(const float* __restrict__ GCp, float* __restrict__ GC){
  int b=blockIdx.y;
  int idx=blockIdx.x*256+threadIdx.x;
  float s=0.f;
  #pragma unroll
  for(int k=0;k<9;k++) s += GCp[((size_t)(b*9+k))*4096 + idx];
  GC[(size_t)b*4096 + idx]=s;
}

// MFMA Gram v2: fragments loaded directly from global. grid (nblkx, BB) x 4 waves.
// Wave owns slab = blk*4+wid covering 512 px; computes full 4x4 tile set:
// fr[t] = X[p0+(lane>>4)*8+jj][16t+(lane&15)] (zeros OOB); acc[mt][nt]+=mfma(fr[mt],fr[nt]).
// Round-8-verified D mapping: G[16mt+4g+e][16nt+m_] = acc[mt][nt][e].
__global__ void __launch_bounds__(256) k_gramp(const bf16* __restrict__ X,
        float* __restrict__ Gpart, float* __restrict__ Spart, int HR, int WR){
  int b = blockIdx.y, blk = blockIdx.x;
  int npix = HR*WR;
  int tid=threadIdx.x, wid=tid>>6, l=tid&63;
  int m_=l&15, g=l>>4;
  int slab = blk*4 + wid;
  const bf16* xb = X + (size_t)b*NPIX*64;
  f32x4 acc[4][4];
  #pragma unroll
  for(int mt=0;mt<4;mt++){
    #pragma unroll
    for(int nt=0;nt<4;nt++) acc[mt][nt]=f32x4{0.f,0.f,0.f,0.f};
  }
  float cs[4]={0.f,0.f,0.f,0.f};
  for(int kc=0;kc<16;kc++){
    int pbase = slab*512 + kc*32 + g*8;
    int hh0=0, ww0=0;
    if(WR!=NN){ hh0 = pbase/WR; ww0 = pbase - hh0*WR; }
    const bf16* ptr[8];
    #pragma unroll
    for(int jj=0;jj<8;jj++){
      int p = pbase + jj;
      int gp;
      if(WR==NN) gp = p;
      else {
        int ww2 = ww0 + jj;
        int hh  = hh0;
        if(ww2>=WR){ ww2-=WR; hh++; }
        gp = hh*NN + ww2;
      }
      ptr[jj] = (p<npix) ? (xb + (size_t)gp*64) : (const bf16*)0;
    }
    s8v fr[4];
    #pragma unroll
    for(int t=0;t<4;t++){
      s8v f;
      float s=0.f;
      #pragma unroll
      for(int jj=0;jj<8;jj++){
        unsigned short v=0;
        if(ptr[jj]){ bf16 hv = ptr[jj][16*t+m_]; __builtin_memcpy(&v,&hv,2); }
        f[jj]=(short)v;
        s += bu2f(v);
      }
      fr[t]=f;
      cs[t]+=s;
    }
    #pragma unroll
    for(int nt=0;nt<4;nt++){
      #pragma unroll
      for(int mt=0;mt<4;mt++)
        acc[mt][nt]=__builtin_amdgcn_mfma_f32_16x16x32_bf16(fr[mt],fr[nt],acc[mt][nt],0,0,0);
    }
  }
  float* gp_ = Gpart + ((size_t)(b*GNB + slab))*4096;
  #pragma unroll
  for(int mt=0;mt<4;mt++){
    #pragma unroll
    for(int nt=0;nt<4;nt++){
      #pragma unroll
      for(int e=0;e<4;e++)
        gp_[(size_t)(16*mt + 4*g + e)*64 + 16*nt + m_] = acc[mt][nt][e];
    }
  }
  #pragma unroll
  for(int t=0;t<4;t++){
    float s=cs[t];
    s += __shfl_xor(s,16,64);
    s += __shfl_xor(s,32,64);
    if(g==0) Spart[((size_t)(b*GNB+slab))*64 + 16*t + m_] = s;
  }
}

// Parallel slab reduce: grid (16, BB). Gfin[b][4096], Sfin[b][64].
__global__ void __launch_bounds__(256) k_gramr(const float* __restrict__ Gpart,
        const float* __restrict__ Spart, float* __restrict__ Gfin,
        float* __restrict__ Sfin, int nblk){
  int b = blockIdx.y;
  int idx = blockIdx.x*256 + threadIdx.x;
  float s0=0.f,s1=0.f,s2=0.f,s3=0.f;
  int k=0;
  for(;k+3<nblk;k+=4){
    s0 += Gpart[((size_t)b*GNB + k  )*4096 + idx];
    s1 += Gpart[((size_t)b*GNB + k+1)*4096 + idx];
    s2 += Gpart[((size_t)b*GNB + k+2)*4096 + idx];
    s3 += Gpart[((size_t)b*GNB + k+3)*4096 + idx];
  }
  for(;k<nblk;k++) s0 += Gpart[((size_t)b*GNB + k)*4096 + idx];
  Gfin[(size_t)b*4096 + idx] = (s0+s1)+(s2+s3);
  if(blockIdx.x==0 && threadIdx.x<64){
    float ss=0.f;
    for(int j=0;j<nblk;j++) ss += Spart[((size_t)b*GNB + j)*64 + threadIdx.x];
    Sfin[b*64 + threadIdx.x]=ss;
  }
}

// Merged stats (grid 16): zb<8 -> Cb-stats from GC/SC (Parseval); zb>=8 -> A-stats
// from the pre-reduced Gfin/Sfin.
__global__ void __launch_bounds__(256) k_statsA(
        const float* __restrict__ GC, const float* __restrict__ SC,
        const float* __restrict__ Gfin, const float* __restrict__ Sfin,
        const float* __restrict__ m1wl, const float* __restrict__ m1bl,
        const float* __restrict__ wwl,  const float* __restrict__ wbl,
        float* __restrict__ TSTAT, float* __restrict__ USTAT){
  __shared__ float Gs[4096];
  __shared__ float Ss[64];
  __shared__ float rs[256], rq[256];
  int zb=blockIdx.x, t=threadIdx.x;
  const float* GS = (zb<8)? (GC + (size_t)zb*4096) : (Gfin + (size_t)(zb-8)*4096);
  const float* SS_ = (zb<8)? (SC + (size_t)zb*64)   : (Sfin + (size_t)(zb-8)*64);
  #pragma unroll
  for(int e=0;e<16;e++) Gs[t*16+e]=GS[t*16+e];
  if(t<64) Ss[t]=SS_[t];
  __syncthreads();
  const float* W    = (zb<8)? m1wl : wwl;
  const float* bias = (zb<8)? m1bl : wbl;
  float* stat       = (zb<8)? TSTAT : USTAT;
  int b = (zb<8)? zb : zb-8;
  int o = t&63, sl = t>>6;
  float w[64];
  #pragma unroll
  for(int j2=0;j2<64;j2++) w[j2]=bu2f(f2bu(W[(size_t)o*64+j2]));
  const float* Gr = Gs + (size_t)(sl*16)*64;
  float quad=0.f;
  #pragma unroll
  for(int r=0;r<16;r++){
    const float* gr = Gr + r*64;
    float tt=0.f;
    #pragma unroll
    for(int j2=0;j2<64;j2++) tt += gr[j2]*w[j2];
    quad += w[sl*16+r]*tt;
  }
  float dot=0.f;
  #pragma unroll
  for(int j2=0;j2<64;j2++) dot += w[j2]*Ss[j2];
  float bo = bias[o];
  float Nf = (float)NPIX;
  float sm = (sl==0)? (dot + Nf*bo) : 0.f;
  float sq = quad + ((sl==0)? (2.f*bo*dot + Nf*bo*bo) : 0.f);
  rs[t]=sm; rq[t]=sq;
  __syncthreads();
  if(t<64){
    float s2 = rs[t]+rs[t+64]+rs[t+128]+rs[t+192];
    float q2 = rq[t]+rq[t+64]+rq[t+128]+rq[t+192];
    for(int off=16;off>0;off>>=1){
      s2 += __shfl_down(s2,off,32);
      q2 += __shfl_down(q2,off,32);
    }
    if((t&31)==0){
      int g=t>>5;
      float invN = 1.f/(Nf*32.f);
      float mean = s2*invN;
      float var = q2*invN - mean*mean;
      stat[b*4+g*2]   = mean;
      stat[b*4+g*2+1] = rsqrtf(fmaxf(var,0.f)+1e-5f);
    }
  }
}

// Head stats from pre-reduced Gfin/Sfin (grid 8).
__global__ void __launch_bounds__(256) k_statsQ(const float* __restrict__ Gfin,
        const float* __restrict__ Sfin,
        const float* __restrict__ W, const float* __restrict__ bias,
        float* __restrict__ stat){
  __shared__ float Gs[4096];
  __shared__ float Ss[64];
  __shared__ float red[8];
  int b=blockIdx.x, t=threadIdx.x;
  #pragma unroll
  for(int e=0;e<16;e++) Gs[t*16+e]=Gfin[(size_t)b*4096 + t*16+e];
  if(t<64) Ss[t]=Sfin[b*64+t];
  __syncthreads();
  float w[64];
  #pragma unroll
  for(int j2=0;j2<64;j2++) w[j2]=bu2f(f2bu(W[(size_t)t*64+j2]));
  float quad=0.f;
  #pragma unroll
  for(int i=0;i<64;i++){
    const float* gr = Gs + i*64;
    float tt=0.f;
    #pragma unroll
    for(int j2=0;j2<64;j2++) tt += gr[j2]*w[j2];
    quad += w[i]*tt;
  }
  float dot=0.f;
  #pragma unroll
  for(int j2=0;j2<64;j2++) dot += w[j2]*Ss[j2];
  float bo=bias[t];
  float Nf=(float)QPIX;
  float sm = dot + Nf*bo;
  float sq = quad + 2.f*bo*dot + Nf*bo*bo;
  for(int off=32;off>0;off>>=1){
    sm += __shfl_down(sm,off,64);
    sq += __shfl_down(sq,off,64);
  }
  int wid=t>>6;
  if((t&63)==0){ red[wid*2]=sm; red[wid*2+1]=sq; }
  __syncthreads();
  if(t<2){
    float smt = red[t*4+0]+red[t*4+2];
    float sqt = red[t*4+1]+red[t*4+3];
    float invN = 1.f/(Nf*128.f);
    float mean = smt*invN;
    float var = sqt*invN - mean*mean;
    stat[b*4+t*2]   = mean;
    stat[b*4+t*2+1] = rsqrtf(fmaxf(var,0.f)+1e-5f);
  }
}

// MFMA fused layer with packed weights.
__global__ void __launch_bounds__(256) k_fuse(const bf16* __restrict__ Cb,
    bf16* __restrict__ A,
    const unsigned short* __restrict__ wp1, const float* __restrict__ m1b,
    const float* __restrict__ mg,  const float* __restrict__ mbt,
    const unsigned short* __restrict__ wp2, const float* __restrict__ m2b,
    const unsigned short* __restrict__ wpw, const float* __restrict__ wbk,
    const float* __restrict__ ng,  const float* __restrict__ nb,
    const float* __restrict__ tstat, const float* __restrict__ ustat, int last){
  __shared__ unsigned short vlds[4][64][72];
  int tid=threadIdx.x;
  int wid=tid>>6, l=tid&63;
  int m_=l&15, g=l>>4;
  int b=blockIdx.y;
  int p0=blockIdx.x*256 + wid*64;
  const bf16* cbb = Cb + (size_t)b*NPIX*64;
  const bf16* ab  = A  + (size_t)b*NPIX*64;

  s8v af[4][2];
  f32x4 acc[4][4];

  #pragma unroll
  for(int mt=0;mt<4;mt++){
    #pragma unroll
    for(int kh=0;kh<2;kh++)
      af[mt][kh]=*(const s8v*)(wp1 + (mt*2+kh)*512 + l*8);
    float4 b4 = *(const float4*)(m1b + 16*mt + 4*g);
    #pragma unroll
    for(int nt=0;nt<4;nt++) acc[mt][nt]=f32x4{b4.x,b4.y,b4.z,b4.w};
  }
  #pragma unroll
  for(int nt=0;nt<4;nt++){
    int p = p0 + 16*nt + m_;
    int pc = p<NPIX? p : NPIX-1;
    const s8v* xb = (const s8v*)(cbb + (size_t)pc*64);
    s8v b0 = xb[g], b1 = xb[4+g];
    #pragma unroll
    for(int mt=0;mt<4;mt++){
      acc[mt][nt]=__builtin_amdgcn_mfma_f32_16x16x32_bf16(af[mt][0],b0,acc[mt][nt],0,0,0);
      acc[mt][nt]=__builtin_amdgcn_mfma_f32_16x16x32_bf16(af[mt][1],b1,acc[mt][nt],0,0,0);
    }
  }
  {
    float tm0=tstat[b*4],tr0=tstat[b*4+1],tm1=tstat[b*4+2],tr1=tstat[b*4+3];
    #pragma unroll
    for(int mt=0;mt<4;mt++){
      float4 g4 = *(const float4*)(mg  + 16*mt + 4*g);
      float4 t4 = *(const float4*)(mbt + 16*mt + 4*g);
      float mn = (mt<2)? tm0 : tm1;
      float rs = (mt<2)? tr0 : tr1;
      #pragma unroll
      for(int nt=0;nt<4;nt++){
        int pl = 16*nt + m_;
        f32x4 t = acc[mt][nt];
        float v0 = gelu_f((t[0]-mn)*rs*g4.x + t4.x);
        float v1 = gelu_f((t[1]-mn)*rs*g4.y + t4.y);
        float v2 = gelu_f((t[2]-mn)*rs*g4.z + t4.z);
        float v3 = gelu_f((t[3]-mn)*rs*g4.w + t4.w);
        uint2 pk;
        pk.x = (unsigned)f2bu(v0) | ((unsigned)f2bu(v1)<<16);
        pk.y = (unsigned)f2bu(v2) | ((unsigned)f2bu(v3)<<16);
        *(uint2*)&vlds[wid][pl][16*mt+4*g] = pk;
      }
    }
  }
  __syncthreads();
  #pragma unroll
  for(int mt=0;mt<4;mt++){
    #pragma unroll
    for(int kh=0;kh<2;kh++)
      af[mt][kh]=*(const s8v*)(wpw + (mt*2+kh)*512 + l*8);
    float4 b4 = *(const float4*)(wbk + 16*mt + 4*g);
    #pragma unroll
    for(int nt=0;nt<4;nt++) acc[mt][nt]=f32x4{b4.x,b4.y,b4.z,b4.w};
  }
  #pragma unroll
  for(int nt=0;nt<4;nt++){
    int p = p0 + 16*nt + m_;
    int pc = p<NPIX? p : NPIX-1;
    const s8v* xb = (const s8v*)(ab + (size_t)pc*64);
    s8v b0 = xb[g], b1 = xb[4+g];
    #pragma unroll
    for(int mt=0;mt<4;mt++){
      acc[mt][nt]=__builtin_amdgcn_mfma_f32_16x16x32_bf16(af[mt][0],b0,acc[mt][nt],0,0,0);
      acc[mt][nt]=__builtin_amdgcn_mfma_f32_16x16x32_bf16(af[mt][1],b1,acc[mt][nt],0,0,0);
    }
  }
  {
    float um0=ustat[b*4],ur0=ustat[b*4+1],um1=ustat[b*4+2],ur1=ustat[b*4+3];
    #pragma unroll
    for(int mt=0;mt<4;mt++){
      float4 n4 = *(const float4*)(ng  + 16*mt + 4*g);
      float4 nb4= *(const float4*)(nb  + 16*mt + 4*g);
      float4 m24= *(const float4*)(m2b + 16*mt + 4*g);
      float mn = (mt<2)? um0 : um1;
      float rs = (mt<2)? ur0 : ur1;
      #pragma unroll
      for(int nt=0;nt<4;nt++){
        f32x4 u = acc[mt][nt];
        u[0] = m24.x + (u[0]-mn)*rs*n4.x + nb4.x;
        u[1] = m24.y + (u[1]-mn)*rs*n4.y + nb4.y;
        u[2] = m24.z + (u[2]-mn)*rs*n4.z + nb4.z;
        u[3] = m24.w + (u[3]-mn)*rs*n4.w + nb4.w;
        acc[mt][nt]=u;
      }
    }
  }
  #pragma unroll
  for(int mt=0;mt<4;mt++){
    #pragma unroll
    for(int kh=0;kh<2;kh++)
      af[mt][kh]=*(const s8v*)(wp2 + (mt*2+kh)*512 + l*8);
  }
  #pragma unroll
  for(int nt=0;nt<4;nt++){
    int pl = 16*nt + m_;
    const s8v* vp = (const s8v*)&vlds[wid][pl][0];
    s8v b0 = vp[g], b1 = vp[4+g];
    #pragma unroll
    for(int mt=0;mt<4;mt++){
      acc[mt][nt]=__builtin_amdgcn_mfma_f32_16x16x32_bf16(af[mt][0],b0,acc[mt][nt],0,0,0);
      acc[mt][nt]=__builtin_amdgcn_mfma_f32_16x16x32_bf16(af[mt][1],b1,acc[mt][nt],0,0,0);
    }
  }
  #pragma unroll
  for(int nt=0;nt<4;nt++){
    int p = p0 + 16*nt + m_;
    if(p>=NPIX) continue;
    bf16* dp = A + ((size_t)b*NPIX + p)*64;
    #pragma unroll
    for(int mt=0;mt<4;mt++){
      f32x4 h = acc[mt][nt];
      float h0=h[0],h1=h[1],h2=h[2],h3=h[3];
      if(!last){ h0=gelu_f(h0); h1=gelu_f(h1); h2=gelu_f(h2); h3=gelu_f(h3); }
      uint2 pk;
      pk.x = (unsigned)f2bu(h0) | ((unsigned)f2bu(h1)<<16);
      pk.y = (unsigned)f2bu(h2) | ((unsigned)f2bu(h3)<<16);
      *(uint2*)(dp + 16*mt + 4*g) = pk;
    }
  }
}

// Head: block stages 256 px of A-crop into LDS once; wave = one oc chunk; LDS reduce.
__global__ void __launch_bounds__(256) k_qout(const bf16* __restrict__ A,
    const unsigned short* __restrict__ qpack, const float* __restrict__ q1b,
    const float* __restrict__ qg, const float* __restrict__ qbt,
    const float* __restrict__ q2w, const float* __restrict__ q2b,
    const float* __restrict__ qstat, float* __restrict__ out){
  __shared__ unsigned short xq[256][72];
  __shared__ float part[4][256];
  int tid=threadIdx.x;
  int wid=tid>>6, l=tid&63;
  int m_=l&15, g=l>>4;
  int b=blockIdx.y;
  int px0=blockIdx.x*256;
  {
    int p = px0 + tid;
    int hh=p/SS, ww2=p-hh*SS;
    const uint4* src=(const uint4*)(A + (((size_t)b*NPIX) + (size_t)hh*NN + ww2)*64);
    uint4* drow=(uint4*)&xq[tid][0];
    #pragma unroll
    for(int i=0;i<8;i++) drow[i]=src[i];
  }
  __syncthreads();
  int oc=wid;
  const unsigned short* wp = qpack + (size_t)oc*4096;
  s8v af[4][2];
  f32x4 bi4[4];
  float4 g4[4], t4[4], w4[4];
  #pragma unroll
  for(int mt=0;mt<4;mt++){
    #pragma unroll
    for(int kh=0;kh<2;kh++)
      af[mt][kh]=*(const s8v*)(wp + (mt*2+kh)*512 + l*8);
    float4 b4=*(const float4*)(q1b + 64*oc + 16*mt + 4*g);
    bi4[mt]=f32x4{b4.x,b4.y,b4.z,b4.w};
    g4[mt]=*(const float4*)(qg  + 64*oc + 16*mt + 4*g);
    t4[mt]=*(const float4*)(qbt + 64*oc + 16*mt + 4*g);
    w4[mt]=*(const float4*)(q2w + 64*oc + 16*mt + 4*g);
  }
  float m0=qstat[b*4],r0=qstat[b*4+1],m1=qstat[b*4+2],r1=qstat[b*4+3];
  float mn=(oc<2)?m0:m1, rs=(oc<2)?r0:r1;
  #pragma unroll
  for(int nt=0;nt<16;nt++){
    const s8v* vp = (const s8v*)&xq[16*nt+m_][0];
    s8v b0=vp[g], b1=vp[4+g];
    f32x4 acc[4];
    #pragma unroll
    for(int mt=0;mt<4;mt++) acc[mt]=bi4[mt];
    #pragma unroll
    for(int mt=0;mt<4;mt++){
      acc[mt]=__builtin_amdgcn_mfma_f32_16x16x32_bf16(af[mt][0],b0,acc[mt],0,0,0);
      acc[mt]=__builtin_amdgcn_mfma_f32_16x16x32_bf16(af[mt][1],b1,acc[mt],0,0,0);
    }
    float pp=0.f;
    #pragma unroll
    for(int mt=0;mt<4;mt++){
      f32x4 t=acc[mt];
      pp += gelu_f((t[0]-mn)*rs*g4[mt].x + t4[mt].x)*w4[mt].x;
      pp += gelu_f((t[1]-mn)*rs*g4[mt].y + t4[mt].y)*w4[mt].y;
      pp += gelu_f((t[2]-mn)*rs*g4[mt].z + t4[mt].z)*w4[mt].z;
      pp += gelu_f((t[3]-mn)*rs*g4[mt].w + t4[mt].w)*w4[mt].w;
    }
    pp += __shfl_xor(pp,16,64);
    pp += __shfl_xor(pp,32,64);
    if(g==0) part[wid][16*nt+m_]=pp;
  }
  __syncthreads();
  out[(size_t)b*QPIX + px0 + tid] =
      q2b[0] + part[0][tid]+part[1][tid]+part[2][tid]+part[3][tid];
}

extern "C" void kernel_launch(void* const* d_in, const int* in_sizes, int n_in,
                              void* d_out, int out_size, void* d_ws, size_t ws_size,
                              hipStream_t stream){
  const float* x   = (const float*)d_in[0];
  const float* Wp  = (const float*)d_in[1];
  const float* bp  = (const float*)d_in[2];
  const float* sw1 = (const float*)d_in[3];
  const float* sw2 = (const float*)d_in[4];
  const float* m1w = (const float*)d_in[5];
  const float* m1b = (const float*)d_in[6];
  const float* mg  = (const float*)d_in[7];
  const float* mbt = (const float*)d_in[8];
  const float* m2w = (const float*)d_in[9];
  const float* m2b = (const float*)d_in[10];
  const float* ww  = (const float*)d_in[11];
  const float* wb  = (const float*)d_in[12];
  const float* ng  = (const float*)d_in[13];
  const float* nb  = (const float*)d_in[14];
  const float* q1w = (const float*)d_in[15];
  const float* q1b = (const float*)d_in[16];
  const float* qg  = (const float*)d_in[17];
  const float* qbt = (const float*)d_in[18];
  const float* q2w = (const float*)d_in[19];
  const float* q2b = (const float*)d_in[20];
  float* out = (float*)d_out;

  char* w8 = (char*)d_ws;
  const size_t ACT_B = (size_t)64*BB*NPIX*sizeof(bf16);   // 41,370,624
  bf16*  A    = (bf16*)(w8);
  bf16*  Cb   = (bf16*)(w8 + ACT_B);
  float* SPEC = (float*)(w8 + 2*ACT_B);                    // XW / WT / GCp / Gpart overlays
  float* XF   = (float*)(w8 + 2*ACT_B + 9879552);
  float* XO   = (float*)(w8 + 2*ACT_B + 9879552 + 1179648);
  float* TB   = (float*)(w8 + 2*ACT_B + 9879552 + 2*1179648);
  char*  g8   = w8 + 2*ACT_B + 9879552 + 2*1179648 + 20992;
  float* TSTAT= (float*)g8;
  float* USTAT= TSTAT + 32;
  float* QSTAT= USTAT + 32;
  float* UxT  = QSTAT + 32;                  // 192*64
  float* UyT  = UxT + 12288;                 // 192*64
  unsigned short* WPK = (unsigned short*)(UyT + 12288);   // 16*4096 bf16
  float* GC   = (float*)(WPK + 16*4096);     // 8*4096 (Parseval gram, reduced)
  float* SC   = GC + 8*4096;                 // 8*64
  float* GFIN = SC + 8*64;                   // 8*4096 (reduced bypass gram)
  float* SFIN = GFIN + 8*4096;               // 8*64
  unsigned short* TPK = (unsigned short*)(SFIN + 8*64);   // 13*512 bf16 twiddle frags
  float* GCp  = SPEC;                        // 8*9*4096 fl = 1.18MB (dead-SPEC overlay)
  float* Gpart = SPEC;                       // 8*80*4096 fl = 10.49MB <= SPEC+XF
  float* Spart = Gpart + (size_t)8*GNB*4096;
  float* WT = SPEC;                          // 288*8192 floats = 9.44MB
  size_t needed = (size_t)(2*ACT_B) + 9879552 + 2*1179648 + 20992
                + 3*32*4 + 2*12288*4 + 16*4096*2 + 2*(8*4096+8*64)*4 + 13312;
  if(ws_size < needed) return;

  k_tab<<<11,256,0,stream>>>(TB);
  k_tpack<<<26,256,0,stream>>>(TB, TPK);
  k_pretab<<<dim3(192,2),64,0,stream>>>(Wp, bp, UxT, UyT);
  k_wpack<<<16,256,0,stream>>>(m1w, m2w, ww, q1w, WPK);
  k_encoder<<<dim3(158,BB),256,0,stream>>>(x, Wp, UxT, UyT, A);

  for(int l=0;l<4;l++){
    const float* sw1l = sw1 + (size_t)l*1179648;
    const float* sw2l = sw2 + (size_t)l*1179648;
    k_dftw<<<402,256,0,stream>>>(A, TB, SPEC);
    k_dfth<<<dim3(12,BB,4),256,0,stream>>>(SPEC, TB, XF);
    k_wtrans<<<dim3(64,5,2),256,0,stream>>>(sw1l, sw2l, WT);
    k_modemix<<<288,512,0,stream>>>(XF, WT, XO);
    k_ispec<<<1608,256,0,stream>>>(XO, TB, TPK, Cb);
    k_gramC<<<dim3(9,BB),256,0,stream>>>(XO, GCp, SC);
    k_gcred<<<dim3(16,BB),256,0,stream>>>(GCp, GC);
    k_gramp<<<dim3(20,BB),256,0,stream>>>(A, Gpart, Spart, NN, NN);
    k_gramr<<<dim3(16,BB),256,0,stream>>>(Gpart, Spart, GFIN, SFIN, 80);
    k_statsA<<<16,256,0,stream>>>(GC, SC, GFIN, SFIN,
          m1w + (size_t)l*4096, m1b + l*64, ww + (size_t)l*4096, wb + l*64,
          TSTAT, USTAT);
    k_fuse<<<dim3(158,BB),256,0,stream>>>(Cb, A,
          WPK + (size_t)(l*3+0)*4096, m1b + l*64, mg + l*64, mbt + l*64,
          WPK + (size_t)(l*3+1)*4096, m2b + l*64,
          WPK + (size_t)(l*3+2)*4096, wb  + l*64, ng + l*64, nb + l*64,
          TSTAT, USTAT, (l==3)?1:0);
  }

  k_gramp<<<dim3(18,BB),256,0,stream>>>(A, Gpart, Spart, SS, SS);
  k_gramr<<<dim3(16,BB),256,0,stream>>>(Gpart, Spart, GFIN, SFIN, 72);
  k_statsQ<<<BB,256,0,stream>>>(GFIN, SFIN, q1w, q1b, QSTAT);
  k_qout<<<dim3(144,BB),256,0,stream>>>(A, WPK + (size_t)12*4096, q1b,
          qg, qbt, q2w, q2b, QSTAT, out);
}

// Round 17
// 981.533 us; speedup vs baseline: 2.2436x; 1.0128x over previous
//
#include <hip/hip_runtime.h>
#include <hip/hip_bf16.h>
#include <math.h>

// FNO2d: B=8, S=192, pad->201x201, C=64, modes 12x12, 4 layers.
// Pixel-major activations [b][p][c]; MFMA conv GEMMs; MFMA inverse-W (ispec);
// chunked Parseval Gram (k_gramC); MFMA bypass Gram v2 (global-frag);
// fast sigmoid-gelu with folded GN coefficients; 128px head blocks.

#define NN 201
#define SS 192
#define NPIX 40401
#define QPIX 36864
#define BB 8
#define GNB 80           // gram slabs per b, 512 px each (one slab per wave)
#define XWPL 1234944     // 1608*12*64 (re/im plane stride in floats)
#define PI_F 3.14159265358979323846f

typedef __hip_bfloat16 bf16;
typedef __attribute__((ext_vector_type(8))) short s8v;
typedef __attribute__((ext_vector_type(4))) float f32x4;

// tanh-form gelu via sigmoid: x*sigma(1.5957691x + 0.0713548x^3); |err| <= ~1e-3
__device__ __forceinline__ float gelu_f(float x){
  float x2 = x*x;
  float t  = fmaf(x2, 0.0713548162f, 1.5957691216f);
  float e  = __expf(-x*t);
  return x*__builtin_amdgcn_rcpf(1.0f+e);
}
__device__ __forceinline__ float b2f(bf16 v){ return __bfloat162float(v); }
__device__ __forceinline__ bf16  f2b(float v){ return __float2bfloat16(v); }
__device__ __forceinline__ unsigned short f2bu(float x){
  bf16 h = __float2bfloat16(x);
  unsigned short u; __builtin_memcpy(&u,&h,2); return u;
}
__device__ __forceinline__ float bu2f(unsigned short u){
  unsigned int x = ((unsigned int)u)<<16; float f; __builtin_memcpy(&f,&x,4); return f;
}

// tab[k][n]: cos/sin(2*pi*k*n/201), k=0..12, exact mod-201 reduction
__global__ void k_tab(float* __restrict__ tab){
  int t = blockIdx.x*blockDim.x+threadIdx.x;
  if(t>=13*NN) return;
  int k=t/NN, n=t-k*NN;
  int m=(k*n)%NN;
  float ang = (2.0f*PI_F/201.0f)*(float)m;
  tab[2*t]   = cosf(ang);
  tab[2*t+1] = sinf(ang);
}

// Pack inverse-W twiddles into MFMA A-fragment order (bf16).
__global__ void k_tpack(const float* __restrict__ tab, unsigned short* __restrict__ TPK){
  int e = blockIdx.x*256 + threadIdx.x;
  if(e>=6656) return;
  int wt=e>>9, lane=(e>>3)&63, j=e&7;
  int m_=lane&15, g=lane>>4;
  int w = wt*16+m_;
  int k24 = g*8+j;
  float v=0.f;
  if(k24<24 && w<201){
    float2 cs = ((const float2*)tab)[(k24>>1)*NN + w];
    v = (k24&1)? cs.y : cs.x;
  }
  TPK[e]=f2bu(v);
}

// Separable encoder tables. grid (192,2), 64 thr.
__global__ void k_pretab(const float* __restrict__ Wp, const float* __restrict__ bp,
                         float* __restrict__ Ux, float* __restrict__ Uy){
  int i = blockIdx.x;
  int ax = blockIdx.y;
  int c = threadIdx.x;
  float g = (float)i*(1.0f/191.0f);
  float acc;
  if(ax==0) acc = bp[c] + g*Wp[64+c];
  else      acc = g*Wp[128+c];
  int cosBase = (ax==0)? 3 : 4;
  int sinBase = (ax==0)? 23 : 24;
  #pragma unroll
  for(int l=0;l<10;l++){
    float f = PI_F*(float)(1<<l);
    float sv,cv;
    sincosf(g*f,&sv,&cv);
    acc += cv*Wp[(cosBase+2*l)*64+c] + sv*Wp[(sinBase+2*l)*64+c];
  }
  float* U = (ax==0)? Ux : Uy;
  U[i*64+c] = acc;
}

// Pack 16 64x64 weight matrices into bf16 MFMA-fragment order.
__global__ void k_wpack(const float* __restrict__ m1w, const float* __restrict__ m2w,
                        const float* __restrict__ ww,  const float* __restrict__ q1w,
                        unsigned short* __restrict__ WPK){
  int bx = blockIdx.x, tid = threadIdx.x;
  const float* src;
  if(bx<12){
    int l=bx/3, sel=bx-l*3;
    src = (sel==0)? m1w+(size_t)l*4096 : (sel==1)? m2w+(size_t)l*4096 : ww+(size_t)l*4096;
  } else {
    src = q1w + (size_t)(bx-12)*4096;
  }
  unsigned short* dst = WPK + (size_t)bx*4096;
  #pragma unroll
  for(int t=0;t<16;t++){
    int d = tid*16+t;
    int frag=d>>9, lane=(d>>3)&63, j=d&7;
    int mt=frag>>1, kh=frag&1, m_=lane&15, g=lane>>4;
    dst[d] = f2bu(src[(size_t)(16*mt+m_)*64 + 32*kh + 8*g + j]);
  }
}

// Transpose spectral weights for layer into WT[m][comp][io].
__global__ void __launch_bounds__(256) k_wtrans(const float* __restrict__ w1,
        const float* __restrict__ w2, float* __restrict__ WT){
  __shared__ float tile[64][65];
  int io0 = blockIdx.x*64;
  int c0  = blockIdx.y*64;
  int z   = blockIdx.z;
  const float* src = (z==0)? w1 : w2;
  int tid = threadIdx.x;
  #pragma unroll
  for(int it=0;it<16;it++){
    int e = tid + 256*it;
    int r = e>>6, c = e&63;
    if(c0+c<288) tile[r][c] = src[(size_t)(io0+r)*288 + c0 + c];
  }
  __syncthreads();
  #pragma unroll
  for(int it=0;it<16;it++){
    int e = tid + 256*it;
    int rp = e>>6, cp = e&63;
    int col = c0 + rp;
    if(col<288){
      int ky = col/24, rm = col - ky*24;
      int kx = rm>>1, comp = rm&1;
      int m = z*144 + ky*12 + kx;
      WT[(size_t)m*8192 + comp*4096 + io0 + cp] = tile[cp][rp];
    }
  }
}

// encoder: A[b][p][c] = x*Wp0[c] + Ux[hh][c] + Uy[ww][c]; zeros in pad.
__global__ void k_encoder(const float* __restrict__ x, const float* __restrict__ Wp,
                          const float* __restrict__ Ux, const float* __restrict__ Uy,
                          bf16* __restrict__ A){
  int tid=threadIdx.x;
  int p = blockIdx.x*256+tid;
  if(p>=NPIX) return;
  int b = blockIdx.y;
  uint4* dst = (uint4*)(A + ((size_t)b*NPIX + p)*64);
  int hh=p/NN, ww=p-hh*NN;
  if(hh>=SS || ww>=SS){
    uint4 z = {0,0,0,0};
    #pragma unroll
    for(int i=0;i<8;i++) dst[i]=z;
    return;
  }
  float xv = x[((size_t)b*SS+hh)*SS+ww];
  const float4* ux = (const float4*)(Ux + hh*64);
  const float4* uy = (const float4*)(Uy + ww*64);
  const float4* w0 = (const float4*)Wp;
  #pragma unroll
  for(int i=0;i<8;i++){
    float4 a0 = ux[2*i],   a1 = ux[2*i+1];
    float4 b0 = uy[2*i],   b1 = uy[2*i+1];
    float4 c0 = w0[2*i],   c1 = w0[2*i+1];
    float v0=xv*c0.x+a0.x+b0.x, v1=xv*c0.y+a0.y+b0.y;
    float v2=xv*c0.z+a0.z+b0.z, v3=xv*c0.w+a0.w+b0.w;
    float v4=xv*c1.x+a1.x+b1.x, v5=xv*c1.y+a1.y+b1.y;
    float v6=xv*c1.z+a1.z+b1.z, v7=xv*c1.w+a1.w+b1.w;
    uint4 v;
    v.x = (unsigned)f2bu(v0) | ((unsigned)f2bu(v1)<<16);
    v.y = (unsigned)f2bu(v2) | ((unsigned)f2bu(v3)<<16);
    v.z = (unsigned)f2bu(v4) | ((unsigned)f2bu(v5)<<16);
    v.w = (unsigned)f2bu(v6) | ((unsigned)f2bu(v7)<<16);
    dst[i]=v;
  }
}

// DFT along W. Wave per row R=b*201+h, lane=c. XW[re/im][R][kx][c].
__global__ void __launch_bounds__(256) k_dftw(const bf16* __restrict__ A,
        const float* __restrict__ tab, float* __restrict__ XW){
  __shared__ float2 st[2412];
  int tid=threadIdx.x;
  for(int i=tid;i<2412;i+=256) st[i]=((const float2*)tab)[i];
  __syncthreads();
  int R = blockIdx.x*4 + (tid>>6);
  int l = tid&63;
  const bf16* base = A + ((size_t)R*NN)*64 + l;
  float ar0=0.f;
  float ar[11], ai[11];
  #pragma unroll
  for(int k=0;k<11;k++){ ar[k]=0.f; ai[k]=0.f; }
  for(int w=0;w<NN;w++){
    float a = b2f(base[(size_t)w*64]);
    ar0 += a;
    #pragma unroll
    for(int k=0;k<11;k++){
      float2 cs = st[(k+1)*NN+w];
      ar[k] += a*cs.x;
      ai[k] += a*cs.y;
    }
  }
  float* xre = XW + ((size_t)R*12)*64 + l;
  float* xim = xre + XWPL;
  xre[0]=ar0; xim[0]=0.f;
  #pragma unroll
  for(int k=0;k<11;k++){
    xre[(size_t)(k+1)*64] = ar[k];
    xim[(size_t)(k+1)*64] = -ai[k];
  }
}

// DFT along H, LDS-staged: grid (12, 8, 4); z = (jhalf<<1)|chalf. ILP x2.
__global__ void __launch_bounds__(256) k_dfth(const float* __restrict__ XW,
        const float* __restrict__ tab, float* __restrict__ XF){
  __shared__ float sre[201*32];
  __shared__ float sim[201*32];
  __shared__ float2 tw[13*NN];
  int kx=blockIdx.x, b=blockIdx.y;
  int z=blockIdx.z; int jh=z>>1, ch=z&1;
  int tid=threadIdx.x;
  for(int i=tid;i<13*NN;i+=256) tw[i]=((const float2*)tab)[i];
  for(int i=tid;i<201*32;i+=256){
    int h=i>>5, c=ch*32+(i&31);
    size_t idx=(((size_t)b*NN+h)*12+kx)*64+c;
    sre[i]=XW[idx];
    sim[i]=XW[idx+XWPL];
  }
  __syncthreads();
  for(int o=tid;o<384;o+=256){
    int jj=o>>5, cl=o&31;
    int j=jh*12+jj;
    int k2=(j<12)?j:24-j;
    float sgn=(j<12)?-1.f:1.f;
    float re0=0.f,im0=0.f,re1=0.f,im1=0.f;
    const float* pr=sre+cl;
    const float* pi=sim+cl;
    const float2* tk=tw+k2*NN;
    int h=0;
    for(;h+1<NN;h+=2){
      float a0=pr[h*32], b0=pi[h*32];
      float2 cs0=tk[h];
      float c0=cs0.x, s0=sgn*cs0.y;
      re0 = fmaf(a0,c0, fmaf(-b0,s0, re0));
      im0 = fmaf(a0,s0, fmaf( b0,c0, im0));
      float a1=pr[(h+1)*32], b1=pi[(h+1)*32];
      float2 cs1=tk[h+1];
      float c1=cs1.x, s1=sgn*cs1.y;
      re1 = fmaf(a1,c1, fmaf(-b1,s1, re1));
      im1 = fmaf(a1,s1, fmaf( b1,c1, im1));
    }
    {
      float a0=pr[h*32], b0=pi[h*32];
      float2 cs0=tk[h];
      float c0=cs0.x, s0=sgn*cs0.y;
      re0 = fmaf(a0,c0, fmaf(-b0,s0, re0));
      im0 = fmaf(a0,s0, fmaf( b0,c0, im0));
    }
    int m=j*12+kx;
    int c=ch*32+cl;
    XF[(size_t)m*1024+(b*64+c)*2]  =re0+re1;
    XF[(size_t)m*1024+(b*64+c)*2+1]=im0+im1;
  }
}

// per-mode 64x64 complex mix; ILP split accumulators.
__global__ void __launch_bounds__(512) k_modemix(const float* __restrict__ XF,
     const float* __restrict__ WT, float* __restrict__ XO){
  __shared__ float sx[1024];
  __shared__ float swr[4096], swi[4096];
  int m=blockIdx.x;
  int tid=threadIdx.x;
  sx[tid]     = XF[(size_t)m*1024+tid];
  sx[tid+512] = XF[(size_t)m*1024+tid+512];
  const float* wr = WT + (size_t)m*8192;
  const float* wi = wr + 4096;
  for(int io=tid;io<4096;io+=512){
    swr[io]=wr[io];
    swi[io]=wi[io];
  }
  __syncthreads();
  int b=tid>>6, o=tid&63;
  const float* xb = sx + b*128;
  float re0=0.f,re1=0.f,im0=0.f,im1=0.f;
  #pragma unroll 8
  for(int i=0;i<64;i+=2){
    float a=xb[2*i], b2=xb[2*i+1];
    float c=swr[i*64+o], d=swi[i*64+o];
    re0 = fmaf(a,c, fmaf(-b2,d, re0));
    im0 = fmaf(a,d, fmaf( b2,c, im0));
    float a1=xb[2*i+2], b3=xb[2*i+3];
    float c1=swr[(i+1)*64+o], d1=swi[(i+1)*64+o];
    re1 = fmaf(a1,c1, fmaf(-b3,d1, re1));
    im1 = fmaf(a1,d1, fmaf( b3,c1, im1));
  }
  XO[2*((size_t)m*512+tid)]  =re0+re1;
  XO[2*((size_t)m*512+tid)+1]=im0+im1;
}

// Merged inverse: per row R, idfth into LDS (factors folded), then the C2R
// along W as MFMA: C[w][o] = sum_k24 T[w][k24]*Y24[k24][o], T prepacked (TPK).
__global__ void __launch_bounds__(256) k_ispec(const float* __restrict__ XO,
        const float* __restrict__ tab, const unsigned short* __restrict__ TPK,
        bf16* __restrict__ C){
  __shared__ float2 yl[12][64];
  __shared__ float2 cs13[13];
  int R=blockIdx.x;
  int b=R/NN, h=R-b*NN;
  int tid=threadIdx.x;
  if(tid<13) cs13[tid]=((const float2*)tab)[tid*NN+h];
  __syncthreads();
  const float sc = 1.0f/40401.0f;
  #pragma unroll
  for(int it=0;it<3;it++){
    int item = tid + 256*it;
    int kx = item>>6, o = item&63;
    float re0=0.f,im0=0.f,re1=0.f,im1=0.f;
    #pragma unroll
    for(int j=0;j<24;j+=2){
      {
        int k2=(j<12)?j:24-j;
        float sgn=(j<12)?1.0f:-1.0f;
        float2 xo = *(const float2*)(XO + 2*(((size_t)(j*12+kx)*512) + b*64 + o));
        float2 cs = cs13[k2];
        float cc=cs.x, s2=sgn*cs.y;
        re0 = fmaf(xo.x,cc, fmaf(-xo.y,s2, re0));
        im0 = fmaf(xo.x,s2, fmaf( xo.y,cc, im0));
      }
      {
        int j1=j+1;
        int k2=(j1<12)?j1:24-j1;
        float sgn=(j1<12)?1.0f:-1.0f;
        float2 xo = *(const float2*)(XO + 2*(((size_t)(j1*12+kx)*512) + b*64 + o));
        float2 cs = cs13[k2];
        float cc=cs.x, s2=sgn*cs.y;
        re1 = fmaf(xo.x,cc, fmaf(-xo.y,s2, re1));
        im1 = fmaf(xo.x,s2, fmaf( xo.y,cc, im1));
      }
    }
    float fr = (kx==0)? sc : 2.0f*sc;
    float fi = (kx==0)? sc : -2.0f*sc;
    yl[kx][o] = float2{ (re0+re1)*fr, (im0+im1)*fi };
  }
  __syncthreads();
  int wid=tid>>6, l=tid&63, m_=l&15, g=l>>4;
  int o = wid*16 + m_;
  s8v bfr;
  #pragma unroll
  for(int j=0;j<4;j++){
    float2 v = yl[4*g+j][o];
    bfr[2*j]   = (short)f2bu(v.x);
    bfr[2*j+1] = (short)f2bu(v.y);
  }
  bf16* cp = C + (size_t)R*NN*64;
  #pragma unroll
  for(int wt=0; wt<13; wt++){
    s8v af = *(const s8v*)(TPK + (size_t)wt*512 + l*8);
    f32x4 acc = f32x4{0.f,0.f,0.f,0.f};
    acc = __builtin_amdgcn_mfma_f32_16x16x32_bf16(af, bfr, acc, 0,0,0);
    #pragma unroll
    for(int e=0;e<4;e++){
      int w = wt*16 + 4*g + e;
      if(w<NN) cp[(size_t)w*64 + o] = f2b(acc[e]);
    }
  }
}

// Chunked Parseval Gram from XO: grid (9, BB). Block = 64-feature chunk.
__global__ void __launch_bounds__(256) k_gramC(const float* __restrict__ XO,
        float* __restrict__ GCp, float* __restrict__ SC){
  __shared__ unsigned short V[64][72];
  int chunk=blockIdx.x, b=blockIdx.y, tid=threadIdx.x;
  const float s1=1.0f/201.0f;
  const float r2=0.70710678118f;
  const float q2=1.41421356237f;
  #pragma unroll
  for(int it=0;it<16;it++){
    int e = tid + it*256;
    int fl=e>>6, ch=e&63;
    int f = chunk*64 + fl;
    int base = b*64+ch;
    float v=0.f;
    if(f<528){
      int comp=f&1, kxm=f>>1;
      int kx0=kxm/24;
      int kx=1+kx0, m=kxm-kx0*24;
      v = q2*XO[2*((size_t)(m*12+kx)*512 + base)+comp];
    } else if(f==528){
      v = XO[2*(size_t)base];
    } else if(f<551){
      int q=f-529; int mm=1+(q>>1);
      const float* p1 = XO + 2*((size_t)(mm*12)*512 + base);
      const float* p2 = XO + 2*((size_t)((24-mm)*12)*512 + base);
      v = ((q&1)==0)? r2*(p1[0]+p2[0]) : r2*(p1[1]-p2[1]);
    } else if(f==551){
      v = r2*XO[2*((size_t)(144)*512 + base)];
    } else if(f==552){
      v = r2*XO[2*((size_t)(144)*512 + base)+1];
    }
    V[ch][fl]=f2bu(v*s1);
  }
  __syncthreads();
  int wid=tid>>6, l=tid&63, m_=l&15, g=l>>4;
  f32x4 acc[4];
  #pragma unroll
  for(int mt=0;mt<4;mt++) acc[mt]=f32x4{0.f,0.f,0.f,0.f};
  #pragma unroll
  for(int kc=0;kc<2;kc++){
    s8v bfr = *(const s8v*)&V[16*wid+m_][kc*32+8*g];
    #pragma unroll
    for(int mt=0;mt<4;mt++){
      s8v afr = *(const s8v*)&V[16*mt+m_][kc*32+8*g];
      acc[mt]=__builtin_amdgcn_mfma_f32_16x16x32_bf16(afr,bfr,acc[mt],0,0,0);
    }
  }
  float* gb = GCp + ((size_t)(b*9+chunk))*4096;
  #pragma unroll
  for(int mt=0;mt<4;mt++){
    #pragma unroll
    for(int e=0;e<4;e++)
      gb[(size_t)(16*mt+4*g+e)*64 + 16*wid + m_] = acc[mt][e];
  }
  if(chunk==0 && tid<64) SC[b*64+tid] = XO[2*(size_t)(b*64+tid)];
}

// Reduce GCp chunks -> GC. grid (16, BB).
__global__ void k_gcred(const float* __restrict__ GCp, float* __restrict__ GC){
  int b=blockIdx.y;
  int idx=blockIdx.x*256+threadIdx.x;
  float s=0.f;
  #pragma unroll
  for(int k=0;k<9;k++) s += GCp[((size_t)(b*9+k))*4096 + idx];
  GC[(size_t)b*4096 + idx]=s;
}

// MFMA Gram v2: fragments loaded directly from global. grid (nblkx, BB) x 4 waves.
__global__ void __launch_bounds__(256) k_gramp(const bf16* __restrict__ X,
        float* __restrict__ Gpart, float* __restrict__ Spart, int HR, int WR){
  int b = blockIdx.y, blk = blockIdx.x;
  int npix = HR*WR;
  int tid=threadIdx.x, wid=tid>>6, l=tid&63;
  int m_=l&15, g=l>>4;
  int slab = blk*4 + wid;
  const bf16* xb = X + (size_t)b*NPIX*64;
  f32x4 acc[4][4];
  #pragma unroll
  for(int mt=0;mt<4;mt++){
    #pragma unroll
    for(int nt=0;nt<4;nt++) acc[mt][nt]=f32x4{0.f,0.f,0.f,0.f};
  }
  float cs[4]={0.f,0.f,0.f,0.f};
  for(int kc=0;kc<16;kc++){
    int pbase = slab*512 + kc*32 + g*8;
    int hh0=0, ww0=0;
    if(WR!=NN){ hh0 = pbase/WR; ww0 = pbase - hh0*WR; }
    const bf16* ptr[8];
    #pragma unroll
    for(int jj=0;jj<8;jj++){
      int p = pbase + jj;
      int gp;
      if(WR==NN) gp = p;
      else {
        int ww2 = ww0 + jj;
        int hh  = hh0;
        if(ww2>=WR){ ww2-=WR; hh++; }
        gp = hh*NN + ww2;
      }
      ptr[jj] = (p<npix) ? (xb + (size_t)gp*64) : (const bf16*)0;
    }
    s8v fr[4];
    #pragma unroll
    for(int t=0;t<4;t++){
      s8v f;
      float s=0.f;
      #pragma unroll
      for(int jj=0;jj<8;jj++){
        unsigned short v=0;
        if(ptr[jj]){ bf16 hv = ptr[jj][16*t+m_]; __builtin_memcpy(&v,&hv,2); }
        f[jj]=(short)v;
        s += bu2f(v);
      }
      fr[t]=f;
      cs[t]+=s;
    }
    #pragma unroll
    for(int nt=0;nt<4;nt++){
      #pragma unroll
      for(int mt=0;mt<4;mt++)
        acc[mt][nt]=__builtin_amdgcn_mfma_f32_16x16x32_bf16(fr[mt],fr[nt],acc[mt][nt],0,0,0);
    }
  }
  float* gp_ = Gpart + ((size_t)(b*GNB + slab))*4096;
  #pragma unroll
  for(int mt=0;mt<4;mt++){
    #pragma unroll
    for(int nt=0;nt<4;nt++){
      #pragma unroll
      for(int e=0;e<4;e++)
        gp_[(size_t)(16*mt + 4*g + e)*64 + 16*nt + m_] = acc[mt][nt][e];
    }
  }
  #pragma unroll
  for(int t=0;t<4;t++){
    float s=cs[t];
    s += __shfl_xor(s,16,64);
    s += __shfl_xor(s,32,64);
    if(g==0) Spart[((size_t)(b*GNB+slab))*64 + 16*t + m_] = s;
  }
}

// Parallel slab reduce: grid (16, BB). Gfin[b][4096], Sfin[b][64].
__global__ void __launch_bounds__(256) k_gramr(const float* __restrict__ Gpart,
        const float* __restrict__ Spart, float* __restrict__ Gfin,
        float* __restrict__ Sfin, int nblk){
  int b = blockIdx.y;
  int idx = blockIdx.x*256 + threadIdx.x;
  float s0=0.f,s1=0.f,s2=0.f,s3=0.f;
  int k=0;
  for(;k+3<nblk;k+=4){
    s0 += Gpart[((size_t)b*GNB + k  )*4096 + idx];
    s1 += Gpart[((size_t)b*GNB + k+1)*4096 + idx];
    s2 += Gpart[((size_t)b*GNB + k+2)*4096 + idx];
    s3 += Gpart[((size_t)b*GNB + k+3)*4096 + idx];
  }
  for(;k<nblk;k++) s0 += Gpart[((size_t)b*GNB + k)*4096 + idx];
  Gfin[(size_t)b*4096 + idx] = (s0+s1)+(s2+s3);
  if(blockIdx.x==0 && threadIdx.x<64){
    float ss=0.f;
    for(int j=0;j<nblk;j++) ss += Spart[((size_t)b*GNB + j)*64 + threadIdx.x];
    Sfin[b*64 + threadIdx.x]=ss;
  }
}

// Merged stats (grid 16): zb<8 -> Cb-stats from GC/SC (Parseval); zb>=8 -> A-stats
// from the pre-reduced Gfin/Sfin.
__global__ void __launch_bounds__(256) k_statsA(
        const float* __restrict__ GC, const float* __restrict__ SC,
        const float* __restrict__ Gfin, const float* __restrict__ Sfin,
        const float* __restrict__ m1wl, const float* __restrict__ m1bl,
        const float* __restrict__ wwl,  const float* __restrict__ wbl,
        float* __restrict__ TSTAT, float* __restrict__ USTAT){
  __shared__ float Gs[4096];
  __shared__ float Ss[64];
  __shared__ float rs[256], rq[256];
  int zb=blockIdx.x, t=threadIdx.x;
  const float* GS = (zb<8)? (GC + (size_t)zb*4096) : (Gfin + (size_t)(zb-8)*4096);
  const float* SS_ = (zb<8)? (SC + (size_t)zb*64)   : (Sfin + (size_t)(zb-8)*64);
  #pragma unroll
  for(int e=0;e<16;e++) Gs[t*16+e]=GS[t*16+e];
  if(t<64) Ss[t]=SS_[t];
  __syncthreads();
  const float* W    = (zb<8)? m1wl : wwl;
  const float* bias = (zb<8)? m1bl : wbl;
  float* stat       = (zb<8)? TSTAT : USTAT;
  int b = (zb<8)? zb : zb-8;
  int o = t&63, sl = t>>6;
  float w[64];
  #pragma unroll
  for(int j2=0;j2<64;j2++) w[j2]=bu2f(f2bu(W[(size_t)o*64+j2]));
  const float* Gr = Gs + (size_t)(sl*16)*64;
  float quad=0.f;
  #pragma unroll
  for(int r=0;r<16;r++){
    const float* gr = Gr + r*64;
    float tt=0.f;
    #pragma unroll
    for(int j2=0;j2<64;j2++) tt += gr[j2]*w[j2];
    quad += w[sl*16+r]*tt;
  }
  float dot=0.f;
  #pragma unroll
  for(int j2=0;j2<64;j2++) dot += w[j2]*Ss[j2];
  float bo = bias[o];
  float Nf = (float)NPIX;
  float sm = (sl==0)? (dot + Nf*bo) : 0.f;
  float sq = quad + ((sl==0)? (2.f*bo*dot + Nf*bo*bo) : 0.f);
  rs[t]=sm; rq[t]=sq;
  __syncthreads();
  if(t<64){
    float s2 = rs[t]+rs[t+64]+rs[t+128]+rs[t+192];
    float q2 = rq[t]+rq[t+64]+rq[t+128]+rq[t+192];
    for(int off=16;off>0;off>>=1){
      s2 += __shfl_down(s2,off,32);
      q2 += __shfl_down(q2,off,32);
    }
    if((t&31)==0){
      int g=t>>5;
      float invN = 1.f/(Nf*32.f);
      float mean = s2*invN;
      float var = q2*invN - mean*mean;
      stat[b*4+g*2]   = mean;
      stat[b*4+g*2+1] = rsqrtf(fmaxf(var,0.f)+1e-5f);
    }
  }
}

// Head stats from pre-reduced Gfin/Sfin (grid 8).
__global__ void __launch_bounds__(256) k_statsQ(const float* __restrict__ Gfin,
        const float* __restrict__ Sfin,
        const float* __restrict__ W, const float* __restrict__ bias,
        float* __restrict__ stat){
  __shared__ float Gs[4096];
  __shared__ float Ss[64];
  __shared__ float red[8];
  int b=blockIdx.x, t=threadIdx.x;
  #pragma unroll
  for(int e=0;e<16;e++) Gs[t*16+e]=Gfin[(size_t)b*4096 + t*16+e];
  if(t<64) Ss[t]=Sfin[b*64+t];
  __syncthreads();
  float w[64];
  #pragma unroll
  for(int j2=0;j2<64;j2++) w[j2]=bu2f(f2bu(W[(size_t)t*64+j2]));
  float quad=0.f;
  #pragma unroll
  for(int i=0;i<64;i++){
    const float* gr = Gs + i*64;
    float tt=0.f;
    #pragma unroll
    for(int j2=0;j2<64;j2++) tt += gr[j2]*w[j2];
    quad += w[i]*tt;
  }
  float dot=0.f;
  #pragma unroll
  for(int j2=0;j2<64;j2++) dot += w[j2]*Ss[j2];
  float bo=bias[t];
  float Nf=(float)QPIX;
  float sm = dot + Nf*bo;
  float sq = quad + 2.f*bo*dot + Nf*bo*bo;
  for(int off=32;off>0;off>>=1){
    sm += __shfl_down(sm,off,64);
    sq += __shfl_down(sq,off,64);
  }
  int wid=t>>6;
  if((t&63)==0){ red[wid*2]=sm; red[wid*2+1]=sq; }
  __syncthreads();
  if(t<2){
    float smt = red[t*4+0]+red[t*4+2];
    float sqt = red[t*4+1]+red[t*4+3];
    float invN = 1.f/(Nf*128.f);
    float mean = smt*invN;
    float var = sqt*invN - mean*mean;
    stat[b*4+t*2]   = mean;
    stat[b*4+t*2+1] = rsqrtf(fmaxf(var,0.f)+1e-5f);
  }
}

// MFMA fused layer with packed weights; GN affine folded to single fma.
__global__ void __launch_bounds__(256) k_fuse(const bf16* __restrict__ Cb,
    bf16* __restrict__ A,
    const unsigned short* __restrict__ wp1, const float* __restrict__ m1b,
    const float* __restrict__ mg,  const float* __restrict__ mbt,
    const unsigned short* __restrict__ wp2, const float* __restrict__ m2b,
    const unsigned short* __restrict__ wpw, const float* __restrict__ wbk,
    const float* __restrict__ ng,  const float* __restrict__ nb,
    const float* __restrict__ tstat, const float* __restrict__ ustat, int last){
  __shared__ unsigned short vlds[4][64][72];
  int tid=threadIdx.x;
  int wid=tid>>6, l=tid&63;
  int m_=l&15, g=l>>4;
  int b=blockIdx.y;
  int p0=blockIdx.x*256 + wid*64;
  const bf16* cbb = Cb + (size_t)b*NPIX*64;
  const bf16* ab  = A  + (size_t)b*NPIX*64;

  s8v af[4][2];
  f32x4 acc[4][4];

  #pragma unroll
  for(int mt=0;mt<4;mt++){
    #pragma unroll
    for(int kh=0;kh<2;kh++)
      af[mt][kh]=*(const s8v*)(wp1 + (mt*2+kh)*512 + l*8);
    float4 b4 = *(const float4*)(m1b + 16*mt + 4*g);
    #pragma unroll
    for(int nt=0;nt<4;nt++) acc[mt][nt]=f32x4{b4.x,b4.y,b4.z,b4.w};
  }
  #pragma unroll
  for(int nt=0;nt<4;nt++){
    int p = p0 + 16*nt + m_;
    int pc = p<NPIX? p : NPIX-1;
    const s8v* xb = (const s8v*)(cbb + (size_t)pc*64);
    s8v b0 = xb[g], b1 = xb[4+g];
    #pragma unroll
    for(int mt=0;mt<4;mt++){
      acc[mt][nt]=__builtin_amdgcn_mfma_f32_16x16x32_bf16(af[mt][0],b0,acc[mt][nt],0,0,0);
      acc[mt][nt]=__builtin_amdgcn_mfma_f32_16x16x32_bf16(af[mt][1],b1,acc[mt][nt],0,0,0);
    }
  }
  {
    float tm0=tstat[b*4],tr0=tstat[b*4+1],tm1=tstat[b*4+2],tr1=tstat[b*4+3];
    #pragma unroll
    for(int mt=0;mt<4;mt++){
      float4 g4 = *(const float4*)(mg  + 16*mt + 4*g);
      float4 t4 = *(const float4*)(mbt + 16*mt + 4*g);
      float mn = (mt<2)? tm0 : tm1;
      float rs = (mt<2)? tr0 : tr1;
      float ax=rs*g4.x, ay=rs*g4.y, az=rs*g4.z, aw=rs*g4.w;
      float cx=t4.x-mn*ax, cy=t4.y-mn*ay, cz=t4.z-mn*az, cw=t4.w-mn*aw;
      #pragma unroll
      for(int nt=0;nt<4;nt++){
        int pl = 16*nt + m_;
        f32x4 t = acc[mt][nt];
        float v0 = gelu_f(fmaf(t[0],ax,cx));
        float v1 = gelu_f(fmaf(t[1],ay,cy));
        float v2 = gelu_f(fmaf(t[2],az,cz));
        float v3 = gelu_f(fmaf(t[3],aw,cw));
        uint2 pk;
        pk.x = (unsigned)f2bu(v0) | ((unsigned)f2bu(v1)<<16);
        pk.y = (unsigned)f2bu(v2) | ((unsigned)f2bu(v3)<<16);
        *(uint2*)&vlds[wid][pl][16*mt+4*g] = pk;
      }
    }
  }
  __syncthreads();
  #pragma unroll
  for(int mt=0;mt<4;mt++){
    #pragma unroll
    for(int kh=0;kh<2;kh++)
      af[mt][kh]=*(const s8v*)(wpw + (mt*2+kh)*512 + l*8);
    float4 b4 = *(const float4*)(wbk + 16*mt + 4*g);
    #pragma unroll
    for(int nt=0;nt<4;nt++) acc[mt][nt]=f32x4{b4.x,b4.y,b4.z,b4.w};
  }
  #pragma unroll
  for(int nt=0;nt<4;nt++){
    int p = p0 + 16*nt + m_;
    int pc = p<NPIX? p : NPIX-1;
    const s8v* xb = (const s8v*)(ab + (size_t)pc*64);
    s8v b0 = xb[g], b1 = xb[4+g];
    #pragma unroll
    for(int mt=0;mt<4;mt++){
      acc[mt][nt]=__builtin_amdgcn_mfma_f32_16x16x32_bf16(af[mt][0],b0,acc[mt][nt],0,0,0);
      acc[mt][nt]=__builtin_amdgcn_mfma_f32_16x16x32_bf16(af[mt][1],b1,acc[mt][nt],0,0,0);
    }
  }
  {
    float um0=ustat[b*4],ur0=ustat[b*4+1],um1=ustat[b*4+2],ur1=ustat[b*4+3];
    #pragma unroll
    for(int mt=0;mt<4;mt++){
      float4 n4 = *(const float4*)(ng  + 16*mt + 4*g);
      float4 nb4= *(const float4*)(nb  + 16*mt + 4*g);
      float4 m24= *(const float4*)(m2b + 16*mt + 4*g);
      float mn = (mt<2)? um0 : um1;
      float rs = (mt<2)? ur0 : ur1;
      float ax=rs*n4.x, ay=rs*n4.y, az=rs*n4.z, aw=rs*n4.w;
      float cx=m24.x+nb4.x-mn*ax, cy=m24.y+nb4.y-mn*ay;
      float cz=m24.z+nb4.z-mn*az, cw=m24.w+nb4.w-mn*aw;
      #pragma unroll
      for(int nt=0;nt<4;nt++){
        f32x4 u = acc[mt][nt];
        u[0] = fmaf(u[0],ax,cx);
        u[1] = fmaf(u[1],ay,cy);
        u[2] = fmaf(u[2],az,cz);
        u[3] = fmaf(u[3],aw,cw);
        acc[mt][nt]=u;
      }
    }
  }
  #pragma unroll
  for(int mt=0;mt<4;mt++){
    #pragma unroll
    for(int kh=0;kh<2;kh++)
      af[mt][kh]=*(const s8v*)(wp2 + (mt*2+kh)*512 + l*8);
  }
  #pragma unroll
  for(int nt=0;nt<4;nt++){
    int pl = 16*nt + m_;
    const s8v* vp = (const s8v*)&vlds[wid][pl][0];
    s8v b0 = vp[g], b1 = vp[4+g];
    #pragma unroll
    for(int mt=0;mt<4;mt++){
      acc[mt][nt]=__builtin_amdgcn_mfma_f32_16x16x32_bf16(af[mt][0],b0,acc[mt][nt],0,0,0);
      acc[mt][nt]=__builtin_amdgcn_mfma_f32_16x16x32_bf16(af[mt][1],b1,acc[mt][nt],0,0,0);
    }
  }
  #pragma unroll
  for(int nt=0;nt<4;nt++){
    int p = p0 + 16*nt + m_;
    if(p>=NPIX) continue;
    bf16* dp = A + ((size_t)b*NPIX + p)*64;
    #pragma unroll
    for(int mt=0;mt<4;mt++){
      f32x4 h = acc[mt][nt];
      float h0=h[0],h1=h[1],h2=h[2],h3=h[3];
      if(!last){ h0=gelu_f(h0); h1=gelu_f(h1); h2=gelu_f(h2); h3=gelu_f(h3); }
      uint2 pk;
      pk.x = (unsigned)f2bu(h0) | ((unsigned)f2bu(h1)<<16);
      pk.y = (unsigned)f2bu(h2) | ((unsigned)f2bu(h3)<<16);
      *(uint2*)(dp + 16*mt + 4*g) = pk;
    }
  }
}

// Head: 128px/block (grid 288,BB); wave = one oc chunk over 8 nt; folded GN coeffs.
__global__ void __launch_bounds__(256) k_qout(const bf16* __restrict__ A,
    const unsigned short* __restrict__ qpack, const float* __restrict__ q1b,
    const float* __restrict__ qg, const float* __restrict__ qbt,
    const float* __restrict__ q2w, const float* __restrict__ q2b,
    const float* __restrict__ qstat, float* __restrict__ out){
  __shared__ unsigned short xq[128][72];
  __shared__ float part[4][128];
  int tid=threadIdx.x;
  int wid=tid>>6, l=tid&63;
  int m_=l&15, g=l>>4;
  int b=blockIdx.y;
  int px0=blockIdx.x*128;
  {
    int p = px0 + (tid>>1);
    int half = tid&1;
    int hh=p/SS, ww2=p-hh*SS;
    const uint4* src=(const uint4*)(A + (((size_t)b*NPIX) + (size_t)hh*NN + ww2)*64 + half*32);
    uint4* drow=(uint4*)&xq[tid>>1][half*32];
    #pragma unroll
    for(int i=0;i<4;i++) drow[i]=src[i];
  }
  __syncthreads();
  int oc=wid;
  const unsigned short* wp = qpack + (size_t)oc*4096;
  s8v af[4][2];
  f32x4 bi4[4];
  float4 a4[4], c4[4], w4[4];
  float m0=qstat[b*4],r0=qstat[b*4+1],m1=qstat[b*4+2],r1=qstat[b*4+3];
  float mn=(oc<2)?m0:m1, rs=(oc<2)?r0:r1;
  #pragma unroll
  for(int mt=0;mt<4;mt++){
    #pragma unroll
    for(int kh=0;kh<2;kh++)
      af[mt][kh]=*(const s8v*)(wp + (mt*2+kh)*512 + l*8);
    float4 b4=*(const float4*)(q1b + 64*oc + 16*mt + 4*g);
    bi4[mt]=f32x4{b4.x,b4.y,b4.z,b4.w};
    float4 g4=*(const float4*)(qg  + 64*oc + 16*mt + 4*g);
    float4 t4=*(const float4*)(qbt + 64*oc + 16*mt + 4*g);
    w4[mt]=*(const float4*)(q2w + 64*oc + 16*mt + 4*g);
    a4[mt]=float4{rs*g4.x, rs*g4.y, rs*g4.z, rs*g4.w};
    c4[mt]=float4{t4.x-mn*a4[mt].x, t4.y-mn*a4[mt].y, t4.z-mn*a4[mt].z, t4.w-mn*a4[mt].w};
  }
  #pragma unroll
  for(int nt=0;nt<8;nt++){
    const s8v* vp = (const s8v*)&xq[16*nt+m_][0];
    s8v b0=vp[g], b1=vp[4+g];
    f32x4 acc[4];
    #pragma unroll
    for(int mt=0;mt<4;mt++) acc[mt]=bi4[mt];
    #pragma unroll
    for(int mt=0;mt<4;mt++){
      acc[mt]=__builtin_amdgcn_mfma_f32_16x16x32_bf16(af[mt][0],b0,acc[mt],0,0,0);
      acc[mt]=__builtin_amdgcn_mfma_f32_16x16x32_bf16(af[mt][1],b1,acc[mt],0,0,0);
    }
    float pp=0.f;
    #pragma unroll
    for(int mt=0;mt<4;mt++){
      f32x4 t=acc[mt];
      pp += gelu_f(fmaf(t[0],a4[mt].x,c4[mt].x))*w4[mt].x;
      pp += gelu_f(fmaf(t[1],a4[mt].y,c4[mt].y))*w4[mt].y;
      pp += gelu_f(fmaf(t[2],a4[mt].z,c4[mt].z))*w4[mt].z;
      pp += gelu_f(fmaf(t[3],a4[mt].w,c4[mt].w))*w4[mt].w;
    }
    pp += __shfl_xor(pp,16,64);
    pp += __shfl_xor(pp,32,64);
    if(g==0) part[wid][16*nt+m_]=pp;
  }
  __syncthreads();
  if(tid<128)
    out[(size_t)b*QPIX + px0 + tid] =
        q2b[0] + part[0][tid]+part[1][tid]+part[2][tid]+part[3][tid];
}

extern "C" void kernel_launch(void* const* d_in, const int* in_sizes, int n_in,
                              void* d_out, int out_size, void* d_ws, size_t ws_size,
                              hipStream_t stream){
  const float* x   = (const float*)d_in[0];
  const float* Wp  = (const float*)d_in[1];
  const float* bp  = (const float*)d_in[2];
  const float* sw1 = (const float*)d_in[3];
  const float* sw2 = (const float*)d_in[4];
  const float* m1w = (const float*)d_in[5];
  const float* m1b = (const float*)d_in[6];
  const float* mg  = (const float*)d_in[7];
  const float* mbt = (const float*)d_in[8];
  const float* m2w = (const float*)d_in[9];
  const float* m2b = (const float*)d_in[10];
  const float* ww  = (const float*)d_in[11];
  const float* wb  = (const float*)d_in[12];
  const float* ng  = (const float*)d_in[13];
  const float* nb  = (const float*)d_in[14];
  const float* q1w = (const float*)d_in[15];
  const float* q1b = (const float*)d_in[16];
  const float* qg  = (const float*)d_in[17];
  const float* qbt = (const float*)d_in[18];
  const float* q2w = (const float*)d_in[19];
  const float* q2b = (const float*)d_in[20];
  float* out = (float*)d_out;

  char* w8 = (char*)d_ws;
  const size_t ACT_B = (size_t)64*BB*NPIX*sizeof(bf16);   // 41,370,624
  bf16*  A    = (bf16*)(w8);
  bf16*  Cb   = (bf16*)(w8 + ACT_B);
  float* SPEC = (float*)(w8 + 2*ACT_B);                    // XW / WT / GCp / Gpart overlays
  float* XF   = (float*)(w8 + 2*ACT_B + 9879552);
  float* XO   = (float*)(w8 + 2*ACT_B + 9879552 + 1179648);
  float* TB   = (float*)(w8 + 2*ACT_B + 9879552 + 2*1179648);
  char*  g8   = w8 + 2*ACT_B + 9879552 + 2*1179648 + 20992;
  float* TSTAT= (float*)g8;
  float* USTAT= TSTAT + 32;
  float* QSTAT= USTAT + 32;
  float* UxT  = QSTAT + 32;                  // 192*64
  float* UyT  = UxT + 12288;                 // 192*64
  unsigned short* WPK = (unsigned short*)(UyT + 12288);   // 16*4096 bf16
  float* GC   = (float*)(WPK + 16*4096);     // 8*4096 (Parseval gram, reduced)
  float* SC   = GC + 8*4096;                 // 8*64
  float* GFIN = SC + 8*64;                   // 8*4096 (reduced bypass gram)
  float* SFIN = GFIN + 8*4096;               // 8*64
  unsigned short* TPK = (unsigned short*)(SFIN + 8*64);   // 13*512 bf16 twiddle frags
  float* GCp  = SPEC;                        // 8*9*4096 fl (dead-SPEC overlay)
  float* Gpart = SPEC;                       // 8*80*4096 fl = 10.49MB <= SPEC+XF
  float* Spart = Gpart + (size_t)8*GNB*4096;
  float* WT = SPEC;                          // 288*8192 floats = 9.44MB
  size_t needed = (size_t)(2*ACT_B) + 9879552 + 2*1179648 + 20992
                + 3*32*4 + 2*12288*4 + 16*4096*2 + 2*(8*4096+8*64)*4 + 13312;
  if(ws_size < needed) return;

  k_tab<<<11,256,0,stream>>>(TB);
  k_tpack<<<26,256,0,stream>>>(TB, TPK);
  k_pretab<<<dim3(192,2),64,0,stream>>>(Wp, bp, UxT, UyT);
  k_wpack<<<16,256,0,stream>>>(m1w, m2w, ww, q1w, WPK);
  k_encoder<<<dim3(158,BB),256,0,stream>>>(x, Wp, UxT, UyT, A);

  for(int l=0;l<4;l++){
    const float* sw1l = sw1 + (size_t)l*1179648;
    const float* sw2l = sw2 + (size_t)l*1179648;
    k_dftw<<<402,256,0,stream>>>(A, TB, SPEC);
    k_dfth<<<dim3(12,BB,4),256,0,stream>>>(SPEC, TB, XF);
    k_wtrans<<<dim3(64,5,2),256,0,stream>>>(sw1l, sw2l, WT);
    k_modemix<<<288,512,0,stream>>>(XF, WT, XO);
    k_ispec<<<1608,256,0,stream>>>(XO, TB, TPK, Cb);
    k_gramC<<<dim3(9,BB),256,0,stream>>>(XO, GCp, SC);
    k_gcred<<<dim3(16,BB),256,0,stream>>>(GCp, GC);
    k_gramp<<<dim3(20,BB),256,0,stream>>>(A, Gpart, Spart, NN, NN);
    k_gramr<<<dim3(16,BB),256,0,stream>>>(Gpart, Spart, GFIN, SFIN, 80);
    k_statsA<<<16,256,0,stream>>>(GC, SC, GFIN, SFIN,
          m1w + (size_t)l*4096, m1b + l*64, ww + (size_t)l*4096, wb + l*64,
          TSTAT, USTAT);
    k_fuse<<<dim3(158,BB),256,0,stream>>>(Cb, A,
          WPK + (size_t)(l*3+0)*4096, m1b + l*64, mg + l*64, mbt + l*64,
          WPK + (size_t)(l*3+1)*4096, m2b + l*64,
          WPK + (size_t)(l*3+2)*4096, wb  + l*64, ng + l*64, nb + l*64,
          TSTAT, USTAT, (l==3)?1:0);
  }

  k_gramp<<<dim3(18,BB),256,0,stream>>>(A, Gpart, Spart, SS, SS);
  k_gramr<<<dim3(16,BB),256,0,stream>>>(Gpart, Spart, GFIN, SFIN, 72);
  k_statsQ<<<BB,256,0,stream>>>(GFIN, SFIN, q1w, q1b, QSTAT);
  k_qout<<<dim3(288,BB),256,0,stream>>>(A, WPK + (size_t)12*4096, q1b,
          qg, qbt, q2w, q2b, QSTAT, out);
}

// Round 18
// 885.842 us; speedup vs baseline: 2.4859x; 1.1080x over previous
//
#include <hip/hip_runtime.h>
#include <hip/hip_bf16.h>
#include <math.h>

// FNO2d: B=8, S=192, pad->201x201, C=64, modes 12x12, 4 layers.
// Pixel-major activations [b][p][c]; MFMA conv GEMMs; MFMA forward-W (dftw)
// and inverse-W (ispec); chunked Parseval Gram; MFMA bypass Gram v2;
// fast sigmoid-gelu with folded GN coefficients.

#define NN 201
#define SS 192
#define NPIX 40401
#define QPIX 36864
#define BB 8
#define GNB 80           // gram slabs per b, 512 px each (one slab per wave)
#define XWPL 1234944     // 1608*12*64 (re/im plane stride in floats)
#define PI_F 3.14159265358979323846f

typedef __hip_bfloat16 bf16;
typedef __attribute__((ext_vector_type(8))) short s8v;
typedef __attribute__((ext_vector_type(4))) float f32x4;

// tanh-form gelu via sigmoid: x*sigma(1.5957691x + 0.0713548x^3); |err| <= ~1e-3
__device__ __forceinline__ float gelu_f(float x){
  float x2 = x*x;
  float t  = fmaf(x2, 0.0713548162f, 1.5957691216f);
  float e  = __expf(-x*t);
  return x*__builtin_amdgcn_rcpf(1.0f+e);
}
__device__ __forceinline__ float b2f(bf16 v){ return __bfloat162float(v); }
__device__ __forceinline__ bf16  f2b(float v){ return __float2bfloat16(v); }
__device__ __forceinline__ unsigned short f2bu(float x){
  bf16 h = __float2bfloat16(x);
  unsigned short u; __builtin_memcpy(&u,&h,2); return u;
}
__device__ __forceinline__ float bu2f(unsigned short u){
  unsigned int x = ((unsigned int)u)<<16; float f; __builtin_memcpy(&f,&x,4); return f;
}

// tab[k][n]: cos/sin(2*pi*k*n/201), k=0..12, exact mod-201 reduction
__global__ void k_tab(float* __restrict__ tab){
  int t = blockIdx.x*blockDim.x+threadIdx.x;
  if(t>=13*NN) return;
  int k=t/NN, n=t-k*NN;
  int m=(k*n)%NN;
  float ang = (2.0f*PI_F/201.0f)*(float)m;
  tab[2*t]   = cosf(ang);
  tab[2*t+1] = sinf(ang);
}

// Pack inverse-W twiddles into MFMA A-fragment order (bf16).
__global__ void k_tpack(const float* __restrict__ tab, unsigned short* __restrict__ TPK){
  int e = blockIdx.x*256 + threadIdx.x;
  if(e>=6656) return;
  int wt=e>>9, lane=(e>>3)&63, j=e&7;
  int m_=lane&15, g=lane>>4;
  int w = wt*16+m_;
  int k24 = g*8+j;
  float v=0.f;
  if(k24<24 && w<201){
    float2 cs = ((const float2*)tab)[(k24>>1)*NN + w];
    v = (k24&1)? cs.y : cs.x;
  }
  TPK[e]=f2bu(v);
}

// Pack forward-W twiddles into MFMA A-fragment order (bf16), sign folded:
// T2PK[(mt*7+chunk)][lane][j]: A[m=kx24][k=w]; kx24=mt*16+(lane&15),
// w=chunk*32+(lane>>4)*8+j. T2[w][2k]=cos, T2[w][2k+1]=-sin; zero pad.
__global__ void k_tpack2(const float* __restrict__ tab, unsigned short* __restrict__ T2PK){
  int e = blockIdx.x*256 + threadIdx.x;
  if(e>=7168) return;
  int idx = e>>9;
  int mt = idx/7, chunk = idx - mt*7;
  int lane=(e>>3)&63, j=e&7;
  int m_=lane&15, g=lane>>4;
  int kx24 = mt*16 + m_;
  int w = chunk*32 + g*8 + j;
  float v=0.f;
  if(kx24<24 && w<NN){
    float2 cs = ((const float2*)tab)[(kx24>>1)*NN + w];
    v = (kx24&1)? -cs.y : cs.x;
  }
  T2PK[e]=f2bu(v);
}

// Separable encoder tables. grid (192,2), 64 thr.
__global__ void k_pretab(const float* __restrict__ Wp, const float* __restrict__ bp,
                         float* __restrict__ Ux, float* __restrict__ Uy){
  int i = blockIdx.x;
  int ax = blockIdx.y;
  int c = threadIdx.x;
  float g = (float)i*(1.0f/191.0f);
  float acc;
  if(ax==0) acc = bp[c] + g*Wp[64+c];
  else      acc = g*Wp[128+c];
  int cosBase = (ax==0)? 3 : 4;
  int sinBase = (ax==0)? 23 : 24;
  #pragma unroll
  for(int l=0;l<10;l++){
    float f = PI_F*(float)(1<<l);
    float sv,cv;
    sincosf(g*f,&sv,&cv);
    acc += cv*Wp[(cosBase+2*l)*64+c] + sv*Wp[(sinBase+2*l)*64+c];
  }
  float* U = (ax==0)? Ux : Uy;
  U[i*64+c] = acc;
}

// Pack 16 64x64 weight matrices into bf16 MFMA-fragment order.
__global__ void k_wpack(const float* __restrict__ m1w, const float* __restrict__ m2w,
                        const float* __restrict__ ww,  const float* __restrict__ q1w,
                        unsigned short* __restrict__ WPK){
  int bx = blockIdx.x, tid = threadIdx.x;
  const float* src;
  if(bx<12){
    int l=bx/3, sel=bx-l*3;
    src = (sel==0)? m1w+(size_t)l*4096 : (sel==1)? m2w+(size_t)l*4096 : ww+(size_t)l*4096;
  } else {
    src = q1w + (size_t)(bx-12)*4096;
  }
  unsigned short* dst = WPK + (size_t)bx*4096;
  #pragma unroll
  for(int t=0;t<16;t++){
    int d = tid*16+t;
    int frag=d>>9, lane=(d>>3)&63, j=d&7;
    int mt=frag>>1, kh=frag&1, m_=lane&15, g=lane>>4;
    dst[d] = f2bu(src[(size_t)(16*mt+m_)*64 + 32*kh + 8*g + j]);
  }
}

// Transpose spectral weights for layer into WT[m][comp][io].
__global__ void __launch_bounds__(256) k_wtrans(const float* __restrict__ w1,
        const float* __restrict__ w2, float* __restrict__ WT){
  __shared__ float tile[64][65];
  int io0 = blockIdx.x*64;
  int c0  = blockIdx.y*64;
  int z   = blockIdx.z;
  const float* src = (z==0)? w1 : w2;
  int tid = threadIdx.x;
  #pragma unroll
  for(int it=0;it<16;it++){
    int e = tid + 256*it;
    int r = e>>6, c = e&63;
    if(c0+c<288) tile[r][c] = src[(size_t)(io0+r)*288 + c0 + c];
  }
  __syncthreads();
  #pragma unroll
  for(int it=0;it<16;it++){
    int e = tid + 256*it;
    int rp = e>>6, cp = e&63;
    int col = c0 + rp;
    if(col<288){
      int ky = col/24, rm = col - ky*24;
      int kx = rm>>1, comp = rm&1;
      int m = z*144 + ky*12 + kx;
      WT[(size_t)m*8192 + comp*4096 + io0 + cp] = tile[cp][rp];
    }
  }
}

// encoder: A[b][p][c] = x*Wp0[c] + Ux[hh][c] + Uy[ww][c]; zeros in pad.
__global__ void k_encoder(const float* __restrict__ x, const float* __restrict__ Wp,
                          const float* __restrict__ Ux, const float* __restrict__ Uy,
                          bf16* __restrict__ A){
  int tid=threadIdx.x;
  int p = blockIdx.x*256+tid;
  if(p>=NPIX) return;
  int b = blockIdx.y;
  uint4* dst = (uint4*)(A + ((size_t)b*NPIX + p)*64);
  int hh=p/NN, ww=p-hh*NN;
  if(hh>=SS || ww>=SS){
    uint4 z = {0,0,0,0};
    #pragma unroll
    for(int i=0;i<8;i++) dst[i]=z;
    return;
  }
  float xv = x[((size_t)b*SS+hh)*SS+ww];
  const float4* ux = (const float4*)(Ux + hh*64);
  const float4* uy = (const float4*)(Uy + ww*64);
  const float4* w0 = (const float4*)Wp;
  #pragma unroll
  for(int i=0;i<8;i++){
    float4 a0 = ux[2*i],   a1 = ux[2*i+1];
    float4 b0 = uy[2*i],   b1 = uy[2*i+1];
    float4 c0 = w0[2*i],   c1 = w0[2*i+1];
    float v0=xv*c0.x+a0.x+b0.x, v1=xv*c0.y+a0.y+b0.y;
    float v2=xv*c0.z+a0.z+b0.z, v3=xv*c0.w+a0.w+b0.w;
    float v4=xv*c1.x+a1.x+b1.x, v5=xv*c1.y+a1.y+b1.y;
    float v6=xv*c1.z+a1.z+b1.z, v7=xv*c1.w+a1.w+b1.w;
    uint4 v;
    v.x = (unsigned)f2bu(v0) | ((unsigned)f2bu(v1)<<16);
    v.y = (unsigned)f2bu(v2) | ((unsigned)f2bu(v3)<<16);
    v.z = (unsigned)f2bu(v4) | ((unsigned)f2bu(v5)<<16);
    v.w = (unsigned)f2bu(v6) | ((unsigned)f2bu(v7)<<16);
    dst[i]=v;
  }
}

// MFMA forward DFT along W. grid 402 x 4 waves; wave = one row R=b*201+h.
// XW[kx24][c] = sum_w T2[kx24][w]*A_row[w][c]; re plane kx24=2k, im=2k+1 (sign folded).
__global__ void __launch_bounds__(256) k_dftw(const bf16* __restrict__ A,
        const unsigned short* __restrict__ T2PK, float* __restrict__ XW){
  int tid=threadIdx.x, wid=tid>>6, l=tid&63;
  int m_=l&15, g=l>>4;
  int R = blockIdx.x*4 + wid;
  const bf16* row = A + (size_t)R*NN*64;
  f32x4 acc[2][4];
  #pragma unroll
  for(int mt=0;mt<2;mt++){
    #pragma unroll
    for(int nt=0;nt<4;nt++) acc[mt][nt]=f32x4{0.f,0.f,0.f,0.f};
  }
  for(int chunk=0;chunk<7;chunk++){
    int wbase = chunk*32 + g*8;
    s8v bf[4];
    if(chunk<6){
      #pragma unroll
      for(int nt=0;nt<4;nt++){
        s8v f;
        #pragma unroll
        for(int j=0;j<8;j++){
          unsigned short v;
          bf16 hv = row[(size_t)(wbase+j)*64 + 16*nt + m_];
          __builtin_memcpy(&v,&hv,2);
          f[j]=(short)v;
        }
        bf[nt]=f;
      }
    } else {
      #pragma unroll
      for(int nt=0;nt<4;nt++){
        s8v f;
        #pragma unroll
        for(int j=0;j<8;j++){
          unsigned short v=0;
          if(wbase+j<NN){
            bf16 hv = row[(size_t)(wbase+j)*64 + 16*nt + m_];
            __builtin_memcpy(&v,&hv,2);
          }
          f[j]=(short)v;
        }
        bf[nt]=f;
      }
    }
    #pragma unroll
    for(int mt=0;mt<2;mt++){
      s8v af = *(const s8v*)(T2PK + (size_t)(mt*7+chunk)*512 + l*8);
      #pragma unroll
      for(int nt=0;nt<4;nt++)
        acc[mt][nt]=__builtin_amdgcn_mfma_f32_16x16x32_bf16(af,bf[nt],acc[mt][nt],0,0,0);
    }
  }
  #pragma unroll
  for(int mt=0;mt<2;mt++){
    #pragma unroll
    for(int nt=0;nt<4;nt++){
      #pragma unroll
      for(int e=0;e<4;e++){
        int kx24 = mt*16 + 4*g + e;
        if(kx24<24){
          int plane = kx24&1, kx = kx24>>1;
          XW[(size_t)plane*XWPL + ((size_t)R*12+kx)*64 + 16*nt + m_] = acc[mt][nt][e];
        }
      }
    }
  }
}

// DFT along H, LDS-staged: grid (12, 8, 4); z = (jhalf<<1)|chalf. ILP x2.
__global__ void __launch_bounds__(256) k_dfth(const float* __restrict__ XW,
        const float* __restrict__ tab, float* __restrict__ XF){
  __shared__ float sre[201*32];
  __shared__ float sim[201*32];
  __shared__ float2 tw[13*NN];
  int kx=blockIdx.x, b=blockIdx.y;
  int z=blockIdx.z; int jh=z>>1, ch=z&1;
  int tid=threadIdx.x;
  for(int i=tid;i<13*NN;i+=256) tw[i]=((const float2*)tab)[i];
  for(int i=tid;i<201*32;i+=256){
    int h=i>>5, c=ch*32+(i&31);
    size_t idx=(((size_t)b*NN+h)*12+kx)*64+c;
    sre[i]=XW[idx];
    sim[i]=XW[idx+XWPL];
  }
  __syncthreads();
  for(int o=tid;o<384;o+=256){
    int jj=o>>5, cl=o&31;
    int j=jh*12+jj;
    int k2=(j<12)?j:24-j;
    float sgn=(j<12)?-1.f:1.f;
    float re0=0.f,im0=0.f,re1=0.f,im1=0.f;
    const float* pr=sre+cl;
    const float* pi=sim+cl;
    const float2* tk=tw+k2*NN;
    int h=0;
    for(;h+1<NN;h+=2){
      float a0=pr[h*32], b0=pi[h*32];
      float2 cs0=tk[h];
      float c0=cs0.x, s0=sgn*cs0.y;
      re0 = fmaf(a0,c0, fmaf(-b0,s0, re0));
      im0 = fmaf(a0,s0, fmaf( b0,c0, im0));
      float a1=pr[(h+1)*32], b1=pi[(h+1)*32];
      float2 cs1=tk[h+1];
      float c1=cs1.x, s1=sgn*cs1.y;
      re1 = fmaf(a1,c1, fmaf(-b1,s1, re1));
      im1 = fmaf(a1,s1, fmaf( b1,c1, im1));
    }
    {
      float a0=pr[h*32], b0=pi[h*32];
      float2 cs0=tk[h];
      float c0=cs0.x, s0=sgn*cs0.y;
      re0 = fmaf(a0,c0, fmaf(-b0,s0, re0));
      im0 = fmaf(a0,s0, fmaf( b0,c0, im0));
    }
    int m=j*12+kx;
    int c=ch*32+cl;
    XF[(size_t)m*1024+(b*64+c)*2]  =re0+re1;
    XF[(size_t)m*1024+(b*64+c)*2+1]=im0+im1;
  }
}

// per-mode 64x64 complex mix; ILP split accumulators.
__global__ void __launch_bounds__(512) k_modemix(const float* __restrict__ XF,
     const float* __restrict__ WT, float* __restrict__ XO){
  __shared__ float sx[1024];
  __shared__ float swr[4096], swi[4096];
  int m=blockIdx.x;
  int tid=threadIdx.x;
  sx[tid]     = XF[(size_t)m*1024+tid];
  sx[tid+512] = XF[(size_t)m*1024+tid+512];
  const float* wr = WT + (size_t)m*8192;
  const float* wi = wr + 4096;
  for(int io=tid;io<4096;io+=512){
    swr[io]=wr[io];
    swi[io]=wi[io];
  }
  __syncthreads();
  int b=tid>>6, o=tid&63;
  const float* xb = sx + b*128;
  float re0=0.f,re1=0.f,im0=0.f,im1=0.f;
  #pragma unroll 8
  for(int i=0;i<64;i+=2){
    float a=xb[2*i], b2=xb[2*i+1];
    float c=swr[i*64+o], d=swi[i*64+o];
    re0 = fmaf(a,c, fmaf(-b2,d, re0));
    im0 = fmaf(a,d, fmaf( b2,c, im0));
    float a1=xb[2*i+2], b3=xb[2*i+3];
    float c1=swr[(i+1)*64+o], d1=swi[(i+1)*64+o];
    re1 = fmaf(a1,c1, fmaf(-b3,d1, re1));
    im1 = fmaf(a1,d1, fmaf( b3,c1, im1));
  }
  XO[2*((size_t)m*512+tid)]  =re0+re1;
  XO[2*((size_t)m*512+tid)+1]=im0+im1;
}

// Merged inverse: per row R, idfth into LDS (factors folded), then the C2R
// along W as MFMA: C[w][o] = sum_k24 T[w][k24]*Y24[k24][o], T prepacked (TPK).
__global__ void __launch_bounds__(256) k_ispec(const float* __restrict__ XO,
        const float* __restrict__ tab, const unsigned short* __restrict__ TPK,
        bf16* __restrict__ C){
  __shared__ float2 yl[12][64];
  __shared__ float2 cs13[13];
  int R=blockIdx.x;
  int b=R/NN, h=R-b*NN;
  int tid=threadIdx.x;
  if(tid<13) cs13[tid]=((const float2*)tab)[tid*NN+h];
  __syncthreads();
  const float sc = 1.0f/40401.0f;
  #pragma unroll
  for(int it=0;it<3;it++){
    int item = tid + 256*it;
    int kx = item>>6, o = item&63;
    float re0=0.f,im0=0.f,re1=0.f,im1=0.f;
    #pragma unroll
    for(int j=0;j<24;j+=2){
      {
        int k2=(j<12)?j:24-j;
        float sgn=(j<12)?1.0f:-1.0f;
        float2 xo = *(const float2*)(XO + 2*(((size_t)(j*12+kx)*512) + b*64 + o));
        float2 cs = cs13[k2];
        float cc=cs.x, s2=sgn*cs.y;
        re0 = fmaf(xo.x,cc, fmaf(-xo.y,s2, re0));
        im0 = fmaf(xo.x,s2, fmaf( xo.y,cc, im0));
      }
      {
        int j1=j+1;
        int k2=(j1<12)?j1:24-j1;
        float sgn=(j1<12)?1.0f:-1.0f;
        float2 xo = *(const float2*)(XO + 2*(((size_t)(j1*12+kx)*512) + b*64 + o));
        float2 cs = cs13[k2];
        float cc=cs.x, s2=sgn*cs.y;
        re1 = fmaf(xo.x,cc, fmaf(-xo.y,s2, re1));
        im1 = fmaf(xo.x,s2, fmaf( xo.y,cc, im1));
      }
    }
    float fr = (kx==0)? sc : 2.0f*sc;
    float fi = (kx==0)? sc : -2.0f*sc;
    yl[kx][o] = float2{ (re0+re1)*fr, (im0+im1)*fi };
  }
  __syncthreads();
  int wid=tid>>6, l=tid&63, m_=l&15, g=l>>4;
  int o = wid*16 + m_;
  s8v bfr;
  #pragma unroll
  for(int j=0;j<4;j++){
    float2 v = yl[4*g+j][o];
    bfr[2*j]   = (short)f2bu(v.x);
    bfr[2*j+1] = (short)f2bu(v.y);
  }
  bf16* cp = C + (size_t)R*NN*64;
  #pragma unroll
  for(int wt=0; wt<13; wt++){
    s8v af = *(const s8v*)(TPK + (size_t)wt*512 + l*8);
    f32x4 acc = f32x4{0.f,0.f,0.f,0.f};
    acc = __builtin_amdgcn_mfma_f32_16x16x32_bf16(af, bfr, acc, 0,0,0);
    #pragma unroll
    for(int e=0;e<4;e++){
      int w = wt*16 + 4*g + e;
      if(w<NN) cp[(size_t)w*64 + o] = f2b(acc[e]);
    }
  }
}

// Chunked Parseval Gram from XO: grid (9, BB). Block = 64-feature chunk.
__global__ void __launch_bounds__(256) k_gramC(const float* __restrict__ XO,
        float* __restrict__ GCp, float* __restrict__ SC){
  __shared__ unsigned short V[64][72];
  int chunk=blockIdx.x, b=blockIdx.y, tid=threadIdx.x;
  const float s1=1.0f/201.0f;
  const float r2=0.70710678118f;
  const float q2=1.41421356237f;
  #pragma unroll
  for(int it=0;it<16;it++){
    int e = tid + it*256;
    int fl=e>>6, ch=e&63;
    int f = chunk*64 + fl;
    int base = b*64+ch;
    float v=0.f;
    if(f<528){
      int comp=f&1, kxm=f>>1;
      int kx0=kxm/24;
      int kx=1+kx0, m=kxm-kx0*24;
      v = q2*XO[2*((size_t)(m*12+kx)*512 + base)+comp];
    } else if(f==528){
      v = XO[2*(size_t)base];
    } else if(f<551){
      int q=f-529; int mm=1+(q>>1);
      const float* p1 = XO + 2*((size_t)(mm*12)*512 + base);
      const float* p2 = XO + 2*((size_t)((24-mm)*12)*512 + base);
      v = ((q&1)==0)? r2*(p1[0]+p2[0]) : r2*(p1[1]-p2[1]);
    } else if(f==551){
      v = r2*XO[2*((size_t)(144)*512 + base)];
    } else if(f==552){
      v = r2*XO[2*((size_t)(144)*512 + base)+1];
    }
    V[ch][fl]=f2bu(v*s1);
  }
  __syncthreads();
  int wid=tid>>6, l=tid&63, m_=l&15, g=l>>4;
  f32x4 acc[4];
  #pragma unroll
  for(int mt=0;mt<4;mt++) acc[mt]=f32x4{0.f,0.f,0.f,0.f};
  #pragma unroll
  for(int kc=0;kc<2;kc++){
    s8v bfr = *(const s8v*)&V[16*wid+m_][kc*32+8*g];
    #pragma unroll
    for(int mt=0;mt<4;mt++){
      s8v afr = *(const s8v*)&V[16*mt+m_][kc*32+8*g];
      acc[mt]=__builtin_amdgcn_mfma_f32_16x16x32_bf16(afr,bfr,acc[mt],0,0,0);
    }
  }
  float* gb = GCp + ((size_t)(b*9+chunk))*4096;
  #pragma unroll
  for(int mt=0;mt<4;mt++){
    #pragma unroll
    for(int e=0;e<4;e++)
      gb[(size_t)(16*mt+4*g+e)*64 + 16*wid + m_] = acc[mt][e];
  }
  if(chunk==0 && tid<64) SC[b*64+tid] = XO[2*(size_t)(b*64+tid)];
}

// Reduce GCp chunks -> GC. grid (16, BB).
__global__ void k_gcred(const float* __restrict__ GCp, float* __restrict__ GC){
  int b=blockIdx.y;
  int idx=blockIdx.x*256+threadIdx.x;
  float s=0.f;
  #pragma unroll
  for(int k=0;k<9;k++) s += GCp[((size_t)(b*9+k))*4096 + idx];
  GC[(size_t)b*4096 + idx]=s;
}

// MFMA Gram v2: fragments loaded directly from global. grid (nblkx, BB) x 4 waves.
__global__ void __launch_bounds__(256) k_gramp(const bf16* __restrict__ X,
        float* __restrict__ Gpart, float* __restrict__ Spart, int HR, int WR){
  int b = blockIdx.y, blk = blockIdx.x;
  int npix = HR*WR;
  int tid=threadIdx.x, wid=tid>>6, l=tid&63;
  int m_=l&15, g=l>>4;
  int slab = blk*4 + wid;
  const bf16* xb = X + (size_t)b*NPIX*64;
  f32x4 acc[4][4];
  #pragma unroll
  for(int mt=0;mt<4;mt++){
    #pragma unroll
    for(int nt=0;nt<4;nt++) acc[mt][nt]=f32x4{0.f,0.f,0.f,0.f};
  }
  float cs[4]={0.f,0.f,0.f,0.f};
  for(int kc=0;kc<16;kc++){
    int pbase = slab*512 + kc*32 + g*8;
    int hh0=0, ww0=0;
    if(WR!=NN){ hh0 = pbase/WR; ww0 = pbase - hh0*WR; }
    const bf16* ptr[8];
    #pragma unroll
    for(int jj=0;jj<8;jj++){
      int p = pbase + jj;
      int gp;
      if(WR==NN) gp = p;
      else {
        int ww2 = ww0 + jj;
        int hh  = hh0;
        if(ww2>=WR){ ww2-=WR; hh++; }
        gp = hh*NN + ww2;
      }
      ptr[jj] = (p<npix) ? (xb + (size_t)gp*64) : (const bf16*)0;
    }
    s8v fr[4];
    #pragma unroll
    for(int t=0;t<4;t++){
      s8v f;
      float s=0.f;
      #pragma unroll
      for(int jj=0;jj<8;jj++){
        unsigned short v=0;
        if(ptr[jj]){ bf16 hv = ptr[jj][16*t+m_]; __builtin_memcpy(&v,&hv,2); }
        f[jj]=(short)v;
        s += bu2f(v);
      }
      fr[t]=f;
      cs[t]+=s;
    }
    #pragma unroll
    for(int nt=0;nt<4;nt++){
      #pragma unroll
      for(int mt=0;mt<4;mt++)
        acc[mt][nt]=__builtin_amdgcn_mfma_f32_16x16x32_bf16(fr[mt],fr[nt],acc[mt][nt],0,0,0);
    }
  }
  float* gp_ = Gpart + ((size_t)(b*GNB + slab))*4096;
  #pragma unroll
  for(int mt=0;mt<4;mt++){
    #pragma unroll
    for(int nt=0;nt<4;nt++){
      #pragma unroll
      for(int e=0;e<4;e++)
        gp_[(size_t)(16*mt + 4*g + e)*64 + 16*nt + m_] = acc[mt][nt][e];
    }
  }
  #pragma unroll
  for(int t=0;t<4;t++){
    float s=cs[t];
    s += __shfl_xor(s,16,64);
    s += __shfl_xor(s,32,64);
    if(g==0) Spart[((size_t)(b*GNB+slab))*64 + 16*t + m_] = s;
  }
}

// Parallel slab reduce: grid (16, BB). Gfin[b][4096], Sfin[b][64].
__global__ void __launch_bounds__(256) k_gramr(const float* __restrict__ Gpart,
        const float* __restrict__ Spart, float* __restrict__ Gfin,
        float* __restrict__ Sfin, int nblk){
  int b = blockIdx.y;
  int idx = blockIdx.x*256 + threadIdx.x;
  float s0=0.f,s1=0.f,s2=0.f,s3=0.f;
  int k=0;
  for(;k+3<nblk;k+=4){
    s0 += Gpart[((size_t)b*GNB + k  )*4096 + idx];
    s1 += Gpart[((size_t)b*GNB + k+1)*4096 + idx];
    s2 += Gpart[((size_t)b*GNB + k+2)*4096 + idx];
    s3 += Gpart[((size_t)b*GNB + k+3)*4096 + idx];
  }
  for(;k<nblk;k++) s0 += Gpart[((size_t)b*GNB + k)*4096 + idx];
  Gfin[(size_t)b*4096 + idx] = (s0+s1)+(s2+s3);
  if(blockIdx.x==0 && threadIdx.x<64){
    float ss=0.f;
    for(int j=0;j<nblk;j++) ss += Spart[((size_t)b*GNB + j)*64 + threadIdx.x];
    Sfin[b*64 + threadIdx.x]=ss;
  }
}

// Merged stats (grid 16): zb<8 -> Cb-stats from GC/SC (Parseval); zb>=8 -> A-stats
// from the pre-reduced Gfin/Sfin.
__global__ void __launch_bounds__(256) k_statsA(
        const float* __restrict__ GC, const float* __restrict__ SC,
        const float* __restrict__ Gfin, const float* __restrict__ Sfin,
        const float* __restrict__ m1wl, const float* __restrict__ m1bl,
        const float* __restrict__ wwl,  const float* __restrict__ wbl,
        float* __restrict__ TSTAT, float* __restrict__ USTAT){
  __shared__ float Gs[4096];
  __shared__ float Ss[64];
  __shared__ float rs[256], rq[256];
  int zb=blockIdx.x, t=threadIdx.x;
  const float* GS = (zb<8)? (GC + (size_t)zb*4096) : (Gfin + (size_t)(zb-8)*4096);
  const float* SS_ = (zb<8)? (SC + (size_t)zb*64)   : (Sfin + (size_t)(zb-8)*64);
  #pragma unroll
  for(int e=0;e<16;e++) Gs[t*16+e]=GS[t*16+e];
  if(t<64) Ss[t]=SS_[t];
  __syncthreads();
  const float* W    = (zb<8)? m1wl : wwl;
  const float* bias = (zb<8)? m1bl : wbl;
  float* stat       = (zb<8)? TSTAT : USTAT;
  int b = (zb<8)? zb : zb-8;
  int o = t&63, sl = t>>6;
  float w[64];
  #pragma unroll
  for(int j2=0;j2<64;j2++) w[j2]=bu2f(f2bu(W[(size_t)o*64+j2]));
  const float* Gr = Gs + (size_t)(sl*16)*64;
  float quad=0.f;
  #pragma unroll
  for(int r=0;r<16;r++){
    const float* gr = Gr + r*64;
    float tt=0.f;
    #pragma unroll
    for(int j2=0;j2<64;j2++) tt += gr[j2]*w[j2];
    quad += w[sl*16+r]*tt;
  }
  float dot=0.f;
  #pragma unroll
  for(int j2=0;j2<64;j2++) dot += w[j2]*Ss[j2];
  float bo = bias[o];
  float Nf = (float)NPIX;
  float sm = (sl==0)? (dot + Nf*bo) : 0.f;
  float sq = quad + ((sl==0)? (2.f*bo*dot + Nf*bo*bo) : 0.f);
  rs[t]=sm; rq[t]=sq;
  __syncthreads();
  if(t<64){
    float s2 = rs[t]+rs[t+64]+rs[t+128]+rs[t+192];
    float q2 = rq[t]+rq[t+64]+rq[t+128]+rq[t+192];
    for(int off=16;off>0;off>>=1){
      s2 += __shfl_down(s2,off,32);
      q2 += __shfl_down(q2,off,32);
    }
    if((t&31)==0){
      int g=t>>5;
      float invN = 1.f/(Nf*32.f);
      float mean = s2*invN;
      float var = q2*invN - mean*mean;
      stat[b*4+g*2]   = mean;
      stat[b*4+g*2+1] = rsqrtf(fmaxf(var,0.f)+1e-5f);
    }
  }
}

// Head stats from pre-reduced Gfin/Sfin (grid 8).
__global__ void __launch_bounds__(256) k_statsQ(const float* __restrict__ Gfin,
        const float* __restrict__ Sfin,
        const float* __restrict__ W, const float* __restrict__ bias,
        float* __restrict__ stat){
  __shared__ float Gs[4096];
  __shared__ float Ss[64];
  __shared__ float red[8];
  int b=blockIdx.x, t=threadIdx.x;
  #pragma unroll
  for(int e=0;e<16;e++) Gs[t*16+e]=Gfin[(size_t)b*4096 + t*16+e];
  if(t<64) Ss[t]=Sfin[b*64+t];
  __syncthreads();
  float w[64];
  #pragma unroll
  for(int j2=0;j2<64;j2++) w[j2]=bu2f(f2bu(W[(size_t)t*64+j2]));
  float quad=0.f;
  #pragma unroll
  for(int i=0;i<64;i++){
    const float* gr = Gs + i*64;
    float tt=0.f;
    #pragma unroll
    for(int j2=0;j2<64;j2++) tt += gr[j2]*w[j2];
    quad += w[i]*tt;
  }
  float dot=0.f;
  #pragma unroll
  for(int j2=0;j2<64;j2++) dot += w[j2]*Ss[j2];
  float bo=bias[t];
  float Nf=(float)QPIX;
  float sm = dot + Nf*bo;
  float sq = quad + 2.f*bo*dot + Nf*bo*bo;
  for(int off=32;off>0;off>>=1){
    sm += __shfl_down(sm,off,64);
    sq += __shfl_down(sq,off,64);
  }
  int wid=t>>6;
  if((t&63)==0){ red[wid*2]=sm; red[wid*2+1]=sq; }
  __syncthreads();
  if(t<2){
    float smt = red[t*4+0]+red[t*4+2];
    float sqt = red[t*4+1]+red[t*4+3];
    float invN = 1.f/(Nf*128.f);
    float mean = smt*invN;
    float var = sqt*invN - mean*mean;
    stat[b*4+t*2]   = mean;
    stat[b*4+t*2+1] = rsqrtf(fmaxf(var,0.f)+1e-5f);
  }
}

// MFMA fused layer with packed weights; GN affine folded to single fma.
__global__ void __launch_bounds__(256) k_fuse(const bf16* __restrict__ Cb,
    bf16* __restrict__ A,
    const unsigned short* __restrict__ wp1, const float* __restrict__ m1b,
    const float* __restrict__ mg,  const float* __restrict__ mbt,
    const unsigned short* __restrict__ wp2, const float* __restrict__ m2b,
    const unsigned short* __restrict__ wpw, const float* __restrict__ wbk,
    const float* __restrict__ ng,  const float* __restrict__ nb,
    const float* __restrict__ tstat, const float* __restrict__ ustat, int last){
  __shared__ unsigned short vlds[4][64][72];
  int tid=threadIdx.x;
  int wid=tid>>6, l=tid&63;
  int m_=l&15, g=l>>4;
  int b=blockIdx.y;
  int p0=blockIdx.x*256 + wid*64;
  const bf16* cbb = Cb + (size_t)b*NPIX*64;
  const bf16* ab  = A  + (size_t)b*NPIX*64;

  s8v af[4][2];
  f32x4 acc[4][4];

  #pragma unroll
  for(int mt=0;mt<4;mt++){
    #pragma unroll
    for(int kh=0;kh<2;kh++)
      af[mt][kh]=*(const s8v*)(wp1 + (mt*2+kh)*512 + l*8);
    float4 b4 = *(const float4*)(m1b + 16*mt + 4*g);
    #pragma unroll
    for(int nt=0;nt<4;nt++) acc[mt][nt]=f32x4{b4.x,b4.y,b4.z,b4.w};
  }
  #pragma unroll
  for(int nt=0;nt<4;nt++){
    int p = p0 + 16*nt + m_;
    int pc = p<NPIX? p : NPIX-1;
    const s8v* xb = (const s8v*)(cbb + (size_t)pc*64);
    s8v b0 = xb[g], b1 = xb[4+g];
    #pragma unroll
    for(int mt=0;mt<4;mt++){
      acc[mt][nt]=__builtin_amdgcn_mfma_f32_16x16x32_bf16(af[mt][0],b0,acc[mt][nt],0,0,0);
      acc[mt][nt]=__builtin_amdgcn_mfma_f32_16x16x32_bf16(af[mt][1],b1,acc[mt][nt],0,0,0);
    }
  }
  {
    float tm0=tstat[b*4],tr0=tstat[b*4+1],tm1=tstat[b*4+2],tr1=tstat[b*4+3];
    #pragma unroll
    for(int mt=0;mt<4;mt++){
      float4 g4 = *(const float4*)(mg  + 16*mt + 4*g);
      float4 t4 = *(const float4*)(mbt + 16*mt + 4*g);
      float mn = (mt<2)? tm0 : tm1;
      float rs = (mt<2)? tr0 : tr1;
      float ax=rs*g4.x, ay=rs*g4.y, az=rs*g4.z, aw=rs*g4.w;
      float cx=t4.x-mn*ax, cy=t4.y-mn*ay, cz=t4.z-mn*az, cw=t4.w-mn*aw;
      #pragma unroll
      for(int nt=0;nt<4;nt++){
        int pl = 16*nt + m_;
        f32x4 t = acc[mt][nt];
        float v0 = gelu_f(fmaf(t[0],ax,cx));
        float v1 = gelu_f(fmaf(t[1],ay,cy));
        float v2 = gelu_f(fmaf(t[2],az,cz));
        float v3 = gelu_f(fmaf(t[3],aw,cw));
        uint2 pk;
        pk.x = (unsigned)f2bu(v0) | ((unsigned)f2bu(v1)<<16);
        pk.y = (unsigned)f2bu(v2) | ((unsigned)f2bu(v3)<<16);
        *(uint2*)&vlds[wid][pl][16*mt+4*g] = pk;
      }
    }
  }
  __syncthreads();
  #pragma unroll
  for(int mt=0;mt<4;mt++){
    #pragma unroll
    for(int kh=0;kh<2;kh++)
      af[mt][kh]=*(const s8v*)(wpw + (mt*2+kh)*512 + l*8);
    float4 b4 = *(const float4*)(wbk + 16*mt + 4*g);
    #pragma unroll
    for(int nt=0;nt<4;nt++) acc[mt][nt]=f32x4{b4.x,b4.y,b4.z,b4.w};
  }
  #pragma unroll
  for(int nt=0;nt<4;nt++){
    int p = p0 + 16*nt + m_;
    int pc = p<NPIX? p : NPIX-1;
    const s8v* xb = (const s8v*)(ab + (size_t)pc*64);
    s8v b0 = xb[g], b1 = xb[4+g];
    #pragma unroll
    for(int mt=0;mt<4;mt++){
      acc[mt][nt]=__builtin_amdgcn_mfma_f32_16x16x32_bf16(af[mt][0],b0,acc[mt][nt],0,0,0);
      acc[mt][nt]=__builtin_amdgcn_mfma_f32_16x16x32_bf16(af[mt][1],b1,acc[mt][nt],0,0,0);
    }
  }
  {
    float um0=ustat[b*4],ur0=ustat[b*4+1],um1=ustat[b*4+2],ur1=ustat[b*4+3];
    #pragma unroll
    for(int mt=0;mt<4;mt++){
      float4 n4 = *(const float4*)(ng  + 16*mt + 4*g);
      float4 nb4= *(const float4*)(nb  + 16*mt + 4*g);
      float4 m24= *(const float4*)(m2b + 16*mt + 4*g);
      float mn = (mt<2)? um0 : um1;
      float rs = (mt<2)? ur0 : ur1;
      float ax=rs*n4.x, ay=rs*n4.y, az=rs*n4.z, aw=rs*n4.w;
      float cx=m24.x+nb4.x-mn*ax, cy=m24.y+nb4.y-mn*ay;
      float cz=m24.z+nb4.z-mn*az, cw=m24.w+nb4.w-mn*aw;
      #pragma unroll
      for(int nt=0;nt<4;nt++){
        f32x4 u = acc[mt][nt];
        u[0] = fmaf(u[0],ax,cx);
        u[1] = fmaf(u[1],ay,cy);
        u[2] = fmaf(u[2],az,cz);
        u[3] = fmaf(u[3],aw,cw);
        acc[mt][nt]=u;
      }
    }
  }
  #pragma unroll
  for(int mt=0;mt<4;mt++){
    #pragma unroll
    for(int kh=0;kh<2;kh++)
      af[mt][kh]=*(const s8v*)(wp2 + (mt*2+kh)*512 + l*8);
  }
  #pragma unroll
  for(int nt=0;nt<4;nt++){
    int pl = 16*nt + m_;
    const s8v* vp = (const s8v*)&vlds[wid][pl][0];
    s8v b0 = vp[g], b1 = vp[4+g];
    #pragma unroll
    for(int mt=0;mt<4;mt++){
      acc[mt][nt]=__builtin_amdgcn_mfma_f32_16x16x32_bf16(af[mt][0],b0,acc[mt][nt],0,0,0);
      acc[mt][nt]=__builtin_amdgcn_mfma_f32_16x16x32_bf16(af[mt][1],b1,acc[mt][nt],0,0,0);
    }
  }
  #pragma unroll
  for(int nt=0;nt<4;nt++){
    int p = p0 + 16*nt + m_;
    if(p>=NPIX) continue;
    bf16* dp = A + ((size_t)b*NPIX + p)*64;
    #pragma unroll
    for(int mt=0;mt<4;mt++){
      f32x4 h = acc[mt][nt];
      float h0=h[0],h1=h[1],h2=h[2],h3=h[3];
      if(!last){ h0=gelu_f(h0); h1=gelu_f(h1); h2=gelu_f(h2); h3=gelu_f(h3); }
      uint2 pk;
      pk.x = (unsigned)f2bu(h0) | ((unsigned)f2bu(h1)<<16);
      pk.y = (unsigned)f2bu(h2) | ((unsigned)f2bu(h3)<<16);
      *(uint2*)(dp + 16*mt + 4*g) = pk;
    }
  }
}

// Head: 128px/block (grid 288,BB); wave = one oc chunk over 8 nt; folded GN coeffs.
__global__ void __launch_bounds__(256) k_qout(const bf16* __restrict__ A,
    const unsigned short* __restrict__ qpack, const float* __restrict__ q1b,
    const float* __restrict__ qg, const float* __restrict__ qbt,
    const float* __restrict__ q2w, const float* __restrict__ q2b,
    const float* __restrict__ qstat, float* __restrict__ out){
  __shared__ unsigned short xq[128][72];
  __shared__ float part[4][128];
  int tid=threadIdx.x;
  int wid=tid>>6, l=tid&63;
  int m_=l&15, g=l>>4;
  int b=blockIdx.y;
  int px0=blockIdx.x*128;
  {
    int p = px0 + (tid>>1);
    int half = tid&1;
    int hh=p/SS, ww2=p-hh*SS;
    const uint4* src=(const uint4*)(A + (((size_t)b*NPIX) + (size_t)hh*NN + ww2)*64 + half*32);
    uint4* drow=(uint4*)&xq[tid>>1][half*32];
    #pragma unroll
    for(int i=0;i<4;i++) drow[i]=src[i];
  }
  __syncthreads();
  int oc=wid;
  const unsigned short* wp = qpack + (size_t)oc*4096;
  s8v af[4][2];
  f32x4 bi4[4];
  float4 a4[4], c4[4], w4[4];
  float m0=qstat[b*4],r0=qstat[b*4+1],m1=qstat[b*4+2],r1=qstat[b*4+3];
  float mn=(oc<2)?m0:m1, rs=(oc<2)?r0:r1;
  #pragma unroll
  for(int mt=0;mt<4;mt++){
    #pragma unroll
    for(int kh=0;kh<2;kh++)
      af[mt][kh]=*(const s8v*)(wp + (mt*2+kh)*512 + l*8);
    float4 b4=*(const float4*)(q1b + 64*oc + 16*mt + 4*g);
    bi4[mt]=f32x4{b4.x,b4.y,b4.z,b4.w};
    float4 g4=*(const float4*)(qg  + 64*oc + 16*mt + 4*g);
    float4 t4=*(const float4*)(qbt + 64*oc + 16*mt + 4*g);
    w4[mt]=*(const float4*)(q2w + 64*oc + 16*mt + 4*g);
    a4[mt]=float4{rs*g4.x, rs*g4.y, rs*g4.z, rs*g4.w};
    c4[mt]=float4{t4.x-mn*a4[mt].x, t4.y-mn*a4[mt].y, t4.z-mn*a4[mt].z, t4.w-mn*a4[mt].w};
  }
  #pragma unroll
  for(int nt=0;nt<8;nt++){
    const s8v* vp = (const s8v*)&xq[16*nt+m_][0];
    s8v b0=vp[g], b1=vp[4+g];
    f32x4 acc[4];
    #pragma unroll
    for(int mt=0;mt<4;mt++) acc[mt]=bi4[mt];
    #pragma unroll
    for(int mt=0;mt<4;mt++){
      acc[mt]=__builtin_amdgcn_mfma_f32_16x16x32_bf16(af[mt][0],b0,acc[mt],0,0,0);
      acc[mt]=__builtin_amdgcn_mfma_f32_16x16x32_bf16(af[mt][1],b1,acc[mt],0,0,0);
    }
    float pp=0.f;
    #pragma unroll
    for(int mt=0;mt<4;mt++){
      f32x4 t=acc[mt];
      pp += gelu_f(fmaf(t[0],a4[mt].x,c4[mt].x))*w4[mt].x;
      pp += gelu_f(fmaf(t[1],a4[mt].y,c4[mt].y))*w4[mt].y;
      pp += gelu_f(fmaf(t[2],a4[mt].z,c4[mt].z))*w4[mt].z;
      pp += gelu_f(fmaf(t[3],a4[mt].w,c4[mt].w))*w4[mt].w;
    }
    pp += __shfl_xor(pp,16,64);
    pp += __shfl_xor(pp,32,64);
    if(g==0) part[wid][16*nt+m_]=pp;
  }
  __syncthreads();
  if(tid<128)
    out[(size_t)b*QPIX + px0 + tid] =
        q2b[0] + part[0][tid]+part[1][tid]+part[2][tid]+part[3][tid];
}

extern "C" void kernel_launch(void* const* d_in, const int* in_sizes, int n_in,
                              void* d_out, int out_size, void* d_ws, size_t ws_size,
                              hipStream_t stream){
  const float* x   = (const float*)d_in[0];
  const float* Wp  = (const float*)d_in[1];
  const float* bp  = (const float*)d_in[2];
  const float* sw1 = (const float*)d_in[3];
  const float* sw2 = (const float*)d_in[4];
  const float* m1w = (const float*)d_in[5];
  const float* m1b = (const float*)d_in[6];
  const float* mg  = (const float*)d_in[7];
  const float* mbt = (const float*)d_in[8];
  const float* m2w = (const float*)d_in[9];
  const float* m2b = (const float*)d_in[10];
  const float* ww  = (const float*)d_in[11];
  const float* wb  = (const float*)d_in[12];
  const float* ng  = (const float*)d_in[13];
  const float* nb  = (const float*)d_in[14];
  const float* q1w = (const float*)d_in[15];
  const float* q1b = (const float*)d_in[16];
  const float* qg  = (const float*)d_in[17];
  const float* qbt = (const float*)d_in[18];
  const float* q2w = (const float*)d_in[19];
  const float* q2b = (const float*)d_in[20];
  float* out = (float*)d_out;

  char* w8 = (char*)d_ws;
  const size_t ACT_B = (size_t)64*BB*NPIX*sizeof(bf16);   // 41,370,624
  bf16*  A    = (bf16*)(w8);
  bf16*  Cb   = (bf16*)(w8 + ACT_B);
  float* SPEC = (float*)(w8 + 2*ACT_B);                    // XW / WT / GCp / Gpart overlays
  float* XF   = (float*)(w8 + 2*ACT_B + 9879552);
  float* XO   = (float*)(w8 + 2*ACT_B + 9879552 + 1179648);
  float* TB   = (float*)(w8 + 2*ACT_B + 9879552 + 2*1179648);
  char*  g8   = w8 + 2*ACT_B + 9879552 + 2*1179648 + 20992;
  float* TSTAT= (float*)g8;
  float* USTAT= TSTAT + 32;
  float* QSTAT= USTAT + 32;
  float* UxT  = QSTAT + 32;                  // 192*64
  float* UyT  = UxT + 12288;                 // 192*64
  unsigned short* WPK = (unsigned short*)(UyT + 12288);   // 16*4096 bf16
  float* GC   = (float*)(WPK + 16*4096);     // 8*4096 (Parseval gram, reduced)
  float* SC   = GC + 8*4096;                 // 8*64
  float* GFIN = SC + 8*64;                   // 8*4096 (reduced bypass gram)
  float* SFIN = GFIN + 8*4096;               // 8*64
  unsigned short* TPK = (unsigned short*)(SFIN + 8*64);   // 13*512 bf16 inverse twiddles
  unsigned short* T2PK = TPK + 6656;                      // 14*512 bf16 forward twiddles
  float* GCp  = SPEC;                        // 8*9*4096 fl (dead-SPEC overlay)
  float* Gpart = SPEC;                       // 8*80*4096 fl = 10.49MB <= SPEC+XF
  float* Spart = Gpart + (size_t)8*GNB*4096;
  float* WT = SPEC;                          // 288*8192 floats = 9.44MB
  size_t needed = (size_t)(2*ACT_B) + 9879552 + 2*1179648 + 20992
                + 3*32*4 + 2*12288*4 + 16*4096*2 + 2*(8*4096+8*64)*4 + 13312 + 14336;
  if(ws_size < needed) return;

  k_tab<<<11,256,0,stream>>>(TB);
  k_tpack<<<26,256,0,stream>>>(TB, TPK);
  k_tpack2<<<28,256,0,stream>>>(TB, T2PK);
  k_pretab<<<dim3(192,2),64,0,stream>>>(Wp, bp, UxT, UyT);
  k_wpack<<<16,256,0,stream>>>(m1w, m2w, ww, q1w, WPK);
  k_encoder<<<dim3(158,BB),256,0,stream>>>(x, Wp, UxT, UyT, A);

  for(int l=0;l<4;l++){
    const float* sw1l = sw1 + (size_t)l*1179648;
    const float* sw2l = sw2 + (size_t)l*1179648;
    k_dftw<<<402,256,0,stream>>>(A, T2PK, SPEC);
    k_dfth<<<dim3(12,BB,4),256,0,stream>>>(SPEC, TB, XF);
    k_wtrans<<<dim3(64,5,2),256,0,stream>>>(sw1l, sw2l, WT);
    k_modemix<<<288,512,0,stream>>>(XF, WT, XO);
    k_ispec<<<1608,256,0,stream>>>(XO, TB, TPK, Cb);
    k_gramC<<<dim3(9,BB),256,0,stream>>>(XO, GCp, SC);
    k_gcred<<<dim3(16,BB),256,0,stream>>>(GCp, GC);
    k_gramp<<<dim3(20,BB),256,0,stream>>>(A, Gpart, Spart, NN, NN);
    k_gramr<<<dim3(16,BB),256,0,stream>>>(Gpart, Spart, GFIN, SFIN, 80);
    k_statsA<<<16,256,0,stream>>>(GC, SC, GFIN, SFIN,
          m1w + (size_t)l*4096, m1b + l*64, ww + (size_t)l*4096, wb + l*64,
          TSTAT, USTAT);
    k_fuse<<<dim3(158,BB),256,0,stream>>>(Cb, A,
          WPK + (size_t)(l*3+0)*4096, m1b + l*64, mg + l*64, mbt + l*64,
          WPK + (size_t)(l*3+1)*4096, m2b + l*64,
          WPK + (size_t)(l*3+2)*4096, wb  + l*64, ng + l*64, nb + l*64,
          TSTAT, USTAT, (l==3)?1:0);
  }

  k_gramp<<<dim3(18,BB),256,0,stream>>>(A, Gpart, Spart, SS, SS);
  k_gramr<<<dim3(16,BB),256,0,stream>>>(Gpart, Spart, GFIN, SFIN, 72);
  k_statsQ<<<BB,256,0,stream>>>(GFIN, SFIN, q1w, q1b, QSTAT);
  k_qout<<<dim3(288,BB),256,0,stream>>>(A, WPK + (size_t)12*4096, q1b,
          qg, qbt, q2w, q2b, QSTAT, out);
}

// Round 19
// 858.202 us; speedup vs baseline: 2.5660x; 1.0322x over previous
//
#include <hip/hip_runtime.h>
#include <hip/hip_bf16.h>
#include <math.h>

// FNO2d: B=8, S=192, pad->201x201, C=64, modes 12x12, 4 layers.
// Pixel-major activations [b][p][c]; MFMA conv GEMMs; MFMA forward-W (dftw)
// and inverse-W (ispec); chunked Parseval Gram; MFMA bypass Gram v2;
// fast sigmoid-gelu with folded GN coefficients; parallel GN-stats quad forms.

#define NN 201
#define SS 192
#define NPIX 40401
#define QPIX 36864
#define BB 8
#define GNB 80           // gram slabs per b, 512 px each (one slab per wave)
#define XWPL 1234944     // 1608*12*64 (re/im plane stride in floats)
#define PI_F 3.14159265358979323846f

typedef __hip_bfloat16 bf16;
typedef __attribute__((ext_vector_type(8))) short s8v;
typedef __attribute__((ext_vector_type(4))) float f32x4;

// tanh-form gelu via sigmoid: x*sigma(1.5957691x + 0.0713548x^3); |err| <= ~1e-3
__device__ __forceinline__ float gelu_f(float x){
  float x2 = x*x;
  float t  = fmaf(x2, 0.0713548162f, 1.5957691216f);
  float e  = __expf(-x*t);
  return x*__builtin_amdgcn_rcpf(1.0f+e);
}
__device__ __forceinline__ float b2f(bf16 v){ return __bfloat162float(v); }
__device__ __forceinline__ bf16  f2b(float v){ return __float2bfloat16(v); }
__device__ __forceinline__ unsigned short f2bu(float x){
  bf16 h = __float2bfloat16(x);
  unsigned short u; __builtin_memcpy(&u,&h,2); return u;
}
__device__ __forceinline__ float bu2f(unsigned short u){
  unsigned int x = ((unsigned int)u)<<16; float f; __builtin_memcpy(&f,&x,4); return f;
}

// tab[k][n]: cos/sin(2*pi*k*n/201), k=0..12, exact mod-201 reduction
__global__ void k_tab(float* __restrict__ tab){
  int t = blockIdx.x*blockDim.x+threadIdx.x;
  if(t>=13*NN) return;
  int k=t/NN, n=t-k*NN;
  int m=(k*n)%NN;
  float ang = (2.0f*PI_F/201.0f)*(float)m;
  tab[2*t]   = cosf(ang);
  tab[2*t+1] = sinf(ang);
}

// Pack inverse-W twiddles into MFMA A-fragment order (bf16).
__global__ void k_tpack(const float* __restrict__ tab, unsigned short* __restrict__ TPK){
  int e = blockIdx.x*256 + threadIdx.x;
  if(e>=6656) return;
  int wt=e>>9, lane=(e>>3)&63, j=e&7;
  int m_=lane&15, g=lane>>4;
  int w = wt*16+m_;
  int k24 = g*8+j;
  float v=0.f;
  if(k24<24 && w<201){
    float2 cs = ((const float2*)tab)[(k24>>1)*NN + w];
    v = (k24&1)? cs.y : cs.x;
  }
  TPK[e]=f2bu(v);
}

// Pack forward-W twiddles into MFMA A-fragment order (bf16), sign folded.
__global__ void k_tpack2(const float* __restrict__ tab, unsigned short* __restrict__ T2PK){
  int e = blockIdx.x*256 + threadIdx.x;
  if(e>=7168) return;
  int idx = e>>9;
  int mt = idx/7, chunk = idx - mt*7;
  int lane=(e>>3)&63, j=e&7;
  int m_=lane&15, g=lane>>4;
  int kx24 = mt*16 + m_;
  int w = chunk*32 + g*8 + j;
  float v=0.f;
  if(kx24<24 && w<NN){
    float2 cs = ((const float2*)tab)[(kx24>>1)*NN + w];
    v = (kx24&1)? -cs.y : cs.x;
  }
  T2PK[e]=f2bu(v);
}

// Separable encoder tables. grid (192,2), 64 thr.
__global__ void k_pretab(const float* __restrict__ Wp, const float* __restrict__ bp,
                         float* __restrict__ Ux, float* __restrict__ Uy){
  int i = blockIdx.x;
  int ax = blockIdx.y;
  int c = threadIdx.x;
  float g = (float)i*(1.0f/191.0f);
  float acc;
  if(ax==0) acc = bp[c] + g*Wp[64+c];
  else      acc = g*Wp[128+c];
  int cosBase = (ax==0)? 3 : 4;
  int sinBase = (ax==0)? 23 : 24;
  #pragma unroll
  for(int l=0;l<10;l++){
    float f = PI_F*(float)(1<<l);
    float sv,cv;
    sincosf(g*f,&sv,&cv);
    acc += cv*Wp[(cosBase+2*l)*64+c] + sv*Wp[(sinBase+2*l)*64+c];
  }
  float* U = (ax==0)? Ux : Uy;
  U[i*64+c] = acc;
}

// Pack 16 64x64 weight matrices into bf16 MFMA-fragment order.
__global__ void k_wpack(const float* __restrict__ m1w, const float* __restrict__ m2w,
                        const float* __restrict__ ww,  const float* __restrict__ q1w,
                        unsigned short* __restrict__ WPK){
  int bx = blockIdx.x, tid = threadIdx.x;
  const float* src;
  if(bx<12){
    int l=bx/3, sel=bx-l*3;
    src = (sel==0)? m1w+(size_t)l*4096 : (sel==1)? m2w+(size_t)l*4096 : ww+(size_t)l*4096;
  } else {
    src = q1w + (size_t)(bx-12)*4096;
  }
  unsigned short* dst = WPK + (size_t)bx*4096;
  #pragma unroll
  for(int t=0;t<16;t++){
    int d = tid*16+t;
    int frag=d>>9, lane=(d>>3)&63, j=d&7;
    int mt=frag>>1, kh=frag&1, m_=lane&15, g=lane>>4;
    dst[d] = f2bu(src[(size_t)(16*mt+m_)*64 + 32*kh + 8*g + j]);
  }
}

// Transpose spectral weights for layer into WT[m][comp][io].
__global__ void __launch_bounds__(256) k_wtrans(const float* __restrict__ w1,
        const float* __restrict__ w2, float* __restrict__ WT){
  __shared__ float tile[64][65];
  int io0 = blockIdx.x*64;
  int c0  = blockIdx.y*64;
  int z   = blockIdx.z;
  const float* src = (z==0)? w1 : w2;
  int tid = threadIdx.x;
  #pragma unroll
  for(int it=0;it<16;it++){
    int e = tid + 256*it;
    int r = e>>6, c = e&63;
    if(c0+c<288) tile[r][c] = src[(size_t)(io0+r)*288 + c0 + c];
  }
  __syncthreads();
  #pragma unroll
  for(int it=0;it<16;it++){
    int e = tid + 256*it;
    int rp = e>>6, cp = e&63;
    int col = c0 + rp;
    if(col<288){
      int ky = col/24, rm = col - ky*24;
      int kx = rm>>1, comp = rm&1;
      int m = z*144 + ky*12 + kx;
      WT[(size_t)m*8192 + comp*4096 + io0 + cp] = tile[cp][rp];
    }
  }
}

// encoder: A[b][p][c] = x*Wp0[c] + Ux[hh][c] + Uy[ww][c]; zeros in pad.
__global__ void k_encoder(const float* __restrict__ x, const float* __restrict__ Wp,
                          const float* __restrict__ Ux, const float* __restrict__ Uy,
                          bf16* __restrict__ A){
  int tid=threadIdx.x;
  int p = blockIdx.x*256+tid;
  if(p>=NPIX) return;
  int b = blockIdx.y;
  uint4* dst = (uint4*)(A + ((size_t)b*NPIX + p)*64);
  int hh=p/NN, ww=p-hh*NN;
  if(hh>=SS || ww>=SS){
    uint4 z = {0,0,0,0};
    #pragma unroll
    for(int i=0;i<8;i++) dst[i]=z;
    return;
  }
  float xv = x[((size_t)b*SS+hh)*SS+ww];
  const float4* ux = (const float4*)(Ux + hh*64);
  const float4* uy = (const float4*)(Uy + ww*64);
  const float4* w0 = (const float4*)Wp;
  #pragma unroll
  for(int i=0;i<8;i++){
    float4 a0 = ux[2*i],   a1 = ux[2*i+1];
    float4 b0 = uy[2*i],   b1 = uy[2*i+1];
    float4 c0 = w0[2*i],   c1 = w0[2*i+1];
    float v0=xv*c0.x+a0.x+b0.x, v1=xv*c0.y+a0.y+b0.y;
    float v2=xv*c0.z+a0.z+b0.z, v3=xv*c0.w+a0.w+b0.w;
    float v4=xv*c1.x+a1.x+b1.x, v5=xv*c1.y+a1.y+b1.y;
    float v6=xv*c1.z+a1.z+b1.z, v7=xv*c1.w+a1.w+b1.w;
    uint4 v;
    v.x = (unsigned)f2bu(v0) | ((unsigned)f2bu(v1)<<16);
    v.y = (unsigned)f2bu(v2) | ((unsigned)f2bu(v3)<<16);
    v.z = (unsigned)f2bu(v4) | ((unsigned)f2bu(v5)<<16);
    v.w = (unsigned)f2bu(v6) | ((unsigned)f2bu(v7)<<16);
    dst[i]=v;
  }
}

// MFMA forward DFT along W. grid 402 x 4 waves; wave = one row R=b*201+h.
__global__ void __launch_bounds__(256) k_dftw(const bf16* __restrict__ A,
        const unsigned short* __restrict__ T2PK, float* __restrict__ XW){
  int tid=threadIdx.x, wid=tid>>6, l=tid&63;
  int m_=l&15, g=l>>4;
  int R = blockIdx.x*4 + wid;
  const bf16* row = A + (size_t)R*NN*64;
  f32x4 acc[2][4];
  #pragma unroll
  for(int mt=0;mt<2;mt++){
    #pragma unroll
    for(int nt=0;nt<4;nt++) acc[mt][nt]=f32x4{0.f,0.f,0.f,0.f};
  }
  for(int chunk=0;chunk<7;chunk++){
    int wbase = chunk*32 + g*8;
    s8v bf[4];
    if(chunk<6){
      #pragma unroll
      for(int nt=0;nt<4;nt++){
        s8v f;
        #pragma unroll
        for(int j=0;j<8;j++){
          unsigned short v;
          bf16 hv = row[(size_t)(wbase+j)*64 + 16*nt + m_];
          __builtin_memcpy(&v,&hv,2);
          f[j]=(short)v;
        }
        bf[nt]=f;
      }
    } else {
      #pragma unroll
      for(int nt=0;nt<4;nt++){
        s8v f;
        #pragma unroll
        for(int j=0;j<8;j++){
          unsigned short v=0;
          if(wbase+j<NN){
            bf16 hv = row[(size_t)(wbase+j)*64 + 16*nt + m_];
            __builtin_memcpy(&v,&hv,2);
          }
          f[j]=(short)v;
        }
        bf[nt]=f;
      }
    }
    #pragma unroll
    for(int mt=0;mt<2;mt++){
      s8v af = *(const s8v*)(T2PK + (size_t)(mt*7+chunk)*512 + l*8);
      #pragma unroll
      for(int nt=0;nt<4;nt++)
        acc[mt][nt]=__builtin_amdgcn_mfma_f32_16x16x32_bf16(af,bf[nt],acc[mt][nt],0,0,0);
    }
  }
  #pragma unroll
  for(int mt=0;mt<2;mt++){
    #pragma unroll
    for(int nt=0;nt<4;nt++){
      #pragma unroll
      for(int e=0;e<4;e++){
        int kx24 = mt*16 + 4*g + e;
        if(kx24<24){
          int plane = kx24&1, kx = kx24>>1;
          XW[(size_t)plane*XWPL + ((size_t)R*12+kx)*64 + 16*nt + m_] = acc[mt][nt][e];
        }
      }
    }
  }
}

// DFT along H, LDS-staged: grid (12, 8, 4); z = (jhalf<<1)|chalf. ILP x2.
__global__ void __launch_bounds__(256) k_dfth(const float* __restrict__ XW,
        const float* __restrict__ tab, float* __restrict__ XF){
  __shared__ float sre[201*32];
  __shared__ float sim[201*32];
  __shared__ float2 tw[13*NN];
  int kx=blockIdx.x, b=blockIdx.y;
  int z=blockIdx.z; int jh=z>>1, ch=z&1;
  int tid=threadIdx.x;
  for(int i=tid;i<13*NN;i+=256) tw[i]=((const float2*)tab)[i];
  for(int i=tid;i<201*32;i+=256){
    int h=i>>5, c=ch*32+(i&31);
    size_t idx=(((size_t)b*NN+h)*12+kx)*64+c;
    sre[i]=XW[idx];
    sim[i]=XW[idx+XWPL];
  }
  __syncthreads();
  for(int o=tid;o<384;o+=256){
    int jj=o>>5, cl=o&31;
    int j=jh*12+jj;
    int k2=(j<12)?j:24-j;
    float sgn=(j<12)?-1.f:1.f;
    float re0=0.f,im0=0.f,re1=0.f,im1=0.f;
    const float* pr=sre+cl;
    const float* pi=sim+cl;
    const float2* tk=tw+k2*NN;
    int h=0;
    for(;h+1<NN;h+=2){
      float a0=pr[h*32], b0=pi[h*32];
      float2 cs0=tk[h];
      float c0=cs0.x, s0=sgn*cs0.y;
      re0 = fmaf(a0,c0, fmaf(-b0,s0, re0));
      im0 = fmaf(a0,s0, fmaf( b0,c0, im0));
      float a1=pr[(h+1)*32], b1=pi[(h+1)*32];
      float2 cs1=tk[h+1];
      float c1=cs1.x, s1=sgn*cs1.y;
      re1 = fmaf(a1,c1, fmaf(-b1,s1, re1));
      im1 = fmaf(a1,s1, fmaf( b1,c1, im1));
    }
    {
      float a0=pr[h*32], b0=pi[h*32];
      float2 cs0=tk[h];
      float c0=cs0.x, s0=sgn*cs0.y;
      re0 = fmaf(a0,c0, fmaf(-b0,s0, re0));
      im0 = fmaf(a0,s0, fmaf( b0,c0, im0));
    }
    int m=j*12+kx;
    int c=ch*32+cl;
    XF[(size_t)m*1024+(b*64+c)*2]  =re0+re1;
    XF[(size_t)m*1024+(b*64+c)*2+1]=im0+im1;
  }
}

// per-mode 64x64 complex mix; ILP split accumulators.
__global__ void __launch_bounds__(512) k_modemix(const float* __restrict__ XF,
     const float* __restrict__ WT, float* __restrict__ XO){
  __shared__ float sx[1024];
  __shared__ float swr[4096], swi[4096];
  int m=blockIdx.x;
  int tid=threadIdx.x;
  sx[tid]     = XF[(size_t)m*1024+tid];
  sx[tid+512] = XF[(size_t)m*1024+tid+512];
  const float* wr = WT + (size_t)m*8192;
  const float* wi = wr + 4096;
  for(int io=tid;io<4096;io+=512){
    swr[io]=wr[io];
    swi[io]=wi[io];
  }
  __syncthreads();
  int b=tid>>6, o=tid&63;
  const float* xb = sx + b*128;
  float re0=0.f,re1=0.f,im0=0.f,im1=0.f;
  #pragma unroll 8
  for(int i=0;i<64;i+=2){
    float a=xb[2*i], b2=xb[2*i+1];
    float c=swr[i*64+o], d=swi[i*64+o];
    re0 = fmaf(a,c, fmaf(-b2,d, re0));
    im0 = fmaf(a,d, fmaf( b2,c, im0));
    float a1=xb[2*i+2], b3=xb[2*i+3];
    float c1=swr[(i+1)*64+o], d1=swi[(i+1)*64+o];
    re1 = fmaf(a1,c1, fmaf(-b3,d1, re1));
    im1 = fmaf(a1,d1, fmaf( b3,c1, im1));
  }
  XO[2*((size_t)m*512+tid)]  =re0+re1;
  XO[2*((size_t)m*512+tid)+1]=im0+im1;
}

// Merged inverse: per row R, idfth into LDS (factors folded), then the C2R
// along W as MFMA: C[w][o] = sum_k24 T[w][k24]*Y24[k24][o], T prepacked (TPK).
__global__ void __launch_bounds__(256) k_ispec(const float* __restrict__ XO,
        const float* __restrict__ tab, const unsigned short* __restrict__ TPK,
        bf16* __restrict__ C){
  __shared__ float2 yl[12][64];
  __shared__ float2 cs13[13];
  int R=blockIdx.x;
  int b=R/NN, h=R-b*NN;
  int tid=threadIdx.x;
  if(tid<13) cs13[tid]=((const float2*)tab)[tid*NN+h];
  __syncthreads();
  const float sc = 1.0f/40401.0f;
  #pragma unroll
  for(int it=0;it<3;it++){
    int item = tid + 256*it;
    int kx = item>>6, o = item&63;
    float re0=0.f,im0=0.f,re1=0.f,im1=0.f;
    #pragma unroll
    for(int j=0;j<24;j+=2){
      {
        int k2=(j<12)?j:24-j;
        float sgn=(j<12)?1.0f:-1.0f;
        float2 xo = *(const float2*)(XO + 2*(((size_t)(j*12+kx)*512) + b*64 + o));
        float2 cs = cs13[k2];
        float cc=cs.x, s2=sgn*cs.y;
        re0 = fmaf(xo.x,cc, fmaf(-xo.y,s2, re0));
        im0 = fmaf(xo.x,s2, fmaf( xo.y,cc, im0));
      }
      {
        int j1=j+1;
        int k2=(j1<12)?j1:24-j1;
        float sgn=(j1<12)?1.0f:-1.0f;
        float2 xo = *(const float2*)(XO + 2*(((size_t)(j1*12+kx)*512) + b*64 + o));
        float2 cs = cs13[k2];
        float cc=cs.x, s2=sgn*cs.y;
        re1 = fmaf(xo.x,cc, fmaf(-xo.y,s2, re1));
        im1 = fmaf(xo.x,s2, fmaf( xo.y,cc, im1));
      }
    }
    float fr = (kx==0)? sc : 2.0f*sc;
    float fi = (kx==0)? sc : -2.0f*sc;
    yl[kx][o] = float2{ (re0+re1)*fr, (im0+im1)*fi };
  }
  __syncthreads();
  int wid=tid>>6, l=tid&63, m_=l&15, g=l>>4;
  int o = wid*16 + m_;
  s8v bfr;
  #pragma unroll
  for(int j=0;j<4;j++){
    float2 v = yl[4*g+j][o];
    bfr[2*j]   = (short)f2bu(v.x);
    bfr[2*j+1] = (short)f2bu(v.y);
  }
  bf16* cp = C + (size_t)R*NN*64;
  #pragma unroll
  for(int wt=0; wt<13; wt++){
    s8v af = *(const s8v*)(TPK + (size_t)wt*512 + l*8);
    f32x4 acc = f32x4{0.f,0.f,0.f,0.f};
    acc = __builtin_amdgcn_mfma_f32_16x16x32_bf16(af, bfr, acc, 0,0,0);
    #pragma unroll
    for(int e=0;e<4;e++){
      int w = wt*16 + 4*g + e;
      if(w<NN) cp[(size_t)w*64 + o] = f2b(acc[e]);
    }
  }
}

// Chunked Parseval Gram from XO: grid (9, BB). Block = 64-feature chunk.
__global__ void __launch_bounds__(256) k_gramC(const float* __restrict__ XO,
        float* __restrict__ GCp, float* __restrict__ SC){
  __shared__ unsigned short V[64][72];
  int chunk=blockIdx.x, b=blockIdx.y, tid=threadIdx.x;
  const float s1=1.0f/201.0f;
  const float r2=0.70710678118f;
  const float q2=1.41421356237f;
  #pragma unroll
  for(int it=0;it<16;it++){
    int e = tid + it*256;
    int fl=e>>6, ch=e&63;
    int f = chunk*64 + fl;
    int base = b*64+ch;
    float v=0.f;
    if(f<528){
      int comp=f&1, kxm=f>>1;
      int kx0=kxm/24;
      int kx=1+kx0, m=kxm-kx0*24;
      v = q2*XO[2*((size_t)(m*12+kx)*512 + base)+comp];
    } else if(f==528){
      v = XO[2*(size_t)base];
    } else if(f<551){
      int q=f-529; int mm=1+(q>>1);
      const float* p1 = XO + 2*((size_t)(mm*12)*512 + base);
      const float* p2 = XO + 2*((size_t)((24-mm)*12)*512 + base);
      v = ((q&1)==0)? r2*(p1[0]+p2[0]) : r2*(p1[1]-p2[1]);
    } else if(f==551){
      v = r2*XO[2*((size_t)(144)*512 + base)];
    } else if(f==552){
      v = r2*XO[2*((size_t)(144)*512 + base)+1];
    }
    V[ch][fl]=f2bu(v*s1);
  }
  __syncthreads();
  int wid=tid>>6, l=tid&63, m_=l&15, g=l>>4;
  f32x4 acc[4];
  #pragma unroll
  for(int mt=0;mt<4;mt++) acc[mt]=f32x4{0.f,0.f,0.f,0.f};
  #pragma unroll
  for(int kc=0;kc<2;kc++){
    s8v bfr = *(const s8v*)&V[16*wid+m_][kc*32+8*g];
    #pragma unroll
    for(int mt=0;mt<4;mt++){
      s8v afr = *(const s8v*)&V[16*mt+m_][kc*32+8*g];
      acc[mt]=__builtin_amdgcn_mfma_f32_16x16x32_bf16(afr,bfr,acc[mt],0,0,0);
    }
  }
  float* gb = GCp + ((size_t)(b*9+chunk))*4096;
  #pragma unroll
  for(int mt=0;mt<4;mt++){
    #pragma unroll
    for(int e=0;e<4;e++)
      gb[(size_t)(16*mt+4*g+e)*64 + 16*wid + m_] = acc[mt][e];
  }
  if(chunk==0 && tid<64) SC[b*64+tid] = XO[2*(size_t)(b*64+tid)];
}

// Reduce GCp chunks -> GC. grid (16, BB).
__global__ void k_gcred(const float* __restrict__ GCp, float* __restrict__ GC){
  int b=blockIdx.y;
  int idx=blockIdx.x*256+threadIdx.x;
  float s=0.f;
  #pragma unroll
  for(int k=0;k<9;k++) s += GCp[((size_t)(b*9+k))*4096 + idx];
  GC[(size_t)b*4096 + idx]=s;
}

// MFMA Gram v2: fragments loaded directly from global. grid (nblkx, BB) x 4 waves.
__global__ void __launch_bounds__(256) k_gramp(const bf16* __restrict__ X,
        float* __restrict__ Gpart, float* __restrict__ Spart, int HR, int WR){
  int b = blockIdx.y, blk = blockIdx.x;
  int npix = HR*WR;
  int tid=threadIdx.x, wid=tid>>6, l=tid&63;
  int m_=l&15, g=l>>4;
  int slab = blk*4 + wid;
  const bf16* xb = X + (size_t)b*NPIX*64;
  f32x4 acc[4][4];
  #pragma unroll
  for(int mt=0;mt<4;mt++){
    #pragma unroll
    for(int nt=0;nt<4;nt++) acc[mt][nt]=f32x4{0.f,0.f,0.f,0.f};
  }
  float cs[4]={0.f,0.f,0.f,0.f};
  for(int kc=0;kc<16;kc++){
    int pbase = slab*512 + kc*32 + g*8;
    int hh0=0, ww0=0;
    if(WR!=NN){ hh0 = pbase/WR; ww0 = pbase - hh0*WR; }
    const bf16* ptr[8];
    #pragma unroll
    for(int jj=0;jj<8;jj++){
      int p = pbase + jj;
      int gp;
      if(WR==NN) gp = p;
      else {
        int ww2 = ww0 + jj;
        int hh  = hh0;
        if(ww2>=WR){ ww2-=WR; hh++; }
        gp = hh*NN + ww2;
      }
      ptr[jj] = (p<npix) ? (xb + (size_t)gp*64) : (const bf16*)0;
    }
    s8v fr[4];
    #pragma unroll
    for(int t=0;t<4;t++){
      s8v f;
      float s=0.f;
      #pragma unroll
      for(int jj=0;jj<8;jj++){
        unsigned short v=0;
        if(ptr[jj]){ bf16 hv = ptr[jj][16*t+m_]; __builtin_memcpy(&v,&hv,2); }
        f[jj]=(short)v;
        s += bu2f(v);
      }
      fr[t]=f;
      cs[t]+=s;
    }
    #pragma unroll
    for(int nt=0;nt<4;nt++){
      #pragma unroll
      for(int mt=0;mt<4;mt++)
        acc[mt][nt]=__builtin_amdgcn_mfma_f32_16x16x32_bf16(fr[mt],fr[nt],acc[mt][nt],0,0,0);
    }
  }
  float* gp_ = Gpart + ((size_t)(b*GNB + slab))*4096;
  #pragma unroll
  for(int mt=0;mt<4;mt++){
    #pragma unroll
    for(int nt=0;nt<4;nt++){
      #pragma unroll
      for(int e=0;e<4;e++)
        gp_[(size_t)(16*mt + 4*g + e)*64 + 16*nt + m_] = acc[mt][nt][e];
    }
  }
  #pragma unroll
  for(int t=0;t<4;t++){
    float s=cs[t];
    s += __shfl_xor(s,16,64);
    s += __shfl_xor(s,32,64);
    if(g==0) Spart[((size_t)(b*GNB+slab))*64 + 16*t + m_] = s;
  }
}

// Parallel slab reduce: grid (16, BB). Gfin[b][4096], Sfin[b][64].
__global__ void __launch_bounds__(256) k_gramr(const float* __restrict__ Gpart,
        const float* __restrict__ Spart, float* __restrict__ Gfin,
        float* __restrict__ Sfin, int nblk){
  int b = blockIdx.y;
  int idx = blockIdx.x*256 + threadIdx.x;
  float s0=0.f,s1=0.f,s2=0.f,s3=0.f;
  int k=0;
  for(;k+3<nblk;k+=4){
    s0 += Gpart[((size_t)b*GNB + k  )*4096 + idx];
    s1 += Gpart[((size_t)b*GNB + k+1)*4096 + idx];
    s2 += Gpart[((size_t)b*GNB + k+2)*4096 + idx];
    s3 += Gpart[((size_t)b*GNB + k+3)*4096 + idx];
  }
  for(;k<nblk;k++) s0 += Gpart[((size_t)b*GNB + k)*4096 + idx];
  Gfin[(size_t)b*4096 + idx] = (s0+s1)+(s2+s3);
  if(blockIdx.x==0 && threadIdx.x<64){
    float ss=0.f;
    for(int j=0;j<nblk;j++) ss += Spart[((size_t)b*GNB + j)*64 + threadIdx.x];
    Sfin[b*64 + threadIdx.x]=ss;
  }
}

// Stats for layer (grid 32): zb2 = zb*2+grp. zb<8 -> Cb (Parseval GC/SC);
// zb>=8 -> A (Gfin/Sfin). Block = one GN group of 32 rows; i split 8-ways.
__global__ void __launch_bounds__(256) k_statsA(
        const float* __restrict__ GC, const float* __restrict__ SC,
        const float* __restrict__ Gfin, const float* __restrict__ Sfin,
        const float* __restrict__ m1wl, const float* __restrict__ m1bl,
        const float* __restrict__ wwl,  const float* __restrict__ wbl,
        float* __restrict__ TSTAT, float* __restrict__ USTAT){
  __shared__ float Gs[4096];
  __shared__ float Ss[64];
  __shared__ float rs[256], rq[256];
  int zb2=blockIdx.x;
  int zb=zb2>>1, grp=zb2&1;
  int t=threadIdx.x;
  const float* GS  = (zb<8)? (GC + (size_t)zb*4096) : (Gfin + (size_t)(zb-8)*4096);
  const float* SS_ = (zb<8)? (SC + (size_t)zb*64)   : (Sfin + (size_t)(zb-8)*64);
  #pragma unroll
  for(int e=0;e<16;e++) Gs[t*16+e]=GS[t*16+e];
  if(t<64) Ss[t]=SS_[t];
  __syncthreads();
  const float* W    = (zb<8)? m1wl : wwl;
  const float* bias = (zb<8)? m1bl : wbl;
  float* stat       = (zb<8)? TSTAT : USTAT;
  int b = (zb<8)? zb : zb-8;
  int o = grp*32 + (t&31);
  int sl = t>>5;                 // 8 segments of 8 i-rows
  float w[64];
  #pragma unroll
  for(int j2=0;j2<64;j2++) w[j2]=bu2f(f2bu(W[(size_t)o*64+j2]));
  const float* Gr = Gs + (size_t)(sl*8)*64;
  float quad=0.f;
  #pragma unroll
  for(int r=0;r<8;r++){
    const float* gr = Gr + r*64;
    float tt=0.f;
    #pragma unroll
    for(int j2=0;j2<64;j2++) tt += gr[j2]*w[j2];
    quad += w[sl*8+r]*tt;
  }
  float sm=0.f, sq=quad;
  if(sl==0){
    float dot=0.f;
    #pragma unroll
    for(int j2=0;j2<64;j2++) dot += w[j2]*Ss[j2];
    float bo = bias[o];
    float Nf = (float)NPIX;
    sm = dot + Nf*bo;
    sq += 2.f*bo*dot + Nf*bo*bo;
  }
  rs[t]=sm; rq[t]=sq;
  __syncthreads();
  if(t<32){
    float s2=0.f,q2=0.f;
    #pragma unroll
    for(int k=0;k<8;k++){ s2+=rs[t+32*k]; q2+=rq[t+32*k]; }
    for(int off=16;off>0;off>>=1){
      s2 += __shfl_down(s2,off,32);
      q2 += __shfl_down(q2,off,32);
    }
    if(t==0){
      float invN = 1.f/((float)NPIX*32.f);
      float mean = s2*invN;
      float var = q2*invN - mean*mean;
      stat[b*4+grp*2]   = mean;
      stat[b*4+grp*2+1] = rsqrtf(fmaxf(var,0.f)+1e-5f);
    }
  }
}

// Head stats partials: grid (BB, 4). Block = 64 rows; i split 4-ways.
// atomicAdd partial (sum,sumsq) into QP[b][group] (2 blocks/group; commutative).
__global__ void __launch_bounds__(256) k_statsQ(const float* __restrict__ Gfin,
        const float* __restrict__ Sfin,
        const float* __restrict__ W, const float* __restrict__ bias,
        float* __restrict__ QP){
  __shared__ float Gs[4096];
  __shared__ float Ss[64];
  __shared__ float rs[256], rq[256];
  int b=blockIdx.x, z=blockIdx.y, t=threadIdx.x;
  #pragma unroll
  for(int e=0;e<16;e++) Gs[t*16+e]=Gfin[(size_t)b*4096 + t*16+e];
  if(t<64) Ss[t]=Sfin[b*64+t];
  __syncthreads();
  int o = z*64 + (t&63);
  int sl = t>>6;                // 4 segments of 16 i-rows
  float w[64];
  #pragma unroll
  for(int j2=0;j2<64;j2++) w[j2]=bu2f(f2bu(W[(size_t)o*64+j2]));
  const float* Gr = Gs + (size_t)(sl*16)*64;
  float quad=0.f;
  #pragma unroll
  for(int r=0;r<16;r++){
    const float* gr = Gr + r*64;
    float tt=0.f;
    #pragma unroll
    for(int j2=0;j2<64;j2++) tt += gr[j2]*w[j2];
    quad += w[sl*16+r]*tt;
  }
  float sm=0.f, sq=quad;
  if(sl==0){
    float dot=0.f;
    #pragma unroll
    for(int j2=0;j2<64;j2++) dot += w[j2]*Ss[j2];
    float bo=bias[o];
    float Nf=(float)QPIX;
    sm = dot + Nf*bo;
    sq += 2.f*bo*dot + Nf*bo*bo;
  }
  rs[t]=sm; rq[t]=sq;
  __syncthreads();
  if(t<64){
    float s2 = rs[t]+rs[t+64]+rs[t+128]+rs[t+192];
    float q2 = rq[t]+rq[t+64]+rq[t+128]+rq[t+192];
    for(int off=32;off>0;off>>=1){
      s2 += __shfl_down(s2,off,64);
      q2 += __shfl_down(q2,off,64);
    }
    if(t==0){
      int g = z>>1;
      atomicAdd(&QP[b*4+g*2],   s2);
      atomicAdd(&QP[b*4+g*2+1], q2);
    }
  }
}

// Finalize head stats. grid 1, 16 threads.
__global__ void k_qfin(const float* __restrict__ QP, float* __restrict__ QSTAT){
  int t=threadIdx.x;
  if(t>=16) return;
  int b=t>>1, g=t&1;
  float s=QP[b*4+g*2], ss=QP[b*4+g*2+1];
  float invN=1.f/((float)QPIX*128.f);
  float mean=s*invN, var=ss*invN-mean*mean;
  QSTAT[b*4+g*2]   = mean;
  QSTAT[b*4+g*2+1] = rsqrtf(fmaxf(var,0.f)+1e-5f);
}

// MFMA fused layer with packed weights; GN affine folded to single fma.
__global__ void __launch_bounds__(256) k_fuse(const bf16* __restrict__ Cb,
    bf16* __restrict__ A,
    const unsigned short* __restrict__ wp1, const float* __restrict__ m1b,
    const float* __restrict__ mg,  const float* __restrict__ mbt,
    const unsigned short* __restrict__ wp2, const float* __restrict__ m2b,
    const unsigned short* __restrict__ wpw, const float* __restrict__ wbk,
    const float* __restrict__ ng,  const float* __restrict__ nb,
    const float* __restrict__ tstat, const float* __restrict__ ustat, int last){
  __shared__ unsigned short vlds[4][64][72];
  int tid=threadIdx.x;
  int wid=tid>>6, l=tid&63;
  int m_=l&15, g=l>>4;
  int b=blockIdx.y;
  int p0=blockIdx.x*256 + wid*64;
  const bf16* cbb = Cb + (size_t)b*NPIX*64;
  const bf16* ab  = A  + (size_t)b*NPIX*64;

  s8v af[4][2];
  f32x4 acc[4][4];

  #pragma unroll
  for(int mt=0;mt<4;mt++){
    #pragma unroll
    for(int kh=0;kh<2;kh++)
      af[mt][kh]=*(const s8v*)(wp1 + (mt*2+kh)*512 + l*8);
    float4 b4 = *(const float4*)(m1b + 16*mt + 4*g);
    #pragma unroll
    for(int nt=0;nt<4;nt++) acc[mt][nt]=f32x4{b4.x,b4.y,b4.z,b4.w};
  }
  #pragma unroll
  for(int nt=0;nt<4;nt++){
    int p = p0 + 16*nt + m_;
    int pc = p<NPIX? p : NPIX-1;
    const s8v* xb = (const s8v*)(cbb + (size_t)pc*64);
    s8v b0 = xb[g], b1 = xb[4+g];
    #pragma unroll
    for(int mt=0;mt<4;mt++){
      acc[mt][nt]=__builtin_amdgcn_mfma_f32_16x16x32_bf16(af[mt][0],b0,acc[mt][nt],0,0,0);
      acc[mt][nt]=__builtin_amdgcn_mfma_f32_16x16x32_bf16(af[mt][1],b1,acc[mt][nt],0,0,0);
    }
  }
  {
    float tm0=tstat[b*4],tr0=tstat[b*4+1],tm1=tstat[b*4+2],tr1=tstat[b*4+3];
    #pragma unroll
    for(int mt=0;mt<4;mt++){
      float4 g4 = *(const float4*)(mg  + 16*mt + 4*g);
      float4 t4 = *(const float4*)(mbt + 16*mt + 4*g);
      float mn = (mt<2)? tm0 : tm1;
      float rs = (mt<2)? tr0 : tr1;
      float ax=rs*g4.x, ay=rs*g4.y, az=rs*g4.z, aw=rs*g4.w;
      float cx=t4.x-mn*ax, cy=t4.y-mn*ay, cz=t4.z-mn*az, cw=t4.w-mn*aw;
      #pragma unroll
      for(int nt=0;nt<4;nt++){
        int pl = 16*nt + m_;
        f32x4 t = acc[mt][nt];
        float v0 = gelu_f(fmaf(t[0],ax,cx));
        float v1 = gelu_f(fmaf(t[1],ay,cy));
        float v2 = gelu_f(fmaf(t[2],az,cz));
        float v3 = gelu_f(fmaf(t[3],aw,cw));
        uint2 pk;
        pk.x = (unsigned)f2bu(v0) | ((unsigned)f2bu(v1)<<16);
        pk.y = (unsigned)f2bu(v2) | ((unsigned)f2bu(v3)<<16);
        *(uint2*)&vlds[wid][pl][16*mt+4*g] = pk;
      }
    }
  }
  __syncthreads();
  #pragma unroll
  for(int mt=0;mt<4;mt++){
    #pragma unroll
    for(int kh=0;kh<2;kh++)
      af[mt][kh]=*(const s8v*)(wpw + (mt*2+kh)*512 + l*8);
    float4 b4 = *(const float4*)(wbk + 16*mt + 4*g);
    #pragma unroll
    for(int nt=0;nt<4;nt++) acc[mt][nt]=f32x4{b4.x,b4.y,b4.z,b4.w};
  }
  #pragma unroll
  for(int nt=0;nt<4;nt++){
    int p = p0 + 16*nt + m_;
    int pc = p<NPIX? p : NPIX-1;
    const s8v* xb = (const s8v*)(ab + (size_t)pc*64);
    s8v b0 = xb[g], b1 = xb[4+g];
    #pragma unroll
    for(int mt=0;mt<4;mt++){
      acc[mt][nt]=__builtin_amdgcn_mfma_f32_16x16x32_bf16(af[mt][0],b0,acc[mt][nt],0,0,0);
      acc[mt][nt]=__builtin_amdgcn_mfma_f32_16x16x32_bf16(af[mt][1],b1,acc[mt][nt],0,0,0);
    }
  }
  {
    float um0=ustat[b*4],ur0=ustat[b*4+1],um1=ustat[b*4+2],ur1=ustat[b*4+3];
    #pragma unroll
    for(int mt=0;mt<4;mt++){
      float4 n4 = *(const float4*)(ng  + 16*mt + 4*g);
      float4 nb4= *(const float4*)(nb  + 16*mt + 4*g);
      float4 m24= *(const float4*)(m2b + 16*mt + 4*g);
      float mn = (mt<2)? um0 : um1;
      float rs = (mt<2)? ur0 : ur1;
      float ax=rs*n4.x, ay=rs*n4.y, az=rs*n4.z, aw=rs*n4.w;
      float cx=m24.x+nb4.x-mn*ax, cy=m24.y+nb4.y-mn*ay;
      float cz=m24.z+nb4.z-mn*az, cw=m24.w+nb4.w-mn*aw;
      #pragma unroll
      for(int nt=0;nt<4;nt++){
        f32x4 u = acc[mt][nt];
        u[0] = fmaf(u[0],ax,cx);
        u[1] = fmaf(u[1],ay,cy);
        u[2] = fmaf(u[2],az,cz);
        u[3] = fmaf(u[3],aw,cw);
        acc[mt][nt]=u;
      }
    }
  }
  #pragma unroll
  for(int mt=0;mt<4;mt++){
    #pragma unroll
    for(int kh=0;kh<2;kh++)
      af[mt][kh]=*(const s8v*)(wp2 + (mt*2+kh)*512 + l*8);
  }
  #pragma unroll
  for(int nt=0;nt<4;nt++){
    int pl = 16*nt + m_;
    const s8v* vp = (const s8v*)&vlds[wid][pl][0];
    s8v b0 = vp[g], b1 = vp[4+g];
    #pragma unroll
    for(int mt=0;mt<4;mt++){
      acc[mt][nt]=__builtin_amdgcn_mfma_f32_16x16x32_bf16(af[mt][0],b0,acc[mt][nt],0,0,0);
      acc[mt][nt]=__builtin_amdgcn_mfma_f32_16x16x32_bf16(af[mt][1],b1,acc[mt][nt],0,0,0);
    }
  }
  #pragma unroll
  for(int nt=0;nt<4;nt++){
    int p = p0 + 16*nt + m_;
    if(p>=NPIX) continue;
    bf16* dp = A + ((size_t)b*NPIX + p)*64;
    #pragma unroll
    for(int mt=0;mt<4;mt++){
      f32x4 h = acc[mt][nt];
      float h0=h[0],h1=h[1],h2=h[2],h3=h[3];
      if(!last){ h0=gelu_f(h0); h1=gelu_f(h1); h2=gelu_f(h2); h3=gelu_f(h3); }
      uint2 pk;
      pk.x = (unsigned)f2bu(h0) | ((unsigned)f2bu(h1)<<16);
      pk.y = (unsigned)f2bu(h2) | ((unsigned)f2bu(h3)<<16);
      *(uint2*)(dp + 16*mt + 4*g) = pk;
    }
  }
}

// Head: 128px/block (grid 288,BB); wave = one oc chunk over 8 nt; folded GN coeffs.
__global__ void __launch_bounds__(256) k_qout(const bf16* __restrict__ A,
    const unsigned short* __restrict__ qpack, const float* __restrict__ q1b,
    const float* __restrict__ qg, const float* __restrict__ qbt,
    const float* __restrict__ q2w, const float* __restrict__ q2b,
    const float* __restrict__ qstat, float* __restrict__ out){
  __shared__ unsigned short xq[128][72];
  __shared__ float part[4][128];
  int tid=threadIdx.x;
  int wid=tid>>6, l=tid&63;
  int m_=l&15, g=l>>4;
  int b=blockIdx.y;
  int px0=blockIdx.x*128;
  {
    int p = px0 + (tid>>1);
    int half = tid&1;
    int hh=p/SS, ww2=p-hh*SS;
    const uint4* src=(const uint4*)(A + (((size_t)b*NPIX) + (size_t)hh*NN + ww2)*64 + half*32);
    uint4* drow=(uint4*)&xq[tid>>1][half*32];
    #pragma unroll
    for(int i=0;i<4;i++) drow[i]=src[i];
  }
  __syncthreads();
  int oc=wid;
  const unsigned short* wp = qpack + (size_t)oc*4096;
  s8v af[4][2];
  f32x4 bi4[4];
  float4 a4[4], c4[4], w4[4];
  float m0=qstat[b*4],r0=qstat[b*4+1],m1=qstat[b*4+2],r1=qstat[b*4+3];
  float mn=(oc<2)?m0:m1, rs=(oc<2)?r0:r1;
  #pragma unroll
  for(int mt=0;mt<4;mt++){
    #pragma unroll
    for(int kh=0;kh<2;kh++)
      af[mt][kh]=*(const s8v*)(wp + (mt*2+kh)*512 + l*8);
    float4 b4=*(const float4*)(q1b + 64*oc + 16*mt + 4*g);
    bi4[mt]=f32x4{b4.x,b4.y,b4.z,b4.w};
    float4 g4=*(const float4*)(qg  + 64*oc + 16*mt + 4*g);
    float4 t4=*(const float4*)(qbt + 64*oc + 16*mt + 4*g);
    w4[mt]=*(const float4*)(q2w + 64*oc + 16*mt + 4*g);
    a4[mt]=float4{rs*g4.x, rs*g4.y, rs*g4.z, rs*g4.w};
    c4[mt]=float4{t4.x-mn*a4[mt].x, t4.y-mn*a4[mt].y, t4.z-mn*a4[mt].z, t4.w-mn*a4[mt].w};
  }
  #pragma unroll
  for(int nt=0;nt<8;nt++){
    const s8v* vp = (const s8v*)&xq[16*nt+m_][0];
    s8v b0=vp[g], b1=vp[4+g];
    f32x4 acc[4];
    #pragma unroll
    for(int mt=0;mt<4;mt++) acc[mt]=bi4[mt];
    #pragma unroll
    for(int mt=0;mt<4;mt++){
      acc[mt]=__builtin_amdgcn_mfma_f32_16x16x32_bf16(af[mt][0],b0,acc[mt],0,0,0);
      acc[mt]=__builtin_amdgcn_mfma_f32_16x16x32_bf16(af[mt][1],b1,acc[mt],0,0,0);
    }
    float pp=0.f;
    #pragma unroll
    for(int mt=0;mt<4;mt++){
      f32x4 t=acc[mt];
      pp += gelu_f(fmaf(t[0],a4[mt].x,c4[mt].x))*w4[mt].x;
      pp += gelu_f(fmaf(t[1],a4[mt].y,c4[mt].y))*w4[mt].y;
      pp += gelu_f(fmaf(t[2],a4[mt].z,c4[mt].z))*w4[mt].z;
      pp += gelu_f(fmaf(t[3],a4[mt].w,c4[mt].w))*w4[mt].w;
    }
    pp += __shfl_xor(pp,16,64);
    pp += __shfl_xor(pp,32,64);
    if(g==0) part[wid][16*nt+m_]=pp;
  }
  __syncthreads();
  if(tid<128)
    out[(size_t)b*QPIX + px0 + tid] =
        q2b[0] + part[0][tid]+part[1][tid]+part[2][tid]+part[3][tid];
}

extern "C" void kernel_launch(void* const* d_in, const int* in_sizes, int n_in,
                              void* d_out, int out_size, void* d_ws, size_t ws_size,
                              hipStream_t stream){
  const float* x   = (const float*)d_in[0];
  const float* Wp  = (const float*)d_in[1];
  const float* bp  = (const float*)d_in[2];
  const float* sw1 = (const float*)d_in[3];
  const float* sw2 = (const float*)d_in[4];
  const float* m1w = (const float*)d_in[5];
  const float* m1b = (const float*)d_in[6];
  const float* mg  = (const float*)d_in[7];
  const float* mbt = (const float*)d_in[8];
  const float* m2w = (const float*)d_in[9];
  const float* m2b = (const float*)d_in[10];
  const float* ww  = (const float*)d_in[11];
  const float* wb  = (const float*)d_in[12];
  const float* ng  = (const float*)d_in[13];
  const float* nb  = (const float*)d_in[14];
  const float* q1w = (const float*)d_in[15];
  const float* q1b = (const float*)d_in[16];
  const float* qg  = (const float*)d_in[17];
  const float* qbt = (const float*)d_in[18];
  const float* q2w = (const float*)d_in[19];
  const float* q2b = (const float*)d_in[20];
  float* out = (float*)d_out;

  char* w8 = (char*)d_ws;
  const size_t ACT_B = (size_t)64*BB*NPIX*sizeof(bf16);   // 41,370,624
  bf16*  A    = (bf16*)(w8);
  bf16*  Cb   = (bf16*)(w8 + ACT_B);
  float* SPEC = (float*)(w8 + 2*ACT_B);                    // XW / WT / GCp / Gpart overlays
  float* XF   = (float*)(w8 + 2*ACT_B + 9879552);
  float* XO   = (float*)(w8 + 2*ACT_B + 9879552 + 1179648);
  float* TB   = (float*)(w8 + 2*ACT_B + 9879552 + 2*1179648);
  char*  g8   = w8 + 2*ACT_B + 9879552 + 2*1179648 + 20992;
  float* TSTAT= (float*)g8;
  float* USTAT= TSTAT + 32;
  float* QSTAT= USTAT + 32;
  float* UxT  = QSTAT + 32;                  // 192*64
  float* UyT  = UxT + 12288;                 // 192*64
  unsigned short* WPK = (unsigned short*)(UyT + 12288);   // 16*4096 bf16
  float* GC   = (float*)(WPK + 16*4096);     // 8*4096 (Parseval gram, reduced)
  float* SC   = GC + 8*4096;                 // 8*64
  float* GFIN = SC + 8*64;                   // 8*4096 (reduced bypass gram)
  float* SFIN = GFIN + 8*4096;               // 8*64
  unsigned short* TPK = (unsigned short*)(SFIN + 8*64);   // 13*512 bf16 inverse twiddles
  unsigned short* T2PK = TPK + 6656;                      // 14*512 bf16 forward twiddles
  float* QP   = (float*)(T2PK + 7168);       // 32 (head stat partials)
  float* GCp  = SPEC;                        // 8*9*4096 fl (dead-SPEC overlay)
  float* Gpart = SPEC;                       // 8*80*4096 fl = 10.49MB <= SPEC+XF
  float* Spart = Gpart + (size_t)8*GNB*4096;
  float* WT = SPEC;                          // 288*8192 floats = 9.44MB
  size_t needed = (size_t)(2*ACT_B) + 9879552 + 2*1179648 + 20992
                + 3*32*4 + 2*12288*4 + 16*4096*2 + 2*(8*4096+8*64)*4
                + 13312 + 14336 + 128;
  if(ws_size < needed) return;

  k_tab<<<11,256,0,stream>>>(TB);
  k_tpack<<<26,256,0,stream>>>(TB, TPK);
  k_tpack2<<<28,256,0,stream>>>(TB, T2PK);
  k_pretab<<<dim3(192,2),64,0,stream>>>(Wp, bp, UxT, UyT);
  k_wpack<<<16,256,0,stream>>>(m1w, m2w, ww, q1w, WPK);
  k_encoder<<<dim3(158,BB),256,0,stream>>>(x, Wp, UxT, UyT, A);

  for(int l=0;l<4;l++){
    const float* sw1l = sw1 + (size_t)l*1179648;
    const float* sw2l = sw2 + (size_t)l*1179648;
    k_dftw<<<402,256,0,stream>>>(A, T2PK, SPEC);
    k_dfth<<<dim3(12,BB,4),256,0,stream>>>(SPEC, TB, XF);
    k_wtrans<<<dim3(64,5,2),256,0,stream>>>(sw1l, sw2l, WT);
    k_modemix<<<288,512,0,stream>>>(XF, WT, XO);
    k_ispec<<<1608,256,0,stream>>>(XO, TB, TPK, Cb);
    k_gramC<<<dim3(9,BB),256,0,stream>>>(XO, GCp, SC);
    k_gcred<<<dim3(16,BB),256,0,stream>>>(GCp, GC);
    k_gramp<<<dim3(20,BB),256,0,stream>>>(A, Gpart, Spart, NN, NN);
    k_gramr<<<dim3(16,BB),256,0,stream>>>(Gpart, Spart, GFIN, SFIN, 80);
    k_statsA<<<32,256,0,stream>>>(GC, SC, GFIN, SFIN,
          m1w + (size_t)l*4096, m1b + l*64, ww + (size_t)l*4096, wb + l*64,
          TSTAT, USTAT);
    k_fuse<<<dim3(158,BB),256,0,stream>>>(Cb, A,
          WPK + (size_t)(l*3+0)*4096, m1b + l*64, mg + l*64, mbt + l*64,
          WPK + (size_t)(l*3+1)*4096, m2b + l*64,
          WPK + (size_t)(l*3+2)*4096, wb  + l*64, ng + l*64, nb + l*64,
          TSTAT, USTAT, (l==3)?1:0);
  }

  k_gramp<<<dim3(18,BB),256,0,stream>>>(A, Gpart, Spart, SS, SS);
  k_gramr<<<dim3(16,BB),256,0,stream>>>(Gpart, Spart, GFIN, SFIN, 72);
  hipMemsetAsync(QP, 0, 32*sizeof(float), stream);
  k_statsQ<<<dim3(BB,4),256,0,stream>>>(GFIN, SFIN, q1w, q1b, QP);
  k_qfin<<<1,16,0,stream>>>(QP, QSTAT);
  k_qout<<<dim3(288,BB),256,0,stream>>>(A, WPK + (size_t)12*4096, q1b,
          qg, qbt, q2w, q2b, QSTAT, out);
}